// Round 5
// baseline (1364.568 us; speedup 1.0000x reference)
//
#include <hip/hip_runtime.h>
#include <hip/hip_bf16.h>
#include <math.h>
#include <stdint.h>

typedef __attribute__((ext_vector_type(8))) short bh8;
typedef __attribute__((ext_vector_type(4))) float f32x4;

#define AS1(p) ((const __attribute__((address_space(1))) void*)(p))
#define AS3(p) ((__attribute__((address_space(3))) void*)(p))

__device__ inline ushort f2b(float f){
  uint u = __builtin_bit_cast(uint, f);
  u += 0x7fff + ((u >> 16) & 1);
  return (ushort)(u >> 16);
}
__device__ inline float b2f(ushort b){ return __builtin_bit_cast(float, (uint)b << 16); }

// ---------------- CSR build ----------------
__global__ void fill_zero_i32(int* __restrict__ p, int n){
  int i = blockIdx.x*blockDim.x + threadIdx.x;
  if(i < n) p[i] = 0;
}

// XCD-partitioned count: blocks with blockIdx%8==r handle dst range r (range
// size 2^rshift). All atomics for a cnt region issue from one XCD (heuristic:
// round-robin block->XCD). Correct regardless of actual mapping.
__global__ __launch_bounds__(256) void count_part_k(const int* __restrict__ dst,
    int E, int* __restrict__ cnt, int rshift){
  const int range = blockIdx.x & 7;
  const int j = blockIdx.x >> 3, J = gridDim.x >> 3;
  const int per = (E + J - 1)/J;
  const int beg = j*per;
  int end = beg + per; if(end > E) end = E;
  for(int i = beg + threadIdx.x; i < end; i += 256){
    int d = dst[i];
    if((d >> rshift) == range) atomicAdd(&cnt[d], 1);
  }
}

__global__ __launch_bounds__(256) void scatter_part_k(const int* __restrict__ src,
    const int* __restrict__ dst, int E, int* __restrict__ cursor,
    int* __restrict__ colv, int rshift){
  const int range = blockIdx.x & 7;
  const int j = blockIdx.x >> 3, J = gridDim.x >> 3;
  const int per = (E + J - 1)/J;
  const int beg = j*per;
  int end = beg + per; if(end > E) end = E;
  for(int i = beg + threadIdx.x; i < end; i += 256){
    int d = dst[i];
    if((d >> rshift) == range){
      int p = atomicAdd(&cursor[d], 1);
      colv[p] = src[i];
    }
  }
}

__global__ __launch_bounds__(1024) void scan_excl_k(const int* __restrict__ cnt,
    int* __restrict__ ofs, int* __restrict__ cursor, int n){
  __shared__ int wsum[16];
  __shared__ int carry_s;
  int tid = threadIdx.x, wid = tid >> 6, lane = tid & 63;
  if(tid == 0) carry_s = 0;
  __syncthreads();
  for(int base = 0; base < n; base += 4096){
    int i0 = base + tid*4;
    int4 v = make_int4(0,0,0,0);
    if(i0 + 3 < n) v = *(const int4*)(cnt + i0);
    else if(i0 < n){
      v.x = cnt[i0];
      if(i0+1 < n) v.y = cnt[i0+1];
      if(i0+2 < n) v.z = cnt[i0+2];
    }
    int s1 = v.x + v.y, s2 = s1 + v.z, tot = s2 + v.w;
    int x = tot;
    #pragma unroll
    for(int off = 1; off < 64; off <<= 1){
      int t = __shfl_up(x, off);
      if(lane >= off) x += t;
    }
    if(lane == 63) wsum[wid] = x;
    __syncthreads();
    if(tid < 16){
      int y = wsum[tid];
      #pragma unroll
      for(int off = 1; off < 16; off <<= 1){
        int t = __shfl_up(y, off);
        if(tid >= off) y += t;
      }
      wsum[tid] = y;
    }
    __syncthreads();
    int pre = (wid ? wsum[wid-1] : 0) + carry_s + (x - tot);
    if(i0 + 3 < n){
      int4 o = make_int4(pre, pre+v.x, pre+s1, pre+s2);
      *(int4*)(ofs + i0) = o;
      *(int4*)(cursor + i0) = o;
    } else if(i0 < n){
      ofs[i0] = pre; cursor[i0] = pre;
      if(i0+1 < n){ ofs[i0+1] = pre+v.x; cursor[i0+1] = pre+v.x; }
      if(i0+2 < n){ ofs[i0+2] = pre+s1; cursor[i0+2] = pre+s1; }
    }
    __syncthreads();
    if(tid == 0) carry_s += wsum[15];
    __syncthreads();
  }
  if(tid == 0) ofs[n] = carry_s;
}

// ---------------- fp32 -> bf16 convert (vectorized x4) ----------------
__global__ void f2b_vec(const float* __restrict__ in, ushort* __restrict__ out, int n4){
  int i = blockIdx.x*blockDim.x + threadIdx.x;
  if(i >= n4) return;
  float4 v = ((const float4*)in)[i];
  ushort4 o; o.x = f2b(v.x); o.y = f2b(v.y); o.z = f2b(v.z); o.w = f2b(v.w);
  ((ushort4*)out)[i] = o;
}

// ---------------- weight transpose + convert: WT[n][k] = bf16(W[k][n]), n padded ----------------
__global__ void wT_k(const float* __restrict__ W, ushort* __restrict__ WT,
    int K, int N, int Npad){
  int idx = blockIdx.x*blockDim.x + threadIdx.x;
  if(idx >= Npad*K) return;
  int n = idx / K, k = idx - n*K;
  WT[idx] = (n < N) ? f2b(W[(size_t)k*N + n]) : (ushort)0;
}

// ---------------- attention-weight fold: Wf[k,h] = sum_d W[k, h*D+d]*a[h,d] ----------------
__global__ void fold_k(const float* __restrict__ W, const float* __restrict__ a,
    float* __restrict__ Wf, int K, int D){
  int i = blockIdx.x*blockDim.x + threadIdx.x;
  if(i >= K*4) return;
  int k = i >> 2, h = i & 3;
  const float* wr = W + (size_t)k*4*D + (size_t)h*D;
  const float* ar = a + (size_t)h*D;
  float s = 0.f;
  for(int d = 0; d < D; d++) s += wr[d]*ar[d];
  Wf[k*4 + h] = s;
}

__device__ inline float ldval(const float* p){ return *p; }
__device__ inline float ldval(const ushort* p){ return b2f(*p); }

// ---------------- out[m,0:4] = A[m,:] @ Wf[:,0:4]  (one wave per row) ----------------
template<typename T>
__global__ __launch_bounds__(256) void gemv4_t(const T* __restrict__ A,
    const float* __restrict__ Wf, float* __restrict__ outv, int M, int K, int lda){
  int wid = (blockIdx.x*blockDim.x + threadIdx.x) >> 6;
  int lane = threadIdx.x & 63;
  if(wid >= M) return;
  const T* arow = A + (size_t)wid*lda;
  float a0=0.f, a1=0.f, a2=0.f, a3=0.f;
  for(int k = lane; k < K; k += 64){
    float av = ldval(arow + k);
    float4 w = *(const float4*)(Wf + k*4);
    a0 += av*w.x; a1 += av*w.y; a2 += av*w.z; a3 += av*w.w;
  }
  #pragma unroll
  for(int off = 32; off; off >>= 1){
    a0 += __shfl_down(a0, off); a1 += __shfl_down(a1, off);
    a2 += __shfl_down(a2, off); a3 += __shfl_down(a3, off);
  }
  if(lane == 0){
    float4 r; r.x=a0; r.y=a1; r.z=a2; r.w=a3;
    *(float4*)(outv + (size_t)wid*4) = r;
  }
}

// ---------------- fused dual gemv: el = A@Wfa, er = A@Wfb ----------------
template<typename T>
__global__ __launch_bounds__(256) void gemv8_t(const T* __restrict__ A,
    const float* __restrict__ Wfa, const float* __restrict__ Wfb,
    float* __restrict__ oa, float* __restrict__ ob, int M, int K, int lda){
  int wid = (blockIdx.x*blockDim.x + threadIdx.x) >> 6;
  int lane = threadIdx.x & 63;
  if(wid >= M) return;
  const T* arow = A + (size_t)wid*lda;
  float a0=0.f,a1=0.f,a2=0.f,a3=0.f,b0=0.f,b1=0.f,b2=0.f,b3=0.f;
  for(int k = lane; k < K; k += 64){
    float av = ldval(arow + k);
    float4 wa = *(const float4*)(Wfa + k*4);
    float4 wb = *(const float4*)(Wfb + k*4);
    a0 += av*wa.x; a1 += av*wa.y; a2 += av*wa.z; a3 += av*wa.w;
    b0 += av*wb.x; b1 += av*wb.y; b2 += av*wb.z; b3 += av*wb.w;
  }
  #pragma unroll
  for(int off = 32; off; off >>= 1){
    a0 += __shfl_down(a0, off); a1 += __shfl_down(a1, off);
    a2 += __shfl_down(a2, off); a3 += __shfl_down(a3, off);
    b0 += __shfl_down(b0, off); b1 += __shfl_down(b1, off);
    b2 += __shfl_down(b2, off); b3 += __shfl_down(b3, off);
  }
  if(lane == 0){
    float4 r; r.x=a0; r.y=a1; r.z=a2; r.w=a3;
    *(float4*)(oa + (size_t)wid*4) = r;
    float4 s; s.x=b0; s.y=b1; s.z=b2; s.w=b3;
    *(float4*)(ob + (size_t)wid*4) = s;
  }
}

// ---------------- bf16 MFMA GEMM: C[M,N] = A[M,K](bf16) @ BT[Npad,K](bf16)^T ----------------
template<int BN, typename OutT, bool BIAS>
__global__ __launch_bounds__(256) void gemm_mfma(
    const ushort* __restrict__ A, const ushort* __restrict__ BT,
    const float* __restrict__ bias, OutT* __restrict__ C,
    int M, int N, int K, int lda, int ldc){
  constexpr int BM = 128, BK = 64;
  constexpr int NI = BN/32;
  constexpr int AIT = BM*BK/(256*8);
  constexpr int BIT = BN*BK/(256*8);
  __shared__ ushort lds[BM*BK + BN*BK];
  ushort* ldsA = lds;
  ushort* ldsB = lds + BM*BK;
  const int tid = threadIdx.x, wid = tid >> 6, lane = tid & 63;
  const int wr = wid >> 1, wc = wid & 1;
  const int rowbase = blockIdx.x*BM, colbase = blockIdx.y*BN;

  f32x4 acc[4][NI];
  #pragma unroll
  for(int mi = 0; mi < 4; mi++)
    #pragma unroll
    for(int ni = 0; ni < NI; ni++) acc[mi][ni] = (f32x4)0.f;

  for(int k0 = 0; k0 < K; k0 += BK){
    #pragma unroll
    for(int it = 0; it < AIT; it++){
      int idx = it*256 + wid*64 + lane;
      int r = idx >> 3, sl = idx & 7;
      int kb = sl ^ (r & 7);
      int grow = rowbase + r; if(grow >= M) grow = M-1;
      const ushort* src = A + (size_t)grow*lda + k0 + kb*8;
      __builtin_amdgcn_global_load_lds(AS1(src), AS3(ldsA + (size_t)(it*256 + wid*64)*8), 16, 0, 0);
    }
    #pragma unroll
    for(int it = 0; it < BIT; it++){
      int idx = it*256 + wid*64 + lane;
      int r = idx >> 3, sl = idx & 7;
      int kb = sl ^ (r & 7);
      const ushort* src = BT + (size_t)(colbase + r)*K + k0 + kb*8;
      __builtin_amdgcn_global_load_lds(AS1(src), AS3(ldsB + (size_t)(it*256 + wid*64)*8), 16, 0, 0);
    }
    __syncthreads();
    #pragma unroll
    for(int kk = 0; kk < 2; kk++){
      bh8 af[4], bf[NI];
      #pragma unroll
      for(int mi = 0; mi < 4; mi++){
        int arow = wr*64 + mi*16 + (lane & 15);
        int kb = kk*4 + (lane >> 4);
        af[mi] = *(const bh8*)(ldsA + arow*BK + ((kb ^ (arow & 7)) << 3));
      }
      #pragma unroll
      for(int ni = 0; ni < NI; ni++){
        int brow = wc*(BN/2) + ni*16 + (lane & 15);
        int kb = kk*4 + (lane >> 4);
        bf[ni] = *(const bh8*)(ldsB + brow*BK + ((kb ^ (brow & 7)) << 3));
      }
      #pragma unroll
      for(int mi = 0; mi < 4; mi++)
        #pragma unroll
        for(int ni = 0; ni < NI; ni++)
          acc[mi][ni] = __builtin_amdgcn_mfma_f32_16x16x32_bf16(af[mi], bf[ni], acc[mi][ni], 0, 0, 0);
    }
    __syncthreads();
  }
  #pragma unroll
  for(int mi = 0; mi < 4; mi++){
    #pragma unroll
    for(int ni = 0; ni < NI; ni++){
      int col = colbase + wc*(BN/2) + ni*16 + (lane & 15);
      if(col >= N) continue;
      float bv = BIAS ? bias[col] : 0.f;
      #pragma unroll
      for(int j = 0; j < 4; j++){
        int row = rowbase + wr*64 + mi*16 + (lane >> 4)*4 + j;
        if(row >= M) continue;
        float v = acc[mi][ni][j] + bv;
        if constexpr (sizeof(OutT) == 4) C[(size_t)row*ldc + col] = v;
        else                             C[(size_t)row*ldc + col] = (OutT)f2b(v);
      }
    }
  }
}

// ---------------- GAT aggregate v2: chunked online-softmax ----------------
template<int D>
__global__ __launch_bounds__(256) void gat_agg2(
    const ushort* __restrict__ hs, const float* __restrict__ el,
    const float* __restrict__ er, const int* __restrict__ ofs,
    const int* __restrict__ colv, const float* __restrict__ bias,
    ushort* __restrict__ outv, int Nd){
  constexpr int R = (D == 128) ? 8 : 2;   // features per lane
  constexpr int U = 8;                    // inner unroll (loads in flight)
  const int wslot = threadIdx.x >> 6;
  const int node = blockIdx.x*4 + wslot;
  const int lane = threadIdx.x & 63;
  __shared__ int   lds_s[4][64];
  __shared__ float lds_w[4][256];
  if(node >= Nd) return;
  const int e0 = ofs[node], e1 = ofs[node+1];
  const int h = lane >> 4;                // owning head of this lane's features
  const float4 erv = *(const float4*)(er + (size_t)node*4);
  float m0=-INFINITY, m1=-INFINITY, m2=-INFINITY, m3=-INFINITY;
  float sw0=0.f, sw1=0.f, sw2=0.f, sw3=0.f;
  float acc[R];
  #pragma unroll
  for(int r = 0; r < R; r++) acc[r] = 0.f;

  for(int base = e0; base < e1; base += 64){
    int nch = e1 - base; if(nch > 64) nch = 64;
    int s_l = colv[base + (lane < nch ? lane : nch-1)];
    float4 ev = *(const float4*)(el + (size_t)s_l*4);
    float x0 = ev.x + erv.x; x0 = x0 > 0.f ? x0 : 0.2f*x0;
    float x1 = ev.y + erv.y; x1 = x1 > 0.f ? x1 : 0.2f*x1;
    float x2 = ev.z + erv.z; x2 = x2 > 0.f ? x2 : 0.2f*x2;
    float x3 = ev.w + erv.w; x3 = x3 > 0.f ? x3 : 0.2f*x3;
    if(lane >= nch){ x0 = x1 = x2 = x3 = -INFINITY; }
    float c0=x0, c1=x1, c2=x2, c3=x3;
    #pragma unroll
    for(int off = 32; off; off >>= 1){
      c0 = fmaxf(c0, __shfl_xor(c0, off));
      c1 = fmaxf(c1, __shfl_xor(c1, off));
      c2 = fmaxf(c2, __shfl_xor(c2, off));
      c3 = fmaxf(c3, __shfl_xor(c3, off));
    }
    float n0 = fmaxf(m0,c0), n1 = fmaxf(m1,c1), n2 = fmaxf(m2,c2), n3 = fmaxf(m3,c3);
    float r0 = __expf(m0-n0), r1 = __expf(m1-n1), r2 = __expf(m2-n2), r3 = __expf(m3-n3);
    float w0 = __expf(x0-n0), w1 = __expf(x1-n1), w2 = __expf(x2-n2), w3 = __expf(x3-n3);
    sw0 = sw0*r0 + w0; sw1 = sw1*r1 + w1; sw2 = sw2*r2 + w2; sw3 = sw3*r3 + w3;
    float rh = h==0 ? r0 : (h==1 ? r1 : (h==2 ? r2 : r3));
    #pragma unroll
    for(int r = 0; r < R; r++) acc[r] *= rh;
    m0=n0; m1=n1; m2=n2; m3=n3;
    lds_s[wslot][lane] = s_l;
    lds_w[wslot][lane*4+0] = w0; lds_w[wslot][lane*4+1] = w1;
    lds_w[wslot][lane*4+2] = w2; lds_w[wslot][lane*4+3] = w3;
    // padded entries (lane>=nch) have w==0 and a valid clamped s -> safe
    int npad = (nch + U-1) & ~(U-1);
    for(int j = 0; j < npad; j += U){
      #pragma unroll
      for(int u = 0; u < U; u++){
        int s = lds_s[wslot][j+u];
        float w = lds_w[wslot][(j+u)*4 + h];
        if constexpr (D == 128){
          bh8 hv = *(const bh8*)(hs + (size_t)s*512 + lane*8);
          #pragma unroll
          for(int r = 0; r < 8; r++) acc[r] += w * b2f((ushort)hv[r]);
        } else {
          uint hv = *(const uint*)(hs + (size_t)s*128 + lane*2);
          acc[0] += w * b2f((ushort)(hv & 0xffffu));
          acc[1] += w * b2f((ushort)(hv >> 16));
        }
      }
    }
  }
  #pragma unroll
  for(int off = 32; off; off >>= 1){
    sw0 += __shfl_xor(sw0, off); sw1 += __shfl_xor(sw1, off);
    sw2 += __shfl_xor(sw2, off); sw3 += __shfl_xor(sw3, off);
  }
  float swh = h==0 ? sw0 : (h==1 ? sw1 : (h==2 ? sw2 : sw3));
  float den = (swh == 0.f) ? 1.f : swh;
  if constexpr (D == 128){
    bh8 ov;
    #pragma unroll
    for(int r = 0; r < 8; r++){
      float v = acc[r]/den + bias[lane*8 + r];
      v = v > 0.f ? v : (__expf(v) - 1.f);
      ov[r] = (short)f2b(v);
    }
    *(bh8*)(outv + (size_t)node*512 + lane*8) = ov;
  } else {
    float v0 = acc[0]/den + bias[lane*2 + 0];
    float v1 = acc[1]/den + bias[lane*2 + 1];
    v0 = v0 > 0.f ? v0 : (__expf(v0) - 1.f);
    v1 = v1 > 0.f ? v1 : (__expf(v1) - 1.f);
    *(uint*)(outv + (size_t)node*128 + lane*2) = (uint)f2b(v0) | ((uint)f2b(v1) << 16);
  }
}

// ---------------- host orchestration ----------------
extern "C" void kernel_launch(void* const* d_in, const int* in_sizes, int n_in,
                              void* d_out, int out_size, void* d_ws, size_t ws_size,
                              hipStream_t stream){
  const float* hp   = (const float*)d_in[0];
  const float* hq   = (const float*)d_in[1];
  const float* hk   = (const float*)d_in[2];
  const float* ha   = (const float*)d_in[3];
  const int* meta_src = (const int*)d_in[4];
  const int* meta_dst = (const int*)d_in[5];
  const int* q_src = (const int*)d_in[6];
  const int* q_dst = (const int*)d_in[7];
  const int* k_src = (const int*)d_in[8];
  const int* k_dst = (const int*)d_in[9];
  const int* a_src = (const int*)d_in[10];
  const int* a_dst = (const int*)d_in[11];
  const float* W0  = (const float*)d_in[12]; const float* al0 = (const float*)d_in[13];
  const float* ar0 = (const float*)d_in[14]; const float* b0  = (const float*)d_in[15];
  const float* W1  = (const float*)d_in[16]; const float* al1 = (const float*)d_in[17];
  const float* ar1 = (const float*)d_in[18]; const float* b1  = (const float*)d_in[19];
  const float* Wq  = (const float*)d_in[20]; const float* alq = (const float*)d_in[21];
  const float* arq = (const float*)d_in[22]; const float* bq  = (const float*)d_in[23];
  const float* Wkw = (const float*)d_in[24]; const float* alkw= (const float*)d_in[25];
  const float* arkw= (const float*)d_in[26]; const float* bkw = (const float*)d_in[27];
  const float* Watt= (const float*)d_in[28]; const float* alatt=(const float*)d_in[29];
  const float* aratt=(const float*)d_in[30]; const float* batt= (const float*)d_in[31];
  const float* Wpnn_a = (const float*)d_in[32];
  const float* Wpn_a  = (const float*)d_in[33];
  const float* Wpnn   = (const float*)d_in[34];
  const float* Wpn    = (const float*)d_in[35];
  const float* Wpred  = (const float*)d_in[36];
  const float* bpred  = (const float*)d_in[37];
  (void)n_in; (void)out_size; (void)ws_size;

  const int IN = 128, ATT = 64;
  const int NP = in_sizes[0]/IN, NQ = in_sizes[1]/ATT, NK = in_sizes[2]/ATT, NA = in_sizes[3]/ATT;
  const int EM = in_sizes[4], EQ = in_sizes[6], EK = in_sizes[8], EA = in_sizes[10];

  int rshift = 0;
  while((8 << rshift) < NP) rshift++;

  // ----- workspace layout -----
  uint8_t* wp = (uint8_t*)d_ws;
  auto alloc = [&](size_t bytes)->uint8_t*{
    uint8_t* p = wp; wp += (bytes + 255) & ~(size_t)255; return p;
  };
  ushort* hcat_b = (ushort*)alloc((size_t)NP*256*2);
  ushort* hbuf_b = (ushort*)alloc((size_t)NP*128*2);
  ushort* hp_b   = (ushort*)alloc((size_t)NP*128*2);
  ushort* hpd_b  = (ushort*)alloc((size_t)NP*64*2);
  int NSmax = NQ > NK ? NQ : NK; if(NA > NSmax) NSmax = NA;
  ushort* proj_b = (ushort*)alloc((size_t)NSmax*64*2);
  ushort* fq_b   = (ushort*)alloc((size_t)NQ*64*2);
  ushort* fk_b   = (ushort*)alloc((size_t)NK*64*2);
  ushort* fa_b   = (ushort*)alloc((size_t)NA*64*2);
  float* el   = (float*)alloc((size_t)NP*4*4);
  float* er   = (float*)alloc((size_t)NP*4*4);
  float* wfa  = (float*)alloc(512*4);
  float* wfb  = (float*)alloc(512*4);
  int* cnt    = (int*)alloc((size_t)(NP+4)*4);
  int* cursor = (int*)alloc((size_t)(NP+4)*4);
  int* ofsm   = (int*)alloc((size_t)(NP+4)*4);
  int* ofsq   = (int*)alloc((size_t)(NP+4)*4);
  int* ofsk   = (int*)alloc((size_t)(NP+4)*4);
  int* ofsa   = (int*)alloc((size_t)(NP+4)*4);
  int* colm   = (int*)alloc((size_t)EM*4);
  int* colq   = (int*)alloc((size_t)EQ*4);
  int* colk   = (int*)alloc((size_t)EK*4);
  int* cola   = (int*)alloc((size_t)EA*4);
  ushort* W0T    = (ushort*)alloc(128*128*2);
  ushort* W1T    = (ushort*)alloc(128*128*2);
  ushort* WqT    = (ushort*)alloc(512*64*2);
  ushort* WkwT   = (ushort*)alloc(512*64*2);
  ushort* WattT  = (ushort*)alloc(512*64*2);
  ushort* WpnT   = (ushort*)alloc((size_t)64*512*2);
  ushort* WpnnT  = (ushort*)alloc(64*128*2);
  ushort* Wpnn_aT= (ushort*)alloc(64*128*2);
  ushort* Wpn_aT = (ushort*)alloc(64*64*2);
  ushort* WpredT = (ushort*)alloc((size_t)1024*256*2);

  // big bf16 staging in d_out (dead until final GEMM writes it)
  ushort* o_b  = (ushort*)d_out;
  ushort* hs_b = o_b + (size_t)NP*512;

  auto cvt = [&](const float* in, ushort* out, size_t n){
    int n4 = (int)(n/4);
    f2b_vec<<<(n4+255)/256, 256, 0, stream>>>(in, out, n4);
  };
  auto wT = [&](const float* W, ushort* WT, int K, int N, int Npad){
    int tot = Npad*K;
    wT_k<<<(tot+255)/256, 256, 0, stream>>>(W, WT, K, N, Npad);
  };
  auto build = [&](const int* s, const int* d, int E, int* ofs, int* colv){
    int J = E/16384; if(J < 8) J = 8; if(J > 64) J = 64;
    fill_zero_i32<<<(NP+255)/256, 256, 0, stream>>>(cnt, NP);
    count_part_k<<<8*J, 256, 0, stream>>>(d, E, cnt, rshift);
    scan_excl_k<<<1, 1024, 0, stream>>>(cnt, ofs, cursor, NP);
    scatter_part_k<<<8*J, 256, 0, stream>>>(s, d, E, cursor, colv, rshift);
  };
  auto gemm = [&]<int BN, typename OutT, bool BIAS>(const ushort* A, const ushort* BT,
      const float* bias, OutT* C, int M, int N, int K, int lda, int ldc){
    int Npad = (N + BN - 1)/BN*BN;
    dim3 g((M + 127)/128, Npad/BN);
    gemm_mfma<BN, OutT, BIAS><<<g, 256, 0, stream>>>(A, BT, bias, C, M, N, K, lda, ldc);
  };

  // ----- CSR + conversions -----
  build(meta_src, meta_dst, EM, ofsm, colm);
  build(q_src, q_dst, EQ, ofsq, colq);
  build(k_src, k_dst, EK, ofsk, colk);
  build(a_src, a_dst, EA, ofsa, cola);
  cvt(hp, hp_b, (size_t)NP*128);
  cvt(hq, fq_b, (size_t)NQ*64);
  cvt(hk, fk_b, (size_t)NK*64);
  cvt(ha, fa_b, (size_t)NA*64);
  wT(W0, W0T, 128, 128, 128);      wT(W1, W1T, 128, 128, 128);
  wT(Wq, WqT, 64, 512, 512);       wT(Wkw, WkwT, 64, 512, 512);
  wT(Watt, WattT, 64, 512, 512);   wT(Wpn, WpnT, 512, 64, 64);
  wT(Wpnn, WpnnT, 128, 64, 64);    wT(Wpnn_a, Wpnn_aT, 128, 64, 64);
  wT(Wpn_a, Wpn_aT, 64, 64, 64);   wT(Wpred, WpredT, 256, 1000, 1024);

  // ----- metapath GAT layer 0 -----
  gemm.template operator()<128, ushort, false>(hp_b, W0T, nullptr, hs_b, NP, 128, 128, 128, 128);
  fold_k<<<2, 256, 0, stream>>>(W0, al0, wfa, 128, 32);
  fold_k<<<2, 256, 0, stream>>>(W0, ar0, wfb, 128, 32);
  gemv8_t<float><<<(NP+3)/4, 256, 0, stream>>>(hp, wfa, wfb, el, er, NP, 128, 128);
  gat_agg2<32><<<(NP+3)/4, 256, 0, stream>>>(hs_b, el, er, ofsm, colm, b0, hbuf_b, NP);

  // ----- metapath GAT layer 1 -----
  gemm.template operator()<128, ushort, false>(hbuf_b, W1T, nullptr, hs_b, NP, 128, 128, 128, 128);
  fold_k<<<2, 256, 0, stream>>>(W1, al1, wfa, 128, 32);
  fold_k<<<2, 256, 0, stream>>>(W1, ar1, wfb, 128, 32);
  gemv8_t<ushort><<<(NP+3)/4, 256, 0, stream>>>(hbuf_b, wfa, wfb, el, er, NP, 128, 128);
  gat_agg2<32><<<(NP+3)/4, 256, 0, stream>>>(hs_b, el, er, ofsm, colm, b1, hbuf_b, NP);

  // ----- hcat[:,0:64] = h @ Wpnn ; hpd = hp @ Wpnn_a -----
  gemm.template operator()<64, ushort, false>(hbuf_b, WpnnT, nullptr, hcat_b, NP, 64, 128, 128, 256);
  gemm.template operator()<64, ushort, false>(hp_b, Wpnn_aT, nullptr, hpd_b, NP, 64, 128, 128, 64);

  // ----- bipartite GATs -----
  auto bip = [&](const ushort* feat_b, int Ns, const int* ofs, const int* colv,
                 const float* W, const ushort* WT_, const float* alp, const float* arp,
                 const float* bb, int colofs){
    gemm.template operator()<64, ushort, false>(feat_b, Wpn_aT, nullptr, proj_b, Ns, 64, 64, 64, 64);
    gemm.template operator()<128, ushort, false>(proj_b, WT_, nullptr, hs_b, Ns, 512, 64, 64, 512);
    fold_k<<<1, 256, 0, stream>>>(W, alp, wfa, 64, 128);
    fold_k<<<1, 256, 0, stream>>>(W, arp, wfb, 64, 128);
    gemv4_t<ushort><<<(Ns+3)/4, 256, 0, stream>>>(proj_b, wfa, el, Ns, 64, 64);
    gemv4_t<ushort><<<(NP+3)/4, 256, 0, stream>>>(hpd_b, wfb, er, NP, 64, 64);
    gat_agg2<128><<<(NP+3)/4, 256, 0, stream>>>(hs_b, el, er, ofs, colv, bb, o_b, NP);
    gemm.template operator()<64, ushort, false>(o_b, WpnT, nullptr, hcat_b + colofs, NP, 64, 512, 512, 256);
  };
  bip(fq_b, NQ, ofsq, colq, Wq,  WqT,  alq,  arq,  bq,  64);
  bip(fk_b, NK, ofsk, colk, Wkw, WkwT, alkw, arkw, bkw, 128);
  bip(fa_b, NA, ofsa, cola, Watt,WattT,alatt,aratt,batt,192);

  // ----- final: out = hcat @ Wpred + bpred -----
  gemm.template operator()<128, float, true>(hcat_b, WpredT, bpred, (float*)d_out, NP, 1000, 256, 256, 1000);
}

// Round 6
// 1336.739 us; speedup vs baseline: 1.0208x; 1.0208x over previous
//
#include <hip/hip_runtime.h>
#include <hip/hip_bf16.h>
#include <math.h>
#include <stdint.h>

typedef __attribute__((ext_vector_type(8))) short bh8;
typedef __attribute__((ext_vector_type(4))) float f32x4;

#define AS1(p) ((const __attribute__((address_space(1))) void*)(p))
#define AS3(p) ((__attribute__((address_space(3))) void*)(p))

__device__ inline ushort f2b(float f){
  uint u = __builtin_bit_cast(uint, f);
  u += 0x7fff + ((u >> 16) & 1);
  return (ushort)(u >> 16);
}
__device__ inline float b2f(ushort b){ return __builtin_bit_cast(float, (uint)b << 16); }

// ---------------- CSR build ----------------
__global__ void fill_zero_i32(int* __restrict__ p, int n){
  int i = blockIdx.x*blockDim.x + threadIdx.x;
  if(i < n) p[i] = 0;
}

// simple single-pass count (cnt region tiny; atomic write-amp negligible)
__global__ void count_dst_k(const int* __restrict__ dst, int E, int* __restrict__ cnt){
  int i = blockIdx.x*blockDim.x + threadIdx.x;
  if(i < E) atomicAdd(&cnt[dst[i]], 1);
}

// XCD-cohort scatter with NON-TEMPORAL edge-stream loads: the stream bypasses
// L2 so the cohort's colv window (~800KB) stays dirty-resident -> writes merge.
__global__ __launch_bounds__(256) void scatter_part_k(const int* __restrict__ src,
    const int* __restrict__ dst, int E, int* __restrict__ cursor,
    int* __restrict__ colv, int rshift){
  const int range = blockIdx.x & 7;
  const int j = blockIdx.x >> 3, J = gridDim.x >> 3;
  const int per = (E + J - 1)/J;
  const int beg = j*per;
  int end = beg + per; if(end > E) end = E;
  for(int i = beg + threadIdx.x; i < end; i += 256){
    int d = __builtin_nontemporal_load(dst + i);
    if((d >> rshift) == range){
      int s = __builtin_nontemporal_load(src + i);
      int p = atomicAdd(&cursor[d], 1);
      colv[p] = s;
    }
  }
}

__global__ __launch_bounds__(1024) void scan_excl_k(const int* __restrict__ cnt,
    int* __restrict__ ofs, int* __restrict__ cursor, int n){
  __shared__ int wsum[16];
  __shared__ int carry_s;
  int tid = threadIdx.x, wid = tid >> 6, lane = tid & 63;
  if(tid == 0) carry_s = 0;
  __syncthreads();
  for(int base = 0; base < n; base += 4096){
    int i0 = base + tid*4;
    int4 v = make_int4(0,0,0,0);
    if(i0 + 3 < n) v = *(const int4*)(cnt + i0);
    else if(i0 < n){
      v.x = cnt[i0];
      if(i0+1 < n) v.y = cnt[i0+1];
      if(i0+2 < n) v.z = cnt[i0+2];
    }
    int s1 = v.x + v.y, s2 = s1 + v.z, tot = s2 + v.w;
    int x = tot;
    #pragma unroll
    for(int off = 1; off < 64; off <<= 1){
      int t = __shfl_up(x, off);
      if(lane >= off) x += t;
    }
    if(lane == 63) wsum[wid] = x;
    __syncthreads();
    if(tid < 16){
      int y = wsum[tid];
      #pragma unroll
      for(int off = 1; off < 16; off <<= 1){
        int t = __shfl_up(y, off);
        if(tid >= off) y += t;
      }
      wsum[tid] = y;
    }
    __syncthreads();
    int pre = (wid ? wsum[wid-1] : 0) + carry_s + (x - tot);
    if(i0 + 3 < n){
      int4 o = make_int4(pre, pre+v.x, pre+s1, pre+s2);
      *(int4*)(ofs + i0) = o;
      *(int4*)(cursor + i0) = o;
    } else if(i0 < n){
      ofs[i0] = pre; cursor[i0] = pre;
      if(i0+1 < n){ ofs[i0+1] = pre+v.x; cursor[i0+1] = pre+v.x; }
      if(i0+2 < n){ ofs[i0+2] = pre+s1; cursor[i0+2] = pre+s1; }
    }
    __syncthreads();
    if(tid == 0) carry_s += wsum[15];
    __syncthreads();
  }
  if(tid == 0) ofs[n] = carry_s;
}

// ---------------- fp32 -> bf16 convert (vectorized x4) ----------------
__global__ void f2b_vec(const float* __restrict__ in, ushort* __restrict__ out, int n4){
  int i = blockIdx.x*blockDim.x + threadIdx.x;
  if(i >= n4) return;
  float4 v = ((const float4*)in)[i];
  ushort4 o; o.x = f2b(v.x); o.y = f2b(v.y); o.z = f2b(v.z); o.w = f2b(v.w);
  ((ushort4*)out)[i] = o;
}

// ---------------- weight transpose + convert: WT[n][k] = bf16(W[k][n]) ----------------
__global__ void wT_k(const float* __restrict__ W, ushort* __restrict__ WT,
    int K, int N, int Npad){
  int idx = blockIdx.x*blockDim.x + threadIdx.x;
  if(idx >= Npad*K) return;
  int n = idx / K, k = idx - n*K;
  WT[idx] = (n < N) ? f2b(W[(size_t)k*N + n]) : (ushort)0;
}

// grouped transpose: WT[h][n][k] = bf16(W[k][h*Ng+n]), W row-major [K][ldw]
__global__ void wTg_k(const float* __restrict__ W, ushort* __restrict__ WT,
    int heads, int Ng, int K, int ldw){
  int idx = blockIdx.x*blockDim.x + threadIdx.x;
  if(idx >= heads*Ng*K) return;
  int h = idx/(Ng*K); int rem = idx - h*Ng*K; int n = rem / K; int k = rem - n*K;
  WT[idx] = f2b(W[(size_t)k*ldw + h*Ng + n]);
}

// ---------------- attention-weight fold: Wf[k,h] = sum_d W[k, h*D+d]*a[h,d] ----------------
__global__ void fold_k(const float* __restrict__ W, const float* __restrict__ a,
    float* __restrict__ Wf, int K, int D){
  int i = blockIdx.x*blockDim.x + threadIdx.x;
  if(i >= K*4) return;
  int k = i >> 2, h = i & 3;
  const float* wr = W + (size_t)k*4*D + (size_t)h*D;
  const float* ar = a + (size_t)h*D;
  float s = 0.f;
  for(int d = 0; d < D; d++) s += wr[d]*ar[d];
  Wf[k*4 + h] = s;
}

__device__ inline float ldval(const float* p){ return *p; }
__device__ inline float ldval(const ushort* p){ return b2f(*p); }

// ---------------- out[m,0:4] = A[m,:] @ Wf[:,0:4]  (one wave per row) ----------------
template<typename T>
__global__ __launch_bounds__(256) void gemv4_t(const T* __restrict__ A,
    const float* __restrict__ Wf, float* __restrict__ outv, int M, int K, int lda){
  int wid = (blockIdx.x*blockDim.x + threadIdx.x) >> 6;
  int lane = threadIdx.x & 63;
  if(wid >= M) return;
  const T* arow = A + (size_t)wid*lda;
  float a0=0.f, a1=0.f, a2=0.f, a3=0.f;
  for(int k = lane; k < K; k += 64){
    float av = ldval(arow + k);
    float4 w = *(const float4*)(Wf + k*4);
    a0 += av*w.x; a1 += av*w.y; a2 += av*w.z; a3 += av*w.w;
  }
  #pragma unroll
  for(int off = 32; off; off >>= 1){
    a0 += __shfl_down(a0, off); a1 += __shfl_down(a1, off);
    a2 += __shfl_down(a2, off); a3 += __shfl_down(a3, off);
  }
  if(lane == 0){
    float4 r; r.x=a0; r.y=a1; r.z=a2; r.w=a3;
    *(float4*)(outv + (size_t)wid*4) = r;
  }
}

// ---------------- fused dual gemv: el = A@Wfa, er = A@Wfb ----------------
template<typename T>
__global__ __launch_bounds__(256) void gemv8_t(const T* __restrict__ A,
    const float* __restrict__ Wfa, const float* __restrict__ Wfb,
    float* __restrict__ oa, float* __restrict__ ob, int M, int K, int lda){
  int wid = (blockIdx.x*blockDim.x + threadIdx.x) >> 6;
  int lane = threadIdx.x & 63;
  if(wid >= M) return;
  const T* arow = A + (size_t)wid*lda;
  float a0=0.f,a1=0.f,a2=0.f,a3=0.f,b0=0.f,b1=0.f,b2=0.f,b3=0.f;
  for(int k = lane; k < K; k += 64){
    float av = ldval(arow + k);
    float4 wa = *(const float4*)(Wfa + k*4);
    float4 wb = *(const float4*)(Wfb + k*4);
    a0 += av*wa.x; a1 += av*wa.y; a2 += av*wa.z; a3 += av*wa.w;
    b0 += av*wb.x; b1 += av*wb.y; b2 += av*wb.z; b3 += av*wb.w;
  }
  #pragma unroll
  for(int off = 32; off; off >>= 1){
    a0 += __shfl_down(a0, off); a1 += __shfl_down(a1, off);
    a2 += __shfl_down(a2, off); a3 += __shfl_down(a3, off);
    b0 += __shfl_down(b0, off); b1 += __shfl_down(b1, off);
    b2 += __shfl_down(b2, off); b3 += __shfl_down(b3, off);
  }
  if(lane == 0){
    float4 r; r.x=a0; r.y=a1; r.z=a2; r.w=a3;
    *(float4*)(oa + (size_t)wid*4) = r;
    float4 s; s.x=b0; s.y=b1; s.z=b2; s.w=b3;
    *(float4*)(ob + (size_t)wid*4) = s;
  }
}

// ---------------- bf16 MFMA GEMM ----------------
// Normal: C[M,N] = A[M,K] @ BT[Npad,K]^T.
// GRP (block-diagonal, grid.y = head): C[:, h*BN:(h+1)*BN] = A[:, h*K:(h+1)*K] @ BT_h^T
//   with lda = heads*K, BT stored [head][BN][K]. Optional fused bias+ELU epilogue.
template<int BN, typename OutT, bool BIAS, bool GRP = false, bool ELU = false>
__global__ __launch_bounds__(256) void gemm_mfma(
    const ushort* __restrict__ A, const ushort* __restrict__ BT,
    const float* __restrict__ bias, OutT* __restrict__ C,
    int M, int N, int K, int lda, int ldc){
  constexpr int BM = 128, BK = 64;
  constexpr int NI = BN/32;
  constexpr int AIT = BM*BK/(256*8);
  constexpr int BIT = BN*BK/(256*8);
  __shared__ ushort lds[BM*BK + BN*BK];
  ushort* ldsA = lds;
  ushort* ldsB = lds + BM*BK;
  const int tid = threadIdx.x, wid = tid >> 6, lane = tid & 63;
  const int wr = wid >> 1, wc = wid & 1;
  const int rowbase = blockIdx.x*BM;
  const ushort* Ag = A;
  const ushort* Bg = BT;
  int colbase;
  if constexpr (GRP){
    const int hh = blockIdx.y;
    Ag = A + (size_t)hh*K;
    Bg = BT + (size_t)hh*BN*K;
    colbase = hh*BN;
  } else {
    colbase = blockIdx.y*BN;
  }

  f32x4 acc[4][NI];
  #pragma unroll
  for(int mi = 0; mi < 4; mi++)
    #pragma unroll
    for(int ni = 0; ni < NI; ni++) acc[mi][ni] = (f32x4)0.f;

  for(int k0 = 0; k0 < K; k0 += BK){
    #pragma unroll
    for(int it = 0; it < AIT; it++){
      int idx = it*256 + wid*64 + lane;
      int r = idx >> 3, sl = idx & 7;
      int kb = sl ^ (r & 7);
      int grow = rowbase + r; if(grow >= M) grow = M-1;
      const ushort* src = Ag + (size_t)grow*lda + k0 + kb*8;
      __builtin_amdgcn_global_load_lds(AS1(src), AS3(ldsA + (size_t)(it*256 + wid*64)*8), 16, 0, 0);
    }
    #pragma unroll
    for(int it = 0; it < BIT; it++){
      int idx = it*256 + wid*64 + lane;
      int r = idx >> 3, sl = idx & 7;
      int kb = sl ^ (r & 7);
      int brow = (GRP ? 0 : colbase) + r;
      const ushort* src = Bg + (size_t)brow*K + k0 + kb*8;
      __builtin_amdgcn_global_load_lds(AS1(src), AS3(ldsB + (size_t)(it*256 + wid*64)*8), 16, 0, 0);
    }
    __syncthreads();
    #pragma unroll
    for(int kk = 0; kk < 2; kk++){
      bh8 af[4], bf[NI];
      #pragma unroll
      for(int mi = 0; mi < 4; mi++){
        int arow = wr*64 + mi*16 + (lane & 15);
        int kb = kk*4 + (lane >> 4);
        af[mi] = *(const bh8*)(ldsA + arow*BK + ((kb ^ (arow & 7)) << 3));
      }
      #pragma unroll
      for(int ni = 0; ni < NI; ni++){
        int brow = wc*(BN/2) + ni*16 + (lane & 15);
        int kb = kk*4 + (lane >> 4);
        bf[ni] = *(const bh8*)(ldsB + brow*BK + ((kb ^ (brow & 7)) << 3));
      }
      #pragma unroll
      for(int mi = 0; mi < 4; mi++)
        #pragma unroll
        for(int ni = 0; ni < NI; ni++)
          acc[mi][ni] = __builtin_amdgcn_mfma_f32_16x16x32_bf16(af[mi], bf[ni], acc[mi][ni], 0, 0, 0);
    }
    __syncthreads();
  }
  #pragma unroll
  for(int mi = 0; mi < 4; mi++){
    #pragma unroll
    for(int ni = 0; ni < NI; ni++){
      int col = colbase + wc*(BN/2) + ni*16 + (lane & 15);
      if(col >= N) continue;
      float bv = BIAS ? bias[col] : 0.f;
      #pragma unroll
      for(int j = 0; j < 4; j++){
        int row = rowbase + wr*64 + mi*16 + (lane >> 4)*4 + j;
        if(row >= M) continue;
        float v = acc[mi][ni][j] + bv;
        if constexpr (ELU) v = v > 0.f ? v : (__expf(v) - 1.f);
        if constexpr (sizeof(OutT) == 4) C[(size_t)row*ldc + col] = v;
        else                             C[(size_t)row*ldc + col] = (OutT)f2b(v);
      }
    }
  }
}

// ---------------- GAT aggregate v2 (metapath, D=32): chunked online-softmax ----------------
template<int D>
__global__ __launch_bounds__(256) void gat_agg2(
    const ushort* __restrict__ hs, const float* __restrict__ el,
    const float* __restrict__ er, const int* __restrict__ ofs,
    const int* __restrict__ colv, const float* __restrict__ bias,
    ushort* __restrict__ outv, int Nd){
  constexpr int R = (D == 128) ? 8 : 2;
  constexpr int U = 8;
  const int wslot = threadIdx.x >> 6;
  const int node = blockIdx.x*4 + wslot;
  const int lane = threadIdx.x & 63;
  __shared__ int   lds_s[4][64];
  __shared__ float lds_w[4][256];
  if(node >= Nd) return;
  const int e0 = ofs[node], e1 = ofs[node+1];
  const int h = lane >> 4;
  const float4 erv = *(const float4*)(er + (size_t)node*4);
  float m0=-INFINITY, m1=-INFINITY, m2=-INFINITY, m3=-INFINITY;
  float sw0=0.f, sw1=0.f, sw2=0.f, sw3=0.f;
  float acc[R];
  #pragma unroll
  for(int r = 0; r < R; r++) acc[r] = 0.f;

  for(int base = e0; base < e1; base += 64){
    int nch = e1 - base; if(nch > 64) nch = 64;
    int s_l = colv[base + (lane < nch ? lane : nch-1)];
    float4 ev = *(const float4*)(el + (size_t)s_l*4);
    float x0 = ev.x + erv.x; x0 = x0 > 0.f ? x0 : 0.2f*x0;
    float x1 = ev.y + erv.y; x1 = x1 > 0.f ? x1 : 0.2f*x1;
    float x2 = ev.z + erv.z; x2 = x2 > 0.f ? x2 : 0.2f*x2;
    float x3 = ev.w + erv.w; x3 = x3 > 0.f ? x3 : 0.2f*x3;
    if(lane >= nch){ x0 = x1 = x2 = x3 = -INFINITY; }
    float c0=x0, c1=x1, c2=x2, c3=x3;
    #pragma unroll
    for(int off = 32; off; off >>= 1){
      c0 = fmaxf(c0, __shfl_xor(c0, off));
      c1 = fmaxf(c1, __shfl_xor(c1, off));
      c2 = fmaxf(c2, __shfl_xor(c2, off));
      c3 = fmaxf(c3, __shfl_xor(c3, off));
    }
    float n0 = fmaxf(m0,c0), n1 = fmaxf(m1,c1), n2 = fmaxf(m2,c2), n3 = fmaxf(m3,c3);
    float r0 = __expf(m0-n0), r1 = __expf(m1-n1), r2 = __expf(m2-n2), r3 = __expf(m3-n3);
    float w0 = __expf(x0-n0), w1 = __expf(x1-n1), w2 = __expf(x2-n2), w3 = __expf(x3-n3);
    sw0 = sw0*r0 + w0; sw1 = sw1*r1 + w1; sw2 = sw2*r2 + w2; sw3 = sw3*r3 + w3;
    float rh = h==0 ? r0 : (h==1 ? r1 : (h==2 ? r2 : r3));
    #pragma unroll
    for(int r = 0; r < R; r++) acc[r] *= rh;
    m0=n0; m1=n1; m2=n2; m3=n3;
    lds_s[wslot][lane] = s_l;
    lds_w[wslot][lane*4+0] = w0; lds_w[wslot][lane*4+1] = w1;
    lds_w[wslot][lane*4+2] = w2; lds_w[wslot][lane*4+3] = w3;
    int npad = (nch + U-1) & ~(U-1);
    for(int j = 0; j < npad; j += U){
      #pragma unroll
      for(int u = 0; u < U; u++){
        int s = lds_s[wslot][j+u];
        float w = lds_w[wslot][(j+u)*4 + h];
        if constexpr (D == 128){
          bh8 hv = *(const bh8*)(hs + (size_t)s*512 + lane*8);
          #pragma unroll
          for(int r = 0; r < 8; r++) acc[r] += w * b2f((ushort)hv[r]);
        } else {
          uint hv = *(const uint*)(hs + (size_t)s*128 + lane*2);
          acc[0] += w * b2f((ushort)(hv & 0xffffu));
          acc[1] += w * b2f((ushort)(hv >> 16));
        }
      }
    }
  }
  #pragma unroll
  for(int off = 32; off; off >>= 1){
    sw0 += __shfl_xor(sw0, off); sw1 += __shfl_xor(sw1, off);
    sw2 += __shfl_xor(sw2, off); sw3 += __shfl_xor(sw3, off);
  }
  float swh = h==0 ? sw0 : (h==1 ? sw1 : (h==2 ? sw2 : sw3));
  float den = (swh == 0.f) ? 1.f : swh;
  if constexpr (D == 128){
    bh8 ov;
    #pragma unroll
    for(int r = 0; r < 8; r++){
      float v = acc[r]/den + bias[lane*8 + r];
      v = v > 0.f ? v : (__expf(v) - 1.f);
      ov[r] = (short)f2b(v);
    }
    *(bh8*)(outv + (size_t)node*512 + lane*8) = ov;
  } else {
    float v0 = acc[0]/den + bias[lane*2 + 0];
    float v1 = acc[1]/den + bias[lane*2 + 1];
    v0 = v0 > 0.f ? v0 : (__expf(v0) - 1.f);
    v1 = v1 > 0.f ? v1 : (__expf(v1) - 1.f);
    *(uint*)(outv + (size_t)node*128 + lane*2) = (uint)f2b(v0) | ((uint)f2b(v1) << 16);
  }
}

// ---------------- bipartite GAT aggregate in PROJ space ----------------
// agg[n, h*64+d] = sum_e alpha_e^h * proj[src_e][d]  (normalized). Lane owns dim d,
// keeps 4 head accumulators. 128B gather per edge (vs 1KB in hs space).
__global__ __launch_bounds__(256) void gat_agg_proj(
    const ushort* __restrict__ proj, const float* __restrict__ el,
    const float* __restrict__ er, const int* __restrict__ ofs,
    const int* __restrict__ colv, ushort* __restrict__ aggv, int Nd){
  constexpr int U = 8;
  const int wslot = threadIdx.x >> 6;
  const int node = blockIdx.x*4 + wslot;
  const int lane = threadIdx.x & 63;
  __shared__ int   lds_s[4][64];
  __shared__ float lds_w[4][256];
  if(node >= Nd) return;
  const int e0 = ofs[node], e1 = ofs[node+1];
  const float4 erv = *(const float4*)(er + (size_t)node*4);
  float m0=-INFINITY, m1=-INFINITY, m2=-INFINITY, m3=-INFINITY;
  float sw0=0.f, sw1=0.f, sw2=0.f, sw3=0.f;
  float a0=0.f, a1=0.f, a2=0.f, a3=0.f;

  for(int base = e0; base < e1; base += 64){
    int nch = e1 - base; if(nch > 64) nch = 64;
    int s_l = colv[base + (lane < nch ? lane : nch-1)];
    float4 ev = *(const float4*)(el + (size_t)s_l*4);
    float x0 = ev.x + erv.x; x0 = x0 > 0.f ? x0 : 0.2f*x0;
    float x1 = ev.y + erv.y; x1 = x1 > 0.f ? x1 : 0.2f*x1;
    float x2 = ev.z + erv.z; x2 = x2 > 0.f ? x2 : 0.2f*x2;
    float x3 = ev.w + erv.w; x3 = x3 > 0.f ? x3 : 0.2f*x3;
    if(lane >= nch){ x0 = x1 = x2 = x3 = -INFINITY; }
    float c0=x0, c1=x1, c2=x2, c3=x3;
    #pragma unroll
    for(int off = 32; off; off >>= 1){
      c0 = fmaxf(c0, __shfl_xor(c0, off));
      c1 = fmaxf(c1, __shfl_xor(c1, off));
      c2 = fmaxf(c2, __shfl_xor(c2, off));
      c3 = fmaxf(c3, __shfl_xor(c3, off));
    }
    float n0 = fmaxf(m0,c0), n1 = fmaxf(m1,c1), n2 = fmaxf(m2,c2), n3 = fmaxf(m3,c3);
    float r0 = __expf(m0-n0), r1 = __expf(m1-n1), r2 = __expf(m2-n2), r3 = __expf(m3-n3);
    float w0 = __expf(x0-n0), w1 = __expf(x1-n1), w2 = __expf(x2-n2), w3 = __expf(x3-n3);
    sw0 = sw0*r0 + w0; sw1 = sw1*r1 + w1; sw2 = sw2*r2 + w2; sw3 = sw3*r3 + w3;
    a0 *= r0; a1 *= r1; a2 *= r2; a3 *= r3;
    m0=n0; m1=n1; m2=n2; m3=n3;
    lds_s[wslot][lane] = s_l;
    lds_w[wslot][lane*4+0] = w0; lds_w[wslot][lane*4+1] = w1;
    lds_w[wslot][lane*4+2] = w2; lds_w[wslot][lane*4+3] = w3;
    int npad = (nch + U-1) & ~(U-1);
    for(int j = 0; j < npad; j += U){
      #pragma unroll
      for(int u = 0; u < U; u++){
        int s = lds_s[wslot][j+u];
        float p = b2f(proj[(size_t)s*64 + lane]);
        a0 += lds_w[wslot][(j+u)*4+0]*p;
        a1 += lds_w[wslot][(j+u)*4+1]*p;
        a2 += lds_w[wslot][(j+u)*4+2]*p;
        a3 += lds_w[wslot][(j+u)*4+3]*p;
      }
    }
  }
  #pragma unroll
  for(int off = 32; off; off >>= 1){
    sw0 += __shfl_xor(sw0, off); sw1 += __shfl_xor(sw1, off);
    sw2 += __shfl_xor(sw2, off); sw3 += __shfl_xor(sw3, off);
  }
  float d0 = (sw0 == 0.f) ? 1.f : sw0;
  float d1 = (sw1 == 0.f) ? 1.f : sw1;
  float d2 = (sw2 == 0.f) ? 1.f : sw2;
  float d3 = (sw3 == 0.f) ? 1.f : sw3;
  ushort* orow = aggv + (size_t)node*256;
  orow[lane]       = f2b(a0/d0);
  orow[64 + lane]  = f2b(a1/d1);
  orow[128 + lane] = f2b(a2/d2);
  orow[192 + lane] = f2b(a3/d3);
}

// ---------------- host orchestration ----------------
extern "C" void kernel_launch(void* const* d_in, const int* in_sizes, int n_in,
                              void* d_out, int out_size, void* d_ws, size_t ws_size,
                              hipStream_t stream){
  const float* hp   = (const float*)d_in[0];
  const float* hq   = (const float*)d_in[1];
  const float* hk   = (const float*)d_in[2];
  const float* ha   = (const float*)d_in[3];
  const int* meta_src = (const int*)d_in[4];
  const int* meta_dst = (const int*)d_in[5];
  const int* q_src = (const int*)d_in[6];
  const int* q_dst = (const int*)d_in[7];
  const int* k_src = (const int*)d_in[8];
  const int* k_dst = (const int*)d_in[9];
  const int* a_src = (const int*)d_in[10];
  const int* a_dst = (const int*)d_in[11];
  const float* W0  = (const float*)d_in[12]; const float* al0 = (const float*)d_in[13];
  const float* ar0 = (const float*)d_in[14]; const float* b0  = (const float*)d_in[15];
  const float* W1  = (const float*)d_in[16]; const float* al1 = (const float*)d_in[17];
  const float* ar1 = (const float*)d_in[18]; const float* b1  = (const float*)d_in[19];
  const float* Wq  = (const float*)d_in[20]; const float* alq = (const float*)d_in[21];
  const float* arq = (const float*)d_in[22]; const float* bq  = (const float*)d_in[23];
  const float* Wkw = (const float*)d_in[24]; const float* alkw= (const float*)d_in[25];
  const float* arkw= (const float*)d_in[26]; const float* bkw = (const float*)d_in[27];
  const float* Watt= (const float*)d_in[28]; const float* alatt=(const float*)d_in[29];
  const float* aratt=(const float*)d_in[30]; const float* batt= (const float*)d_in[31];
  const float* Wpnn_a = (const float*)d_in[32];
  const float* Wpn_a  = (const float*)d_in[33];
  const float* Wpnn   = (const float*)d_in[34];
  const float* Wpn    = (const float*)d_in[35];
  const float* Wpred  = (const float*)d_in[36];
  const float* bpred  = (const float*)d_in[37];
  (void)n_in; (void)out_size; (void)ws_size;

  const int IN = 128, ATT = 64;
  const int NP = in_sizes[0]/IN, NQ = in_sizes[1]/ATT, NK = in_sizes[2]/ATT, NA = in_sizes[3]/ATT;
  const int EM = in_sizes[4], EQ = in_sizes[6], EK = in_sizes[8], EA = in_sizes[10];

  int rshift = 0;
  while((8 << rshift) < NP) rshift++;

  // ----- workspace layout -----
  uint8_t* wp = (uint8_t*)d_ws;
  auto alloc = [&](size_t bytes)->uint8_t*{
    uint8_t* p = wp; wp += (bytes + 255) & ~(size_t)255; return p;
  };
  ushort* hcat_b = (ushort*)alloc((size_t)NP*256*2);
  ushort* hbuf_b = (ushort*)alloc((size_t)NP*128*2);
  ushort* hp_b   = (ushort*)alloc((size_t)NP*128*2);
  ushort* hpd_b  = (ushort*)alloc((size_t)NP*64*2);
  int NSmax = NQ > NK ? NQ : NK; if(NA > NSmax) NSmax = NA;
  ushort* proj_b = (ushort*)alloc((size_t)NSmax*64*2);
  ushort* fq_b   = (ushort*)alloc((size_t)NQ*64*2);
  ushort* fk_b   = (ushort*)alloc((size_t)NK*64*2);
  ushort* fa_b   = (ushort*)alloc((size_t)NA*64*2);
  float* el   = (float*)alloc((size_t)NP*4*4);
  float* er   = (float*)alloc((size_t)NP*4*4);
  float* wfa  = (float*)alloc(512*4);
  float* wfb  = (float*)alloc(512*4);
  int* cnt    = (int*)alloc((size_t)(NP+4)*4);
  int* cursor = (int*)alloc((size_t)(NP+4)*4);
  int* ofsm   = (int*)alloc((size_t)(NP+4)*4);
  int* ofsq   = (int*)alloc((size_t)(NP+4)*4);
  int* ofsk   = (int*)alloc((size_t)(NP+4)*4);
  int* ofsa   = (int*)alloc((size_t)(NP+4)*4);
  int* colm   = (int*)alloc((size_t)EM*4);
  int* colq   = (int*)alloc((size_t)EQ*4);
  int* colk   = (int*)alloc((size_t)EK*4);
  int* cola   = (int*)alloc((size_t)EA*4);
  ushort* W0T    = (ushort*)alloc(128*128*2);
  ushort* W1T    = (ushort*)alloc(128*128*2);
  ushort* WTg    = (ushort*)alloc((size_t)4*128*64*2);
  ushort* WpnT   = (ushort*)alloc((size_t)64*512*2);
  ushort* WpnnT  = (ushort*)alloc(64*128*2);
  ushort* Wpnn_aT= (ushort*)alloc(64*128*2);
  ushort* Wpn_aT = (ushort*)alloc(64*64*2);
  ushort* WpredT = (ushort*)alloc((size_t)1024*256*2);

  // big bf16 staging in d_out (dead until final GEMM writes it)
  ushort* o_b   = (ushort*)d_out;              // [NP,512]
  ushort* agg_b = o_b + (size_t)NP*512;        // [NP,256]
  ushort* hs_b  = agg_b + (size_t)NP*256;      // [NP,128] metapath hs

  auto cvt = [&](const float* in, ushort* out, size_t n){
    int n4 = (int)(n/4);
    f2b_vec<<<(n4+255)/256, 256, 0, stream>>>(in, out, n4);
  };
  auto wT = [&](const float* W, ushort* WT, int K, int N, int Npad){
    int tot = Npad*K;
    wT_k<<<(tot+255)/256, 256, 0, stream>>>(W, WT, K, N, Npad);
  };
  auto build = [&](const int* s, const int* d, int E, int* ofs, int* colv){
    int J = E/16384; if(J < 8) J = 8; if(J > 64) J = 64;
    fill_zero_i32<<<(NP+255)/256, 256, 0, stream>>>(cnt, NP);
    count_dst_k<<<(E+255)/256, 256, 0, stream>>>(d, E, cnt);
    scan_excl_k<<<1, 1024, 0, stream>>>(cnt, ofs, cursor, NP);
    scatter_part_k<<<8*J, 256, 0, stream>>>(s, d, E, cursor, colv, rshift);
  };
  auto gemm = [&]<int BN, typename OutT, bool BIAS>(const ushort* A, const ushort* BT,
      const float* bias, OutT* C, int M, int N, int K, int lda, int ldc){
    int Npad = (N + BN - 1)/BN*BN;
    dim3 g((M + 127)/128, Npad/BN);
    gemm_mfma<BN, OutT, BIAS><<<g, 256, 0, stream>>>(A, BT, bias, C, M, N, K, lda, ldc);
  };

  // ----- CSR + conversions -----
  build(meta_src, meta_dst, EM, ofsm, colm);
  build(q_src, q_dst, EQ, ofsq, colq);
  build(k_src, k_dst, EK, ofsk, colk);
  build(a_src, a_dst, EA, ofsa, cola);
  cvt(hp, hp_b, (size_t)NP*128);
  cvt(hq, fq_b, (size_t)NQ*64);
  cvt(hk, fk_b, (size_t)NK*64);
  cvt(ha, fa_b, (size_t)NA*64);
  wT(W0, W0T, 128, 128, 128);      wT(W1, W1T, 128, 128, 128);
  wT(Wpn, WpnT, 512, 64, 64);      wT(Wpnn, WpnnT, 128, 64, 64);
  wT(Wpnn_a, Wpnn_aT, 128, 64, 64);wT(Wpn_a, Wpn_aT, 64, 64, 64);
  wT(Wpred, WpredT, 256, 1000, 1024);

  // ----- metapath GAT layer 0 -----
  gemm.template operator()<128, ushort, false>(hp_b, W0T, nullptr, hs_b, NP, 128, 128, 128, 128);
  fold_k<<<2, 256, 0, stream>>>(W0, al0, wfa, 128, 32);
  fold_k<<<2, 256, 0, stream>>>(W0, ar0, wfb, 128, 32);
  gemv8_t<float><<<(NP+3)/4, 256, 0, stream>>>(hp, wfa, wfb, el, er, NP, 128, 128);
  gat_agg2<32><<<(NP+3)/4, 256, 0, stream>>>(hs_b, el, er, ofsm, colm, b0, hbuf_b, NP);

  // ----- metapath GAT layer 1 -----
  gemm.template operator()<128, ushort, false>(hbuf_b, W1T, nullptr, hs_b, NP, 128, 128, 128, 128);
  fold_k<<<2, 256, 0, stream>>>(W1, al1, wfa, 128, 32);
  fold_k<<<2, 256, 0, stream>>>(W1, ar1, wfb, 128, 32);
  gemv8_t<ushort><<<(NP+3)/4, 256, 0, stream>>>(hbuf_b, wfa, wfb, el, er, NP, 128, 128);
  gat_agg2<32><<<(NP+3)/4, 256, 0, stream>>>(hs_b, el, er, ofsm, colm, b1, hbuf_b, NP);

  // ----- hcat[:,0:64] = h @ Wpnn ; hpd = hp @ Wpnn_a -----
  gemm.template operator()<64, ushort, false>(hbuf_b, WpnnT, nullptr, hcat_b, NP, 64, 128, 128, 256);
  gemm.template operator()<64, ushort, false>(hp_b, Wpnn_aT, nullptr, hpd_b, NP, 64, 128, 128, 64);

  // ----- bipartite GATs (proj-space aggregation + block-diag GEMM w/ fused bias+elu) -----
  auto bip = [&](const ushort* feat_b, int Ns, const int* ofs, const int* colv,
                 const float* W, const float* alp, const float* arp,
                 const float* bb, int colofs){
    gemm.template operator()<64, ushort, false>(feat_b, Wpn_aT, nullptr, proj_b, Ns, 64, 64, 64, 64);
    fold_k<<<1, 256, 0, stream>>>(W, alp, wfa, 64, 128);
    fold_k<<<1, 256, 0, stream>>>(W, arp, wfb, 64, 128);
    gemv4_t<ushort><<<(Ns+3)/4, 256, 0, stream>>>(proj_b, wfa, el, Ns, 64, 64);
    gemv4_t<ushort><<<(NP+3)/4, 256, 0, stream>>>(hpd_b, wfb, er, NP, 64, 64);
    gat_agg_proj<<<(NP+3)/4, 256, 0, stream>>>(proj_b, el, er, ofs, colv, agg_b, NP);
    wTg_k<<<(4*128*64+255)/256, 256, 0, stream>>>(W, WTg, 4, 128, 64, 512);
    dim3 g((NP+127)/128, 4);
    gemm_mfma<128, ushort, true, true, true><<<g, 256, 0, stream>>>(
        agg_b, WTg, bb, o_b, NP, 512, 64, 256, 512);
    gemm.template operator()<64, ushort, false>(o_b, WpnT, nullptr, hcat_b + colofs, NP, 64, 512, 512, 256);
  };
  bip(fq_b, NQ, ofsq, colq, Wq,  alq,  arq,  bq,  64);
  bip(fk_b, NK, ofsk, colk, Wkw, alkw, arkw, bkw, 128);
  bip(fa_b, NA, ofsa, cola, Watt,alatt,aratt,batt,192);

  // ----- final: out = hcat @ Wpred + bpred -----
  gemm.template operator()<128, float, true>(hcat_b, WpredT, bpred, (float*)d_out, NP, 1000, 256, 256, 1000);
}

// Round 7
// 1247.589 us; speedup vs baseline: 1.0938x; 1.0715x over previous
//
#include <hip/hip_runtime.h>
#include <hip/hip_bf16.h>
#include <math.h>
#include <stdint.h>

typedef __attribute__((ext_vector_type(8))) short bh8;
typedef __attribute__((ext_vector_type(4))) float f32x4;

#define AS1(p) ((const __attribute__((address_space(1))) void*)(p))
#define AS3(p) ((__attribute__((address_space(3))) void*)(p))

__device__ inline ushort f2b(float f){
  uint u = __builtin_bit_cast(uint, f);
  u += 0x7fff + ((u >> 16) & 1);
  return (ushort)(u >> 16);
}
__device__ inline float b2f(ushort b){ return __builtin_bit_cast(float, (uint)b << 16); }

// ---------------- CSR build (bucketed two-pass) ----------------
__global__ void fill_zero_i32(int* __restrict__ p, int n){
  int i = blockIdx.x*blockDim.x + threadIdx.x;
  if(i < n) p[i] = 0;
}

// Pass A: partition edges into 8 dst-range buckets. LDS-aggregated cursors ->
// one global atomic per bucket per 256-edge chunk; int2(dst,src) runs written
// mostly-sequentially (no write amplification).
__global__ __launch_bounds__(256) void partition_k(const int* __restrict__ src,
    const int* __restrict__ dst, int E, int range, int* __restrict__ bcur,
    int2* __restrict__ ebuf, int cap){
  __shared__ int hist[8], base[8];
  const int tid = threadIdx.x;
  for(int c0 = blockIdx.x*256; c0 < E; c0 += gridDim.x*256){
    int i = c0 + tid;
    int d = 0, s = 0, b = -1;
    if(i < E){ d = dst[i]; s = src[i]; b = d / range; }
    if(tid < 8) hist[tid] = 0;
    __syncthreads();
    int rank = 0;
    if(b >= 0) rank = atomicAdd(&hist[b], 1);
    __syncthreads();
    if(tid < 8) base[tid] = hist[tid] ? atomicAdd(&bcur[tid], hist[tid]) : 0;
    __syncthreads();
    if(b >= 0){
      int pos = base[b] + rank;
      if(pos < cap) ebuf[(size_t)b*cap + pos] = make_int2(d, s);
    }
    __syncthreads();
  }
}

// Pass B1: per-bucket count. Cohort blockIdx&7 -> XCD round-robin heuristic:
// each bucket's cnt slice + edge stream stay inside ONE 4MB L2.
__global__ __launch_bounds__(256) void count_bucket_k(const int2* __restrict__ ebuf,
    int cap, const int* __restrict__ bcur, int* __restrict__ cnt){
  const int b = blockIdx.x & 7;
  const int j = blockIdx.x >> 3, J = gridDim.x >> 3;
  int nb = bcur[b]; if(nb > cap) nb = cap;
  const int2* eb = ebuf + (size_t)b*cap;
  int per = (nb + J - 1)/J;
  int beg = j*per; int end = beg + per; if(end > nb) end = nb;
  for(int i = beg + threadIdx.x; i < end; i += 256)
    atomicAdd(&cnt[eb[i].x], 1);
}

// Pass B2: per-bucket scatter into colv (colv window ~800KB L2-resident).
__global__ __launch_bounds__(256) void scatter_bucket_k(const int2* __restrict__ ebuf,
    int cap, const int* __restrict__ bcur, int* __restrict__ cursor,
    int* __restrict__ colv){
  const int b = blockIdx.x & 7;
  const int j = blockIdx.x >> 3, J = gridDim.x >> 3;
  int nb = bcur[b]; if(nb > cap) nb = cap;
  const int2* eb = ebuf + (size_t)b*cap;
  int per = (nb + J - 1)/J;
  int beg = j*per; int end = beg + per; if(end > nb) end = nb;
  for(int i = beg + threadIdx.x; i < end; i += 256){
    int2 e = eb[i];
    int p = atomicAdd(&cursor[e.x], 1);
    colv[p] = e.y;
  }
}

__global__ __launch_bounds__(1024) void scan_excl_k(const int* __restrict__ cnt,
    int* __restrict__ ofs, int* __restrict__ cursor, int n){
  __shared__ int wsum[16];
  __shared__ int carry_s;
  int tid = threadIdx.x, wid = tid >> 6, lane = tid & 63;
  if(tid == 0) carry_s = 0;
  __syncthreads();
  for(int base = 0; base < n; base += 4096){
    int i0 = base + tid*4;
    int4 v = make_int4(0,0,0,0);
    if(i0 + 3 < n) v = *(const int4*)(cnt + i0);
    else if(i0 < n){
      v.x = cnt[i0];
      if(i0+1 < n) v.y = cnt[i0+1];
      if(i0+2 < n) v.z = cnt[i0+2];
    }
    int s1 = v.x + v.y, s2 = s1 + v.z, tot = s2 + v.w;
    int x = tot;
    #pragma unroll
    for(int off = 1; off < 64; off <<= 1){
      int t = __shfl_up(x, off);
      if(lane >= off) x += t;
    }
    if(lane == 63) wsum[wid] = x;
    __syncthreads();
    if(tid < 16){
      int y = wsum[tid];
      #pragma unroll
      for(int off = 1; off < 16; off <<= 1){
        int t = __shfl_up(y, off);
        if(tid >= off) y += t;
      }
      wsum[tid] = y;
    }
    __syncthreads();
    int pre = (wid ? wsum[wid-1] : 0) + carry_s + (x - tot);
    if(i0 + 3 < n){
      int4 o = make_int4(pre, pre+v.x, pre+s1, pre+s2);
      *(int4*)(ofs + i0) = o;
      *(int4*)(cursor + i0) = o;
    } else if(i0 < n){
      ofs[i0] = pre; cursor[i0] = pre;
      if(i0+1 < n){ ofs[i0+1] = pre+v.x; cursor[i0+1] = pre+v.x; }
      if(i0+2 < n){ ofs[i0+2] = pre+s1; cursor[i0+2] = pre+s1; }
    }
    __syncthreads();
    if(tid == 0) carry_s += wsum[15];
    __syncthreads();
  }
  if(tid == 0) ofs[n] = carry_s;
}

// ---------------- fp32 -> bf16 convert (vectorized x4) ----------------
__global__ void f2b_vec(const float* __restrict__ in, ushort* __restrict__ out, int n4){
  int i = blockIdx.x*blockDim.x + threadIdx.x;
  if(i >= n4) return;
  float4 v = ((const float4*)in)[i];
  ushort4 o; o.x = f2b(v.x); o.y = f2b(v.y); o.z = f2b(v.z); o.w = f2b(v.w);
  ((ushort4*)out)[i] = o;
}

// ---------------- weight transpose + convert: WT[n][k] = bf16(W[k][n]) ----------------
__global__ void wT_k(const float* __restrict__ W, ushort* __restrict__ WT,
    int K, int N, int Npad){
  int idx = blockIdx.x*blockDim.x + threadIdx.x;
  if(idx >= Npad*K) return;
  int n = idx / K, k = idx - n*K;
  WT[idx] = (n < N) ? f2b(W[(size_t)k*N + n]) : (ushort)0;
}

// grouped transpose: WT[h][n][k] = bf16(W[k][h*Ng+n]), W row-major [K][ldw]
__global__ void wTg_k(const float* __restrict__ W, ushort* __restrict__ WT,
    int heads, int Ng, int K, int ldw){
  int idx = blockIdx.x*blockDim.x + threadIdx.x;
  if(idx >= heads*Ng*K) return;
  int h = idx/(Ng*K); int rem = idx - h*Ng*K; int n = rem / K; int k = rem - n*K;
  WT[idx] = f2b(W[(size_t)k*ldw + h*Ng + n]);
}

// ---------------- attention-weight fold: Wf[k,h] = sum_d W[k, h*D+d]*a[h,d] ----------------
__global__ void fold_k(const float* __restrict__ W, const float* __restrict__ a,
    float* __restrict__ Wf, int K, int D){
  int i = blockIdx.x*blockDim.x + threadIdx.x;
  if(i >= K*4) return;
  int k = i >> 2, h = i & 3;
  const float* wr = W + (size_t)k*4*D + (size_t)h*D;
  const float* ar = a + (size_t)h*D;
  float s = 0.f;
  for(int d = 0; d < D; d++) s += wr[d]*ar[d];
  Wf[k*4 + h] = s;
}

__device__ inline float ldval(const float* p){ return *p; }
__device__ inline float ldval(const ushort* p){ return b2f(*p); }

// ---------------- out[m,0:4] = A[m,:] @ Wf[:,0:4]  (one wave per row) ----------------
template<typename T>
__global__ __launch_bounds__(256) void gemv4_t(const T* __restrict__ A,
    const float* __restrict__ Wf, float* __restrict__ outv, int M, int K, int lda){
  int wid = (blockIdx.x*blockDim.x + threadIdx.x) >> 6;
  int lane = threadIdx.x & 63;
  if(wid >= M) return;
  const T* arow = A + (size_t)wid*lda;
  float a0=0.f, a1=0.f, a2=0.f, a3=0.f;
  for(int k = lane; k < K; k += 64){
    float av = ldval(arow + k);
    float4 w = *(const float4*)(Wf + k*4);
    a0 += av*w.x; a1 += av*w.y; a2 += av*w.z; a3 += av*w.w;
  }
  #pragma unroll
  for(int off = 32; off; off >>= 1){
    a0 += __shfl_down(a0, off); a1 += __shfl_down(a1, off);
    a2 += __shfl_down(a2, off); a3 += __shfl_down(a3, off);
  }
  if(lane == 0){
    float4 r; r.x=a0; r.y=a1; r.z=a2; r.w=a3;
    *(float4*)(outv + (size_t)wid*4) = r;
  }
}

// ---------------- fused dual gemv: el = A@Wfa, er = A@Wfb ----------------
template<typename T>
__global__ __launch_bounds__(256) void gemv8_t(const T* __restrict__ A,
    const float* __restrict__ Wfa, const float* __restrict__ Wfb,
    float* __restrict__ oa, float* __restrict__ ob, int M, int K, int lda){
  int wid = (blockIdx.x*blockDim.x + threadIdx.x) >> 6;
  int lane = threadIdx.x & 63;
  if(wid >= M) return;
  const T* arow = A + (size_t)wid*lda;
  float a0=0.f,a1=0.f,a2=0.f,a3=0.f,b0=0.f,b1=0.f,b2=0.f,b3=0.f;
  for(int k = lane; k < K; k += 64){
    float av = ldval(arow + k);
    float4 wa = *(const float4*)(Wfa + k*4);
    float4 wb = *(const float4*)(Wfb + k*4);
    a0 += av*wa.x; a1 += av*wa.y; a2 += av*wa.z; a3 += av*wa.w;
    b0 += av*wb.x; b1 += av*wb.y; b2 += av*wb.z; b3 += av*wb.w;
  }
  #pragma unroll
  for(int off = 32; off; off >>= 1){
    a0 += __shfl_down(a0, off); a1 += __shfl_down(a1, off);
    a2 += __shfl_down(a2, off); a3 += __shfl_down(a3, off);
    b0 += __shfl_down(b0, off); b1 += __shfl_down(b1, off);
    b2 += __shfl_down(b2, off); b3 += __shfl_down(b3, off);
  }
  if(lane == 0){
    float4 r; r.x=a0; r.y=a1; r.z=a2; r.w=a3;
    *(float4*)(oa + (size_t)wid*4) = r;
    float4 s; s.x=b0; s.y=b1; s.z=b2; s.w=b3;
    *(float4*)(ob + (size_t)wid*4) = s;
  }
}

// ---------------- bf16 MFMA GEMM ----------------
template<int BN, typename OutT, bool BIAS, bool GRP = false, bool ELU = false>
__global__ __launch_bounds__(256) void gemm_mfma(
    const ushort* __restrict__ A, const ushort* __restrict__ BT,
    const float* __restrict__ bias, OutT* __restrict__ C,
    int M, int N, int K, int lda, int ldc){
  constexpr int BM = 128, BK = 64;
  constexpr int NI = BN/32;
  constexpr int AIT = BM*BK/(256*8);
  constexpr int BIT = BN*BK/(256*8);
  __shared__ ushort lds[BM*BK + BN*BK];
  ushort* ldsA = lds;
  ushort* ldsB = lds + BM*BK;
  const int tid = threadIdx.x, wid = tid >> 6, lane = tid & 63;
  const int wr = wid >> 1, wc = wid & 1;
  const int rowbase = blockIdx.x*BM;
  const ushort* Ag = A;
  const ushort* Bg = BT;
  int colbase;
  if constexpr (GRP){
    const int hh = blockIdx.y;
    Ag = A + (size_t)hh*K;
    Bg = BT + (size_t)hh*BN*K;
    colbase = hh*BN;
  } else {
    colbase = blockIdx.y*BN;
  }

  f32x4 acc[4][NI];
  #pragma unroll
  for(int mi = 0; mi < 4; mi++)
    #pragma unroll
    for(int ni = 0; ni < NI; ni++) acc[mi][ni] = (f32x4)0.f;

  for(int k0 = 0; k0 < K; k0 += BK){
    #pragma unroll
    for(int it = 0; it < AIT; it++){
      int idx = it*256 + wid*64 + lane;
      int r = idx >> 3, sl = idx & 7;
      int kb = sl ^ (r & 7);
      int grow = rowbase + r; if(grow >= M) grow = M-1;
      const ushort* src = Ag + (size_t)grow*lda + k0 + kb*8;
      __builtin_amdgcn_global_load_lds(AS1(src), AS3(ldsA + (size_t)(it*256 + wid*64)*8), 16, 0, 0);
    }
    #pragma unroll
    for(int it = 0; it < BIT; it++){
      int idx = it*256 + wid*64 + lane;
      int r = idx >> 3, sl = idx & 7;
      int kb = sl ^ (r & 7);
      int brow = (GRP ? 0 : colbase) + r;
      const ushort* src = Bg + (size_t)brow*K + k0 + kb*8;
      __builtin_amdgcn_global_load_lds(AS1(src), AS3(ldsB + (size_t)(it*256 + wid*64)*8), 16, 0, 0);
    }
    __syncthreads();
    #pragma unroll
    for(int kk = 0; kk < 2; kk++){
      bh8 af[4], bf[NI];
      #pragma unroll
      for(int mi = 0; mi < 4; mi++){
        int arow = wr*64 + mi*16 + (lane & 15);
        int kb = kk*4 + (lane >> 4);
        af[mi] = *(const bh8*)(ldsA + arow*BK + ((kb ^ (arow & 7)) << 3));
      }
      #pragma unroll
      for(int ni = 0; ni < NI; ni++){
        int brow = wc*(BN/2) + ni*16 + (lane & 15);
        int kb = kk*4 + (lane >> 4);
        bf[ni] = *(const bh8*)(ldsB + brow*BK + ((kb ^ (brow & 7)) << 3));
      }
      #pragma unroll
      for(int mi = 0; mi < 4; mi++)
        #pragma unroll
        for(int ni = 0; ni < NI; ni++)
          acc[mi][ni] = __builtin_amdgcn_mfma_f32_16x16x32_bf16(af[mi], bf[ni], acc[mi][ni], 0, 0, 0);
    }
    __syncthreads();
  }
  #pragma unroll
  for(int mi = 0; mi < 4; mi++){
    #pragma unroll
    for(int ni = 0; ni < NI; ni++){
      int col = colbase + wc*(BN/2) + ni*16 + (lane & 15);
      if(col >= N) continue;
      float bv = BIAS ? bias[col] : 0.f;
      #pragma unroll
      for(int j = 0; j < 4; j++){
        int row = rowbase + wr*64 + mi*16 + (lane >> 4)*4 + j;
        if(row >= M) continue;
        float v = acc[mi][ni][j] + bv;
        if constexpr (ELU) v = v > 0.f ? v : (__expf(v) - 1.f);
        if constexpr (sizeof(OutT) == 4) C[(size_t)row*ldc + col] = v;
        else                             C[(size_t)row*ldc + col] = (OutT)f2b(v);
      }
    }
  }
}

// ---------------- GAT aggregate v2 (metapath, D=32): chunked online-softmax ----------------
template<int D>
__global__ __launch_bounds__(256) void gat_agg2(
    const ushort* __restrict__ hs, const float* __restrict__ el,
    const float* __restrict__ er, const int* __restrict__ ofs,
    const int* __restrict__ colv, const float* __restrict__ bias,
    ushort* __restrict__ outv, int Nd){
  constexpr int R = (D == 128) ? 8 : 2;
  constexpr int U = 8;
  const int wslot = threadIdx.x >> 6;
  const int node = blockIdx.x*4 + wslot;
  const int lane = threadIdx.x & 63;
  __shared__ int   lds_s[4][64];
  __shared__ float lds_w[4][256];
  if(node >= Nd) return;
  const int e0 = ofs[node], e1 = ofs[node+1];
  const int h = lane >> 4;
  const float4 erv = *(const float4*)(er + (size_t)node*4);
  float m0=-INFINITY, m1=-INFINITY, m2=-INFINITY, m3=-INFINITY;
  float sw0=0.f, sw1=0.f, sw2=0.f, sw3=0.f;
  float acc[R];
  #pragma unroll
  for(int r = 0; r < R; r++) acc[r] = 0.f;

  for(int base = e0; base < e1; base += 64){
    int nch = e1 - base; if(nch > 64) nch = 64;
    int s_l = colv[base + (lane < nch ? lane : nch-1)];
    float4 ev = *(const float4*)(el + (size_t)s_l*4);
    float x0 = ev.x + erv.x; x0 = x0 > 0.f ? x0 : 0.2f*x0;
    float x1 = ev.y + erv.y; x1 = x1 > 0.f ? x1 : 0.2f*x1;
    float x2 = ev.z + erv.z; x2 = x2 > 0.f ? x2 : 0.2f*x2;
    float x3 = ev.w + erv.w; x3 = x3 > 0.f ? x3 : 0.2f*x3;
    if(lane >= nch){ x0 = x1 = x2 = x3 = -INFINITY; }
    float c0=x0, c1=x1, c2=x2, c3=x3;
    #pragma unroll
    for(int off = 32; off; off >>= 1){
      c0 = fmaxf(c0, __shfl_xor(c0, off));
      c1 = fmaxf(c1, __shfl_xor(c1, off));
      c2 = fmaxf(c2, __shfl_xor(c2, off));
      c3 = fmaxf(c3, __shfl_xor(c3, off));
    }
    float n0 = fmaxf(m0,c0), n1 = fmaxf(m1,c1), n2 = fmaxf(m2,c2), n3 = fmaxf(m3,c3);
    float r0 = __expf(m0-n0), r1 = __expf(m1-n1), r2 = __expf(m2-n2), r3 = __expf(m3-n3);
    float w0 = __expf(x0-n0), w1 = __expf(x1-n1), w2 = __expf(x2-n2), w3 = __expf(x3-n3);
    sw0 = sw0*r0 + w0; sw1 = sw1*r1 + w1; sw2 = sw2*r2 + w2; sw3 = sw3*r3 + w3;
    float rh = h==0 ? r0 : (h==1 ? r1 : (h==2 ? r2 : r3));
    #pragma unroll
    for(int r = 0; r < R; r++) acc[r] *= rh;
    m0=n0; m1=n1; m2=n2; m3=n3;
    lds_s[wslot][lane] = s_l;
    lds_w[wslot][lane*4+0] = w0; lds_w[wslot][lane*4+1] = w1;
    lds_w[wslot][lane*4+2] = w2; lds_w[wslot][lane*4+3] = w3;
    int npad = (nch + U-1) & ~(U-1);
    for(int j = 0; j < npad; j += U){
      #pragma unroll
      for(int u = 0; u < U; u++){
        int s = lds_s[wslot][j+u];
        float w = lds_w[wslot][(j+u)*4 + h];
        if constexpr (D == 128){
          bh8 hv = *(const bh8*)(hs + (size_t)s*512 + lane*8);
          #pragma unroll
          for(int r = 0; r < 8; r++) acc[r] += w * b2f((ushort)hv[r]);
        } else {
          uint hv = *(const uint*)(hs + (size_t)s*128 + lane*2);
          acc[0] += w * b2f((ushort)(hv & 0xffffu));
          acc[1] += w * b2f((ushort)(hv >> 16));
        }
      }
    }
  }
  #pragma unroll
  for(int off = 32; off; off >>= 1){
    sw0 += __shfl_xor(sw0, off); sw1 += __shfl_xor(sw1, off);
    sw2 += __shfl_xor(sw2, off); sw3 += __shfl_xor(sw3, off);
  }
  float swh = h==0 ? sw0 : (h==1 ? sw1 : (h==2 ? sw2 : sw3));
  float den = (swh == 0.f) ? 1.f : swh;
  if constexpr (D == 128){
    bh8 ov;
    #pragma unroll
    for(int r = 0; r < 8; r++){
      float v = acc[r]/den + bias[lane*8 + r];
      v = v > 0.f ? v : (__expf(v) - 1.f);
      ov[r] = (short)f2b(v);
    }
    *(bh8*)(outv + (size_t)node*512 + lane*8) = ov;
  } else {
    float v0 = acc[0]/den + bias[lane*2 + 0];
    float v1 = acc[1]/den + bias[lane*2 + 1];
    v0 = v0 > 0.f ? v0 : (__expf(v0) - 1.f);
    v1 = v1 > 0.f ? v1 : (__expf(v1) - 1.f);
    *(uint*)(outv + (size_t)node*128 + lane*2) = (uint)f2b(v0) | ((uint)f2b(v1) << 16);
  }
}

// ---------------- bipartite GAT aggregate in PROJ space ----------------
__global__ __launch_bounds__(256) void gat_agg_proj(
    const ushort* __restrict__ proj, const float* __restrict__ el,
    const float* __restrict__ er, const int* __restrict__ ofs,
    const int* __restrict__ colv, ushort* __restrict__ aggv, int Nd){
  constexpr int U = 8;
  const int wslot = threadIdx.x >> 6;
  const int node = blockIdx.x*4 + wslot;
  const int lane = threadIdx.x & 63;
  __shared__ int   lds_s[4][64];
  __shared__ float lds_w[4][256];
  if(node >= Nd) return;
  const int e0 = ofs[node], e1 = ofs[node+1];
  const float4 erv = *(const float4*)(er + (size_t)node*4);
  float m0=-INFINITY, m1=-INFINITY, m2=-INFINITY, m3=-INFINITY;
  float sw0=0.f, sw1=0.f, sw2=0.f, sw3=0.f;
  float a0=0.f, a1=0.f, a2=0.f, a3=0.f;

  for(int base = e0; base < e1; base += 64){
    int nch = e1 - base; if(nch > 64) nch = 64;
    int s_l = colv[base + (lane < nch ? lane : nch-1)];
    float4 ev = *(const float4*)(el + (size_t)s_l*4);
    float x0 = ev.x + erv.x; x0 = x0 > 0.f ? x0 : 0.2f*x0;
    float x1 = ev.y + erv.y; x1 = x1 > 0.f ? x1 : 0.2f*x1;
    float x2 = ev.z + erv.z; x2 = x2 > 0.f ? x2 : 0.2f*x2;
    float x3 = ev.w + erv.w; x3 = x3 > 0.f ? x3 : 0.2f*x3;
    if(lane >= nch){ x0 = x1 = x2 = x3 = -INFINITY; }
    float c0=x0, c1=x1, c2=x2, c3=x3;
    #pragma unroll
    for(int off = 32; off; off >>= 1){
      c0 = fmaxf(c0, __shfl_xor(c0, off));
      c1 = fmaxf(c1, __shfl_xor(c1, off));
      c2 = fmaxf(c2, __shfl_xor(c2, off));
      c3 = fmaxf(c3, __shfl_xor(c3, off));
    }
    float n0 = fmaxf(m0,c0), n1 = fmaxf(m1,c1), n2 = fmaxf(m2,c2), n3 = fmaxf(m3,c3);
    float r0 = __expf(m0-n0), r1 = __expf(m1-n1), r2 = __expf(m2-n2), r3 = __expf(m3-n3);
    float w0 = __expf(x0-n0), w1 = __expf(x1-n1), w2 = __expf(x2-n2), w3 = __expf(x3-n3);
    sw0 = sw0*r0 + w0; sw1 = sw1*r1 + w1; sw2 = sw2*r2 + w2; sw3 = sw3*r3 + w3;
    a0 *= r0; a1 *= r1; a2 *= r2; a3 *= r3;
    m0=n0; m1=n1; m2=n2; m3=n3;
    lds_s[wslot][lane] = s_l;
    lds_w[wslot][lane*4+0] = w0; lds_w[wslot][lane*4+1] = w1;
    lds_w[wslot][lane*4+2] = w2; lds_w[wslot][lane*4+3] = w3;
    int npad = (nch + U-1) & ~(U-1);
    for(int j = 0; j < npad; j += U){
      #pragma unroll
      for(int u = 0; u < U; u++){
        int s = lds_s[wslot][j+u];
        float p = b2f(proj[(size_t)s*64 + lane]);
        a0 += lds_w[wslot][(j+u)*4+0]*p;
        a1 += lds_w[wslot][(j+u)*4+1]*p;
        a2 += lds_w[wslot][(j+u)*4+2]*p;
        a3 += lds_w[wslot][(j+u)*4+3]*p;
      }
    }
  }
  #pragma unroll
  for(int off = 32; off; off >>= 1){
    sw0 += __shfl_xor(sw0, off); sw1 += __shfl_xor(sw1, off);
    sw2 += __shfl_xor(sw2, off); sw3 += __shfl_xor(sw3, off);
  }
  float d0 = (sw0 == 0.f) ? 1.f : sw0;
  float d1 = (sw1 == 0.f) ? 1.f : sw1;
  float d2 = (sw2 == 0.f) ? 1.f : sw2;
  float d3 = (sw3 == 0.f) ? 1.f : sw3;
  ushort* orow = aggv + (size_t)node*256;
  orow[lane]       = f2b(a0/d0);
  orow[64 + lane]  = f2b(a1/d1);
  orow[128 + lane] = f2b(a2/d2);
  orow[192 + lane] = f2b(a3/d3);
}

// ---------------- host orchestration ----------------
extern "C" void kernel_launch(void* const* d_in, const int* in_sizes, int n_in,
                              void* d_out, int out_size, void* d_ws, size_t ws_size,
                              hipStream_t stream){
  const float* hp   = (const float*)d_in[0];
  const float* hq   = (const float*)d_in[1];
  const float* hk   = (const float*)d_in[2];
  const float* ha   = (const float*)d_in[3];
  const int* meta_src = (const int*)d_in[4];
  const int* meta_dst = (const int*)d_in[5];
  const int* q_src = (const int*)d_in[6];
  const int* q_dst = (const int*)d_in[7];
  const int* k_src = (const int*)d_in[8];
  const int* k_dst = (const int*)d_in[9];
  const int* a_src = (const int*)d_in[10];
  const int* a_dst = (const int*)d_in[11];
  const float* W0  = (const float*)d_in[12]; const float* al0 = (const float*)d_in[13];
  const float* ar0 = (const float*)d_in[14]; const float* b0  = (const float*)d_in[15];
  const float* W1  = (const float*)d_in[16]; const float* al1 = (const float*)d_in[17];
  const float* ar1 = (const float*)d_in[18]; const float* b1  = (const float*)d_in[19];
  const float* Wq  = (const float*)d_in[20]; const float* alq = (const float*)d_in[21];
  const float* arq = (const float*)d_in[22]; const float* bq  = (const float*)d_in[23];
  const float* Wkw = (const float*)d_in[24]; const float* alkw= (const float*)d_in[25];
  const float* arkw= (const float*)d_in[26]; const float* bkw = (const float*)d_in[27];
  const float* Watt= (const float*)d_in[28]; const float* alatt=(const float*)d_in[29];
  const float* aratt=(const float*)d_in[30]; const float* batt= (const float*)d_in[31];
  const float* Wpnn_a = (const float*)d_in[32];
  const float* Wpn_a  = (const float*)d_in[33];
  const float* Wpnn   = (const float*)d_in[34];
  const float* Wpn    = (const float*)d_in[35];
  const float* Wpred  = (const float*)d_in[36];
  const float* bpred  = (const float*)d_in[37];
  (void)n_in; (void)out_size; (void)ws_size;

  const int IN = 128, ATT = 64;
  const int NP = in_sizes[0]/IN, NQ = in_sizes[1]/ATT, NK = in_sizes[2]/ATT, NA = in_sizes[3]/ATT;
  const int EM = in_sizes[4], EQ = in_sizes[6], EK = in_sizes[8], EA = in_sizes[10];

  const int range = (NP + 7)/8;   // even dst ranges -> balanced buckets

  // ----- workspace layout -----
  uint8_t* wp = (uint8_t*)d_ws;
  auto alloc = [&](size_t bytes)->uint8_t*{
    uint8_t* p = wp; wp += (bytes + 255) & ~(size_t)255; return p;
  };
  ushort* hcat_b = (ushort*)alloc((size_t)NP*256*2);
  ushort* hbuf_b = (ushort*)alloc((size_t)NP*128*2);
  ushort* hp_b   = (ushort*)alloc((size_t)NP*128*2);
  ushort* hpd_b  = (ushort*)alloc((size_t)NP*64*2);
  int NSmax = NQ > NK ? NQ : NK; if(NA > NSmax) NSmax = NA;
  ushort* proj_b = (ushort*)alloc((size_t)NSmax*64*2);
  ushort* fq_b   = (ushort*)alloc((size_t)NQ*64*2);
  ushort* fk_b   = (ushort*)alloc((size_t)NK*64*2);
  ushort* fa_b   = (ushort*)alloc((size_t)NA*64*2);
  float* el   = (float*)alloc((size_t)NP*4*4);
  float* er   = (float*)alloc((size_t)NP*4*4);
  float* wfa  = (float*)alloc(512*4);
  float* wfb  = (float*)alloc(512*4);
  int* cnt    = (int*)alloc((size_t)(NP+16)*4);   // +8 bucket cursors appended
  int* cursor = (int*)alloc((size_t)(NP+4)*4);
  int* ofsm   = (int*)alloc((size_t)(NP+4)*4);
  int* ofsq   = (int*)alloc((size_t)(NP+4)*4);
  int* ofsk   = (int*)alloc((size_t)(NP+4)*4);
  int* ofsa   = (int*)alloc((size_t)(NP+4)*4);
  int* colm   = (int*)alloc((size_t)EM*4);
  int* colq   = (int*)alloc((size_t)EQ*4);
  int* colk   = (int*)alloc((size_t)EK*4);
  int* cola   = (int*)alloc((size_t)EA*4);
  const int capM = EM/4 + 1024;
  int2* ebuf  = (int2*)alloc((size_t)8*capM*8);   // partition staging (max graph)
  ushort* W0T    = (ushort*)alloc(128*128*2);
  ushort* W1T    = (ushort*)alloc(128*128*2);
  ushort* WTg    = (ushort*)alloc((size_t)4*128*64*2);
  ushort* WpnT   = (ushort*)alloc((size_t)64*512*2);
  ushort* WpnnT  = (ushort*)alloc(64*128*2);
  ushort* Wpnn_aT= (ushort*)alloc(64*128*2);
  ushort* Wpn_aT = (ushort*)alloc(64*64*2);
  ushort* WpredT = (ushort*)alloc((size_t)1024*256*2);
  int* bcur = cnt + NP;  // 8 bucket cursors, zeroed together with cnt

  // big bf16 staging in d_out (dead until final GEMM writes it)
  ushort* o_b   = (ushort*)d_out;              // [NP,512]
  ushort* agg_b = o_b + (size_t)NP*512;        // [NP,256]
  ushort* hs_b  = agg_b + (size_t)NP*256;      // [NP,128] metapath hs

  auto cvt = [&](const float* in, ushort* out, size_t n){
    int n4 = (int)(n/4);
    f2b_vec<<<(n4+255)/256, 256, 0, stream>>>(in, out, n4);
  };
  auto wT = [&](const float* W, ushort* WT, int K, int N, int Npad){
    int tot = Npad*K;
    wT_k<<<(tot+255)/256, 256, 0, stream>>>(W, WT, K, N, Npad);
  };
  auto build = [&](const int* s, const int* d, int E, int* ofs, int* colv){
    const int cap = E/4 + 1024;
    fill_zero_i32<<<(NP+8+255)/256, 256, 0, stream>>>(cnt, NP+8);
    int pg = (E+255)/256; if(pg > 2048) pg = 2048;
    partition_k<<<pg, 256, 0, stream>>>(s, d, E, range, bcur, ebuf, cap);
    int J = E/65536 + 8; if(J > 48) J = 48;
    count_bucket_k<<<8*J, 256, 0, stream>>>(ebuf, cap, bcur, cnt);
    scan_excl_k<<<1, 1024, 0, stream>>>(cnt, ofs, cursor, NP);
    scatter_bucket_k<<<8*J, 256, 0, stream>>>(ebuf, cap, bcur, cursor, colv);
  };
  auto gemm = [&]<int BN, typename OutT, bool BIAS>(const ushort* A, const ushort* BT,
      const float* bias, OutT* C, int M, int N, int K, int lda, int ldc){
    int Npad = (N + BN - 1)/BN*BN;
    dim3 g((M + 127)/128, Npad/BN);
    gemm_mfma<BN, OutT, BIAS><<<g, 256, 0, stream>>>(A, BT, bias, C, M, N, K, lda, ldc);
  };

  // ----- CSR + conversions -----
  build(meta_src, meta_dst, EM, ofsm, colm);
  build(q_src, q_dst, EQ, ofsq, colq);
  build(k_src, k_dst, EK, ofsk, colk);
  build(a_src, a_dst, EA, ofsa, cola);
  cvt(hp, hp_b, (size_t)NP*128);
  cvt(hq, fq_b, (size_t)NQ*64);
  cvt(hk, fk_b, (size_t)NK*64);
  cvt(ha, fa_b, (size_t)NA*64);
  wT(W0, W0T, 128, 128, 128);      wT(W1, W1T, 128, 128, 128);
  wT(Wpn, WpnT, 512, 64, 64);      wT(Wpnn, WpnnT, 128, 64, 64);
  wT(Wpnn_a, Wpnn_aT, 128, 64, 64);wT(Wpn_a, Wpn_aT, 64, 64, 64);
  wT(Wpred, WpredT, 256, 1000, 1024);

  // ----- metapath GAT layer 0 -----
  gemm.template operator()<128, ushort, false>(hp_b, W0T, nullptr, hs_b, NP, 128, 128, 128, 128);
  fold_k<<<2, 256, 0, stream>>>(W0, al0, wfa, 128, 32);
  fold_k<<<2, 256, 0, stream>>>(W0, ar0, wfb, 128, 32);
  gemv8_t<float><<<(NP+3)/4, 256, 0, stream>>>(hp, wfa, wfb, el, er, NP, 128, 128);
  gat_agg2<32><<<(NP+3)/4, 256, 0, stream>>>(hs_b, el, er, ofsm, colm, b0, hbuf_b, NP);

  // ----- metapath GAT layer 1 -----
  gemm.template operator()<128, ushort, false>(hbuf_b, W1T, nullptr, hs_b, NP, 128, 128, 128, 128);
  fold_k<<<2, 256, 0, stream>>>(W1, al1, wfa, 128, 32);
  fold_k<<<2, 256, 0, stream>>>(W1, ar1, wfb, 128, 32);
  gemv8_t<ushort><<<(NP+3)/4, 256, 0, stream>>>(hbuf_b, wfa, wfb, el, er, NP, 128, 128);
  gat_agg2<32><<<(NP+3)/4, 256, 0, stream>>>(hs_b, el, er, ofsm, colm, b1, hbuf_b, NP);

  // ----- hcat[:,0:64] = h @ Wpnn ; hpd = hp @ Wpnn_a -----
  gemm.template operator()<64, ushort, false>(hbuf_b, WpnnT, nullptr, hcat_b, NP, 64, 128, 128, 256);
  gemm.template operator()<64, ushort, false>(hp_b, Wpnn_aT, nullptr, hpd_b, NP, 64, 128, 128, 64);

  // ----- bipartite GATs (proj-space aggregation + block-diag GEMM w/ fused bias+elu) -----
  auto bip = [&](const ushort* feat_b, int Ns, const int* ofs, const int* colv,
                 const float* W, const float* alp, const float* arp,
                 const float* bb, int colofs){
    gemm.template operator()<64, ushort, false>(feat_b, Wpn_aT, nullptr, proj_b, Ns, 64, 64, 64, 64);
    fold_k<<<1, 256, 0, stream>>>(W, alp, wfa, 64, 128);
    fold_k<<<1, 256, 0, stream>>>(W, arp, wfb, 64, 128);
    gemv4_t<ushort><<<(Ns+3)/4, 256, 0, stream>>>(proj_b, wfa, el, Ns, 64, 64);
    gemv4_t<ushort><<<(NP+3)/4, 256, 0, stream>>>(hpd_b, wfb, er, NP, 64, 64);
    gat_agg_proj<<<(NP+3)/4, 256, 0, stream>>>(proj_b, el, er, ofs, colv, agg_b, NP);
    wTg_k<<<(4*128*64+255)/256, 256, 0, stream>>>(W, WTg, 4, 128, 64, 512);
    dim3 g((NP+127)/128, 4);
    gemm_mfma<128, ushort, true, true, true><<<g, 256, 0, stream>>>(
        agg_b, WTg, bb, o_b, NP, 512, 64, 256, 512);
    gemm.template operator()<64, ushort, false>(o_b, WpnT, nullptr, hcat_b + colofs, NP, 64, 512, 512, 256);
  };
  bip(fq_b, NQ, ofsq, colq, Wq,  alq,  arq,  bq,  64);
  bip(fk_b, NK, ofsk, colk, Wkw, alkw, arkw, bkw, 128);
  bip(fa_b, NA, ofsa, cola, Watt,alatt,aratt,batt,192);

  // ----- final: out = hcat @ Wpred + bpred -----
  gemm.template operator()<128, float, true>(hcat_b, WpredT, bpred, (float*)d_out, NP, 1000, 256, 256, 1000);
}

// Round 8
// 978.258 us; speedup vs baseline: 1.3949x; 1.2753x over previous
//
#include <hip/hip_runtime.h>
#include <hip/hip_bf16.h>
#include <math.h>
#include <stdint.h>

typedef __attribute__((ext_vector_type(8))) short bh8;
typedef __attribute__((ext_vector_type(4))) float f32x4;

#define AS1(p) ((const __attribute__((address_space(1))) void*)(p))
#define AS3(p) ((__attribute__((address_space(3))) void*)(p))

__device__ inline ushort f2b(float f){
  uint u = __builtin_bit_cast(uint, f);
  u += 0x7fff + ((u >> 16) & 1);
  return (ushort)(u >> 16);
}
__device__ inline float b2f(ushort b){ return __builtin_bit_cast(float, (uint)b << 16); }

// ================= CSR build (all 4 graphs fused) =================
__global__ void fill_zero_i32(int* __restrict__ p, int n){
  int i = blockIdx.x*blockDim.x + threadIdx.x;
  if(i < n) p[i] = 0;
}

struct P4 { const int* src; const int* dst; int2* ebuf; int E; int cap; int bbeg; int bend; };

__global__ __launch_bounds__(256) void partition_all_k(P4 g0, P4 g1, P4 g2, P4 g3,
    int* __restrict__ bcur, int range){
  P4 G; int gi;
  int b = blockIdx.x;
  if(b < g0.bend){ G = g0; gi = 0; }
  else if(b < g1.bend){ G = g1; gi = 1; }
  else if(b < g2.bend){ G = g2; gi = 2; }
  else { G = g3; gi = 3; }
  const int lb = b - G.bbeg, nb = G.bend - G.bbeg;
  __shared__ int hist[8], base[8];
  const int tid = threadIdx.x;
  int* bc = bcur + gi*8;
  for(int c0 = lb*256; c0 < G.E; c0 += nb*256){
    int i = c0 + tid;
    int d = 0, s = 0, bk = -1;
    if(i < G.E){ d = G.dst[i]; s = G.src[i]; bk = d / range; }
    if(tid < 8) hist[tid] = 0;
    __syncthreads();
    int rank = 0;
    if(bk >= 0) rank = atomicAdd(&hist[bk], 1);
    __syncthreads();
    if(tid < 8) base[tid] = hist[tid] ? atomicAdd(&bc[tid], hist[tid]) : 0;
    __syncthreads();
    if(bk >= 0){
      int pos = base[bk] + rank;
      if(pos < G.cap) G.ebuf[(size_t)bk*G.cap + pos] = make_int2(d, s);
    }
    __syncthreads();
  }
}

struct B4 { const int2* ebuf; int cap; int* cnt; int bbeg; int bend; };
__global__ __launch_bounds__(256) void count_all_k(B4 g0, B4 g1, B4 g2, B4 g3,
    const int* __restrict__ bcur){
  B4 G; int gi;
  int b = blockIdx.x;
  if(b < g0.bend){ G = g0; gi = 0; }
  else if(b < g1.bend){ G = g1; gi = 1; }
  else if(b < g2.bend){ G = g2; gi = 2; }
  else { G = g3; gi = 3; }
  const int local = b - G.bbeg, J = (G.bend - G.bbeg) >> 3;
  const int bk = local & 7, j = local >> 3;
  int nb = bcur[gi*8 + bk]; if(nb > G.cap) nb = G.cap;
  const int2* eb = G.ebuf + (size_t)bk*G.cap;
  int per = (nb + J - 1)/J;
  int beg = j*per, end = beg + per; if(end > nb) end = nb;
  for(int i = beg + threadIdx.x; i < end; i += 256)
    atomicAdd(&G.cnt[eb[i].x], 1);
}

struct SB4 { const int2* ebuf; int cap; int* cursor; int* colv; int bbeg; int bend; };
__global__ __launch_bounds__(256) void scatter_all_k(SB4 g0, SB4 g1, SB4 g2, SB4 g3,
    const int* __restrict__ bcur){
  SB4 G; int gi;
  int b = blockIdx.x;
  if(b < g0.bend){ G = g0; gi = 0; }
  else if(b < g1.bend){ G = g1; gi = 1; }
  else if(b < g2.bend){ G = g2; gi = 2; }
  else { G = g3; gi = 3; }
  const int local = b - G.bbeg, J = (G.bend - G.bbeg) >> 3;
  const int bk = local & 7, j = local >> 3;
  int nb = bcur[gi*8 + bk]; if(nb > G.cap) nb = G.cap;
  const int2* eb = G.ebuf + (size_t)bk*G.cap;
  int per = (nb + J - 1)/J;
  int beg = j*per, end = beg + per; if(end > nb) end = nb;
  for(int i = beg + threadIdx.x; i < end; i += 256){
    int2 e = eb[i];
    int p = atomicAdd(&G.cursor[e.x], 1);
    G.colv[p] = e.y;
  }
}

// 4 independent exclusive scans, one block each (parallel across blocks)
__global__ __launch_bounds__(1024) void scan4_k(
    const int* c0, const int* c1, const int* c2, const int* c3,
    int* o0, int* o1, int* o2, int* o3,
    int* u0, int* u1, int* u2, int* u3, int n){
  const int* cnt = blockIdx.x==0?c0:(blockIdx.x==1?c1:(blockIdx.x==2?c2:c3));
  int* ofs    = blockIdx.x==0?o0:(blockIdx.x==1?o1:(blockIdx.x==2?o2:o3));
  int* cursor = blockIdx.x==0?u0:(blockIdx.x==1?u1:(blockIdx.x==2?u2:u3));
  __shared__ int wsum[16];
  __shared__ int carry_s;
  int tid = threadIdx.x, wid = tid >> 6, lane = tid & 63;
  if(tid == 0) carry_s = 0;
  __syncthreads();
  for(int base = 0; base < n; base += 4096){
    int i0 = base + tid*4;
    int4 v = make_int4(0,0,0,0);
    if(i0 + 3 < n) v = *(const int4*)(cnt + i0);
    else if(i0 < n){
      v.x = cnt[i0];
      if(i0+1 < n) v.y = cnt[i0+1];
      if(i0+2 < n) v.z = cnt[i0+2];
    }
    int s1 = v.x + v.y, s2 = s1 + v.z, tot = s2 + v.w;
    int x = tot;
    #pragma unroll
    for(int off = 1; off < 64; off <<= 1){
      int t = __shfl_up(x, off);
      if(lane >= off) x += t;
    }
    if(lane == 63) wsum[wid] = x;
    __syncthreads();
    if(tid < 16){
      int y = wsum[tid];
      #pragma unroll
      for(int off = 1; off < 16; off <<= 1){
        int t = __shfl_up(y, off);
        if(tid >= off) y += t;
      }
      wsum[tid] = y;
    }
    __syncthreads();
    int pre = (wid ? wsum[wid-1] : 0) + carry_s + (x - tot);
    if(i0 + 3 < n){
      int4 o = make_int4(pre, pre+v.x, pre+s1, pre+s2);
      *(int4*)(ofs + i0) = o;
      *(int4*)(cursor + i0) = o;
    } else if(i0 < n){
      ofs[i0] = pre; cursor[i0] = pre;
      if(i0+1 < n){ ofs[i0+1] = pre+v.x; cursor[i0+1] = pre+v.x; }
      if(i0+2 < n){ ofs[i0+2] = pre+s1; cursor[i0+2] = pre+s1; }
    }
    __syncthreads();
    if(tid == 0) carry_s += wsum[15];
    __syncthreads();
  }
  if(tid == 0) ofs[n] = carry_s;
}

// ================= preprocessing (fused) =================
// 4 fp32->bf16 segments in one kernel
__global__ void cvt_all_k(const float* i0, const float* i1, const float* i2, const float* i3,
    ushort* o0, ushort* o1, ushort* o2, ushort* o3, int4 cum){
  int i = blockIdx.x*blockDim.x + threadIdx.x;
  const float* in; ushort* out; int base;
  if(i < cum.x){ in=i0; out=o0; base=0; }
  else if(i < cum.y){ in=i1; out=o1; base=cum.x; }
  else if(i < cum.z){ in=i2; out=o2; base=cum.y; }
  else if(i < cum.w){ in=i3; out=o3; base=cum.z; }
  else return;
  int l = i - base;
  float4 v = ((const float4*)in)[l];
  ushort4 o; o.x=f2b(v.x); o.y=f2b(v.y); o.z=f2b(v.z); o.w=f2b(v.w);
  ((ushort4*)out)[l] = o;
}

struct WTD { const float* W; ushort* WT; int K; int N; };
struct WTAll { WTD d[7]; int cum[8]; };
__global__ void wT_all_k(WTAll a){
  int idx = blockIdx.x*blockDim.x + threadIdx.x;
  if(idx >= a.cum[7]) return;
  int j = 0;
  #pragma unroll
  for(int t = 1; t < 7; t++) if(idx >= a.cum[t]) j = t;
  int l = idx - a.cum[j];
  WTD d = a.d[j];
  int n = l / d.K, k = l - n*d.K;
  d.WT[l] = (n < d.N) ? f2b(d.W[(size_t)k*d.N + n]) : (ushort)0;
}

// 3 grouped transposes (Wq,Wkw,Watt): WT[g][h][n][k] = W_g[k][h*128+n], K=64
__global__ void wTg3_k(const float* W0, const float* W1, const float* W2, ushort* WT){
  int idx = blockIdx.x*blockDim.x + threadIdx.x;
  if(idx >= 3*32768) return;
  int g = idx >> 15, rem = idx & 32767;
  const float* W = g==0 ? W0 : (g==1 ? W1 : W2);
  int h = rem >> 13, r2 = rem & 8191;
  int n = r2 >> 6, k = r2 & 63;
  WT[idx] = f2b(W[(size_t)k*512 + h*128 + n]);
}

// 10 attention folds: out[k*4+h] = sum_d W[k][h*D+d]*a[h][d]
struct FD { const float* W; const float* a; float* out; int K; int D; };
struct FAll { FD d[10]; };
__global__ void fold_all_k(FAll f){
  FD d = f.d[blockIdx.x];
  for(int i = threadIdx.x; i < d.K*4; i += 256){
    int k = i >> 2, h = i & 3;
    const float* wr = d.W + (size_t)k*4*d.D + (size_t)h*d.D;
    const float* ar = d.a + (size_t)h*d.D;
    float s = 0.f;
    for(int dd = 0; dd < d.D; dd++) s += wr[dd]*ar[dd];
    d.out[i] = s;
  }
}

// ================= gemv (vector-load versions) =================
__device__ inline void ld4v(const float* p, float* v){
  float4 t = *(const float4*)p; v[0]=t.x; v[1]=t.y; v[2]=t.z; v[3]=t.w;
}
__device__ inline void ld4v(const ushort* p, float* v){
  ushort4 t = *(const ushort4*)p; v[0]=b2f(t.x); v[1]=b2f(t.y); v[2]=b2f(t.z); v[3]=b2f(t.w);
}

// K=64: 4 rows/wave (16 lanes x 4 elems each)
template<typename T>
__global__ __launch_bounds__(256) void gemv4v(const T* __restrict__ A,
    const float* __restrict__ Wf, float* __restrict__ outv, int M, int lda){
  const int w = (blockIdx.x*blockDim.x + threadIdx.x) >> 6;
  const int lane = threadIdx.x & 63;
  const int r = lane >> 4, q = lane & 15;
  int row = w*4 + r;
  bool valid = row < M;
  int rowc = valid ? row : (M-1);
  float av[4];
  ld4v(A + (size_t)rowc*lda + q*4, av);
  float a[4] = {0.f,0.f,0.f,0.f};
  #pragma unroll
  for(int kk = 0; kk < 4; kk++){
    float4 wv = *(const float4*)(Wf + (q*4+kk)*4);
    a[0] += av[kk]*wv.x; a[1] += av[kk]*wv.y; a[2] += av[kk]*wv.z; a[3] += av[kk]*wv.w;
  }
  #pragma unroll
  for(int off = 1; off < 16; off <<= 1){
    a[0] += __shfl_xor(a[0], off); a[1] += __shfl_xor(a[1], off);
    a[2] += __shfl_xor(a[2], off); a[3] += __shfl_xor(a[3], off);
  }
  if(valid && q == 0){
    float4 o; o.x=a[0]; o.y=a[1]; o.z=a[2]; o.w=a[3];
    *(float4*)(outv + (size_t)row*4) = o;
  }
}

// K=128, dual tables: 2 rows/wave (32 lanes x 4 elems each)
template<typename T>
__global__ __launch_bounds__(256) void gemv8v(const T* __restrict__ A,
    const float* __restrict__ Wfa, const float* __restrict__ Wfb,
    float* __restrict__ oa, float* __restrict__ ob, int M, int lda){
  const int w = (blockIdx.x*blockDim.x + threadIdx.x) >> 6;
  const int lane = threadIdx.x & 63;
  const int r = lane >> 5, q = lane & 31;
  int row = w*2 + r;
  bool valid = row < M;
  int rowc = valid ? row : (M-1);
  float av[4];
  ld4v(A + (size_t)rowc*lda + q*4, av);
  float a[4] = {0.f,0.f,0.f,0.f}, b[4] = {0.f,0.f,0.f,0.f};
  #pragma unroll
  for(int kk = 0; kk < 4; kk++){
    float4 wa = *(const float4*)(Wfa + (q*4+kk)*4);
    float4 wb = *(const float4*)(Wfb + (q*4+kk)*4);
    a[0] += av[kk]*wa.x; a[1] += av[kk]*wa.y; a[2] += av[kk]*wa.z; a[3] += av[kk]*wa.w;
    b[0] += av[kk]*wb.x; b[1] += av[kk]*wb.y; b[2] += av[kk]*wb.z; b[3] += av[kk]*wb.w;
  }
  #pragma unroll
  for(int off = 1; off < 32; off <<= 1){
    a[0] += __shfl_xor(a[0], off); a[1] += __shfl_xor(a[1], off);
    a[2] += __shfl_xor(a[2], off); a[3] += __shfl_xor(a[3], off);
    b[0] += __shfl_xor(b[0], off); b[1] += __shfl_xor(b[1], off);
    b[2] += __shfl_xor(b[2], off); b[3] += __shfl_xor(b[3], off);
  }
  if(valid && q == 0){
    float4 o; o.x=a[0]; o.y=a[1]; o.z=a[2]; o.w=a[3];
    *(float4*)(oa + (size_t)row*4) = o;
    float4 p; p.x=b[0]; p.y=b[1]; p.z=b[2]; p.w=b[3];
    *(float4*)(ob + (size_t)row*4) = p;
  }
}

// ================= bf16 MFMA GEMM =================
template<int BN, typename OutT, bool BIAS, bool GRP = false, bool ELU = false>
__global__ __launch_bounds__(256) void gemm_mfma(
    const ushort* __restrict__ A, const ushort* __restrict__ BT,
    const float* __restrict__ bias, OutT* __restrict__ C,
    int M, int N, int K, int lda, int ldc){
  constexpr int BM = 128, BK = 64;
  constexpr int NI = BN/32;
  constexpr int AIT = BM*BK/(256*8);
  constexpr int BIT = BN*BK/(256*8);
  __shared__ ushort lds[BM*BK + BN*BK];
  ushort* ldsA = lds;
  ushort* ldsB = lds + BM*BK;
  const int tid = threadIdx.x, wid = tid >> 6, lane = tid & 63;
  const int wr = wid >> 1, wc = wid & 1;
  const int rowbase = blockIdx.x*BM;
  const ushort* Ag = A;
  const ushort* Bg = BT;
  int colbase;
  if constexpr (GRP){
    const int hh = blockIdx.y;
    Ag = A + (size_t)hh*K;
    Bg = BT + (size_t)hh*BN*K;
    colbase = hh*BN;
  } else {
    colbase = blockIdx.y*BN;
  }

  f32x4 acc[4][NI];
  #pragma unroll
  for(int mi = 0; mi < 4; mi++)
    #pragma unroll
    for(int ni = 0; ni < NI; ni++) acc[mi][ni] = (f32x4)0.f;

  for(int k0 = 0; k0 < K; k0 += BK){
    #pragma unroll
    for(int it = 0; it < AIT; it++){
      int idx = it*256 + wid*64 + lane;
      int r = idx >> 3, sl = idx & 7;
      int kb = sl ^ (r & 7);
      int grow = rowbase + r; if(grow >= M) grow = M-1;
      const ushort* src = Ag + (size_t)grow*lda + k0 + kb*8;
      __builtin_amdgcn_global_load_lds(AS1(src), AS3(ldsA + (size_t)(it*256 + wid*64)*8), 16, 0, 0);
    }
    #pragma unroll
    for(int it = 0; it < BIT; it++){
      int idx = it*256 + wid*64 + lane;
      int r = idx >> 3, sl = idx & 7;
      int kb = sl ^ (r & 7);
      int brow = (GRP ? 0 : colbase) + r;
      const ushort* src = Bg + (size_t)brow*K + k0 + kb*8;
      __builtin_amdgcn_global_load_lds(AS1(src), AS3(ldsB + (size_t)(it*256 + wid*64)*8), 16, 0, 0);
    }
    __syncthreads();
    #pragma unroll
    for(int kk = 0; kk < 2; kk++){
      bh8 af[4], bf[NI];
      #pragma unroll
      for(int mi = 0; mi < 4; mi++){
        int arow = wr*64 + mi*16 + (lane & 15);
        int kb = kk*4 + (lane >> 4);
        af[mi] = *(const bh8*)(ldsA + arow*BK + ((kb ^ (arow & 7)) << 3));
      }
      #pragma unroll
      for(int ni = 0; ni < NI; ni++){
        int brow = wc*(BN/2) + ni*16 + (lane & 15);
        int kb = kk*4 + (lane >> 4);
        bf[ni] = *(const bh8*)(ldsB + brow*BK + ((kb ^ (brow & 7)) << 3));
      }
      #pragma unroll
      for(int mi = 0; mi < 4; mi++)
        #pragma unroll
        for(int ni = 0; ni < NI; ni++)
          acc[mi][ni] = __builtin_amdgcn_mfma_f32_16x16x32_bf16(af[mi], bf[ni], acc[mi][ni], 0, 0, 0);
    }
    __syncthreads();
  }
  #pragma unroll
  for(int mi = 0; mi < 4; mi++){
    #pragma unroll
    for(int ni = 0; ni < NI; ni++){
      int col = colbase + wc*(BN/2) + ni*16 + (lane & 15);
      if(col >= N) continue;
      float bv = BIAS ? bias[col] : 0.f;
      #pragma unroll
      for(int j = 0; j < 4; j++){
        int row = rowbase + wr*64 + mi*16 + (lane >> 4)*4 + j;
        if(row >= M) continue;
        float v = acc[mi][ni][j] + bv;
        if constexpr (ELU) v = v > 0.f ? v : (__expf(v) - 1.f);
        if constexpr (sizeof(OutT) == 4) C[(size_t)row*ldc + col] = v;
        else                             C[(size_t)row*ldc + col] = (OutT)f2b(v);
      }
    }
  }
}

// ================= metapath GAT aggregate (D=32, 128 feat) =================
// 16 lanes per edge x 16B -> 4 edges per load instruction; 8 edges per iteration.
__global__ __launch_bounds__(256) void gat_agg_meta(
    const ushort* __restrict__ hs, const float* __restrict__ el,
    const float* __restrict__ er, const int* __restrict__ ofs,
    const int* __restrict__ colv, const float* __restrict__ bias,
    ushort* __restrict__ outv, int Nd){
  const int wslot = threadIdx.x >> 6;
  const int node = blockIdx.x*4 + wslot;
  const int lane = threadIdx.x & 63;
  __shared__ int   lds_s[4][64];
  __shared__ float lds_w[4][256];
  if(node >= Nd) return;
  const int e0 = ofs[node], e1 = ofs[node+1];
  const int g = lane >> 4, q = lane & 15;
  const int hh = q >> 2;                 // head owning this lane's 8 dims
  const float4 erv = *(const float4*)(er + (size_t)node*4);
  float m0=-INFINITY, m1=-INFINITY, m2=-INFINITY, m3=-INFINITY;
  float sw0=0.f, sw1=0.f, sw2=0.f, sw3=0.f;
  float acc[8];
  #pragma unroll
  for(int r = 0; r < 8; r++) acc[r] = 0.f;

  for(int base = e0; base < e1; base += 64){
    int nch = e1 - base; if(nch > 64) nch = 64;
    int s_l = colv[base + (lane < nch ? lane : nch-1)];
    float4 ev = *(const float4*)(el + (size_t)s_l*4);
    float x0 = ev.x + erv.x; x0 = x0 > 0.f ? x0 : 0.2f*x0;
    float x1 = ev.y + erv.y; x1 = x1 > 0.f ? x1 : 0.2f*x1;
    float x2 = ev.z + erv.z; x2 = x2 > 0.f ? x2 : 0.2f*x2;
    float x3 = ev.w + erv.w; x3 = x3 > 0.f ? x3 : 0.2f*x3;
    if(lane >= nch){ x0 = x1 = x2 = x3 = -INFINITY; }
    float c0=x0, c1=x1, c2=x2, c3=x3;
    #pragma unroll
    for(int off = 32; off; off >>= 1){
      c0 = fmaxf(c0, __shfl_xor(c0, off));
      c1 = fmaxf(c1, __shfl_xor(c1, off));
      c2 = fmaxf(c2, __shfl_xor(c2, off));
      c3 = fmaxf(c3, __shfl_xor(c3, off));
    }
    float n0 = fmaxf(m0,c0), n1 = fmaxf(m1,c1), n2 = fmaxf(m2,c2), n3 = fmaxf(m3,c3);
    float r0 = __expf(m0-n0), r1 = __expf(m1-n1), r2 = __expf(m2-n2), r3 = __expf(m3-n3);
    float w0 = __expf(x0-n0), w1 = __expf(x1-n1), w2 = __expf(x2-n2), w3 = __expf(x3-n3);
    sw0 = sw0*r0 + w0; sw1 = sw1*r1 + w1; sw2 = sw2*r2 + w2; sw3 = sw3*r3 + w3;
    float rh = hh==0 ? r0 : (hh==1 ? r1 : (hh==2 ? r2 : r3));
    #pragma unroll
    for(int r = 0; r < 8; r++) acc[r] *= rh;
    m0=n0; m1=n1; m2=n2; m3=n3;
    lds_s[wslot][lane] = s_l;
    lds_w[wslot][lane*4+0] = w0; lds_w[wslot][lane*4+1] = w1;
    lds_w[wslot][lane*4+2] = w2; lds_w[wslot][lane*4+3] = w3;
    // padded entries (>=nch) have w==0 and valid clamped s -> safe to include
    int npad = (nch + 7) & ~7;
    for(int j = 0; j < npad; j += 8){
      int sA = lds_s[wslot][j + g];
      int sB = lds_s[wslot][j + 4 + g];
      float wA = lds_w[wslot][(j + g)*4 + hh];
      float wB = lds_w[wslot][(j + 4 + g)*4 + hh];
      bh8 vA = *(const bh8*)(hs + (size_t)sA*128 + q*8);
      bh8 vB = *(const bh8*)(hs + (size_t)sB*128 + q*8);
      #pragma unroll
      for(int r = 0; r < 8; r++) acc[r] += wA * b2f((ushort)vA[r]);
      #pragma unroll
      for(int r = 0; r < 8; r++) acc[r] += wB * b2f((ushort)vB[r]);
    }
  }
  #pragma unroll
  for(int off = 32; off; off >>= 1){
    sw0 += __shfl_xor(sw0, off); sw1 += __shfl_xor(sw1, off);
    sw2 += __shfl_xor(sw2, off); sw3 += __shfl_xor(sw3, off);
  }
  // merge the 4 edge-groups
  #pragma unroll
  for(int r = 0; r < 8; r++){
    acc[r] += __shfl_xor(acc[r], 16);
    acc[r] += __shfl_xor(acc[r], 32);
  }
  float swh = hh==0 ? sw0 : (hh==1 ? sw1 : (hh==2 ? sw2 : sw3));
  float den = (swh == 0.f) ? 1.f : swh;
  if(g == 0){
    bh8 ov;
    #pragma unroll
    for(int r = 0; r < 8; r++){
      float v = acc[r]/den + bias[q*8 + r];
      v = v > 0.f ? v : (__expf(v) - 1.f);
      ov[r] = (short)f2b(v);
    }
    *(bh8*)(outv + (size_t)node*128 + q*8) = ov;
  }
}

// ================= bipartite GAT aggregate in PROJ space (64 feat) =================
// 16 lanes per edge x 8B (4 dims) -> 4 edges per load instr; 8 edges/iter.
__global__ __launch_bounds__(256) void gat_agg_projv(
    const ushort* __restrict__ proj, const float* __restrict__ el,
    const float* __restrict__ er, const int* __restrict__ ofs,
    const int* __restrict__ colv, ushort* __restrict__ aggv, int Nd){
  const int wslot = threadIdx.x >> 6;
  const int node = blockIdx.x*4 + wslot;
  const int lane = threadIdx.x & 63;
  __shared__ int   lds_s[4][64];
  __shared__ float lds_w[4][256];
  if(node >= Nd) return;
  const int e0 = ofs[node], e1 = ofs[node+1];
  const int g = lane >> 4, q = lane & 15;   // 4 dims per lane: q*4..q*4+3
  const float4 erv = *(const float4*)(er + (size_t)node*4);
  float m0=-INFINITY, m1=-INFINITY, m2=-INFINITY, m3=-INFINITY;
  float sw0=0.f, sw1=0.f, sw2=0.f, sw3=0.f;
  float acc[4][4];   // [dim][head]
  #pragma unroll
  for(int d = 0; d < 4; d++)
    #pragma unroll
    for(int h = 0; h < 4; h++) acc[d][h] = 0.f;

  for(int base = e0; base < e1; base += 64){
    int nch = e1 - base; if(nch > 64) nch = 64;
    int s_l = colv[base + (lane < nch ? lane : nch-1)];
    float4 ev = *(const float4*)(el + (size_t)s_l*4);
    float x0 = ev.x + erv.x; x0 = x0 > 0.f ? x0 : 0.2f*x0;
    float x1 = ev.y + erv.y; x1 = x1 > 0.f ? x1 : 0.2f*x1;
    float x2 = ev.z + erv.z; x2 = x2 > 0.f ? x2 : 0.2f*x2;
    float x3 = ev.w + erv.w; x3 = x3 > 0.f ? x3 : 0.2f*x3;
    if(lane >= nch){ x0 = x1 = x2 = x3 = -INFINITY; }
    float c0=x0, c1=x1, c2=x2, c3=x3;
    #pragma unroll
    for(int off = 32; off; off >>= 1){
      c0 = fmaxf(c0, __shfl_xor(c0, off));
      c1 = fmaxf(c1, __shfl_xor(c1, off));
      c2 = fmaxf(c2, __shfl_xor(c2, off));
      c3 = fmaxf(c3, __shfl_xor(c3, off));
    }
    float n0 = fmaxf(m0,c0), n1 = fmaxf(m1,c1), n2 = fmaxf(m2,c2), n3 = fmaxf(m3,c3);
    float r0 = __expf(m0-n0), r1 = __expf(m1-n1), r2 = __expf(m2-n2), r3 = __expf(m3-n3);
    float w0 = __expf(x0-n0), w1 = __expf(x1-n1), w2 = __expf(x2-n2), w3 = __expf(x3-n3);
    sw0 = sw0*r0 + w0; sw1 = sw1*r1 + w1; sw2 = sw2*r2 + w2; sw3 = sw3*r3 + w3;
    #pragma unroll
    for(int d = 0; d < 4; d++){
      acc[d][0] *= r0; acc[d][1] *= r1; acc[d][2] *= r2; acc[d][3] *= r3;
    }
    m0=n0; m1=n1; m2=n2; m3=n3;
    lds_s[wslot][lane] = s_l;
    lds_w[wslot][lane*4+0] = w0; lds_w[wslot][lane*4+1] = w1;
    lds_w[wslot][lane*4+2] = w2; lds_w[wslot][lane*4+3] = w3;
    int npad = (nch + 7) & ~7;
    for(int j = 0; j < npad; j += 8){
      int sA = lds_s[wslot][j + g];
      int sB = lds_s[wslot][j + 4 + g];
      float4 wvA = *(const float4*)&lds_w[wslot][(j + g)*4];
      float4 wvB = *(const float4*)&lds_w[wslot][(j + 4 + g)*4];
      ushort4 pA = *(const ushort4*)(proj + (size_t)sA*64 + q*4);
      ushort4 pB = *(const ushort4*)(proj + (size_t)sB*64 + q*4);
      float fA[4] = {b2f(pA.x), b2f(pA.y), b2f(pA.z), b2f(pA.w)};
      float fB[4] = {b2f(pB.x), b2f(pB.y), b2f(pB.z), b2f(pB.w)};
      #pragma unroll
      for(int d = 0; d < 4; d++){
        acc[d][0] += wvA.x*fA[d]; acc[d][1] += wvA.y*fA[d];
        acc[d][2] += wvA.z*fA[d]; acc[d][3] += wvA.w*fA[d];
        acc[d][0] += wvB.x*fB[d]; acc[d][1] += wvB.y*fB[d];
        acc[d][2] += wvB.z*fB[d]; acc[d][3] += wvB.w*fB[d];
      }
    }
  }
  #pragma unroll
  for(int off = 32; off; off >>= 1){
    sw0 += __shfl_xor(sw0, off); sw1 += __shfl_xor(sw1, off);
    sw2 += __shfl_xor(sw2, off); sw3 += __shfl_xor(sw3, off);
  }
  #pragma unroll
  for(int d = 0; d < 4; d++)
    #pragma unroll
    for(int h = 0; h < 4; h++){
      acc[d][h] += __shfl_xor(acc[d][h], 16);
      acc[d][h] += __shfl_xor(acc[d][h], 32);
    }
  float dn[4];
  dn[0] = (sw0 == 0.f) ? 1.f : sw0;
  dn[1] = (sw1 == 0.f) ? 1.f : sw1;
  dn[2] = (sw2 == 0.f) ? 1.f : sw2;
  dn[3] = (sw3 == 0.f) ? 1.f : sw3;
  if(g == 0){
    ushort* orow = aggv + (size_t)node*256;
    #pragma unroll
    for(int h = 0; h < 4; h++){
      ushort4 o;
      o.x = f2b(acc[0][h]/dn[h]); o.y = f2b(acc[1][h]/dn[h]);
      o.z = f2b(acc[2][h]/dn[h]); o.w = f2b(acc[3][h]/dn[h]);
      *(ushort4*)(orow + h*64 + q*4) = o;
    }
  }
}

// ================= host orchestration =================
extern "C" void kernel_launch(void* const* d_in, const int* in_sizes, int n_in,
                              void* d_out, int out_size, void* d_ws, size_t ws_size,
                              hipStream_t stream){
  const float* hp   = (const float*)d_in[0];
  const float* hq   = (const float*)d_in[1];
  const float* hk   = (const float*)d_in[2];
  const float* ha   = (const float*)d_in[3];
  const int* meta_src = (const int*)d_in[4];
  const int* meta_dst = (const int*)d_in[5];
  const int* q_src = (const int*)d_in[6];
  const int* q_dst = (const int*)d_in[7];
  const int* k_src = (const int*)d_in[8];
  const int* k_dst = (const int*)d_in[9];
  const int* a_src = (const int*)d_in[10];
  const int* a_dst = (const int*)d_in[11];
  const float* W0  = (const float*)d_in[12]; const float* al0 = (const float*)d_in[13];
  const float* ar0 = (const float*)d_in[14]; const float* b0  = (const float*)d_in[15];
  const float* W1  = (const float*)d_in[16]; const float* al1 = (const float*)d_in[17];
  const float* ar1 = (const float*)d_in[18]; const float* b1  = (const float*)d_in[19];
  const float* Wq  = (const float*)d_in[20]; const float* alq = (const float*)d_in[21];
  const float* arq = (const float*)d_in[22]; const float* bq  = (const float*)d_in[23];
  const float* Wkw = (const float*)d_in[24]; const float* alkw= (const float*)d_in[25];
  const float* arkw= (const float*)d_in[26]; const float* bkw = (const float*)d_in[27];
  const float* Watt= (const float*)d_in[28]; const float* alatt=(const float*)d_in[29];
  const float* aratt=(const float*)d_in[30]; const float* batt= (const float*)d_in[31];
  const float* Wpnn_a = (const float*)d_in[32];
  const float* Wpn_a  = (const float*)d_in[33];
  const float* Wpnn   = (const float*)d_in[34];
  const float* Wpn    = (const float*)d_in[35];
  const float* Wpred  = (const float*)d_in[36];
  const float* bpred  = (const float*)d_in[37];
  (void)n_in; (void)out_size; (void)ws_size;

  const int IN = 128, ATT = 64;
  const int NP = in_sizes[0]/IN, NQ = in_sizes[1]/ATT, NK = in_sizes[2]/ATT, NA = in_sizes[3]/ATT;
  const int EM = in_sizes[4], EQ = in_sizes[6], EK = in_sizes[8], EA = in_sizes[10];
  const int range = (NP + 7)/8;

  // ----- workspace layout -----
  uint8_t* wp = (uint8_t*)d_ws;
  auto alloc = [&](size_t bytes)->uint8_t*{
    uint8_t* p = wp; wp += (bytes + 255) & ~(size_t)255; return p;
  };
  ushort* hcat_b = (ushort*)alloc((size_t)NP*256*2);
  ushort* hbuf_b = (ushort*)alloc((size_t)NP*128*2);
  ushort* hp_b   = (ushort*)alloc((size_t)NP*128*2);
  ushort* hpd_b  = (ushort*)alloc((size_t)NP*64*2);
  int NSmax = NQ > NK ? NQ : NK; if(NA > NSmax) NSmax = NA;
  ushort* proj_b = (ushort*)alloc((size_t)NSmax*64*2);
  ushort* fq_b   = (ushort*)alloc((size_t)NQ*64*2);
  ushort* fk_b   = (ushort*)alloc((size_t)NK*64*2);
  ushort* fa_b   = (ushort*)alloc((size_t)NA*64*2);
  float* el   = (float*)alloc((size_t)NP*4*4);
  float* er   = (float*)alloc((size_t)NP*4*4);
  float* wf   = (float*)alloc((size_t)10*512*4);
  int* cnt4   = (int*)alloc((size_t)(4*NP+32)*4);    // 4 cnt arrays + 32 bucket cursors
  int* bcur   = cnt4 + 4*NP;
  int* cur4   = (int*)alloc((size_t)4*NP*4);
  int* ofsm   = (int*)alloc((size_t)(NP+4)*4);
  int* ofsq   = (int*)alloc((size_t)(NP+4)*4);
  int* ofsk   = (int*)alloc((size_t)(NP+4)*4);
  int* ofsa   = (int*)alloc((size_t)(NP+4)*4);
  int* colm   = (int*)alloc((size_t)EM*4);
  int* colq   = (int*)alloc((size_t)EQ*4);
  int* colk   = (int*)alloc((size_t)EK*4);
  int* cola   = (int*)alloc((size_t)EA*4);
  const int capM = EM/4+1024, capQ = EQ/4+1024, capK = EK/4+1024, capA = EA/4+1024;
  int2* ebm = (int2*)alloc((size_t)8*capM*8);
  int2* ebq = (int2*)alloc((size_t)8*capQ*8);
  int2* ebk = (int2*)alloc((size_t)8*capK*8);
  int2* eba = (int2*)alloc((size_t)8*capA*8);
  ushort* W0T    = (ushort*)alloc(128*128*2);
  ushort* W1T    = (ushort*)alloc(128*128*2);
  ushort* WTg3   = (ushort*)alloc((size_t)3*4*128*64*2);
  ushort* WpnT   = (ushort*)alloc((size_t)64*512*2);
  ushort* WpnnT  = (ushort*)alloc(64*128*2);
  ushort* Wpnn_aT= (ushort*)alloc(64*128*2);
  ushort* Wpn_aT = (ushort*)alloc(64*64*2);
  ushort* WpredT = (ushort*)alloc((size_t)1024*256*2);

  // big bf16 staging in d_out (dead until final GEMM writes it)
  ushort* o_b   = (ushort*)d_out;              // [NP,512]
  ushort* agg_b = o_b + (size_t)NP*512;        // [NP,256]
  ushort* hs_b  = agg_b + (size_t)NP*256;      // [NP,128] metapath hs

  // ----- CSR build (5 dispatches) -----
  fill_zero_i32<<<(4*NP+32+255)/256, 256, 0, stream>>>(cnt4, 4*NP+32);
  {
    int bm = EM/1024 + 1, bq2 = EQ/1024 + 1, bk2 = EK/1024 + 1, ba2 = EA/1024 + 1;
    P4 g0{meta_src, meta_dst, ebm, EM, capM, 0, bm};
    P4 g1{q_src, q_dst, ebq, EQ, capQ, bm, bm+bq2};
    P4 g2{k_src, k_dst, ebk, EK, capK, bm+bq2, bm+bq2+bk2};
    P4 g3{a_src, a_dst, eba, EA, capA, bm+bq2+bk2, bm+bq2+bk2+ba2};
    partition_all_k<<<g3.bend, 256, 0, stream>>>(g0, g1, g2, g3, bcur, range);
  }
  auto Jof = [&](int E){ int J = E/65536 + 8; if(J > 48) J = 48; return J; };
  {
    int jm = 8*Jof(EM), jq = 8*Jof(EQ), jk = 8*Jof(EK), ja = 8*Jof(EA);
    B4 g0{ebm, capM, cnt4 + 0*NP, 0, jm};
    B4 g1{ebq, capQ, cnt4 + 1*NP, jm, jm+jq};
    B4 g2{ebk, capK, cnt4 + 2*NP, jm+jq, jm+jq+jk};
    B4 g3{eba, capA, cnt4 + 3*NP, jm+jq+jk, jm+jq+jk+ja};
    count_all_k<<<g3.bend, 256, 0, stream>>>(g0, g1, g2, g3, bcur);
    scan4_k<<<4, 1024, 0, stream>>>(cnt4, cnt4+NP, cnt4+2*NP, cnt4+3*NP,
                                    ofsm, ofsq, ofsk, ofsa,
                                    cur4, cur4+NP, cur4+2*NP, cur4+3*NP, NP);
    SB4 s0{ebm, capM, cur4 + 0*NP, colm, 0, jm};
    SB4 s1{ebq, capQ, cur4 + 1*NP, colq, jm, jm+jq};
    SB4 s2{ebk, capK, cur4 + 2*NP, colk, jm+jq, jm+jq+jk};
    SB4 s3{eba, capA, cur4 + 3*NP, cola, jm+jq+jk, jm+jq+jk+ja};
    scatter_all_k<<<s3.bend, 256, 0, stream>>>(s0, s1, s2, s3, bcur);
  }

  // ----- conversions + weight prep (4 dispatches) -----
  {
    int c0 = NP*128/4, c1 = c0 + NQ*64/4, c2 = c1 + NK*64/4, c3 = c2 + NA*64/4;
    cvt_all_k<<<(c3+255)/256, 256, 0, stream>>>(hp, hq, hk, ha, hp_b, fq_b, fk_b, fa_b,
                                                make_int4(c0, c1, c2, c3));
  }
  {
    WTAll a;
    a.d[0] = {W0, W0T, 128, 128};      a.d[1] = {W1, W1T, 128, 128};
    a.d[2] = {Wpn, WpnT, 512, 64};     a.d[3] = {Wpnn, WpnnT, 128, 64};
    a.d[4] = {Wpnn_a, Wpnn_aT, 128, 64}; a.d[5] = {Wpn_a, Wpn_aT, 64, 64};
    a.d[6] = {Wpred, WpredT, 256, 1000};
    int items[7] = {128*128, 128*128, 64*512, 64*128, 64*128, 64*64, 1024*256};
    a.cum[0] = 0;
    for(int t = 0; t < 7; t++) a.cum[t+1] = a.cum[t] + items[t];
    wT_all_k<<<(a.cum[7]+255)/256, 256, 0, stream>>>(a);
  }
  wTg3_k<<<(3*32768+255)/256, 256, 0, stream>>>(Wq, Wkw, Watt, WTg3);
  {
    FAll f;
    f.d[0] = {W0, al0, wf+0*512, 128, 32};  f.d[1] = {W0, ar0, wf+1*512, 128, 32};
    f.d[2] = {W1, al1, wf+2*512, 128, 32};  f.d[3] = {W1, ar1, wf+3*512, 128, 32};
    f.d[4] = {Wq, alq, wf+4*512, 64, 128};  f.d[5] = {Wq, arq, wf+5*512, 64, 128};
    f.d[6] = {Wkw, alkw, wf+6*512, 64, 128};f.d[7] = {Wkw, arkw, wf+7*512, 64, 128};
    f.d[8] = {Watt, alatt, wf+8*512, 64, 128};f.d[9] = {Watt, aratt, wf+9*512, 64, 128};
    fold_all_k<<<10, 256, 0, stream>>>(f);
  }

  auto gemm = [&]<int BN, typename OutT, bool BIAS>(const ushort* A, const ushort* BT,
      const float* bias, OutT* C, int M, int N, int K, int lda, int ldc){
    int Npad = (N + BN - 1)/BN*BN;
    dim3 g((M + 127)/128, Npad/BN);
    gemm_mfma<BN, OutT, BIAS><<<g, 256, 0, stream>>>(A, BT, bias, C, M, N, K, lda, ldc);
  };

  // ----- metapath GAT layer 0 -----
  gemm.template operator()<128, ushort, false>(hp_b, W0T, nullptr, hs_b, NP, 128, 128, 128, 128);
  gemv8v<float><<<(NP/2+3)/4, 256, 0, stream>>>(hp, wf+0*512, wf+1*512, el, er, NP, 128);
  gat_agg_meta<<<(NP+3)/4, 256, 0, stream>>>(hs_b, el, er, ofsm, colm, b0, hbuf_b, NP);

  // ----- metapath GAT layer 1 -----
  gemm.template operator()<128, ushort, false>(hbuf_b, W1T, nullptr, hs_b, NP, 128, 128, 128, 128);
  gemv8v<ushort><<<(NP/2+3)/4, 256, 0, stream>>>(hbuf_b, wf+2*512, wf+3*512, el, er, NP, 128);
  gat_agg_meta<<<(NP+3)/4, 256, 0, stream>>>(hs_b, el, er, ofsm, colm, b1, hbuf_b, NP);

  // ----- hcat[:,0:64] = h @ Wpnn ; hpd = hp @ Wpnn_a -----
  gemm.template operator()<64, ushort, false>(hbuf_b, WpnnT, nullptr, hcat_b, NP, 64, 128, 128, 256);
  gemm.template operator()<64, ushort, false>(hp_b, Wpnn_aT, nullptr, hpd_b, NP, 64, 128, 128, 64);

  // ----- bipartite GATs -----
  auto bip = [&](const ushort* feat_b, int Ns, const int* ofs, const int* colv,
                 int wfi, const ushort* WTg_, const float* bb, int colofs){
    gemm.template operator()<64, ushort, false>(feat_b, Wpn_aT, nullptr, proj_b, Ns, 64, 64, 64, 64);
    gemv4v<ushort><<<(Ns/4+3)/4, 256, 0, stream>>>(proj_b, wf+wfi*512, el, Ns, 64);
    gemv4v<ushort><<<(NP/4+3)/4, 256, 0, stream>>>(hpd_b, wf+(wfi+1)*512, er, NP, 64);
    gat_agg_projv<<<(NP+3)/4, 256, 0, stream>>>(proj_b, el, er, ofs, colv, agg_b, NP);
    dim3 g((NP+127)/128, 4);
    gemm_mfma<128, ushort, true, true, true><<<g, 256, 0, stream>>>(
        agg_b, WTg_, bb, o_b, NP, 512, 64, 256, 512);
    gemm.template operator()<64, ushort, false>(o_b, WpnT, nullptr, hcat_b + colofs, NP, 64, 512, 512, 256);
  };
  bip(fq_b, NQ, ofsq, colq, 4, WTg3 + 0*32768, bq,  64);
  bip(fk_b, NK, ofsk, colk, 6, WTg3 + 1*32768, bkw, 128);
  bip(fa_b, NA, ofsa, cola, 8, WTg3 + 2*32768, batt,192);

  // ----- final: out = hcat @ Wpred + bpred -----
  gemm.template operator()<128, float, true>(hcat_b, WpredT, bpred, (float*)d_out, NP, 1000, 256, 256, 1000);
}

// Round 9
// 930.714 us; speedup vs baseline: 1.4662x; 1.0511x over previous
//
#include <hip/hip_runtime.h>
#include <hip/hip_bf16.h>
#include <math.h>
#include <stdint.h>

typedef __attribute__((ext_vector_type(8))) short bh8;
typedef __attribute__((ext_vector_type(4))) float f32x4;

#define AS1(p) ((const __attribute__((address_space(1))) void*)(p))
#define AS3(p) ((__attribute__((address_space(3))) void*)(p))

__device__ inline ushort f2b(float f){
  uint u = __builtin_bit_cast(uint, f);
  u += 0x7fff + ((u >> 16) & 1);
  return (ushort)(u >> 16);
}
__device__ inline float b2f(ushort b){ return __builtin_bit_cast(float, (uint)b << 16); }

// ================= CSR build (all 4 graphs fused, packed staging) =================
// packed edge: u = (src<<13) | (dst - bucket*range); requires range<=8192, src<2^19.
__global__ void fill_zero_i32(int* __restrict__ p, int n){
  int i = blockIdx.x*blockDim.x + threadIdx.x;
  if(i < n) p[i] = 0;
}

struct P4 { const int* src; const int* dst; uint* ebuf; int E; int cap; int bbeg; int bend; };

__global__ __launch_bounds__(256) void partition_all_k(P4 g0, P4 g1, P4 g2, P4 g3,
    int* __restrict__ bcur, int range){
  P4 G; int gi;
  int b = blockIdx.x;
  if(b < g0.bend){ G = g0; gi = 0; }
  else if(b < g1.bend){ G = g1; gi = 1; }
  else if(b < g2.bend){ G = g2; gi = 2; }
  else { G = g3; gi = 3; }
  const int lb = b - G.bbeg, nb = G.bend - G.bbeg;
  __shared__ int hist[8], base[8];
  const int tid = threadIdx.x;
  int* bc = bcur + gi*8;
  for(int c0 = lb*256; c0 < G.E; c0 += nb*256){
    int i = c0 + tid;
    int d = 0, s = 0, bk = -1;
    if(i < G.E){ d = G.dst[i]; s = G.src[i]; bk = d / range; }
    if(tid < 8) hist[tid] = 0;
    __syncthreads();
    int rank = 0;
    if(bk >= 0) rank = atomicAdd(&hist[bk], 1);
    __syncthreads();
    if(tid < 8) base[tid] = hist[tid] ? atomicAdd(&bc[tid], hist[tid]) : 0;
    __syncthreads();
    if(bk >= 0){
      int pos = base[bk] + rank;
      if(pos < G.cap) G.ebuf[(size_t)bk*G.cap + pos] = ((uint)s << 13) | (uint)(d - bk*range);
    }
    __syncthreads();
  }
}

struct B4 { const uint* ebuf; int cap; int* cnt; int bbeg; int bend; };
__global__ __launch_bounds__(256) void count_all_k(B4 g0, B4 g1, B4 g2, B4 g3,
    const int* __restrict__ bcur, int range){
  B4 G; int gi;
  int b = blockIdx.x;
  if(b < g0.bend){ G = g0; gi = 0; }
  else if(b < g1.bend){ G = g1; gi = 1; }
  else if(b < g2.bend){ G = g2; gi = 2; }
  else { G = g3; gi = 3; }
  const int local = b - G.bbeg, J = (G.bend - G.bbeg) >> 3;
  const int bk = local & 7, j = local >> 3;
  int nb = bcur[gi*8 + bk]; if(nb > G.cap) nb = G.cap;
  const uint* eb = G.ebuf + (size_t)bk*G.cap;
  int* cb = G.cnt + bk*range;
  int per = (nb + J - 1)/J;
  int beg = j*per, end = beg + per; if(end > nb) end = nb;
  for(int i = beg + threadIdx.x; i < end; i += 256)
    atomicAdd(&cb[eb[i] & 8191u], 1);
}

struct SB4 { const uint* ebuf; int cap; int* cursor; int* colv; int bbeg; int bend; };
__global__ __launch_bounds__(256) void scatter_all_k(SB4 g0, SB4 g1, SB4 g2, SB4 g3,
    const int* __restrict__ bcur, int range){
  SB4 G; int gi;
  int b = blockIdx.x;
  if(b < g0.bend){ G = g0; gi = 0; }
  else if(b < g1.bend){ G = g1; gi = 1; }
  else if(b < g2.bend){ G = g2; gi = 2; }
  else { G = g3; gi = 3; }
  const int local = b - G.bbeg, J = (G.bend - G.bbeg) >> 3;
  const int bk = local & 7, j = local >> 3;
  int nb = bcur[gi*8 + bk]; if(nb > G.cap) nb = G.cap;
  const uint* eb = G.ebuf + (size_t)bk*G.cap;
  int* ub = G.cursor + bk*range;
  int per = (nb + J - 1)/J;
  int beg = j*per, end = beg + per; if(end > nb) end = nb;
  for(int i = beg + threadIdx.x; i < end; i += 256){
    uint e = eb[i];
    int p = atomicAdd(&ub[e & 8191u], 1);
    G.colv[p] = (int)(e >> 13);
  }
}

// 4 independent exclusive scans, one block each
__global__ __launch_bounds__(1024) void scan4_k(
    const int* c0, const int* c1, const int* c2, const int* c3,
    int* o0, int* o1, int* o2, int* o3,
    int* u0, int* u1, int* u2, int* u3, int n){
  const int* cnt = blockIdx.x==0?c0:(blockIdx.x==1?c1:(blockIdx.x==2?c2:c3));
  int* ofs    = blockIdx.x==0?o0:(blockIdx.x==1?o1:(blockIdx.x==2?o2:o3));
  int* cursor = blockIdx.x==0?u0:(blockIdx.x==1?u1:(blockIdx.x==2?u2:u3));
  __shared__ int wsum[16];
  __shared__ int carry_s;
  int tid = threadIdx.x, wid = tid >> 6, lane = tid & 63;
  if(tid == 0) carry_s = 0;
  __syncthreads();
  for(int base = 0; base < n; base += 4096){
    int i0 = base + tid*4;
    int4 v = make_int4(0,0,0,0);
    if(i0 + 3 < n) v = *(const int4*)(cnt + i0);
    else if(i0 < n){
      v.x = cnt[i0];
      if(i0+1 < n) v.y = cnt[i0+1];
      if(i0+2 < n) v.z = cnt[i0+2];
    }
    int s1 = v.x + v.y, s2 = s1 + v.z, tot = s2 + v.w;
    int x = tot;
    #pragma unroll
    for(int off = 1; off < 64; off <<= 1){
      int t = __shfl_up(x, off);
      if(lane >= off) x += t;
    }
    if(lane == 63) wsum[wid] = x;
    __syncthreads();
    if(tid < 16){
      int y = wsum[tid];
      #pragma unroll
      for(int off = 1; off < 16; off <<= 1){
        int t = __shfl_up(y, off);
        if(tid >= off) y += t;
      }
      wsum[tid] = y;
    }
    __syncthreads();
    int pre = (wid ? wsum[wid-1] : 0) + carry_s + (x - tot);
    if(i0 + 3 < n){
      int4 o = make_int4(pre, pre+v.x, pre+s1, pre+s2);
      *(int4*)(ofs + i0) = o;
      *(int4*)(cursor + i0) = o;
    } else if(i0 < n){
      ofs[i0] = pre; cursor[i0] = pre;
      if(i0+1 < n){ ofs[i0+1] = pre+v.x; cursor[i0+1] = pre+v.x; }
      if(i0+2 < n){ ofs[i0+2] = pre+s1; cursor[i0+2] = pre+s1; }
    }
    __syncthreads();
    if(tid == 0) carry_s += wsum[15];
    __syncthreads();
  }
  if(tid == 0) ofs[n] = carry_s;
}

// ================= preprocessing (fused) =================
__global__ void cvt_all_k(const float* i0, const float* i1,
    ushort* o0, ushort* o1, int2 cum){
  int i = blockIdx.x*blockDim.x + threadIdx.x;
  const float* in; ushort* out; int base;
  if(i < cum.x){ in=i0; out=o0; base=0; }
  else if(i < cum.y){ in=i1; out=o1; base=cum.x; }
  else return;
  int l = i - base;
  float4 v = ((const float4*)in)[l];
  ushort4 o; o.x=f2b(v.x); o.y=f2b(v.y); o.z=f2b(v.z); o.w=f2b(v.w);
  ((ushort4*)out)[l] = o;
}

struct WTD { const float* W; ushort* WT; int K; int N; };
struct WTAll { WTD d[7]; int cum[8]; };
__global__ void wT_all_k(WTAll a){
  int idx = blockIdx.x*blockDim.x + threadIdx.x;
  if(idx >= a.cum[7]) return;
  int j = 0;
  #pragma unroll
  for(int t = 1; t < 7; t++) if(idx >= a.cum[t]) j = t;
  int l = idx - a.cum[j];
  WTD d = a.d[j];
  int n = l / d.K, k = l - n*d.K;
  d.WT[l] = (n < d.N) ? f2b(d.W[(size_t)k*d.N + n]) : (ushort)0;
}

__global__ void wTg3_k(const float* W0, const float* W1, const float* W2, ushort* WT){
  int idx = blockIdx.x*blockDim.x + threadIdx.x;
  if(idx >= 3*32768) return;
  int g = idx >> 15, rem = idx & 32767;
  const float* W = g==0 ? W0 : (g==1 ? W1 : W2);
  int h = rem >> 13, r2 = rem & 8191;
  int n = r2 >> 6, k = r2 & 63;
  WT[idx] = f2b(W[(size_t)k*512 + h*128 + n]);
}

struct FD { const float* W; const float* a; float* out; int K; int D; };
struct FAll { FD d[10]; };
__global__ void fold_all_k(FAll f){
  FD d = f.d[blockIdx.x];
  for(int i = threadIdx.x; i < d.K*4; i += 256){
    int k = i >> 2, h = i & 3;
    const float* wr = d.W + (size_t)k*4*d.D + (size_t)h*d.D;
    const float* ar = d.a + (size_t)h*d.D;
    float s = 0.f;
    for(int dd = 0; dd < d.D; dd++) s += wr[dd]*ar[dd];
    d.out[i] = s;
  }
}

// ================= gemv =================
__device__ inline void ld4v(const float* p, float* v){
  float4 t = *(const float4*)p; v[0]=t.x; v[1]=t.y; v[2]=t.z; v[3]=t.w;
}
__device__ inline void ld4v(const ushort* p, float* v){
  ushort4 t = *(const ushort4*)p; v[0]=b2f(t.x); v[1]=b2f(t.y); v[2]=b2f(t.z); v[3]=b2f(t.w);
}

// K=64, 3 row-segments with per-segment weight tables (bip el)
__global__ __launch_bounds__(256) void gemv4v_seg3(const ushort* __restrict__ A,
    const float* __restrict__ W0, const float* __restrict__ W1, const float* __restrict__ W2,
    float* __restrict__ outv, int M, int b1, int b2){
  const int w = (blockIdx.x*blockDim.x + threadIdx.x) >> 6;
  const int lane = threadIdx.x & 63;
  const int r = lane >> 4, q = lane & 15;
  int row = w*4 + r;
  bool valid = row < M;
  int rowc = valid ? row : (M-1);
  const float* Wf = rowc < b1 ? W0 : (rowc < b2 ? W1 : W2);
  float av[4];
  ld4v(A + (size_t)rowc*64 + q*4, av);
  float a[4] = {0.f,0.f,0.f,0.f};
  #pragma unroll
  for(int kk = 0; kk < 4; kk++){
    float4 wv = *(const float4*)(Wf + (q*4+kk)*4);
    a[0] += av[kk]*wv.x; a[1] += av[kk]*wv.y; a[2] += av[kk]*wv.z; a[3] += av[kk]*wv.w;
  }
  #pragma unroll
  for(int off = 1; off < 16; off <<= 1){
    a[0] += __shfl_xor(a[0], off); a[1] += __shfl_xor(a[1], off);
    a[2] += __shfl_xor(a[2], off); a[3] += __shfl_xor(a[3], off);
  }
  if(valid && q == 0){
    float4 o; o.x=a[0]; o.y=a[1]; o.z=a[2]; o.w=a[3];
    *(float4*)(outv + (size_t)row*4) = o;
  }
}

// K=64, one input, 3 tables -> 3 outputs (bip er, reads hpd once)
__global__ __launch_bounds__(256) void gemv4v_er3(const ushort* __restrict__ A,
    const float* __restrict__ W0, const float* __restrict__ W1, const float* __restrict__ W2,
    float* __restrict__ o0, float* __restrict__ o1, float* __restrict__ o2, int M){
  const int w = (blockIdx.x*blockDim.x + threadIdx.x) >> 6;
  const int lane = threadIdx.x & 63;
  const int r = lane >> 4, q = lane & 15;
  int row = w*4 + r;
  bool valid = row < M;
  int rowc = valid ? row : (M-1);
  float av[4];
  ld4v(A + (size_t)rowc*64 + q*4, av);
  float a[12];
  #pragma unroll
  for(int t = 0; t < 12; t++) a[t] = 0.f;
  #pragma unroll
  for(int kk = 0; kk < 4; kk++){
    float4 w0 = *(const float4*)(W0 + (q*4+kk)*4);
    float4 w1 = *(const float4*)(W1 + (q*4+kk)*4);
    float4 w2 = *(const float4*)(W2 + (q*4+kk)*4);
    a[0] += av[kk]*w0.x; a[1] += av[kk]*w0.y; a[2] += av[kk]*w0.z; a[3] += av[kk]*w0.w;
    a[4] += av[kk]*w1.x; a[5] += av[kk]*w1.y; a[6] += av[kk]*w1.z; a[7] += av[kk]*w1.w;
    a[8] += av[kk]*w2.x; a[9] += av[kk]*w2.y; a[10]+= av[kk]*w2.z; a[11]+= av[kk]*w2.w;
  }
  #pragma unroll
  for(int off = 1; off < 16; off <<= 1)
    #pragma unroll
    for(int t = 0; t < 12; t++) a[t] += __shfl_xor(a[t], off);
  if(valid && q == 0){
    float4 x; x.x=a[0]; x.y=a[1]; x.z=a[2]; x.w=a[3];
    *(float4*)(o0 + (size_t)row*4) = x;
    float4 y; y.x=a[4]; y.y=a[5]; y.z=a[6]; y.w=a[7];
    *(float4*)(o1 + (size_t)row*4) = y;
    float4 z; z.x=a[8]; z.y=a[9]; z.z=a[10]; z.w=a[11];
    *(float4*)(o2 + (size_t)row*4) = z;
  }
}

// K=128, dual tables: 2 rows/wave (metapath el+er)
template<typename T>
__global__ __launch_bounds__(256) void gemv8v(const T* __restrict__ A,
    const float* __restrict__ Wfa, const float* __restrict__ Wfb,
    float* __restrict__ oa, float* __restrict__ ob, int M, int lda){
  const int w = (blockIdx.x*blockDim.x + threadIdx.x) >> 6;
  const int lane = threadIdx.x & 63;
  const int r = lane >> 5, q = lane & 31;
  int row = w*2 + r;
  bool valid = row < M;
  int rowc = valid ? row : (M-1);
  float av[4];
  ld4v(A + (size_t)rowc*lda + q*4, av);
  float a[4] = {0.f,0.f,0.f,0.f}, b[4] = {0.f,0.f,0.f,0.f};
  #pragma unroll
  for(int kk = 0; kk < 4; kk++){
    float4 wa = *(const float4*)(Wfa + (q*4+kk)*4);
    float4 wb = *(const float4*)(Wfb + (q*4+kk)*4);
    a[0] += av[kk]*wa.x; a[1] += av[kk]*wa.y; a[2] += av[kk]*wa.z; a[3] += av[kk]*wa.w;
    b[0] += av[kk]*wb.x; b[1] += av[kk]*wb.y; b[2] += av[kk]*wb.z; b[3] += av[kk]*wb.w;
  }
  #pragma unroll
  for(int off = 1; off < 32; off <<= 1){
    a[0] += __shfl_xor(a[0], off); a[1] += __shfl_xor(a[1], off);
    a[2] += __shfl_xor(a[2], off); a[3] += __shfl_xor(a[3], off);
    b[0] += __shfl_xor(b[0], off); b[1] += __shfl_xor(b[1], off);
    b[2] += __shfl_xor(b[2], off); b[3] += __shfl_xor(b[3], off);
  }
  if(valid && q == 0){
    float4 o; o.x=a[0]; o.y=a[1]; o.z=a[2]; o.w=a[3];
    *(float4*)(oa + (size_t)row*4) = o;
    float4 p; p.x=b[0]; p.y=b[1]; p.z=b[2]; p.w=b[3];
    *(float4*)(ob + (size_t)row*4) = p;
  }
}

// ================= batched bf16 MFMA GEMM (blockIdx.z = segment) =================
struct GSeg { const ushort* A; const ushort* BT; const float* bias; void* C; int ldc; };

template<int BN, typename OutT, bool BIAS, bool GRP, bool ELU>
__global__ __launch_bounds__(256) void gemm_mfma_b(GSeg s0, GSeg s1, GSeg s2,
    int M, int N, int K, int lda){
  constexpr int BM = 128, BK = 64;
  constexpr int NI = BN/32;
  constexpr int AIT = BM*BK/(256*8);
  constexpr int BIT = BN*BK/(256*8);
  __shared__ ushort lds[BM*BK + BN*BK];
  ushort* ldsA = lds;
  ushort* ldsB = lds + BM*BK;
  GSeg S = blockIdx.z == 0 ? s0 : (blockIdx.z == 1 ? s1 : s2);
  const int tid = threadIdx.x, wid = tid >> 6, lane = tid & 63;
  const int wr = wid >> 1, wc = wid & 1;
  const int rowbase = blockIdx.x*BM;
  const ushort* Ag = S.A;
  const ushort* Bg = S.BT;
  int colbase;
  if constexpr (GRP){
    const int hh = blockIdx.y;
    Ag = S.A + (size_t)hh*K;
    Bg = S.BT + (size_t)hh*BN*K;
    colbase = hh*BN;
  } else {
    colbase = blockIdx.y*BN;
  }

  f32x4 acc[4][NI];
  #pragma unroll
  for(int mi = 0; mi < 4; mi++)
    #pragma unroll
    for(int ni = 0; ni < NI; ni++) acc[mi][ni] = (f32x4)0.f;

  for(int k0 = 0; k0 < K; k0 += BK){
    #pragma unroll
    for(int it = 0; it < AIT; it++){
      int idx = it*256 + wid*64 + lane;
      int r = idx >> 3, sl = idx & 7;
      int kb = sl ^ (r & 7);
      int grow = rowbase + r; if(grow >= M) grow = M-1;
      const ushort* src = Ag + (size_t)grow*lda + k0 + kb*8;
      __builtin_amdgcn_global_load_lds(AS1(src), AS3(ldsA + (size_t)(it*256 + wid*64)*8), 16, 0, 0);
    }
    #pragma unroll
    for(int it = 0; it < BIT; it++){
      int idx = it*256 + wid*64 + lane;
      int r = idx >> 3, sl = idx & 7;
      int kb = sl ^ (r & 7);
      int brow = (GRP ? 0 : colbase) + r;
      const ushort* src = Bg + (size_t)brow*K + k0 + kb*8;
      __builtin_amdgcn_global_load_lds(AS1(src), AS3(ldsB + (size_t)(it*256 + wid*64)*8), 16, 0, 0);
    }
    __syncthreads();
    #pragma unroll
    for(int kk = 0; kk < 2; kk++){
      bh8 af[4], bf[NI];
      #pragma unroll
      for(int mi = 0; mi < 4; mi++){
        int arow = wr*64 + mi*16 + (lane & 15);
        int kb = kk*4 + (lane >> 4);
        af[mi] = *(const bh8*)(ldsA + arow*BK + ((kb ^ (arow & 7)) << 3));
      }
      #pragma unroll
      for(int ni = 0; ni < NI; ni++){
        int brow = wc*(BN/2) + ni*16 + (lane & 15);
        int kb = kk*4 + (lane >> 4);
        bf[ni] = *(const bh8*)(ldsB + brow*BK + ((kb ^ (brow & 7)) << 3));
      }
      #pragma unroll
      for(int mi = 0; mi < 4; mi++)
        #pragma unroll
        for(int ni = 0; ni < NI; ni++)
          acc[mi][ni] = __builtin_amdgcn_mfma_f32_16x16x32_bf16(af[mi], bf[ni], acc[mi][ni], 0, 0, 0);
    }
    __syncthreads();
  }
  OutT* C = (OutT*)S.C;
  #pragma unroll
  for(int mi = 0; mi < 4; mi++){
    #pragma unroll
    for(int ni = 0; ni < NI; ni++){
      int col = colbase + wc*(BN/2) + ni*16 + (lane & 15);
      if(col >= N) continue;
      float bv = BIAS ? S.bias[col] : 0.f;
      #pragma unroll
      for(int j = 0; j < 4; j++){
        int row = rowbase + wr*64 + mi*16 + (lane >> 4)*4 + j;
        if(row >= M) continue;
        float v = acc[mi][ni][j] + bv;
        if constexpr (ELU) v = v > 0.f ? v : (__expf(v) - 1.f);
        if constexpr (sizeof(OutT) == 4) C[(size_t)row*S.ldc + col] = v;
        else                             C[(size_t)row*S.ldc + col] = (OutT)f2b(v);
      }
    }
  }
}

// ================= metapath GAT aggregate (D=32, 128 feat) =================
__global__ __launch_bounds__(256) void gat_agg_meta(
    const ushort* __restrict__ hs, const float* __restrict__ el,
    const float* __restrict__ er, const int* __restrict__ ofs,
    const int* __restrict__ colv, const float* __restrict__ bias,
    ushort* __restrict__ outv, int Nd){
  const int wslot = threadIdx.x >> 6;
  const int node = blockIdx.x*4 + wslot;
  const int lane = threadIdx.x & 63;
  __shared__ int   lds_s[4][64];
  __shared__ float lds_w[4][256];
  if(node >= Nd) return;
  const int e0 = ofs[node], e1 = ofs[node+1];
  const int g = lane >> 4, q = lane & 15;
  const int hh = q >> 2;
  const float4 erv = *(const float4*)(er + (size_t)node*4);
  float m0=-INFINITY, m1=-INFINITY, m2=-INFINITY, m3=-INFINITY;
  float sw0=0.f, sw1=0.f, sw2=0.f, sw3=0.f;
  float acc[8];
  #pragma unroll
  for(int r = 0; r < 8; r++) acc[r] = 0.f;

  for(int base = e0; base < e1; base += 64){
    int nch = e1 - base; if(nch > 64) nch = 64;
    int s_l = colv[base + (lane < nch ? lane : nch-1)];
    float4 ev = *(const float4*)(el + (size_t)s_l*4);
    float x0 = ev.x + erv.x; x0 = x0 > 0.f ? x0 : 0.2f*x0;
    float x1 = ev.y + erv.y; x1 = x1 > 0.f ? x1 : 0.2f*x1;
    float x2 = ev.z + erv.z; x2 = x2 > 0.f ? x2 : 0.2f*x2;
    float x3 = ev.w + erv.w; x3 = x3 > 0.f ? x3 : 0.2f*x3;
    if(lane >= nch){ x0 = x1 = x2 = x3 = -INFINITY; }
    float c0=x0, c1=x1, c2=x2, c3=x3;
    #pragma unroll
    for(int off = 32; off; off >>= 1){
      c0 = fmaxf(c0, __shfl_xor(c0, off));
      c1 = fmaxf(c1, __shfl_xor(c1, off));
      c2 = fmaxf(c2, __shfl_xor(c2, off));
      c3 = fmaxf(c3, __shfl_xor(c3, off));
    }
    float n0 = fmaxf(m0,c0), n1 = fmaxf(m1,c1), n2 = fmaxf(m2,c2), n3 = fmaxf(m3,c3);
    float r0 = __expf(m0-n0), r1 = __expf(m1-n1), r2 = __expf(m2-n2), r3 = __expf(m3-n3);
    float w0 = __expf(x0-n0), w1 = __expf(x1-n1), w2 = __expf(x2-n2), w3 = __expf(x3-n3);
    sw0 = sw0*r0 + w0; sw1 = sw1*r1 + w1; sw2 = sw2*r2 + w2; sw3 = sw3*r3 + w3;
    float rh = hh==0 ? r0 : (hh==1 ? r1 : (hh==2 ? r2 : r3));
    #pragma unroll
    for(int r = 0; r < 8; r++) acc[r] *= rh;
    m0=n0; m1=n1; m2=n2; m3=n3;
    lds_s[wslot][lane] = s_l;
    lds_w[wslot][lane*4+0] = w0; lds_w[wslot][lane*4+1] = w1;
    lds_w[wslot][lane*4+2] = w2; lds_w[wslot][lane*4+3] = w3;
    int npad = (nch + 7) & ~7;
    for(int j = 0; j < npad; j += 8){
      int sA = lds_s[wslot][j + g];
      int sB = lds_s[wslot][j + 4 + g];
      float wA = lds_w[wslot][(j + g)*4 + hh];
      float wB = lds_w[wslot][(j + 4 + g)*4 + hh];
      bh8 vA = *(const bh8*)(hs + (size_t)sA*128 + q*8);
      bh8 vB = *(const bh8*)(hs + (size_t)sB*128 + q*8);
      #pragma unroll
      for(int r = 0; r < 8; r++) acc[r] += wA * b2f((ushort)vA[r]);
      #pragma unroll
      for(int r = 0; r < 8; r++) acc[r] += wB * b2f((ushort)vB[r]);
    }
  }
  #pragma unroll
  for(int off = 32; off; off >>= 1){
    sw0 += __shfl_xor(sw0, off); sw1 += __shfl_xor(sw1, off);
    sw2 += __shfl_xor(sw2, off); sw3 += __shfl_xor(sw3, off);
  }
  #pragma unroll
  for(int r = 0; r < 8; r++){
    acc[r] += __shfl_xor(acc[r], 16);
    acc[r] += __shfl_xor(acc[r], 32);
  }
  float swh = hh==0 ? sw0 : (hh==1 ? sw1 : (hh==2 ? sw2 : sw3));
  float den = (swh == 0.f) ? 1.f : swh;
  if(g == 0){
    bh8 ov;
    #pragma unroll
    for(int r = 0; r < 8; r++){
      float v = acc[r]/den + bias[q*8 + r];
      v = v > 0.f ? v : (__expf(v) - 1.f);
      ov[r] = (short)f2b(v);
    }
    *(bh8*)(outv + (size_t)node*128 + q*8) = ov;
  }
}

// ================= bipartite GAT aggregate in PROJ space, 3 graphs batched =================
struct ASeg { const int* ofs; const int* colv; const float* el; const float* er; ushort* agg; };
__global__ __launch_bounds__(256) void gat_agg_proj3(ASeg s0, ASeg s1, ASeg s2,
    const ushort* __restrict__ proj, int2 pbase, int Nd, int nb){
  const int seg = blockIdx.x / nb;
  const ASeg S = seg == 0 ? s0 : (seg == 1 ? s1 : s2);
  const ushort* pj = proj + (size_t)(seg == 0 ? 0 : (seg == 1 ? pbase.x : pbase.y))*64;
  const int wslot = threadIdx.x >> 6;
  const int node = (blockIdx.x - seg*nb)*4 + wslot;
  const int lane = threadIdx.x & 63;
  __shared__ int   lds_s[4][64];
  __shared__ float lds_w[4][256];
  if(node >= Nd) return;
  const int e0 = S.ofs[node], e1 = S.ofs[node+1];
  const int g = lane >> 4, q = lane & 15;
  const float4 erv = *(const float4*)(S.er + (size_t)node*4);
  float m0=-INFINITY, m1=-INFINITY, m2=-INFINITY, m3=-INFINITY;
  float sw0=0.f, sw1=0.f, sw2=0.f, sw3=0.f;
  float acc[4][4];
  #pragma unroll
  for(int d = 0; d < 4; d++)
    #pragma unroll
    for(int h = 0; h < 4; h++) acc[d][h] = 0.f;

  for(int base = e0; base < e1; base += 64){
    int nch = e1 - base; if(nch > 64) nch = 64;
    int s_l = S.colv[base + (lane < nch ? lane : nch-1)];
    float4 ev = *(const float4*)(S.el + (size_t)s_l*4);
    float x0 = ev.x + erv.x; x0 = x0 > 0.f ? x0 : 0.2f*x0;
    float x1 = ev.y + erv.y; x1 = x1 > 0.f ? x1 : 0.2f*x1;
    float x2 = ev.z + erv.z; x2 = x2 > 0.f ? x2 : 0.2f*x2;
    float x3 = ev.w + erv.w; x3 = x3 > 0.f ? x3 : 0.2f*x3;
    if(lane >= nch){ x0 = x1 = x2 = x3 = -INFINITY; }
    float c0=x0, c1=x1, c2=x2, c3=x3;
    #pragma unroll
    for(int off = 32; off; off >>= 1){
      c0 = fmaxf(c0, __shfl_xor(c0, off));
      c1 = fmaxf(c1, __shfl_xor(c1, off));
      c2 = fmaxf(c2, __shfl_xor(c2, off));
      c3 = fmaxf(c3, __shfl_xor(c3, off));
    }
    float n0 = fmaxf(m0,c0), n1 = fmaxf(m1,c1), n2 = fmaxf(m2,c2), n3 = fmaxf(m3,c3);
    float r0 = __expf(m0-n0), r1 = __expf(m1-n1), r2 = __expf(m2-n2), r3 = __expf(m3-n3);
    float w0 = __expf(x0-n0), w1 = __expf(x1-n1), w2 = __expf(x2-n2), w3 = __expf(x3-n3);
    sw0 = sw0*r0 + w0; sw1 = sw1*r1 + w1; sw2 = sw2*r2 + w2; sw3 = sw3*r3 + w3;
    #pragma unroll
    for(int d = 0; d < 4; d++){
      acc[d][0] *= r0; acc[d][1] *= r1; acc[d][2] *= r2; acc[d][3] *= r3;
    }
    m0=n0; m1=n1; m2=n2; m3=n3;
    lds_s[wslot][lane] = s_l;
    lds_w[wslot][lane*4+0] = w0; lds_w[wslot][lane*4+1] = w1;
    lds_w[wslot][lane*4+2] = w2; lds_w[wslot][lane*4+3] = w3;
    int npad = (nch + 7) & ~7;
    for(int j = 0; j < npad; j += 8){
      int sA = lds_s[wslot][j + g];
      int sB = lds_s[wslot][j + 4 + g];
      float4 wvA = *(const float4*)&lds_w[wslot][(j + g)*4];
      float4 wvB = *(const float4*)&lds_w[wslot][(j + 4 + g)*4];
      ushort4 pA = *(const ushort4*)(pj + (size_t)sA*64 + q*4);
      ushort4 pB = *(const ushort4*)(pj + (size_t)sB*64 + q*4);
      float fA[4] = {b2f(pA.x), b2f(pA.y), b2f(pA.z), b2f(pA.w)};
      float fB[4] = {b2f(pB.x), b2f(pB.y), b2f(pB.z), b2f(pB.w)};
      #pragma unroll
      for(int d = 0; d < 4; d++){
        acc[d][0] += wvA.x*fA[d]; acc[d][1] += wvA.y*fA[d];
        acc[d][2] += wvA.z*fA[d]; acc[d][3] += wvA.w*fA[d];
        acc[d][0] += wvB.x*fB[d]; acc[d][1] += wvB.y*fB[d];
        acc[d][2] += wvB.z*fB[d]; acc[d][3] += wvB.w*fB[d];
      }
    }
  }
  #pragma unroll
  for(int off = 32; off; off >>= 1){
    sw0 += __shfl_xor(sw0, off); sw1 += __shfl_xor(sw1, off);
    sw2 += __shfl_xor(sw2, off); sw3 += __shfl_xor(sw3, off);
  }
  #pragma unroll
  for(int d = 0; d < 4; d++)
    #pragma unroll
    for(int h = 0; h < 4; h++){
      acc[d][h] += __shfl_xor(acc[d][h], 16);
      acc[d][h] += __shfl_xor(acc[d][h], 32);
    }
  float dn[4];
  dn[0] = (sw0 == 0.f) ? 1.f : sw0;
  dn[1] = (sw1 == 0.f) ? 1.f : sw1;
  dn[2] = (sw2 == 0.f) ? 1.f : sw2;
  dn[3] = (sw3 == 0.f) ? 1.f : sw3;
  if(g == 0){
    ushort* orow = S.agg + (size_t)node*256;
    #pragma unroll
    for(int h = 0; h < 4; h++){
      ushort4 o;
      o.x = f2b(acc[0][h]/dn[h]); o.y = f2b(acc[1][h]/dn[h]);
      o.z = f2b(acc[2][h]/dn[h]); o.w = f2b(acc[3][h]/dn[h]);
      *(ushort4*)(orow + h*64 + q*4) = o;
    }
  }
}

// ================= host orchestration =================
extern "C" void kernel_launch(void* const* d_in, const int* in_sizes, int n_in,
                              void* d_out, int out_size, void* d_ws, size_t ws_size,
                              hipStream_t stream){
  const float* hp   = (const float*)d_in[0];
  const float* hq   = (const float*)d_in[1];
  const float* hk   = (const float*)d_in[2];
  const float* ha   = (const float*)d_in[3];
  const int* meta_src = (const int*)d_in[4];
  const int* meta_dst = (const int*)d_in[5];
  const int* q_src = (const int*)d_in[6];
  const int* q_dst = (const int*)d_in[7];
  const int* k_src = (const int*)d_in[8];
  const int* k_dst = (const int*)d_in[9];
  const int* a_src = (const int*)d_in[10];
  const int* a_dst = (const int*)d_in[11];
  const float* W0  = (const float*)d_in[12]; const float* al0 = (const float*)d_in[13];
  const float* ar0 = (const float*)d_in[14]; const float* b0  = (const float*)d_in[15];
  const float* W1  = (const float*)d_in[16]; const float* al1 = (const float*)d_in[17];
  const float* ar1 = (const float*)d_in[18]; const float* b1  = (const float*)d_in[19];
  const float* Wq  = (const float*)d_in[20]; const float* alq = (const float*)d_in[21];
  const float* arq = (const float*)d_in[22]; const float* bq  = (const float*)d_in[23];
  const float* Wkw = (const float*)d_in[24]; const float* alkw= (const float*)d_in[25];
  const float* arkw= (const float*)d_in[26]; const float* bkw = (const float*)d_in[27];
  const float* Watt= (const float*)d_in[28]; const float* alatt=(const float*)d_in[29];
  const float* aratt=(const float*)d_in[30]; const float* batt= (const float*)d_in[31];
  const float* Wpnn_a = (const float*)d_in[32];
  const float* Wpn_a  = (const float*)d_in[33];
  const float* Wpnn   = (const float*)d_in[34];
  const float* Wpn    = (const float*)d_in[35];
  const float* Wpred  = (const float*)d_in[36];
  const float* bpred  = (const float*)d_in[37];
  (void)n_in; (void)out_size; (void)ws_size;

  const int IN = 128, ATT = 64;
  const int NP = in_sizes[0]/IN, NQ = in_sizes[1]/ATT, NK = in_sizes[2]/ATT, NA = in_sizes[3]/ATT;
  const int EM = in_sizes[4], EQ = in_sizes[6], EK = in_sizes[8], EA = in_sizes[10];
  const int range = (NP + 7)/8;   // <= 8192 required for packed ebuf
  const int NS = NQ + NK + NA;

  // ----- workspace layout (all staging in d_ws; d_out written only by final GEMM) -----
  uint8_t* wp = (uint8_t*)d_ws;
  auto alloc = [&](size_t bytes)->uint8_t*{
    uint8_t* p = wp; wp += (bytes + 255) & ~(size_t)255; return p;
  };
  ushort* hcat_b = (ushort*)alloc((size_t)NP*256*2);
  ushort* hbuf_b = (ushort*)alloc((size_t)NP*128*2);
  ushort* hp_b   = (ushort*)alloc((size_t)NP*128*2);
  ushort* hpd_b  = (ushort*)alloc((size_t)NP*64*2);
  ushort* hs_b   = (ushort*)alloc((size_t)NP*128*2);
  ushort* feat_all = (ushort*)alloc((size_t)NS*64*2);   // [hq|hk|ha] bf16
  ushort* proj_all = (ushort*)alloc((size_t)NS*64*2);
  ushort* agg_all  = (ushort*)alloc((size_t)3*NP*256*2);
  ushort* o_all    = (ushort*)alloc((size_t)3*NP*512*2);
  float* el    = (float*)alloc((size_t)NP*4*4);         // metapath el
  float* er    = (float*)alloc((size_t)NP*4*4);         // metapath er
  float* el_all= (float*)alloc((size_t)NS*4*4);         // bip el (src-local rows)
  float* er_all= (float*)alloc((size_t)3*NP*4*4);       // bip er x3
  float* wf    = (float*)alloc((size_t)10*512*4);
  int* cnt4    = (int*)alloc((size_t)(4*NP+32)*4);
  int* bcur    = cnt4 + 4*NP;
  int* cur4    = (int*)alloc((size_t)4*NP*4);
  int* ofsm    = (int*)alloc((size_t)(NP+4)*4);
  int* ofsq    = (int*)alloc((size_t)(NP+4)*4);
  int* ofsk    = (int*)alloc((size_t)(NP+4)*4);
  int* ofsa    = (int*)alloc((size_t)(NP+4)*4);
  int* colm    = (int*)alloc((size_t)EM*4);
  int* colq    = (int*)alloc((size_t)EQ*4);
  int* colk    = (int*)alloc((size_t)EK*4);
  int* cola    = (int*)alloc((size_t)EA*4);
  const int capM = EM/4+1024, capQ = EQ/4+1024, capK = EK/4+1024, capA = EA/4+1024;
  uint* ebm = (uint*)alloc((size_t)8*capM*4);
  uint* ebq = (uint*)alloc((size_t)8*capQ*4);
  uint* ebk = (uint*)alloc((size_t)8*capK*4);
  uint* eba = (uint*)alloc((size_t)8*capA*4);
  ushort* W0T    = (ushort*)alloc(128*128*2);
  ushort* W1T    = (ushort*)alloc(128*128*2);
  ushort* WTg3   = (ushort*)alloc((size_t)3*4*128*64*2);
  ushort* WpnT   = (ushort*)alloc((size_t)64*512*2);
  ushort* WpnnT  = (ushort*)alloc(64*128*2);
  ushort* Wpnn_aT= (ushort*)alloc(64*128*2);
  ushort* Wpn_aT = (ushort*)alloc(64*64*2);
  ushort* WpredT = (ushort*)alloc((size_t)1024*256*2);

  // ----- CSR build (5 dispatches) -----
  fill_zero_i32<<<(4*NP+32+255)/256, 256, 0, stream>>>(cnt4, 4*NP+32);
  {
    int bm = EM/1024 + 1, bq2 = EQ/1024 + 1, bk2 = EK/1024 + 1, ba2 = EA/1024 + 1;
    P4 g0{meta_src, meta_dst, ebm, EM, capM, 0, bm};
    P4 g1{q_src, q_dst, ebq, EQ, capQ, bm, bm+bq2};
    P4 g2{k_src, k_dst, ebk, EK, capK, bm+bq2, bm+bq2+bk2};
    P4 g3{a_src, a_dst, eba, EA, capA, bm+bq2+bk2, bm+bq2+bk2+ba2};
    partition_all_k<<<g3.bend, 256, 0, stream>>>(g0, g1, g2, g3, bcur, range);
  }
  auto Jof = [&](int E){ int J = E/65536 + 8; if(J > 48) J = 48; return J; };
  {
    int jm = 8*Jof(EM), jq = 8*Jof(EQ), jk = 8*Jof(EK), ja = 8*Jof(EA);
    B4 g0{ebm, capM, cnt4 + 0*NP, 0, jm};
    B4 g1{ebq, capQ, cnt4 + 1*NP, jm, jm+jq};
    B4 g2{ebk, capK, cnt4 + 2*NP, jm+jq, jm+jq+jk};
    B4 g3{eba, capA, cnt4 + 3*NP, jm+jq+jk, jm+jq+jk+ja};
    count_all_k<<<g3.bend, 256, 0, stream>>>(g0, g1, g2, g3, bcur, range);
    scan4_k<<<4, 1024, 0, stream>>>(cnt4, cnt4+NP, cnt4+2*NP, cnt4+3*NP,
                                    ofsm, ofsq, ofsk, ofsa,
                                    cur4, cur4+NP, cur4+2*NP, cur4+3*NP, NP);
    SB4 s0{ebm, capM, cur4 + 0*NP, colm, 0, jm};
    SB4 s1{ebq, capQ, cur4 + 1*NP, colq, jm, jm+jq};
    SB4 s2{ebk, capK, cur4 + 2*NP, colk, jm+jq, jm+jq+jk};
    SB4 s3{eba, capA, cur4 + 3*NP, cola, jm+jq+jk, jm+jq+jk+ja};
    scatter_all_k<<<s3.bend, 256, 0, stream>>>(s0, s1, s2, s3, bcur, range);
  }

  // ----- conversions + weight prep (4 dispatches) -----
  {
    // hp -> hp_b ; [hq|hk|ha] contiguous src? they are separate inputs: convert
    // hp in seg0; hq/hk/ha into feat_all via three sub-ranges handled by seg1
    // trick: hq,hk,ha are separate pointers -> do hp + hq in one, hk+ha appended
    int c0 = NP*128/4, c1 = c0 + NQ*64/4;
    cvt_all_k<<<(c1+255)/256, 256, 0, stream>>>(hp, hq, hp_b, feat_all, make_int2(c0, c1));
    int d0 = NK*64/4, d1 = d0 + NA*64/4;
    cvt_all_k<<<(d1+255)/256, 256, 0, stream>>>(hk, ha,
        feat_all + (size_t)NQ*64, feat_all + (size_t)(NQ+NK)*64, make_int2(d0, d1));
  }
  {
    WTAll a;
    a.d[0] = {W0, W0T, 128, 128};      a.d[1] = {W1, W1T, 128, 128};
    a.d[2] = {Wpn, WpnT, 512, 64};     a.d[3] = {Wpnn, WpnnT, 128, 64};
    a.d[4] = {Wpnn_a, Wpnn_aT, 128, 64}; a.d[5] = {Wpn_a, Wpn_aT, 64, 64};
    a.d[6] = {Wpred, WpredT, 256, 1000};
    int items[7] = {128*128, 128*128, 64*512, 64*128, 64*128, 64*64, 1024*256};
    a.cum[0] = 0;
    for(int t = 0; t < 7; t++) a.cum[t+1] = a.cum[t] + items[t];
    wT_all_k<<<(a.cum[7]+255)/256, 256, 0, stream>>>(a);
  }
  wTg3_k<<<(3*32768+255)/256, 256, 0, stream>>>(Wq, Wkw, Watt, WTg3);
  {
    FAll f;
    f.d[0] = {W0, al0, wf+0*512, 128, 32};  f.d[1] = {W0, ar0, wf+1*512, 128, 32};
    f.d[2] = {W1, al1, wf+2*512, 128, 32};  f.d[3] = {W1, ar1, wf+3*512, 128, 32};
    f.d[4] = {Wq, alq, wf+4*512, 64, 128};  f.d[5] = {Wq, arq, wf+5*512, 64, 128};
    f.d[6] = {Wkw, alkw, wf+6*512, 64, 128};f.d[7] = {Wkw, arkw, wf+7*512, 64, 128};
    f.d[8] = {Watt, alatt, wf+8*512, 64, 128};f.d[9] = {Watt, aratt, wf+9*512, 64, 128};
    fold_all_k<<<10, 256, 0, stream>>>(f);
  }

  auto launch_gemm = [&]<int BN, typename OutT, bool BIAS, bool GRP, bool ELU>(
      GSeg a, GSeg b, GSeg c, int nseg, int M, int N, int K, int lda){
    int Npad = (N + BN - 1)/BN*BN;
    dim3 g((M + 127)/128, GRP ? 4 : Npad/BN, nseg);
    gemm_mfma_b<BN, OutT, BIAS, GRP, ELU><<<g, 256, 0, stream>>>(a, b, c, M, N, K, lda);
  };
  GSeg z{};

  // ----- metapath GAT layer 0 -----
  launch_gemm.template operator()<128, ushort, false, false, false>(
      GSeg{hp_b, W0T, nullptr, hs_b, 128}, z, z, 1, NP, 128, 128, 128);
  gemv8v<ushort><<<(NP/2+3)/4, 256, 0, stream>>>(hp_b, wf+0*512, wf+1*512, el, er, NP, 128);
  gat_agg_meta<<<(NP+3)/4, 256, 0, stream>>>(hs_b, el, er, ofsm, colm, b0, hbuf_b, NP);

  // ----- metapath GAT layer 1 -----
  launch_gemm.template operator()<128, ushort, false, false, false>(
      GSeg{hbuf_b, W1T, nullptr, hs_b, 128}, z, z, 1, NP, 128, 128, 128);
  gemv8v<ushort><<<(NP/2+3)/4, 256, 0, stream>>>(hbuf_b, wf+2*512, wf+3*512, el, er, NP, 128);
  gat_agg_meta<<<(NP+3)/4, 256, 0, stream>>>(hs_b, el, er, ofsm, colm, b1, hbuf_b, NP);

  // ----- batched: hcat[:,0:64] = h @ Wpnn ; hpd = hp @ Wpnn_a -----
  launch_gemm.template operator()<64, ushort, false, false, false>(
      GSeg{hbuf_b, WpnnT, nullptr, hcat_b, 256},
      GSeg{hp_b, Wpnn_aT, nullptr, hpd_b, 64}, z, 2, NP, 64, 128, 128);

  // ----- bipartite GATs (fully batched across q/k/a) -----
  launch_gemm.template operator()<64, ushort, false, false, false>(
      GSeg{feat_all, Wpn_aT, nullptr, proj_all, 64}, z, z, 1, NS, 64, 64, 64);
  gemv4v_seg3<<<(NS/4+3)/4, 256, 0, stream>>>(proj_all, wf+4*512, wf+6*512, wf+8*512,
      el_all, NS, NQ, NQ+NK);
  gemv4v_er3<<<(NP/4+3)/4, 256, 0, stream>>>(hpd_b, wf+5*512, wf+7*512, wf+9*512,
      er_all, er_all + (size_t)NP*4, er_all + (size_t)2*NP*4, NP);
  {
    int nb = (NP+3)/4;
    ASeg a0{ofsq, colq, el_all,                    er_all,                    agg_all};
    ASeg a1{ofsk, colk, el_all + (size_t)NQ*4,     er_all + (size_t)NP*4,     agg_all + (size_t)NP*256};
    ASeg a2{ofsa, cola, el_all + (size_t)(NQ+NK)*4,er_all + (size_t)2*NP*4,   agg_all + (size_t)2*NP*256};
    gat_agg_proj3<<<3*nb, 256, 0, stream>>>(a0, a1, a2, proj_all, make_int2(NQ, NQ+NK), NP, nb);
  }
  launch_gemm.template operator()<128, ushort, true, true, true>(
      GSeg{agg_all,                    WTg3 + 0*32768, bq,   o_all, 512},
      GSeg{agg_all + (size_t)NP*256,   WTg3 + 1*32768, bkw,  o_all + (size_t)NP*512, 512},
      GSeg{agg_all + (size_t)2*NP*256, WTg3 + 2*32768, batt, o_all + (size_t)2*NP*512, 512},
      3, NP, 512, 64, 256);
  launch_gemm.template operator()<64, ushort, false, false, false>(
      GSeg{o_all,                    WpnT, nullptr, hcat_b + 64, 256},
      GSeg{o_all + (size_t)NP*512,   WpnT, nullptr, hcat_b + 128, 256},
      GSeg{o_all + (size_t)2*NP*512, WpnT, nullptr, hcat_b + 192, 256},
      3, NP, 64, 512, 512);

  // ----- final: out = hcat @ Wpred + bpred -----
  launch_gemm.template operator()<128, float, true, false, false>(
      GSeg{hcat_b, WpredT, bpred, d_out, 1000}, z, z, 1, NP, 1000, 256, 256);
}

// Round 10
// 838.904 us; speedup vs baseline: 1.6266x; 1.1094x over previous
//
#include <hip/hip_runtime.h>
#include <hip/hip_bf16.h>
#include <math.h>
#include <stdint.h>

typedef __attribute__((ext_vector_type(8))) short bh8;
typedef __attribute__((ext_vector_type(4))) float f32x4;

#define AS1(p) ((const __attribute__((address_space(1))) void*)(p))
#define AS3(p) ((__attribute__((address_space(3))) void*)(p))

__device__ inline ushort f2b(float f){
  uint u = __builtin_bit_cast(uint, f);
  u += 0x7fff + ((u >> 16) & 1);
  return (ushort)(u >> 16);
}
__device__ inline float b2f(ushort b){ return __builtin_bit_cast(float, (uint)b << 16); }

// ================= CSR build (all 4 graphs fused, packed staging) =================
__global__ void fill_zero_i32(int* __restrict__ p, int n){
  int i = blockIdx.x*blockDim.x + threadIdx.x;
  if(i < n) p[i] = 0;
}

struct P4 { const int* src; const int* dst; uint* ebuf; int E; int cap; int bbeg; int bend; };

__global__ __launch_bounds__(256) void partition_all_k(P4 g0, P4 g1, P4 g2, P4 g3,
    int* __restrict__ bcur, int range){
  P4 G; int gi;
  int b = blockIdx.x;
  if(b < g0.bend){ G = g0; gi = 0; }
  else if(b < g1.bend){ G = g1; gi = 1; }
  else if(b < g2.bend){ G = g2; gi = 2; }
  else { G = g3; gi = 3; }
  const int lb = b - G.bbeg, nb = G.bend - G.bbeg;
  __shared__ int hist[8], base[8];
  const int tid = threadIdx.x;
  int* bc = bcur + gi*8;
  for(int c0 = lb*256; c0 < G.E; c0 += nb*256){
    int i = c0 + tid;
    int d = 0, s = 0, bk = -1;
    if(i < G.E){ d = G.dst[i]; s = G.src[i]; bk = d / range; }
    if(tid < 8) hist[tid] = 0;
    __syncthreads();
    int rank = 0;
    if(bk >= 0) rank = atomicAdd(&hist[bk], 1);
    __syncthreads();
    if(tid < 8) base[tid] = hist[tid] ? atomicAdd(&bc[tid], hist[tid]) : 0;
    __syncthreads();
    if(bk >= 0){
      int pos = base[bk] + rank;
      if(pos < G.cap) G.ebuf[(size_t)bk*G.cap + pos] = ((uint)s << 13) | (uint)(d - bk*range);
    }
    __syncthreads();
  }
}

struct B4 { const uint* ebuf; int cap; int* cnt; int bbeg; int bend; };
__global__ __launch_bounds__(256) void count_all_k(B4 g0, B4 g1, B4 g2, B4 g3,
    const int* __restrict__ bcur, int range){
  B4 G; int gi;
  int b = blockIdx.x;
  if(b < g0.bend){ G = g0; gi = 0; }
  else if(b < g1.bend){ G = g1; gi = 1; }
  else if(b < g2.bend){ G = g2; gi = 2; }
  else { G = g3; gi = 3; }
  const int local = b - G.bbeg, J = (G.bend - G.bbeg) >> 3;
  const int bk = local & 7, j = local >> 3;
  int nb = bcur[gi*8 + bk]; if(nb > G.cap) nb = G.cap;
  const uint* eb = G.ebuf + (size_t)bk*G.cap;
  int* cb = G.cnt + bk*range;
  int per = (nb + J - 1)/J;
  int beg = j*per, end = beg + per; if(end > nb) end = nb;
  for(int i = beg + threadIdx.x; i < end; i += 256)
    atomicAdd(&cb[eb[i] & 8191u], 1);
}

struct SB4 { const uint* ebuf; int cap; int* cursor; int* colv; int bbeg; int bend; };
__global__ __launch_bounds__(256) void scatter_all_k(SB4 g0, SB4 g1, SB4 g2, SB4 g3,
    const int* __restrict__ bcur, int range){
  SB4 G; int gi;
  int b = blockIdx.x;
  if(b < g0.bend){ G = g0; gi = 0; }
  else if(b < g1.bend){ G = g1; gi = 1; }
  else if(b < g2.bend){ G = g2; gi = 2; }
  else { G = g3; gi = 3; }
  const int local = b - G.bbeg, J = (G.bend - G.bbeg) >> 3;
  const int bk = local & 7, j = local >> 3;
  int nb = bcur[gi*8 + bk]; if(nb > G.cap) nb = G.cap;
  const uint* eb = G.ebuf + (size_t)bk*G.cap;
  int* ub = G.cursor + bk*range;
  int per = (nb + J - 1)/J;
  int beg = j*per, end = beg + per; if(end > nb) end = nb;
  for(int i = beg + threadIdx.x; i < end; i += 256){
    uint e = eb[i];
    int p = atomicAdd(&ub[e & 8191u], 1);
    G.colv[p] = (int)(e >> 13);
  }
}

__global__ __launch_bounds__(1024) void scan4_k(
    const int* c0, const int* c1, const int* c2, const int* c3,
    int* o0, int* o1, int* o2, int* o3,
    int* u0, int* u1, int* u2, int* u3, int n){
  const int* cnt = blockIdx.x==0?c0:(blockIdx.x==1?c1:(blockIdx.x==2?c2:c3));
  int* ofs    = blockIdx.x==0?o0:(blockIdx.x==1?o1:(blockIdx.x==2?o2:o3));
  int* cursor = blockIdx.x==0?u0:(blockIdx.x==1?u1:(blockIdx.x==2?u2:u3));
  __shared__ int wsum[16];
  __shared__ int carry_s;
  int tid = threadIdx.x, wid = tid >> 6, lane = tid & 63;
  if(tid == 0) carry_s = 0;
  __syncthreads();
  for(int base = 0; base < n; base += 4096){
    int i0 = base + tid*4;
    int4 v = make_int4(0,0,0,0);
    if(i0 + 3 < n) v = *(const int4*)(cnt + i0);
    else if(i0 < n){
      v.x = cnt[i0];
      if(i0+1 < n) v.y = cnt[i0+1];
      if(i0+2 < n) v.z = cnt[i0+2];
    }
    int s1 = v.x + v.y, s2 = s1 + v.z, tot = s2 + v.w;
    int x = tot;
    #pragma unroll
    for(int off = 1; off < 64; off <<= 1){
      int t = __shfl_up(x, off);
      if(lane >= off) x += t;
    }
    if(lane == 63) wsum[wid] = x;
    __syncthreads();
    if(tid < 16){
      int y = wsum[tid];
      #pragma unroll
      for(int off = 1; off < 16; off <<= 1){
        int t = __shfl_up(y, off);
        if(tid >= off) y += t;
      }
      wsum[tid] = y;
    }
    __syncthreads();
    int pre = (wid ? wsum[wid-1] : 0) + carry_s + (x - tot);
    if(i0 + 3 < n){
      int4 o = make_int4(pre, pre+v.x, pre+s1, pre+s2);
      *(int4*)(ofs + i0) = o;
      *(int4*)(cursor + i0) = o;
    } else if(i0 < n){
      ofs[i0] = pre; cursor[i0] = pre;
      if(i0+1 < n){ ofs[i0+1] = pre+v.x; cursor[i0+1] = pre+v.x; }
      if(i0+2 < n){ ofs[i0+2] = pre+s1; cursor[i0+2] = pre+s1; }
    }
    __syncthreads();
    if(tid == 0) carry_s += wsum[15];
    __syncthreads();
  }
  if(tid == 0) ofs[n] = carry_s;
}

// ================= preprocessing (fused) =================
__global__ void cvt_all_k(const float* i0, const float* i1,
    ushort* o0, ushort* o1, int2 cum){
  int i = blockIdx.x*blockDim.x + threadIdx.x;
  const float* in; ushort* out; int base;
  if(i < cum.x){ in=i0; out=o0; base=0; }
  else if(i < cum.y){ in=i1; out=o1; base=cum.x; }
  else return;
  int l = i - base;
  float4 v = ((const float4*)in)[l];
  ushort4 o; o.x=f2b(v.x); o.y=f2b(v.y); o.z=f2b(v.z); o.w=f2b(v.w);
  ((ushort4*)out)[l] = o;
}

struct WTD { const float* W; ushort* WT; int K; int N; };
struct WTAll { WTD d[7]; int cum[8]; };
__global__ void wT_all_k(WTAll a){
  int idx = blockIdx.x*blockDim.x + threadIdx.x;
  if(idx >= a.cum[7]) return;
  int j = 0;
  #pragma unroll
  for(int t = 1; t < 7; t++) if(idx >= a.cum[t]) j = t;
  int l = idx - a.cum[j];
  WTD d = a.d[j];
  int n = l / d.K, k = l - n*d.K;
  d.WT[l] = (n < d.N) ? f2b(d.W[(size_t)k*d.N + n]) : (ushort)0;
}

__global__ void wTg3_k(const float* W0, const float* W1, const float* W2, ushort* WT){
  int idx = blockIdx.x*blockDim.x + threadIdx.x;
  if(idx >= 3*32768) return;
  int g = idx >> 15, rem = idx & 32767;
  const float* W = g==0 ? W0 : (g==1 ? W1 : W2);
  int h = rem >> 13, r2 = rem & 8191;
  int n = r2 >> 6, k = r2 & 63;
  WT[idx] = f2b(W[(size_t)k*512 + h*128 + n]);
}

struct FD { const float* W; const float* a; float* out; int K; int D; };
struct FAll { FD d[10]; };
__global__ void fold_all_k(FAll f){
  FD d = f.d[blockIdx.x];
  for(int i = threadIdx.x; i < d.K*4; i += 256){
    int k = i >> 2, h = i & 3;
    const float* wr = d.W + (size_t)k*4*d.D + (size_t)h*d.D;
    const float* ar = d.a + (size_t)h*d.D;
    float s = 0.f;
    for(int dd = 0; dd < d.D; dd++) s += wr[dd]*ar[dd];
    d.out[i] = s;
  }
}

// ================= gemv =================
__device__ inline void ld4v(const float* p, float* v){
  float4 t = *(const float4*)p; v[0]=t.x; v[1]=t.y; v[2]=t.z; v[3]=t.w;
}
__device__ inline void ld4v(const ushort* p, float* v){
  ushort4 t = *(const ushort4*)p; v[0]=b2f(t.x); v[1]=b2f(t.y); v[2]=b2f(t.z); v[3]=b2f(t.w);
}

__global__ __launch_bounds__(256) void gemv4v_seg3(const ushort* __restrict__ A,
    const float* __restrict__ W0, const float* __restrict__ W1, const float* __restrict__ W2,
    float* __restrict__ outv, int M, int b1, int b2){
  const int w = (blockIdx.x*blockDim.x + threadIdx.x) >> 6;
  const int lane = threadIdx.x & 63;
  const int r = lane >> 4, q = lane & 15;
  int row = w*4 + r;
  bool valid = row < M;
  int rowc = valid ? row : (M-1);
  const float* Wf = rowc < b1 ? W0 : (rowc < b2 ? W1 : W2);
  float av[4];
  ld4v(A + (size_t)rowc*64 + q*4, av);
  float a[4] = {0.f,0.f,0.f,0.f};
  #pragma unroll
  for(int kk = 0; kk < 4; kk++){
    float4 wv = *(const float4*)(Wf + (q*4+kk)*4);
    a[0] += av[kk]*wv.x; a[1] += av[kk]*wv.y; a[2] += av[kk]*wv.z; a[3] += av[kk]*wv.w;
  }
  #pragma unroll
  for(int off = 1; off < 16; off <<= 1){
    a[0] += __shfl_xor(a[0], off); a[1] += __shfl_xor(a[1], off);
    a[2] += __shfl_xor(a[2], off); a[3] += __shfl_xor(a[3], off);
  }
  if(valid && q == 0){
    float4 o; o.x=a[0]; o.y=a[1]; o.z=a[2]; o.w=a[3];
    *(float4*)(outv + (size_t)row*4) = o;
  }
}

__global__ __launch_bounds__(256) void gemv4v_er3(const ushort* __restrict__ A,
    const float* __restrict__ W0, const float* __restrict__ W1, const float* __restrict__ W2,
    float* __restrict__ o0, float* __restrict__ o1, float* __restrict__ o2, int M){
  const int w = (blockIdx.x*blockDim.x + threadIdx.x) >> 6;
  const int lane = threadIdx.x & 63;
  const int r = lane >> 4, q = lane & 15;
  int row = w*4 + r;
  bool valid = row < M;
  int rowc = valid ? row : (M-1);
  float av[4];
  ld4v(A + (size_t)rowc*64 + q*4, av);
  float a[12];
  #pragma unroll
  for(int t = 0; t < 12; t++) a[t] = 0.f;
  #pragma unroll
  for(int kk = 0; kk < 4; kk++){
    float4 w0 = *(const float4*)(W0 + (q*4+kk)*4);
    float4 w1 = *(const float4*)(W1 + (q*4+kk)*4);
    float4 w2 = *(const float4*)(W2 + (q*4+kk)*4);
    a[0] += av[kk]*w0.x; a[1] += av[kk]*w0.y; a[2] += av[kk]*w0.z; a[3] += av[kk]*w0.w;
    a[4] += av[kk]*w1.x; a[5] += av[kk]*w1.y; a[6] += av[kk]*w1.z; a[7] += av[kk]*w1.w;
    a[8] += av[kk]*w2.x; a[9] += av[kk]*w2.y; a[10]+= av[kk]*w2.z; a[11]+= av[kk]*w2.w;
  }
  #pragma unroll
  for(int off = 1; off < 16; off <<= 1)
    #pragma unroll
    for(int t = 0; t < 12; t++) a[t] += __shfl_xor(a[t], off);
  if(valid && q == 0){
    float4 x; x.x=a[0]; x.y=a[1]; x.z=a[2]; x.w=a[3];
    *(float4*)(o0 + (size_t)row*4) = x;
    float4 y; y.x=a[4]; y.y=a[5]; y.z=a[6]; y.w=a[7];
    *(float4*)(o1 + (size_t)row*4) = y;
    float4 z; z.x=a[8]; z.y=a[9]; z.z=a[10]; z.w=a[11];
    *(float4*)(o2 + (size_t)row*4) = z;
  }
}

template<typename T>
__global__ __launch_bounds__(256) void gemv8v(const T* __restrict__ A,
    const float* __restrict__ Wfa, const float* __restrict__ Wfb,
    float* __restrict__ oa, float* __restrict__ ob, int M, int lda){
  const int w = (blockIdx.x*blockDim.x + threadIdx.x) >> 6;
  const int lane = threadIdx.x & 63;
  const int r = lane >> 5, q = lane & 31;
  int row = w*2 + r;
  bool valid = row < M;
  int rowc = valid ? row : (M-1);
  float av[4];
  ld4v(A + (size_t)rowc*lda + q*4, av);
  float a[4] = {0.f,0.f,0.f,0.f}, b[4] = {0.f,0.f,0.f,0.f};
  #pragma unroll
  for(int kk = 0; kk < 4; kk++){
    float4 wa = *(const float4*)(Wfa + (q*4+kk)*4);
    float4 wb = *(const float4*)(Wfb + (q*4+kk)*4);
    a[0] += av[kk]*wa.x; a[1] += av[kk]*wa.y; a[2] += av[kk]*wa.z; a[3] += av[kk]*wa.w;
    b[0] += av[kk]*wb.x; b[1] += av[kk]*wb.y; b[2] += av[kk]*wb.z; b[3] += av[kk]*wb.w;
  }
  #pragma unroll
  for(int off = 1; off < 32; off <<= 1){
    a[0] += __shfl_xor(a[0], off); a[1] += __shfl_xor(a[1], off);
    a[2] += __shfl_xor(a[2], off); a[3] += __shfl_xor(a[3], off);
    b[0] += __shfl_xor(b[0], off); b[1] += __shfl_xor(b[1], off);
    b[2] += __shfl_xor(b[2], off); b[3] += __shfl_xor(b[3], off);
  }
  if(valid && q == 0){
    float4 o; o.x=a[0]; o.y=a[1]; o.z=a[2]; o.w=a[3];
    *(float4*)(oa + (size_t)row*4) = o;
    float4 p; p.x=b[0]; p.y=b[1]; p.z=b[2]; p.w=b[3];
    *(float4*)(ob + (size_t)row*4) = p;
  }
}

// ================= batched bf16 MFMA GEMM (blockIdx.z = segment) =================
struct GSeg { const ushort* A; const ushort* BT; const float* bias; void* C; int ldc; };

template<int BN, typename OutT, bool BIAS, bool GRP, bool ELU>
__global__ __launch_bounds__(256) void gemm_mfma_b(GSeg s0, GSeg s1, GSeg s2,
    int M, int N, int K, int lda){
  constexpr int BM = 128, BK = 64;
  constexpr int NI = BN/32;
  constexpr int AIT = BM*BK/(256*8);
  constexpr int BIT = BN*BK/(256*8);
  __shared__ ushort lds[BM*BK + BN*BK];
  ushort* ldsA = lds;
  ushort* ldsB = lds + BM*BK;
  GSeg S = blockIdx.z == 0 ? s0 : (blockIdx.z == 1 ? s1 : s2);
  const int tid = threadIdx.x, wid = tid >> 6, lane = tid & 63;
  const int wr = wid >> 1, wc = wid & 1;
  const int rowbase = blockIdx.x*BM;
  const ushort* Ag = S.A;
  const ushort* Bg = S.BT;
  int colbase;
  if constexpr (GRP){
    const int hh = blockIdx.y;
    Ag = S.A + (size_t)hh*K;
    Bg = S.BT + (size_t)hh*BN*K;
    colbase = hh*BN;
  } else {
    colbase = blockIdx.y*BN;
  }

  f32x4 acc[4][NI];
  #pragma unroll
  for(int mi = 0; mi < 4; mi++)
    #pragma unroll
    for(int ni = 0; ni < NI; ni++) acc[mi][ni] = (f32x4)0.f;

  for(int k0 = 0; k0 < K; k0 += BK){
    #pragma unroll
    for(int it = 0; it < AIT; it++){
      int idx = it*256 + wid*64 + lane;
      int r = idx >> 3, sl = idx & 7;
      int kb = sl ^ (r & 7);
      int grow = rowbase + r; if(grow >= M) grow = M-1;
      const ushort* src = Ag + (size_t)grow*lda + k0 + kb*8;
      __builtin_amdgcn_global_load_lds(AS1(src), AS3(ldsA + (size_t)(it*256 + wid*64)*8), 16, 0, 0);
    }
    #pragma unroll
    for(int it = 0; it < BIT; it++){
      int idx = it*256 + wid*64 + lane;
      int r = idx >> 3, sl = idx & 7;
      int kb = sl ^ (r & 7);
      int brow = (GRP ? 0 : colbase) + r;
      const ushort* src = Bg + (size_t)brow*K + k0 + kb*8;
      __builtin_amdgcn_global_load_lds(AS1(src), AS3(ldsB + (size_t)(it*256 + wid*64)*8), 16, 0, 0);
    }
    __syncthreads();
    #pragma unroll
    for(int kk = 0; kk < 2; kk++){
      bh8 af[4], bf[NI];
      #pragma unroll
      for(int mi = 0; mi < 4; mi++){
        int arow = wr*64 + mi*16 + (lane & 15);
        int kb = kk*4 + (lane >> 4);
        af[mi] = *(const bh8*)(ldsA + arow*BK + ((kb ^ (arow & 7)) << 3));
      }
      #pragma unroll
      for(int ni = 0; ni < NI; ni++){
        int brow = wc*(BN/2) + ni*16 + (lane & 15);
        int kb = kk*4 + (lane >> 4);
        bf[ni] = *(const bh8*)(ldsB + brow*BK + ((kb ^ (brow & 7)) << 3));
      }
      #pragma unroll
      for(int mi = 0; mi < 4; mi++)
        #pragma unroll
        for(int ni = 0; ni < NI; ni++)
          acc[mi][ni] = __builtin_amdgcn_mfma_f32_16x16x32_bf16(af[mi], bf[ni], acc[mi][ni], 0, 0, 0);
    }
    __syncthreads();
  }
  OutT* C = (OutT*)S.C;
  #pragma unroll
  for(int mi = 0; mi < 4; mi++){
    #pragma unroll
    for(int ni = 0; ni < NI; ni++){
      int col = colbase + wc*(BN/2) + ni*16 + (lane & 15);
      if(col >= N) continue;
      float bv = BIAS ? S.bias[col] : 0.f;
      #pragma unroll
      for(int j = 0; j < 4; j++){
        int row = rowbase + wr*64 + mi*16 + (lane >> 4)*4 + j;
        if(row >= M) continue;
        float v = acc[mi][ni][j] + bv;
        if constexpr (ELU) v = v > 0.f ? v : (__expf(v) - 1.f);
        if constexpr (sizeof(OutT) == 4) C[(size_t)row*S.ldc + col] = v;
        else                             C[(size_t)row*S.ldc + col] = (OutT)f2b(v);
      }
    }
  }
}

// ================= metapath GAT aggregate (D=32, 128 feat) =================
__global__ __launch_bounds__(256) void gat_agg_meta(
    const ushort* __restrict__ hs, const float* __restrict__ el,
    const float* __restrict__ er, const int* __restrict__ ofs,
    const int* __restrict__ colv, const float* __restrict__ bias,
    ushort* __restrict__ outv, int Nd){
  const int wslot = threadIdx.x >> 6;
  const int node = blockIdx.x*4 + wslot;
  const int lane = threadIdx.x & 63;
  __shared__ int   lds_s[4][64];
  __shared__ float lds_w[4][256];
  if(node >= Nd) return;
  const int e0 = ofs[node], e1 = ofs[node+1];
  const int g = lane >> 4, q = lane & 15;
  const int hh = q >> 2;
  const float4 erv = *(const float4*)(er + (size_t)node*4);
  float m0=-INFINITY, m1=-INFINITY, m2=-INFINITY, m3=-INFINITY;
  float sw0=0.f, sw1=0.f, sw2=0.f, sw3=0.f;
  float acc[8];
  #pragma unroll
  for(int r = 0; r < 8; r++) acc[r] = 0.f;

  for(int base = e0; base < e1; base += 64){
    int nch = e1 - base; if(nch > 64) nch = 64;
    int s_l = colv[base + (lane < nch ? lane : nch-1)];
    float4 ev = *(const float4*)(el + (size_t)s_l*4);
    float x0 = ev.x + erv.x; x0 = x0 > 0.f ? x0 : 0.2f*x0;
    float x1 = ev.y + erv.y; x1 = x1 > 0.f ? x1 : 0.2f*x1;
    float x2 = ev.z + erv.z; x2 = x2 > 0.f ? x2 : 0.2f*x2;
    float x3 = ev.w + erv.w; x3 = x3 > 0.f ? x3 : 0.2f*x3;
    if(lane >= nch){ x0 = x1 = x2 = x3 = -INFINITY; }
    float c0=x0, c1=x1, c2=x2, c3=x3;
    #pragma unroll
    for(int off = 32; off; off >>= 1){
      c0 = fmaxf(c0, __shfl_xor(c0, off));
      c1 = fmaxf(c1, __shfl_xor(c1, off));
      c2 = fmaxf(c2, __shfl_xor(c2, off));
      c3 = fmaxf(c3, __shfl_xor(c3, off));
    }
    float n0 = fmaxf(m0,c0), n1 = fmaxf(m1,c1), n2 = fmaxf(m2,c2), n3 = fmaxf(m3,c3);
    float r0 = __expf(m0-n0), r1 = __expf(m1-n1), r2 = __expf(m2-n2), r3 = __expf(m3-n3);
    float w0 = __expf(x0-n0), w1 = __expf(x1-n1), w2 = __expf(x2-n2), w3 = __expf(x3-n3);
    sw0 = sw0*r0 + w0; sw1 = sw1*r1 + w1; sw2 = sw2*r2 + w2; sw3 = sw3*r3 + w3;
    float rh = hh==0 ? r0 : (hh==1 ? r1 : (hh==2 ? r2 : r3));
    #pragma unroll
    for(int r = 0; r < 8; r++) acc[r] *= rh;
    m0=n0; m1=n1; m2=n2; m3=n3;
    lds_s[wslot][lane] = s_l;
    lds_w[wslot][lane*4+0] = w0; lds_w[wslot][lane*4+1] = w1;
    lds_w[wslot][lane*4+2] = w2; lds_w[wslot][lane*4+3] = w3;
    int npad = (nch + 7) & ~7;
    for(int j = 0; j < npad; j += 8){
      int sA = lds_s[wslot][j + g];
      int sB = lds_s[wslot][j + 4 + g];
      float wA = lds_w[wslot][(j + g)*4 + hh];
      float wB = lds_w[wslot][(j + 4 + g)*4 + hh];
      bh8 vA = *(const bh8*)(hs + (size_t)sA*128 + q*8);
      bh8 vB = *(const bh8*)(hs + (size_t)sB*128 + q*8);
      #pragma unroll
      for(int r = 0; r < 8; r++) acc[r] += wA * b2f((ushort)vA[r]);
      #pragma unroll
      for(int r = 0; r < 8; r++) acc[r] += wB * b2f((ushort)vB[r]);
    }
  }
  #pragma unroll
  for(int off = 32; off; off >>= 1){
    sw0 += __shfl_xor(sw0, off); sw1 += __shfl_xor(sw1, off);
    sw2 += __shfl_xor(sw2, off); sw3 += __shfl_xor(sw3, off);
  }
  #pragma unroll
  for(int r = 0; r < 8; r++){
    acc[r] += __shfl_xor(acc[r], 16);
    acc[r] += __shfl_xor(acc[r], 32);
  }
  float swh = hh==0 ? sw0 : (hh==1 ? sw1 : (hh==2 ? sw2 : sw3));
  float den = (swh == 0.f) ? 1.f : swh;
  if(g == 0){
    bh8 ov;
    #pragma unroll
    for(int r = 0; r < 8; r++){
      float v = acc[r]/den + bias[q*8 + r];
      v = v > 0.f ? v : (__expf(v) - 1.f);
      ov[r] = (short)f2b(v);
    }
    *(bh8*)(outv + (size_t)node*128 + q*8) = ov;
  }
}

// ================= bipartite GAT aggregate, low-degree version =================
// One 16-lane group per node (4 nodes/wave, 16 nodes/block). Two-pass softmax,
// weight math replicated across the group's lanes (no shuffles, no LDS).
// Lane q owns dims q*4..q*4+3; per edge: broadcast colv/el + 8B coalesced proj.
struct ASeg { const int* ofs; const int* colv; const float* el; const float* er; ushort* agg; };
__global__ __launch_bounds__(256) void gat_agg_proj3(ASeg s0, ASeg s1, ASeg s2,
    const ushort* __restrict__ proj, int2 pbase, int Nd, int nb){
  const int seg = blockIdx.x / nb;
  const ASeg S = seg == 0 ? s0 : (seg == 1 ? s1 : s2);
  const ushort* pj = proj + (size_t)(seg == 0 ? 0 : (seg == 1 ? pbase.x : pbase.y))*64;
  const int node = (blockIdx.x - seg*nb)*16 + (threadIdx.x >> 4);
  const int q = threadIdx.x & 15;
  if(node >= Nd) return;
  const int e0 = S.ofs[node], e1 = S.ofs[node+1];
  const float4 erv = *(const float4*)(S.er + (size_t)node*4);
  // pass 1: per-head max (replicated in all 16 lanes of the group)
  float m0=-INFINITY, m1=-INFINITY, m2=-INFINITY, m3=-INFINITY;
  for(int e = e0; e < e1; e++){
    int s = S.colv[e];
    float4 ev = *(const float4*)(S.el + (size_t)s*4);
    float x0 = ev.x + erv.x; x0 = x0 > 0.f ? x0 : 0.2f*x0;
    float x1 = ev.y + erv.y; x1 = x1 > 0.f ? x1 : 0.2f*x1;
    float x2 = ev.z + erv.z; x2 = x2 > 0.f ? x2 : 0.2f*x2;
    float x3 = ev.w + erv.w; x3 = x3 > 0.f ? x3 : 0.2f*x3;
    m0 = fmaxf(m0,x0); m1 = fmaxf(m1,x1); m2 = fmaxf(m2,x2); m3 = fmaxf(m3,x3);
  }
  // pass 2: weights + aggregate (lane q: 4 dims x 4 heads)
  float sw0=0.f, sw1=0.f, sw2=0.f, sw3=0.f;
  float acc[4][4];
  #pragma unroll
  for(int d = 0; d < 4; d++)
    #pragma unroll
    for(int h = 0; h < 4; h++) acc[d][h] = 0.f;
  for(int e = e0; e < e1; e++){
    int s = S.colv[e];
    float4 ev = *(const float4*)(S.el + (size_t)s*4);
    float x0 = ev.x + erv.x; x0 = x0 > 0.f ? x0 : 0.2f*x0;
    float x1 = ev.y + erv.y; x1 = x1 > 0.f ? x1 : 0.2f*x1;
    float x2 = ev.z + erv.z; x2 = x2 > 0.f ? x2 : 0.2f*x2;
    float x3 = ev.w + erv.w; x3 = x3 > 0.f ? x3 : 0.2f*x3;
    float w0 = __expf(x0-m0), w1 = __expf(x1-m1);
    float w2 = __expf(x2-m2), w3 = __expf(x3-m3);
    sw0 += w0; sw1 += w1; sw2 += w2; sw3 += w3;
    ushort4 p = *(const ushort4*)(pj + (size_t)s*64 + q*4);
    float f0 = b2f(p.x), f1 = b2f(p.y), f2 = b2f(p.z), f3 = b2f(p.w);
    acc[0][0] += w0*f0; acc[0][1] += w1*f0; acc[0][2] += w2*f0; acc[0][3] += w3*f0;
    acc[1][0] += w0*f1; acc[1][1] += w1*f1; acc[1][2] += w2*f1; acc[1][3] += w3*f1;
    acc[2][0] += w0*f2; acc[2][1] += w1*f2; acc[2][2] += w2*f2; acc[2][3] += w3*f2;
    acc[3][0] += w0*f3; acc[3][1] += w1*f3; acc[3][2] += w2*f3; acc[3][3] += w3*f3;
  }
  float dn[4];
  dn[0] = (sw0 == 0.f) ? 1.f : sw0;
  dn[1] = (sw1 == 0.f) ? 1.f : sw1;
  dn[2] = (sw2 == 0.f) ? 1.f : sw2;
  dn[3] = (sw3 == 0.f) ? 1.f : sw3;
  ushort* orow = S.agg + (size_t)node*256;
  #pragma unroll
  for(int h = 0; h < 4; h++){
    ushort4 o;
    o.x = f2b(acc[0][h]/dn[h]); o.y = f2b(acc[1][h]/dn[h]);
    o.z = f2b(acc[2][h]/dn[h]); o.w = f2b(acc[3][h]/dn[h]);
    *(ushort4*)(orow + h*64 + q*4) = o;
  }
}

// ================= host orchestration =================
extern "C" void kernel_launch(void* const* d_in, const int* in_sizes, int n_in,
                              void* d_out, int out_size, void* d_ws, size_t ws_size,
                              hipStream_t stream){
  const float* hp   = (const float*)d_in[0];
  const float* hq   = (const float*)d_in[1];
  const float* hk   = (const float*)d_in[2];
  const float* ha   = (const float*)d_in[3];
  const int* meta_src = (const int*)d_in[4];
  const int* meta_dst = (const int*)d_in[5];
  const int* q_src = (const int*)d_in[6];
  const int* q_dst = (const int*)d_in[7];
  const int* k_src = (const int*)d_in[8];
  const int* k_dst = (const int*)d_in[9];
  const int* a_src = (const int*)d_in[10];
  const int* a_dst = (const int*)d_in[11];
  const float* W0  = (const float*)d_in[12]; const float* al0 = (const float*)d_in[13];
  const float* ar0 = (const float*)d_in[14]; const float* b0  = (const float*)d_in[15];
  const float* W1  = (const float*)d_in[16]; const float* al1 = (const float*)d_in[17];
  const float* ar1 = (const float*)d_in[18]; const float* b1  = (const float*)d_in[19];
  const float* Wq  = (const float*)d_in[20]; const float* alq = (const float*)d_in[21];
  const float* arq = (const float*)d_in[22]; const float* bq  = (const float*)d_in[23];
  const float* Wkw = (const float*)d_in[24]; const float* alkw= (const float*)d_in[25];
  const float* arkw= (const float*)d_in[26]; const float* bkw = (const float*)d_in[27];
  const float* Watt= (const float*)d_in[28]; const float* alatt=(const float*)d_in[29];
  const float* aratt=(const float*)d_in[30]; const float* batt= (const float*)d_in[31];
  const float* Wpnn_a = (const float*)d_in[32];
  const float* Wpn_a  = (const float*)d_in[33];
  const float* Wpnn   = (const float*)d_in[34];
  const float* Wpn    = (const float*)d_in[35];
  const float* Wpred  = (const float*)d_in[36];
  const float* bpred  = (const float*)d_in[37];
  (void)n_in; (void)out_size; (void)ws_size;

  const int IN = 128, ATT = 64;
  const int NP = in_sizes[0]/IN, NQ = in_sizes[1]/ATT, NK = in_sizes[2]/ATT, NA = in_sizes[3]/ATT;
  const int EM = in_sizes[4], EQ = in_sizes[6], EK = in_sizes[8], EA = in_sizes[10];
  const int range = (NP + 7)/8;   // <= 8192 required for packed ebuf
  const int NS = NQ + NK + NA;

  // ----- workspace layout -----
  uint8_t* wp = (uint8_t*)d_ws;
  auto alloc = [&](size_t bytes)->uint8_t*{
    uint8_t* p = wp; wp += (bytes + 255) & ~(size_t)255; return p;
  };
  ushort* hcat_b = (ushort*)alloc((size_t)NP*256*2);
  ushort* hbuf_b = (ushort*)alloc((size_t)NP*128*2);
  ushort* hp_b   = (ushort*)alloc((size_t)NP*128*2);
  ushort* hpd_b  = (ushort*)alloc((size_t)NP*64*2);
  ushort* hs_b   = (ushort*)alloc((size_t)NP*128*2);
  ushort* feat_all = (ushort*)alloc((size_t)NS*64*2);
  ushort* proj_all = (ushort*)alloc((size_t)NS*64*2);
  ushort* agg_all  = (ushort*)alloc((size_t)3*NP*256*2);
  ushort* o_all    = (ushort*)alloc((size_t)3*NP*512*2);
  float* el    = (float*)alloc((size_t)NP*4*4);
  float* er    = (float*)alloc((size_t)NP*4*4);
  float* el_all= (float*)alloc((size_t)NS*4*4);
  float* er_all= (float*)alloc((size_t)3*NP*4*4);
  float* wf    = (float*)alloc((size_t)10*512*4);
  int* cnt4    = (int*)alloc((size_t)(4*NP+32)*4);
  int* bcur    = cnt4 + 4*NP;
  int* cur4    = (int*)alloc((size_t)4*NP*4);
  int* ofsm    = (int*)alloc((size_t)(NP+4)*4);
  int* ofsq    = (int*)alloc((size_t)(NP+4)*4);
  int* ofsk    = (int*)alloc((size_t)(NP+4)*4);
  int* ofsa    = (int*)alloc((size_t)(NP+4)*4);
  int* colm    = (int*)alloc((size_t)EM*4);
  int* colq    = (int*)alloc((size_t)EQ*4);
  int* colk    = (int*)alloc((size_t)EK*4);
  int* cola    = (int*)alloc((size_t)EA*4);
  const int capM = EM/4+1024, capQ = EQ/4+1024, capK = EK/4+1024, capA = EA/4+1024;
  uint* ebm = (uint*)alloc((size_t)8*capM*4);
  uint* ebq = (uint*)alloc((size_t)8*capQ*4);
  uint* ebk = (uint*)alloc((size_t)8*capK*4);
  uint* eba = (uint*)alloc((size_t)8*capA*4);
  ushort* W0T    = (ushort*)alloc(128*128*2);
  ushort* W1T    = (ushort*)alloc(128*128*2);
  ushort* WTg3   = (ushort*)alloc((size_t)3*4*128*64*2);
  ushort* WpnT   = (ushort*)alloc((size_t)64*512*2);
  ushort* WpnnT  = (ushort*)alloc(64*128*2);
  ushort* Wpnn_aT= (ushort*)alloc(64*128*2);
  ushort* Wpn_aT = (ushort*)alloc(64*64*2);
  ushort* WpredT = (ushort*)alloc((size_t)1024*256*2);

  // ----- CSR build (5 dispatches) -----
  fill_zero_i32<<<(4*NP+32+255)/256, 256, 0, stream>>>(cnt4, 4*NP+32);
  {
    int bm = EM/1024 + 1, bq2 = EQ/1024 + 1, bk2 = EK/1024 + 1, ba2 = EA/1024 + 1;
    P4 g0{meta_src, meta_dst, ebm, EM, capM, 0, bm};
    P4 g1{q_src, q_dst, ebq, EQ, capQ, bm, bm+bq2};
    P4 g2{k_src, k_dst, ebk, EK, capK, bm+bq2, bm+bq2+bk2};
    P4 g3{a_src, a_dst, eba, EA, capA, bm+bq2+bk2, bm+bq2+bk2+ba2};
    partition_all_k<<<g3.bend, 256, 0, stream>>>(g0, g1, g2, g3, bcur, range);
  }
  auto Jof = [&](int E){ int J = E/65536 + 8; if(J > 48) J = 48; return J; };
  {
    int jm = 8*Jof(EM), jq = 8*Jof(EQ), jk = 8*Jof(EK), ja = 8*Jof(EA);
    B4 g0{ebm, capM, cnt4 + 0*NP, 0, jm};
    B4 g1{ebq, capQ, cnt4 + 1*NP, jm, jm+jq};
    B4 g2{ebk, capK, cnt4 + 2*NP, jm+jq, jm+jq+jk};
    B4 g3{eba, capA, cnt4 + 3*NP, jm+jq+jk, jm+jq+jk+ja};
    count_all_k<<<g3.bend, 256, 0, stream>>>(g0, g1, g2, g3, bcur, range);
    scan4_k<<<4, 1024, 0, stream>>>(cnt4, cnt4+NP, cnt4+2*NP, cnt4+3*NP,
                                    ofsm, ofsq, ofsk, ofsa,
                                    cur4, cur4+NP, cur4+2*NP, cur4+3*NP, NP);
    SB4 s0{ebm, capM, cur4 + 0*NP, colm, 0, jm};
    SB4 s1{ebq, capQ, cur4 + 1*NP, colq, jm, jm+jq};
    SB4 s2{ebk, capK, cur4 + 2*NP, colk, jm+jq, jm+jq+jk};
    SB4 s3{eba, capA, cur4 + 3*NP, cola, jm+jq+jk, jm+jq+jk+ja};
    scatter_all_k<<<s3.bend, 256, 0, stream>>>(s0, s1, s2, s3, bcur, range);
  }

  // ----- conversions + weight prep (5 dispatches) -----
  {
    int c0 = NP*128/4, c1 = c0 + NQ*64/4;
    cvt_all_k<<<(c1+255)/256, 256, 0, stream>>>(hp, hq, hp_b, feat_all, make_int2(c0, c1));
    int d0 = NK*64/4, d1 = d0 + NA*64/4;
    cvt_all_k<<<(d1+255)/256, 256, 0, stream>>>(hk, ha,
        feat_all + (size_t)NQ*64, feat_all + (size_t)(NQ+NK)*64, make_int2(d0, d1));
  }
  {
    WTAll a;
    a.d[0] = {W0, W0T, 128, 128};      a.d[1] = {W1, W1T, 128, 128};
    a.d[2] = {Wpn, WpnT, 512, 64};     a.d[3] = {Wpnn, WpnnT, 128, 64};
    a.d[4] = {Wpnn_a, Wpnn_aT, 128, 64}; a.d[5] = {Wpn_a, Wpn_aT, 64, 64};
    a.d[6] = {Wpred, WpredT, 256, 1000};
    int items[7] = {128*128, 128*128, 64*512, 64*128, 64*128, 64*64, 1024*256};
    a.cum[0] = 0;
    for(int t = 0; t < 7; t++) a.cum[t+1] = a.cum[t] + items[t];
    wT_all_k<<<(a.cum[7]+255)/256, 256, 0, stream>>>(a);
  }
  wTg3_k<<<(3*32768+255)/256, 256, 0, stream>>>(Wq, Wkw, Watt, WTg3);
  {
    FAll f;
    f.d[0] = {W0, al0, wf+0*512, 128, 32};  f.d[1] = {W0, ar0, wf+1*512, 128, 32};
    f.d[2] = {W1, al1, wf+2*512, 128, 32};  f.d[3] = {W1, ar1, wf+3*512, 128, 32};
    f.d[4] = {Wq, alq, wf+4*512, 64, 128};  f.d[5] = {Wq, arq, wf+5*512, 64, 128};
    f.d[6] = {Wkw, alkw, wf+6*512, 64, 128};f.d[7] = {Wkw, arkw, wf+7*512, 64, 128};
    f.d[8] = {Watt, alatt, wf+8*512, 64, 128};f.d[9] = {Watt, aratt, wf+9*512, 64, 128};
    fold_all_k<<<10, 256, 0, stream>>>(f);
  }

  auto launch_gemm = [&]<int BN, typename OutT, bool BIAS, bool GRP, bool ELU>(
      GSeg a, GSeg b, GSeg c, int nseg, int M, int N, int K, int lda){
    int Npad = (N + BN - 1)/BN*BN;
    dim3 g((M + 127)/128, GRP ? 4 : Npad/BN, nseg);
    gemm_mfma_b<BN, OutT, BIAS, GRP, ELU><<<g, 256, 0, stream>>>(a, b, c, M, N, K, lda);
  };
  GSeg z{};

  // ----- metapath GAT layer 0 -----
  launch_gemm.template operator()<128, ushort, false, false, false>(
      GSeg{hp_b, W0T, nullptr, hs_b, 128}, z, z, 1, NP, 128, 128, 128);
  gemv8v<ushort><<<(NP/2+3)/4, 256, 0, stream>>>(hp_b, wf+0*512, wf+1*512, el, er, NP, 128);
  gat_agg_meta<<<(NP+3)/4, 256, 0, stream>>>(hs_b, el, er, ofsm, colm, b0, hbuf_b, NP);

  // ----- metapath GAT layer 1 -----
  launch_gemm.template operator()<128, ushort, false, false, false>(
      GSeg{hbuf_b, W1T, nullptr, hs_b, 128}, z, z, 1, NP, 128, 128, 128);
  gemv8v<ushort><<<(NP/2+3)/4, 256, 0, stream>>>(hbuf_b, wf+2*512, wf+3*512, el, er, NP, 128);
  gat_agg_meta<<<(NP+3)/4, 256, 0, stream>>>(hs_b, el, er, ofsm, colm, b1, hbuf_b, NP);

  // ----- batched: hcat[:,0:64] = h @ Wpnn ; hpd = hp @ Wpnn_a -----
  launch_gemm.template operator()<64, ushort, false, false, false>(
      GSeg{hbuf_b, WpnnT, nullptr, hcat_b, 256},
      GSeg{hp_b, Wpnn_aT, nullptr, hpd_b, 64}, z, 2, NP, 64, 128, 128);

  // ----- bipartite GATs (fully batched across q/k/a) -----
  launch_gemm.template operator()<64, ushort, false, false, false>(
      GSeg{feat_all, Wpn_aT, nullptr, proj_all, 64}, z, z, 1, NS, 64, 64, 64);
  gemv4v_seg3<<<(NS/4+3)/4, 256, 0, stream>>>(proj_all, wf+4*512, wf+6*512, wf+8*512,
      el_all, NS, NQ, NQ+NK);
  gemv4v_er3<<<(NP/4+3)/4, 256, 0, stream>>>(hpd_b, wf+5*512, wf+7*512, wf+9*512,
      er_all, er_all + (size_t)NP*4, er_all + (size_t)2*NP*4, NP);
  {
    int nb = (NP+15)/16;   // 16 nodes per block (one 16-lane group per node)
    ASeg a0{ofsq, colq, el_all,                    er_all,                    agg_all};
    ASeg a1{ofsk, colk, el_all + (size_t)NQ*4,     er_all + (size_t)NP*4,     agg_all + (size_t)NP*256};
    ASeg a2{ofsa, cola, el_all + (size_t)(NQ+NK)*4,er_all + (size_t)2*NP*4,   agg_all + (size_t)2*NP*256};
    gat_agg_proj3<<<3*nb, 256, 0, stream>>>(a0, a1, a2, proj_all, make_int2(NQ, NQ+NK), NP, nb);
  }
  launch_gemm.template operator()<128, ushort, true, true, true>(
      GSeg{agg_all,                    WTg3 + 0*32768, bq,   o_all, 512},
      GSeg{agg_all + (size_t)NP*256,   WTg3 + 1*32768, bkw,  o_all + (size_t)NP*512, 512},
      GSeg{agg_all + (size_t)2*NP*256, WTg3 + 2*32768, batt, o_all + (size_t)2*NP*512, 512},
      3, NP, 512, 64, 256);
  launch_gemm.template operator()<64, ushort, false, false, false>(
      GSeg{o_all,                    WpnT, nullptr, hcat_b + 64, 256},
      GSeg{o_all + (size_t)NP*512,   WpnT, nullptr, hcat_b + 128, 256},
      GSeg{o_all + (size_t)2*NP*512, WpnT, nullptr, hcat_b + 192, 256},
      3, NP, 64, 512, 512);

  // ----- final: out = hcat @ Wpred + bpred -----
  launch_gemm.template operator()<128, float, true, false, false>(
      GSeg{hcat_b, WpredT, bpred, d_out, 1000}, z, z, 1, NP, 1000, 256, 256);
}

// Round 11
// 805.355 us; speedup vs baseline: 1.6944x; 1.0417x over previous
//
#include <hip/hip_runtime.h>
#include <hip/hip_bf16.h>
#include <math.h>
#include <stdint.h>

typedef __attribute__((ext_vector_type(8))) short bh8;
typedef __attribute__((ext_vector_type(4))) float f32x4;

#define AS1(p) ((const __attribute__((address_space(1))) void*)(p))
#define AS3(p) ((__attribute__((address_space(3))) void*)(p))

__device__ inline ushort f2b(float f){
  uint u = __builtin_bit_cast(uint, f);
  u += 0x7fff + ((u >> 16) & 1);
  return (ushort)(u >> 16);
}
__device__ inline float b2f(ushort b){ return __builtin_bit_cast(float, (uint)b << 16); }

// ================= CSR build (all 4 graphs fused, packed staging) =================
__global__ void fill_zero_i32(int* __restrict__ p, int n){
  int i = blockIdx.x*blockDim.x + threadIdx.x;
  if(i < n) p[i] = 0;
}

struct P4 { const int* src; const int* dst; uint* ebuf; int E; int cap; int bbeg; int bend; };

__global__ __launch_bounds__(256) void partition_all_k(P4 g0, P4 g1, P4 g2, P4 g3,
    int* __restrict__ bcur, int range){
  P4 G; int gi;
  int b = blockIdx.x;
  if(b < g0.bend){ G = g0; gi = 0; }
  else if(b < g1.bend){ G = g1; gi = 1; }
  else if(b < g2.bend){ G = g2; gi = 2; }
  else { G = g3; gi = 3; }
  const int lb = b - G.bbeg, nb = G.bend - G.bbeg;
  __shared__ int hist[8], base[8];
  const int tid = threadIdx.x;
  int* bc = bcur + gi*8;
  for(int c0 = lb*256; c0 < G.E; c0 += nb*256){
    int i = c0 + tid;
    int d = 0, s = 0, bk = -1;
    if(i < G.E){ d = G.dst[i]; s = G.src[i]; bk = d / range; }
    if(tid < 8) hist[tid] = 0;
    __syncthreads();
    int rank = 0;
    if(bk >= 0) rank = atomicAdd(&hist[bk], 1);
    __syncthreads();
    if(tid < 8) base[tid] = hist[tid] ? atomicAdd(&bc[tid], hist[tid]) : 0;
    __syncthreads();
    if(bk >= 0){
      int pos = base[bk] + rank;
      if(pos < G.cap) G.ebuf[(size_t)bk*G.cap + pos] = ((uint)s << 13) | (uint)(d - bk*range);
    }
    __syncthreads();
  }
}

struct B4 { const uint* ebuf; int cap; int* cnt; int bbeg; int bend; };
__global__ __launch_bounds__(256) void count_all_k(B4 g0, B4 g1, B4 g2, B4 g3,
    const int* __restrict__ bcur, int range){
  B4 G; int gi;
  int b = blockIdx.x;
  if(b < g0.bend){ G = g0; gi = 0; }
  else if(b < g1.bend){ G = g1; gi = 1; }
  else if(b < g2.bend){ G = g2; gi = 2; }
  else { G = g3; gi = 3; }
  const int local = b - G.bbeg, J = (G.bend - G.bbeg) >> 3;
  const int bk = local & 7, j = local >> 3;
  int nb = bcur[gi*8 + bk]; if(nb > G.cap) nb = G.cap;
  const uint* eb = G.ebuf + (size_t)bk*G.cap;
  int* cb = G.cnt + bk*range;
  int per = (nb + J - 1)/J;
  int beg = j*per, end = beg + per; if(end > nb) end = nb;
  for(int i = beg + threadIdx.x; i < end; i += 256)
    atomicAdd(&cb[eb[i] & 8191u], 1);
}

struct SB4 { const uint* ebuf; int cap; int* cursor; int* colv; int bbeg; int bend; };
__global__ __launch_bounds__(256) void scatter_all_k(SB4 g0, SB4 g1, SB4 g2, SB4 g3,
    const int* __restrict__ bcur, int range){
  SB4 G; int gi;
  int b = blockIdx.x;
  if(b < g0.bend){ G = g0; gi = 0; }
  else if(b < g1.bend){ G = g1; gi = 1; }
  else if(b < g2.bend){ G = g2; gi = 2; }
  else { G = g3; gi = 3; }
  const int local = b - G.bbeg, J = (G.bend - G.bbeg) >> 3;
  const int bk = local & 7, j = local >> 3;
  int nb = bcur[gi*8 + bk]; if(nb > G.cap) nb = G.cap;
  const uint* eb = G.ebuf + (size_t)bk*G.cap;
  int* ub = G.cursor + bk*range;
  int per = (nb + J - 1)/J;
  int beg = j*per, end = beg + per; if(end > nb) end = nb;
  for(int i = beg + threadIdx.x; i < end; i += 256){
    uint e = eb[i];
    int p = atomicAdd(&ub[e & 8191u], 1);
    G.colv[p] = (int)(e >> 13);
  }
}

__global__ __launch_bounds__(1024) void scan4_k(
    const int* c0, const int* c1, const int* c2, const int* c3,
    int* o0, int* o1, int* o2, int* o3,
    int* u0, int* u1, int* u2, int* u3, int n){
  const int* cnt = blockIdx.x==0?c0:(blockIdx.x==1?c1:(blockIdx.x==2?c2:c3));
  int* ofs    = blockIdx.x==0?o0:(blockIdx.x==1?o1:(blockIdx.x==2?o2:o3));
  int* cursor = blockIdx.x==0?u0:(blockIdx.x==1?u1:(blockIdx.x==2?u2:u3));
  __shared__ int wsum[16];
  __shared__ int carry_s;
  int tid = threadIdx.x, wid = tid >> 6, lane = tid & 63;
  if(tid == 0) carry_s = 0;
  __syncthreads();
  for(int base = 0; base < n; base += 4096){
    int i0 = base + tid*4;
    int4 v = make_int4(0,0,0,0);
    if(i0 + 3 < n) v = *(const int4*)(cnt + i0);
    else if(i0 < n){
      v.x = cnt[i0];
      if(i0+1 < n) v.y = cnt[i0+1];
      if(i0+2 < n) v.z = cnt[i0+2];
    }
    int s1 = v.x + v.y, s2 = s1 + v.z, tot = s2 + v.w;
    int x = tot;
    #pragma unroll
    for(int off = 1; off < 64; off <<= 1){
      int t = __shfl_up(x, off);
      if(lane >= off) x += t;
    }
    if(lane == 63) wsum[wid] = x;
    __syncthreads();
    if(tid < 16){
      int y = wsum[tid];
      #pragma unroll
      for(int off = 1; off < 16; off <<= 1){
        int t = __shfl_up(y, off);
        if(tid >= off) y += t;
      }
      wsum[tid] = y;
    }
    __syncthreads();
    int pre = (wid ? wsum[wid-1] : 0) + carry_s + (x - tot);
    if(i0 + 3 < n){
      int4 o = make_int4(pre, pre+v.x, pre+s1, pre+s2);
      *(int4*)(ofs + i0) = o;
      *(int4*)(cursor + i0) = o;
    } else if(i0 < n){
      ofs[i0] = pre; cursor[i0] = pre;
      if(i0+1 < n){ ofs[i0+1] = pre+v.x; cursor[i0+1] = pre+v.x; }
      if(i0+2 < n){ ofs[i0+2] = pre+s1; cursor[i0+2] = pre+s1; }
    }
    __syncthreads();
    if(tid == 0) carry_s += wsum[15];
    __syncthreads();
  }
  if(tid == 0) ofs[n] = carry_s;
}

// ================= preprocessing (fused) =================
__global__ void cvt_all_k(const float* i0, const float* i1, const float* i2, const float* i3,
    ushort* o0, ushort* o1, ushort* o2, ushort* o3, int4 cum){
  int i = blockIdx.x*blockDim.x + threadIdx.x;
  const float* in; ushort* out; int base;
  if(i < cum.x){ in=i0; out=o0; base=0; }
  else if(i < cum.y){ in=i1; out=o1; base=cum.x; }
  else if(i < cum.z){ in=i2; out=o2; base=cum.y; }
  else if(i < cum.w){ in=i3; out=o3; base=cum.z; }
  else return;
  int l = i - base;
  float4 v = ((const float4*)in)[l];
  ushort4 o; o.x=f2b(v.x); o.y=f2b(v.y); o.z=f2b(v.z); o.w=f2b(v.w);
  ((ushort4*)out)[l] = o;
}

struct WTD { const float* W; ushort* WT; int K; int N; };
struct WTAll { WTD d[7]; int cum[8]; };
__global__ void wT_all_k(WTAll a){
  int idx = blockIdx.x*blockDim.x + threadIdx.x;
  if(idx >= a.cum[7]) return;
  int j = 0;
  #pragma unroll
  for(int t = 1; t < 7; t++) if(idx >= a.cum[t]) j = t;
  int l = idx - a.cum[j];
  WTD d = a.d[j];
  int n = l / d.K, k = l - n*d.K;
  d.WT[l] = (n < d.N) ? f2b(d.W[(size_t)k*d.N + n]) : (ushort)0;
}

__global__ void wTg3_k(const float* W0, const float* W1, const float* W2, ushort* WT){
  int idx = blockIdx.x*blockDim.x + threadIdx.x;
  if(idx >= 3*32768) return;
  int g = idx >> 15, rem = idx & 32767;
  const float* W = g==0 ? W0 : (g==1 ? W1 : W2);
  int h = rem >> 13, r2 = rem & 8191;
  int n = r2 >> 6, k = r2 & 63;
  WT[idx] = f2b(W[(size_t)k*512 + h*128 + n]);
}

struct FD { const float* W; const float* a; float* out; int K; int D; };
struct FAll { FD d[10]; };
__global__ void fold_all_k(FAll f){
  FD d = f.d[blockIdx.x];
  for(int i = threadIdx.x; i < d.K*4; i += 256){
    int k = i >> 2, h = i & 3;
    const float* wr = d.W + (size_t)k*4*d.D + (size_t)h*d.D;
    const float* ar = d.a + (size_t)h*d.D;
    float s = 0.f;
    for(int dd = 0; dd < d.D; dd++) s += wr[dd]*ar[dd];
    d.out[i] = s;
  }
}

// ================= gemv =================
__device__ inline void ld4v(const float* p, float* v){
  float4 t = *(const float4*)p; v[0]=t.x; v[1]=t.y; v[2]=t.z; v[3]=t.w;
}
__device__ inline void ld4v(const ushort* p, float* v){
  ushort4 t = *(const ushort4*)p; v[0]=b2f(t.x); v[1]=b2f(t.y); v[2]=b2f(t.z); v[3]=b2f(t.w);
}

__global__ __launch_bounds__(256) void gemv4v_seg3(const ushort* __restrict__ A,
    const float* __restrict__ W0, const float* __restrict__ W1, const float* __restrict__ W2,
    float* __restrict__ outv, int M, int b1, int b2){
  const int w = (blockIdx.x*blockDim.x + threadIdx.x) >> 6;
  const int lane = threadIdx.x & 63;
  const int r = lane >> 4, q = lane & 15;
  int row = w*4 + r;
  bool valid = row < M;
  int rowc = valid ? row : (M-1);
  const float* Wf = rowc < b1 ? W0 : (rowc < b2 ? W1 : W2);
  float av[4];
  ld4v(A + (size_t)rowc*64 + q*4, av);
  float a[4] = {0.f,0.f,0.f,0.f};
  #pragma unroll
  for(int kk = 0; kk < 4; kk++){
    float4 wv = *(const float4*)(Wf + (q*4+kk)*4);
    a[0] += av[kk]*wv.x; a[1] += av[kk]*wv.y; a[2] += av[kk]*wv.z; a[3] += av[kk]*wv.w;
  }
  #pragma unroll
  for(int off = 1; off < 16; off <<= 1){
    a[0] += __shfl_xor(a[0], off); a[1] += __shfl_xor(a[1], off);
    a[2] += __shfl_xor(a[2], off); a[3] += __shfl_xor(a[3], off);
  }
  if(valid && q == 0){
    float4 o; o.x=a[0]; o.y=a[1]; o.z=a[2]; o.w=a[3];
    *(float4*)(outv + (size_t)row*4) = o;
  }
}

__global__ __launch_bounds__(256) void gemv4v_er3(const ushort* __restrict__ A,
    const float* __restrict__ W0, const float* __restrict__ W1, const float* __restrict__ W2,
    float* __restrict__ o0, float* __restrict__ o1, float* __restrict__ o2, int M){
  const int w = (blockIdx.x*blockDim.x + threadIdx.x) >> 6;
  const int lane = threadIdx.x & 63;
  const int r = lane >> 4, q = lane & 15;
  int row = w*4 + r;
  bool valid = row < M;
  int rowc = valid ? row : (M-1);
  float av[4];
  ld4v(A + (size_t)rowc*64 + q*4, av);
  float a[12];
  #pragma unroll
  for(int t = 0; t < 12; t++) a[t] = 0.f;
  #pragma unroll
  for(int kk = 0; kk < 4; kk++){
    float4 w0 = *(const float4*)(W0 + (q*4+kk)*4);
    float4 w1 = *(const float4*)(W1 + (q*4+kk)*4);
    float4 w2 = *(const float4*)(W2 + (q*4+kk)*4);
    a[0] += av[kk]*w0.x; a[1] += av[kk]*w0.y; a[2] += av[kk]*w0.z; a[3] += av[kk]*w0.w;
    a[4] += av[kk]*w1.x; a[5] += av[kk]*w1.y; a[6] += av[kk]*w1.z; a[7] += av[kk]*w1.w;
    a[8] += av[kk]*w2.x; a[9] += av[kk]*w2.y; a[10]+= av[kk]*w2.z; a[11]+= av[kk]*w2.w;
  }
  #pragma unroll
  for(int off = 1; off < 16; off <<= 1)
    #pragma unroll
    for(int t = 0; t < 12; t++) a[t] += __shfl_xor(a[t], off);
  if(valid && q == 0){
    float4 x; x.x=a[0]; x.y=a[1]; x.z=a[2]; x.w=a[3];
    *(float4*)(o0 + (size_t)row*4) = x;
    float4 y; y.x=a[4]; y.y=a[5]; y.z=a[6]; y.w=a[7];
    *(float4*)(o1 + (size_t)row*4) = y;
    float4 z; z.x=a[8]; z.y=a[9]; z.z=a[10]; z.w=a[11];
    *(float4*)(o2 + (size_t)row*4) = z;
  }
}

template<typename T>
__global__ __launch_bounds__(256) void gemv8v(const T* __restrict__ A,
    const float* __restrict__ Wfa, const float* __restrict__ Wfb,
    float* __restrict__ oa, float* __restrict__ ob, int M, int lda){
  const int w = (blockIdx.x*blockDim.x + threadIdx.x) >> 6;
  const int lane = threadIdx.x & 63;
  const int r = lane >> 5, q = lane & 31;
  int row = w*2 + r;
  bool valid = row < M;
  int rowc = valid ? row : (M-1);
  float av[4];
  ld4v(A + (size_t)rowc*lda + q*4, av);
  float a[4] = {0.f,0.f,0.f,0.f}, b[4] = {0.f,0.f,0.f,0.f};
  #pragma unroll
  for(int kk = 0; kk < 4; kk++){
    float4 wa = *(const float4*)(Wfa + (q*4+kk)*4);
    float4 wb = *(const float4*)(Wfb + (q*4+kk)*4);
    a[0] += av[kk]*wa.x; a[1] += av[kk]*wa.y; a[2] += av[kk]*wa.z; a[3] += av[kk]*wa.w;
    b[0] += av[kk]*wb.x; b[1] += av[kk]*wb.y; b[2] += av[kk]*wb.z; b[3] += av[kk]*wb.w;
  }
  #pragma unroll
  for(int off = 1; off < 32; off <<= 1){
    a[0] += __shfl_xor(a[0], off); a[1] += __shfl_xor(a[1], off);
    a[2] += __shfl_xor(a[2], off); a[3] += __shfl_xor(a[3], off);
    b[0] += __shfl_xor(b[0], off); b[1] += __shfl_xor(b[1], off);
    b[2] += __shfl_xor(b[2], off); b[3] += __shfl_xor(b[3], off);
  }
  if(valid && q == 0){
    float4 o; o.x=a[0]; o.y=a[1]; o.z=a[2]; o.w=a[3];
    *(float4*)(oa + (size_t)row*4) = o;
    float4 p; p.x=b[0]; p.y=b[1]; p.z=b[2]; p.w=b[3];
    *(float4*)(ob + (size_t)row*4) = p;
  }
}

// ================= batched bf16 MFMA GEMM (blockIdx.z = segment) =================
struct GSeg { const ushort* A; const ushort* BT; const float* bias; void* C; int ldc; };

template<int BN, typename OutT, bool BIAS>
__global__ __launch_bounds__(256) void gemm_mfma_b(GSeg s0, GSeg s1, GSeg s2,
    int M, int N, int K, int lda){
  constexpr int BM = 128, BK = 64;
  constexpr int NI = BN/32;
  constexpr int AIT = BM*BK/(256*8);
  constexpr int BIT = BN*BK/(256*8);
  __shared__ ushort lds[BM*BK + BN*BK];
  ushort* ldsA = lds;
  ushort* ldsB = lds + BM*BK;
  GSeg S = blockIdx.z == 0 ? s0 : (blockIdx.z == 1 ? s1 : s2);
  const int tid = threadIdx.x, wid = tid >> 6, lane = tid & 63;
  const int wr = wid >> 1, wc = wid & 1;
  const int rowbase = blockIdx.x*BM;
  const int colbase = blockIdx.y*BN;

  f32x4 acc[4][NI];
  #pragma unroll
  for(int mi = 0; mi < 4; mi++)
    #pragma unroll
    for(int ni = 0; ni < NI; ni++) acc[mi][ni] = (f32x4)0.f;

  for(int k0 = 0; k0 < K; k0 += BK){
    #pragma unroll
    for(int it = 0; it < AIT; it++){
      int idx = it*256 + wid*64 + lane;
      int r = idx >> 3, sl = idx & 7;
      int kb = sl ^ (r & 7);
      int grow = rowbase + r; if(grow >= M) grow = M-1;
      const ushort* src = S.A + (size_t)grow*lda + k0 + kb*8;
      __builtin_amdgcn_global_load_lds(AS1(src), AS3(ldsA + (size_t)(it*256 + wid*64)*8), 16, 0, 0);
    }
    #pragma unroll
    for(int it = 0; it < BIT; it++){
      int idx = it*256 + wid*64 + lane;
      int r = idx >> 3, sl = idx & 7;
      int kb = sl ^ (r & 7);
      const ushort* src = S.BT + (size_t)(colbase + r)*K + k0 + kb*8;
      __builtin_amdgcn_global_load_lds(AS1(src), AS3(ldsB + (size_t)(it*256 + wid*64)*8), 16, 0, 0);
    }
    __syncthreads();
    #pragma unroll
    for(int kk = 0; kk < 2; kk++){
      bh8 af[4], bf[NI];
      #pragma unroll
      for(int mi = 0; mi < 4; mi++){
        int arow = wr*64 + mi*16 + (lane & 15);
        int kb = kk*4 + (lane >> 4);
        af[mi] = *(const bh8*)(ldsA + arow*BK + ((kb ^ (arow & 7)) << 3));
      }
      #pragma unroll
      for(int ni = 0; ni < NI; ni++){
        int brow = wc*(BN/2) + ni*16 + (lane & 15);
        int kb = kk*4 + (lane >> 4);
        bf[ni] = *(const bh8*)(ldsB + brow*BK + ((kb ^ (brow & 7)) << 3));
      }
      #pragma unroll
      for(int mi = 0; mi < 4; mi++)
        #pragma unroll
        for(int ni = 0; ni < NI; ni++)
          acc[mi][ni] = __builtin_amdgcn_mfma_f32_16x16x32_bf16(af[mi], bf[ni], acc[mi][ni], 0, 0, 0);
    }
    __syncthreads();
  }
  OutT* C = (OutT*)S.C;
  #pragma unroll
  for(int mi = 0; mi < 4; mi++){
    #pragma unroll
    for(int ni = 0; ni < NI; ni++){
      int col = colbase + wc*(BN/2) + ni*16 + (lane & 15);
      if(col >= N) continue;
      float bv = BIAS ? S.bias[col] : 0.f;
      #pragma unroll
      for(int j = 0; j < 4; j++){
        int row = rowbase + wr*64 + mi*16 + (lane >> 4)*4 + j;
        if(row >= M) continue;
        float v = acc[mi][ni][j] + bv;
        if constexpr (sizeof(OutT) == 4) C[(size_t)row*S.ldc + col] = v;
        else                             C[(size_t)row*S.ldc + col] = (OutT)f2b(v);
      }
    }
  }
}

// ================= fused bipartite tail: hcat_slice = elu(agg@Wg^T+b) @ Wpn =================
// Per 128-row block & segment: loop heads: P=elu(agg_h@Wg_h^T+b) -> bf16 LDS tile,
// out[128,64] += P @ Wpn_h (K=128). o never hits HBM (saves ~307MB round-trip).
__global__ __launch_bounds__(256) void bip_tail_k(
    const ushort* __restrict__ agg,     // [3][M][256]
    const ushort* __restrict__ WTg3,    // [3][4][128][64] k-contiguous
    const ushort* __restrict__ WpnT,    // [64][512] = Wpn^T
    const float* bias0, const float* bias1, const float* bias2,
    ushort* __restrict__ hcat,          // [M][256]; cols 64+seg*64..
    int M){
  __shared__ ushort ldsA[128*64];
  __shared__ ushort ldsB[128*64];
  __shared__ ushort ldsP[128*128];
  __shared__ ushort ldsW[64*128];
  const int seg = blockIdx.z;
  const ushort* A  = agg + (size_t)seg*M*256;
  const ushort* Wg = WTg3 + (size_t)seg*32768;
  const float* bias = seg==0 ? bias0 : (seg==1 ? bias1 : bias2);
  ushort* outp = hcat + 64 + seg*64;
  const int tid = threadIdx.x, lane = tid & 63, wid = tid >> 6;
  const int wr = wid >> 1, wc = wid & 1;
  const int rowbase = blockIdx.x*128;

  f32x4 acc_out[4][2];
  #pragma unroll
  for(int mi = 0; mi < 4; mi++){ acc_out[mi][0] = (f32x4)0.f; acc_out[mi][1] = (f32x4)0.f; }

  for(int hh = 0; hh < 4; hh++){
    // stage agg head-slice [128][64]
    #pragma unroll
    for(int it = 0; it < 4; it++){
      int idx = it*256 + tid;
      int r = idx >> 3, sl = idx & 7;
      int kb = sl ^ (r & 7);
      int grow = rowbase + r; if(grow >= M) grow = M-1;
      __builtin_amdgcn_global_load_lds(AS1(A + (size_t)grow*256 + hh*64 + kb*8),
                                       AS3(ldsA + (size_t)idx*8), 16, 0, 0);
    }
    // stage Wg head [128][64]
    #pragma unroll
    for(int it = 0; it < 4; it++){
      int idx = it*256 + tid;
      int r = idx >> 3, sl = idx & 7;
      int kb = sl ^ (r & 7);
      __builtin_amdgcn_global_load_lds(AS1(Wg + hh*8192 + r*64 + kb*8),
                                       AS3(ldsB + (size_t)idx*8), 16, 0, 0);
    }
    // stage Wpn head-slice [64][128] (BK=128: 16 slots/row)
    #pragma unroll
    for(int it = 0; it < 4; it++){
      int idx = it*256 + tid;
      int r = idx >> 4, sl = idx & 15;
      int kb = sl ^ (r & 7);
      __builtin_amdgcn_global_load_lds(AS1(WpnT + (size_t)r*512 + hh*128 + kb*8),
                                       AS3(ldsW + (size_t)idx*8), 16, 0, 0);
    }
    __syncthreads();
    // phase 1: P = agg_h @ Wg_h^T  (K=64)
    f32x4 accp[4][4];
    #pragma unroll
    for(int mi = 0; mi < 4; mi++)
      #pragma unroll
      for(int ni = 0; ni < 4; ni++) accp[mi][ni] = (f32x4)0.f;
    #pragma unroll
    for(int kk = 0; kk < 2; kk++){
      bh8 af[4], bf[4];
      int kb = kk*4 + (lane >> 4);
      #pragma unroll
      for(int mi = 0; mi < 4; mi++){
        int arow = wr*64 + mi*16 + (lane & 15);
        af[mi] = *(const bh8*)(ldsA + arow*64 + ((kb ^ (arow & 7)) << 3));
      }
      #pragma unroll
      for(int ni = 0; ni < 4; ni++){
        int brow = wc*64 + ni*16 + (lane & 15);
        bf[ni] = *(const bh8*)(ldsB + brow*64 + ((kb ^ (brow & 7)) << 3));
      }
      #pragma unroll
      for(int mi = 0; mi < 4; mi++)
        #pragma unroll
        for(int ni = 0; ni < 4; ni++)
          accp[mi][ni] = __builtin_amdgcn_mfma_f32_16x16x32_bf16(af[mi], bf[ni], accp[mi][ni], 0, 0, 0);
    }
    // bias + elu -> bf16 P tile in LDS (swizzled A-layout, BK=128)
    #pragma unroll
    for(int mi = 0; mi < 4; mi++)
      #pragma unroll
      for(int ni = 0; ni < 4; ni++){
        int col = wc*64 + ni*16 + (lane & 15);
        float bv = bias[hh*128 + col];
        int rbase = wr*64 + mi*16 + (lane >> 4)*4;
        #pragma unroll
        for(int j = 0; j < 4; j++){
          float v = accp[mi][ni][j] + bv;
          v = v > 0.f ? v : (__expf(v) - 1.f);
          int row = rbase + j;
          ldsP[row*128 + ((((col >> 3) ^ (row & 7))) << 3) + (col & 7)] = f2b(v);
        }
      }
    __syncthreads();
    // phase 2: out += P @ Wpn_h  (K=128)
    #pragma unroll
    for(int kk = 0; kk < 4; kk++){
      bh8 af[4], bf[2];
      int kb = kk*4 + (lane >> 4);
      #pragma unroll
      for(int mi = 0; mi < 4; mi++){
        int arow = wr*64 + mi*16 + (lane & 15);
        af[mi] = *(const bh8*)(ldsP + arow*128 + ((kb ^ (arow & 7)) << 3));
      }
      #pragma unroll
      for(int ni = 0; ni < 2; ni++){
        int brow = wc*32 + ni*16 + (lane & 15);
        bf[ni] = *(const bh8*)(ldsW + brow*128 + ((kb ^ (brow & 7)) << 3));
      }
      #pragma unroll
      for(int mi = 0; mi < 4; mi++)
        #pragma unroll
        for(int ni = 0; ni < 2; ni++)
          acc_out[mi][ni] = __builtin_amdgcn_mfma_f32_16x16x32_bf16(af[mi], bf[ni], acc_out[mi][ni], 0, 0, 0);
    }
    __syncthreads();
  }
  // epilogue
  #pragma unroll
  for(int mi = 0; mi < 4; mi++)
    #pragma unroll
    for(int ni = 0; ni < 2; ni++){
      int col = wc*32 + ni*16 + (lane & 15);
      #pragma unroll
      for(int j = 0; j < 4; j++){
        int row = rowbase + wr*64 + mi*16 + (lane >> 4)*4 + j;
        if(row >= M) continue;
        outp[(size_t)row*256 + col] = f2b(acc_out[mi][ni][j]);
      }
    }
}

// ================= metapath GAT aggregate (D=32, 128 feat) =================
__global__ __launch_bounds__(256) void gat_agg_meta(
    const ushort* __restrict__ hs, const float* __restrict__ el,
    const float* __restrict__ er, const int* __restrict__ ofs,
    const int* __restrict__ colv, const float* __restrict__ bias,
    ushort* __restrict__ outv, int Nd){
  const int wslot = threadIdx.x >> 6;
  const int node = blockIdx.x*4 + wslot;
  const int lane = threadIdx.x & 63;
  __shared__ int   lds_s[4][64];
  __shared__ float lds_w[4][256];
  if(node >= Nd) return;
  const int e0 = ofs[node], e1 = ofs[node+1];
  const int g = lane >> 4, q = lane & 15;
  const int hh = q >> 2;
  const float4 erv = *(const float4*)(er + (size_t)node*4);
  float m0=-INFINITY, m1=-INFINITY, m2=-INFINITY, m3=-INFINITY;
  float sw0=0.f, sw1=0.f, sw2=0.f, sw3=0.f;
  float acc[8];
  #pragma unroll
  for(int r = 0; r < 8; r++) acc[r] = 0.f;

  for(int base = e0; base < e1; base += 64){
    int nch = e1 - base; if(nch > 64) nch = 64;
    int s_l = colv[base + (lane < nch ? lane : nch-1)];
    float4 ev = *(const float4*)(el + (size_t)s_l*4);
    float x0 = ev.x + erv.x; x0 = x0 > 0.f ? x0 : 0.2f*x0;
    float x1 = ev.y + erv.y; x1 = x1 > 0.f ? x1 : 0.2f*x1;
    float x2 = ev.z + erv.z; x2 = x2 > 0.f ? x2 : 0.2f*x2;
    float x3 = ev.w + erv.w; x3 = x3 > 0.f ? x3 : 0.2f*x3;
    if(lane >= nch){ x0 = x1 = x2 = x3 = -INFINITY; }
    float c0=x0, c1=x1, c2=x2, c3=x3;
    #pragma unroll
    for(int off = 32; off; off >>= 1){
      c0 = fmaxf(c0, __shfl_xor(c0, off));
      c1 = fmaxf(c1, __shfl_xor(c1, off));
      c2 = fmaxf(c2, __shfl_xor(c2, off));
      c3 = fmaxf(c3, __shfl_xor(c3, off));
    }
    float n0 = fmaxf(m0,c0), n1 = fmaxf(m1,c1), n2 = fmaxf(m2,c2), n3 = fmaxf(m3,c3);
    float r0 = __expf(m0-n0), r1 = __expf(m1-n1), r2 = __expf(m2-n2), r3 = __expf(m3-n3);
    float w0 = __expf(x0-n0), w1 = __expf(x1-n1), w2 = __expf(x2-n2), w3 = __expf(x3-n3);
    sw0 = sw0*r0 + w0; sw1 = sw1*r1 + w1; sw2 = sw2*r2 + w2; sw3 = sw3*r3 + w3;
    float rh = hh==0 ? r0 : (hh==1 ? r1 : (hh==2 ? r2 : r3));
    #pragma unroll
    for(int r = 0; r < 8; r++) acc[r] *= rh;
    m0=n0; m1=n1; m2=n2; m3=n3;
    lds_s[wslot][lane] = s_l;
    lds_w[wslot][lane*4+0] = w0; lds_w[wslot][lane*4+1] = w1;
    lds_w[wslot][lane*4+2] = w2; lds_w[wslot][lane*4+3] = w3;
    int npad = (nch + 7) & ~7;
    for(int j = 0; j < npad; j += 8){
      int sA = lds_s[wslot][j + g];
      int sB = lds_s[wslot][j + 4 + g];
      float wA = lds_w[wslot][(j + g)*4 + hh];
      float wB = lds_w[wslot][(j + 4 + g)*4 + hh];
      bh8 vA = *(const bh8*)(hs + (size_t)sA*128 + q*8);
      bh8 vB = *(const bh8*)(hs + (size_t)sB*128 + q*8);
      #pragma unroll
      for(int r = 0; r < 8; r++) acc[r] += wA * b2f((ushort)vA[r]);
      #pragma unroll
      for(int r = 0; r < 8; r++) acc[r] += wB * b2f((ushort)vB[r]);
    }
  }
  #pragma unroll
  for(int off = 32; off; off >>= 1){
    sw0 += __shfl_xor(sw0, off); sw1 += __shfl_xor(sw1, off);
    sw2 += __shfl_xor(sw2, off); sw3 += __shfl_xor(sw3, off);
  }
  #pragma unroll
  for(int r = 0; r < 8; r++){
    acc[r] += __shfl_xor(acc[r], 16);
    acc[r] += __shfl_xor(acc[r], 32);
  }
  float swh = hh==0 ? sw0 : (hh==1 ? sw1 : (hh==2 ? sw2 : sw3));
  float den = (swh == 0.f) ? 1.f : swh;
  if(g == 0){
    bh8 ov;
    #pragma unroll
    for(int r = 0; r < 8; r++){
      float v = acc[r]/den + bias[q*8 + r];
      v = v > 0.f ? v : (__expf(v) - 1.f);
      ov[r] = (short)f2b(v);
    }
    *(bh8*)(outv + (size_t)node*128 + q*8) = ov;
  }
}

// ================= bipartite GAT aggregate, low-degree version =================
struct ASeg { const int* ofs; const int* colv; const float* el; const float* er; ushort* agg; };
__global__ __launch_bounds__(256) void gat_agg_proj3(ASeg s0, ASeg s1, ASeg s2,
    const ushort* __restrict__ proj, int2 pbase, int Nd, int nb){
  const int seg = blockIdx.x / nb;
  const ASeg S = seg == 0 ? s0 : (seg == 1 ? s1 : s2);
  const ushort* pj = proj + (size_t)(seg == 0 ? 0 : (seg == 1 ? pbase.x : pbase.y))*64;
  const int node = (blockIdx.x - seg*nb)*16 + (threadIdx.x >> 4);
  const int q = threadIdx.x & 15;
  if(node >= Nd) return;
  const int e0 = S.ofs[node], e1 = S.ofs[node+1];
  const float4 erv = *(const float4*)(S.er + (size_t)node*4);
  float m0=-INFINITY, m1=-INFINITY, m2=-INFINITY, m3=-INFINITY;
  for(int e = e0; e < e1; e++){
    int s = S.colv[e];
    float4 ev = *(const float4*)(S.el + (size_t)s*4);
    float x0 = ev.x + erv.x; x0 = x0 > 0.f ? x0 : 0.2f*x0;
    float x1 = ev.y + erv.y; x1 = x1 > 0.f ? x1 : 0.2f*x1;
    float x2 = ev.z + erv.z; x2 = x2 > 0.f ? x2 : 0.2f*x2;
    float x3 = ev.w + erv.w; x3 = x3 > 0.f ? x3 : 0.2f*x3;
    m0 = fmaxf(m0,x0); m1 = fmaxf(m1,x1); m2 = fmaxf(m2,x2); m3 = fmaxf(m3,x3);
  }
  float sw0=0.f, sw1=0.f, sw2=0.f, sw3=0.f;
  float acc[4][4];
  #pragma unroll
  for(int d = 0; d < 4; d++)
    #pragma unroll
    for(int h = 0; h < 4; h++) acc[d][h] = 0.f;
  for(int e = e0; e < e1; e++){
    int s = S.colv[e];
    float4 ev = *(const float4*)(S.el + (size_t)s*4);
    float x0 = ev.x + erv.x; x0 = x0 > 0.f ? x0 : 0.2f*x0;
    float x1 = ev.y + erv.y; x1 = x1 > 0.f ? x1 : 0.2f*x1;
    float x2 = ev.z + erv.z; x2 = x2 > 0.f ? x2 : 0.2f*x2;
    float x3 = ev.w + erv.w; x3 = x3 > 0.f ? x3 : 0.2f*x3;
    float w0 = __expf(x0-m0), w1 = __expf(x1-m1);
    float w2 = __expf(x2-m2), w3 = __expf(x3-m3);
    sw0 += w0; sw1 += w1; sw2 += w2; sw3 += w3;
    ushort4 p = *(const ushort4*)(pj + (size_t)s*64 + q*4);
    float f0 = b2f(p.x), f1 = b2f(p.y), f2 = b2f(p.z), f3 = b2f(p.w);
    acc[0][0] += w0*f0; acc[0][1] += w1*f0; acc[0][2] += w2*f0; acc[0][3] += w3*f0;
    acc[1][0] += w0*f1; acc[1][1] += w1*f1; acc[1][2] += w2*f1; acc[1][3] += w3*f1;
    acc[2][0] += w0*f2; acc[2][1] += w1*f2; acc[2][2] += w2*f2; acc[2][3] += w3*f2;
    acc[3][0] += w0*f3; acc[3][1] += w1*f3; acc[3][2] += w2*f3; acc[3][3] += w3*f3;
  }
  float dn[4];
  dn[0] = (sw0 == 0.f) ? 1.f : sw0;
  dn[1] = (sw1 == 0.f) ? 1.f : sw1;
  dn[2] = (sw2 == 0.f) ? 1.f : sw2;
  dn[3] = (sw3 == 0.f) ? 1.f : sw3;
  ushort* orow = S.agg + (size_t)node*256;
  #pragma unroll
  for(int h = 0; h < 4; h++){
    ushort4 o;
    o.x = f2b(acc[0][h]/dn[h]); o.y = f2b(acc[1][h]/dn[h]);
    o.z = f2b(acc[2][h]/dn[h]); o.w = f2b(acc[3][h]/dn[h]);
    *(ushort4*)(orow + h*64 + q*4) = o;
  }
}

// ================= host orchestration =================
extern "C" void kernel_launch(void* const* d_in, const int* in_sizes, int n_in,
                              void* d_out, int out_size, void* d_ws, size_t ws_size,
                              hipStream_t stream){
  const float* hp   = (const float*)d_in[0];
  const float* hq   = (const float*)d_in[1];
  const float* hk   = (const float*)d_in[2];
  const float* ha   = (const float*)d_in[3];
  const int* meta_src = (const int*)d_in[4];
  const int* meta_dst = (const int*)d_in[5];
  const int* q_src = (const int*)d_in[6];
  const int* q_dst = (const int*)d_in[7];
  const int* k_src = (const int*)d_in[8];
  const int* k_dst = (const int*)d_in[9];
  const int* a_src = (const int*)d_in[10];
  const int* a_dst = (const int*)d_in[11];
  const float* W0  = (const float*)d_in[12]; const float* al0 = (const float*)d_in[13];
  const float* ar0 = (const float*)d_in[14]; const float* b0  = (const float*)d_in[15];
  const float* W1  = (const float*)d_in[16]; const float* al1 = (const float*)d_in[17];
  const float* ar1 = (const float*)d_in[18]; const float* b1  = (const float*)d_in[19];
  const float* Wq  = (const float*)d_in[20]; const float* alq = (const float*)d_in[21];
  const float* arq = (const float*)d_in[22]; const float* bq  = (const float*)d_in[23];
  const float* Wkw = (const float*)d_in[24]; const float* alkw= (const float*)d_in[25];
  const float* arkw= (const float*)d_in[26]; const float* bkw = (const float*)d_in[27];
  const float* Watt= (const float*)d_in[28]; const float* alatt=(const float*)d_in[29];
  const float* aratt=(const float*)d_in[30]; const float* batt= (const float*)d_in[31];
  const float* Wpnn_a = (const float*)d_in[32];
  const float* Wpn_a  = (const float*)d_in[33];
  const float* Wpnn   = (const float*)d_in[34];
  const float* Wpn    = (const float*)d_in[35];
  const float* Wpred  = (const float*)d_in[36];
  const float* bpred  = (const float*)d_in[37];
  (void)n_in; (void)out_size; (void)ws_size;

  const int IN = 128, ATT = 64;
  const int NP = in_sizes[0]/IN, NQ = in_sizes[1]/ATT, NK = in_sizes[2]/ATT, NA = in_sizes[3]/ATT;
  const int EM = in_sizes[4], EQ = in_sizes[6], EK = in_sizes[8], EA = in_sizes[10];
  const int range = (NP + 7)/8;
  const int NS = NQ + NK + NA;

  // ----- workspace layout -----
  uint8_t* wp = (uint8_t*)d_ws;
  auto alloc = [&](size_t bytes)->uint8_t*{
    uint8_t* p = wp; wp += (bytes + 255) & ~(size_t)255; return p;
  };
  ushort* hcat_b = (ushort*)alloc((size_t)NP*256*2);
  ushort* hbuf_b = (ushort*)alloc((size_t)NP*128*2);
  ushort* hp_b   = (ushort*)alloc((size_t)NP*128*2);
  ushort* hpd_b  = (ushort*)alloc((size_t)NP*64*2);
  ushort* hs_b   = (ushort*)alloc((size_t)NP*128*2);
  ushort* feat_all = (ushort*)alloc((size_t)NS*64*2);
  ushort* proj_all = (ushort*)alloc((size_t)NS*64*2);
  ushort* agg_all  = (ushort*)alloc((size_t)3*NP*256*2);
  float* el    = (float*)alloc((size_t)NP*4*4);
  float* er    = (float*)alloc((size_t)NP*4*4);
  float* el_all= (float*)alloc((size_t)NS*4*4);
  float* er_all= (float*)alloc((size_t)3*NP*4*4);
  float* wf    = (float*)alloc((size_t)10*512*4);
  int* cnt4    = (int*)alloc((size_t)(4*NP+32)*4);
  int* bcur    = cnt4 + 4*NP;
  int* cur4    = (int*)alloc((size_t)4*NP*4);
  int* ofsm    = (int*)alloc((size_t)(NP+4)*4);
  int* ofsq    = (int*)alloc((size_t)(NP+4)*4);
  int* ofsk    = (int*)alloc((size_t)(NP+4)*4);
  int* ofsa    = (int*)alloc((size_t)(NP+4)*4);
  int* colm    = (int*)alloc((size_t)EM*4);
  int* colq    = (int*)alloc((size_t)EQ*4);
  int* colk    = (int*)alloc((size_t)EK*4);
  int* cola    = (int*)alloc((size_t)EA*4);
  const int capM = EM/4+1024, capQ = EQ/4+1024, capK = EK/4+1024, capA = EA/4+1024;
  uint* ebm = (uint*)alloc((size_t)8*capM*4);
  uint* ebq = (uint*)alloc((size_t)8*capQ*4);
  uint* ebk = (uint*)alloc((size_t)8*capK*4);
  uint* eba = (uint*)alloc((size_t)8*capA*4);
  ushort* W0T    = (ushort*)alloc(128*128*2);
  ushort* W1T    = (ushort*)alloc(128*128*2);
  ushort* WTg3   = (ushort*)alloc((size_t)3*4*128*64*2);
  ushort* WpnT   = (ushort*)alloc((size_t)64*512*2);
  ushort* WpnnT  = (ushort*)alloc(64*128*2);
  ushort* Wpnn_aT= (ushort*)alloc(64*128*2);
  ushort* Wpn_aT = (ushort*)alloc(64*64*2);
  ushort* WpredT = (ushort*)alloc((size_t)1024*256*2);

  // ----- CSR build (5 dispatches) -----
  fill_zero_i32<<<(4*NP+32+255)/256, 256, 0, stream>>>(cnt4, 4*NP+32);
  {
    int bm = EM/1024 + 1, bq2 = EQ/1024 + 1, bk2 = EK/1024 + 1, ba2 = EA/1024 + 1;
    P4 g0{meta_src, meta_dst, ebm, EM, capM, 0, bm};
    P4 g1{q_src, q_dst, ebq, EQ, capQ, bm, bm+bq2};
    P4 g2{k_src, k_dst, ebk, EK, capK, bm+bq2, bm+bq2+bk2};
    P4 g3{a_src, a_dst, eba, EA, capA, bm+bq2+bk2, bm+bq2+bk2+ba2};
    partition_all_k<<<g3.bend, 256, 0, stream>>>(g0, g1, g2, g3, bcur, range);
  }
  auto Jof = [&](int E){ int J = E/65536 + 8; if(J > 48) J = 48; return J; };
  {
    int jm = 8*Jof(EM), jq = 8*Jof(EQ), jk = 8*Jof(EK), ja = 8*Jof(EA);
    B4 g0{ebm, capM, cnt4 + 0*NP, 0, jm};
    B4 g1{ebq, capQ, cnt4 + 1*NP, jm, jm+jq};
    B4 g2{ebk, capK, cnt4 + 2*NP, jm+jq, jm+jq+jk};
    B4 g3{eba, capA, cnt4 + 3*NP, jm+jq+jk, jm+jq+jk+ja};
    count_all_k<<<g3.bend, 256, 0, stream>>>(g0, g1, g2, g3, bcur, range);
    scan4_k<<<4, 1024, 0, stream>>>(cnt4, cnt4+NP, cnt4+2*NP, cnt4+3*NP,
                                    ofsm, ofsq, ofsk, ofsa,
                                    cur4, cur4+NP, cur4+2*NP, cur4+3*NP, NP);
    SB4 s0{ebm, capM, cur4 + 0*NP, colm, 0, jm};
    SB4 s1{ebq, capQ, cur4 + 1*NP, colq, jm, jm+jq};
    SB4 s2{ebk, capK, cur4 + 2*NP, colk, jm+jq, jm+jq+jk};
    SB4 s3{eba, capA, cur4 + 3*NP, cola, jm+jq+jk, jm+jq+jk+ja};
    scatter_all_k<<<s3.bend, 256, 0, stream>>>(s0, s1, s2, s3, bcur, range);
  }

  // ----- conversions + weight prep (4 dispatches) -----
  {
    int c0 = NP*128/4, c1 = c0 + NQ*64/4, c2 = c1 + NK*64/4, c3 = c2 + NA*64/4;
    cvt_all_k<<<(c3+255)/256, 256, 0, stream>>>(hp, hq, hk, ha,
        hp_b, feat_all, feat_all + (size_t)NQ*64, feat_all + (size_t)(NQ+NK)*64,
        make_int4(c0, c1, c2, c3));
  }
  {
    WTAll a;
    a.d[0] = {W0, W0T, 128, 128};      a.d[1] = {W1, W1T, 128, 128};
    a.d[2] = {Wpn, WpnT, 512, 64};     a.d[3] = {Wpnn, WpnnT, 128, 64};
    a.d[4] = {Wpnn_a, Wpnn_aT, 128, 64}; a.d[5] = {Wpn_a, Wpn_aT, 64, 64};
    a.d[6] = {Wpred, WpredT, 256, 1000};
    int items[7] = {128*128, 128*128, 64*512, 64*128, 64*128, 64*64, 1024*256};
    a.cum[0] = 0;
    for(int t = 0; t < 7; t++) a.cum[t+1] = a.cum[t] + items[t];
    wT_all_k<<<(a.cum[7]+255)/256, 256, 0, stream>>>(a);
  }
  wTg3_k<<<(3*32768+255)/256, 256, 0, stream>>>(Wq, Wkw, Watt, WTg3);
  {
    FAll f;
    f.d[0] = {W0, al0, wf+0*512, 128, 32};  f.d[1] = {W0, ar0, wf+1*512, 128, 32};
    f.d[2] = {W1, al1, wf+2*512, 128, 32};  f.d[3] = {W1, ar1, wf+3*512, 128, 32};
    f.d[4] = {Wq, alq, wf+4*512, 64, 128};  f.d[5] = {Wq, arq, wf+5*512, 64, 128};
    f.d[6] = {Wkw, alkw, wf+6*512, 64, 128};f.d[7] = {Wkw, arkw, wf+7*512, 64, 128};
    f.d[8] = {Watt, alatt, wf+8*512, 64, 128};f.d[9] = {Watt, aratt, wf+9*512, 64, 128};
    fold_all_k<<<10, 256, 0, stream>>>(f);
  }

  auto launch_gemm = [&]<int BN, typename OutT, bool BIAS>(
      GSeg a, GSeg b, GSeg c, int nseg, int M, int N, int K, int lda){
    int Npad = (N + BN - 1)/BN*BN;
    dim3 g((M + 127)/128, Npad/BN, nseg);
    gemm_mfma_b<BN, OutT, BIAS><<<g, 256, 0, stream>>>(a, b, c, M, N, K, lda);
  };
  GSeg z{};

  // ----- metapath GAT layer 0 -----
  launch_gemm.template operator()<128, ushort, false>(
      GSeg{hp_b, W0T, nullptr, hs_b, 128}, z, z, 1, NP, 128, 128, 128);
  gemv8v<ushort><<<(NP/2+3)/4, 256, 0, stream>>>(hp_b, wf+0*512, wf+1*512, el, er, NP, 128);
  gat_agg_meta<<<(NP+3)/4, 256, 0, stream>>>(hs_b, el, er, ofsm, colm, b0, hbuf_b, NP);

  // ----- metapath GAT layer 1 -----
  launch_gemm.template operator()<128, ushort, false>(
      GSeg{hbuf_b, W1T, nullptr, hs_b, 128}, z, z, 1, NP, 128, 128, 128);
  gemv8v<ushort><<<(NP/2+3)/4, 256, 0, stream>>>(hbuf_b, wf+2*512, wf+3*512, el, er, NP, 128);
  gat_agg_meta<<<(NP+3)/4, 256, 0, stream>>>(hs_b, el, er, ofsm, colm, b1, hbuf_b, NP);

  // ----- batched: hcat[:,0:64] = h @ Wpnn ; hpd = hp @ Wpnn_a -----
  launch_gemm.template operator()<64, ushort, false>(
      GSeg{hbuf_b, WpnnT, nullptr, hcat_b, 256},
      GSeg{hp_b, Wpnn_aT, nullptr, hpd_b, 64}, z, 2, NP, 64, 128, 128);

  // ----- bipartite GATs (batched) -----
  launch_gemm.template operator()<64, ushort, false>(
      GSeg{feat_all, Wpn_aT, nullptr, proj_all, 64}, z, z, 1, NS, 64, 64, 64);
  gemv4v_seg3<<<(NS/4+3)/4, 256, 0, stream>>>(proj_all, wf+4*512, wf+6*512, wf+8*512,
      el_all, NS, NQ, NQ+NK);
  gemv4v_er3<<<(NP/4+3)/4, 256, 0, stream>>>(hpd_b, wf+5*512, wf+7*512, wf+9*512,
      er_all, er_all + (size_t)NP*4, er_all + (size_t)2*NP*4, NP);
  {
    int nb = (NP+15)/16;
    ASeg a0{ofsq, colq, el_all,                    er_all,                    agg_all};
    ASeg a1{ofsk, colk, el_all + (size_t)NQ*4,     er_all + (size_t)NP*4,     agg_all + (size_t)NP*256};
    ASeg a2{ofsa, cola, el_all + (size_t)(NQ+NK)*4,er_all + (size_t)2*NP*4,   agg_all + (size_t)2*NP*256};
    gat_agg_proj3<<<3*nb, 256, 0, stream>>>(a0, a1, a2, proj_all, make_int2(NQ, NQ+NK), NP, nb);
  }
  // fused tail: hcat[:,64+seg*64 ..] = elu(agg@Wg^T+b) @ Wpn   (o never hits HBM)
  {
    dim3 g((NP+127)/128, 1, 3);
    bip_tail_k<<<g, 256, 0, stream>>>(agg_all, WTg3, WpnT, bq, bkw, batt, hcat_b, NP);
  }

  // ----- final: out = hcat @ Wpred + bpred -----
  launch_gemm.template operator()<128, float, true>(
      GSeg{hcat_b, WpredT, bpred, d_out, 1000}, z, z, 1, NP, 1000, 256, 256);
}

// Round 12
// 758.192 us; speedup vs baseline: 1.7998x; 1.0622x over previous
//
#include <hip/hip_runtime.h>
#include <hip/hip_bf16.h>
#include <math.h>
#include <stdint.h>

typedef __attribute__((ext_vector_type(8))) short bh8;
typedef __attribute__((ext_vector_type(4))) float f32x4;

#define AS1(p) ((const __attribute__((address_space(1))) void*)(p))
#define AS3(p) ((__attribute__((address_space(3))) void*)(p))

__device__ inline ushort f2b(float f){
  uint u = __builtin_bit_cast(uint, f);
  u += 0x7fff + ((u >> 16) & 1);
  return (ushort)(u >> 16);
}
__device__ inline float b2f(ushort b){ return __builtin_bit_cast(float, (uint)b << 16); }

// ================= CSR build (all 4 graphs fused, packed staging) =================
__global__ void fill_zero_i32(int* __restrict__ p, int n){
  int i = blockIdx.x*blockDim.x + threadIdx.x;
  if(i < n) p[i] = 0;
}

// partition + count fused: cnt[d] atomics are cheap (200KB region), the bucketed
// ebuf write is the sequential-run trick that avoids colv write amplification.
struct P4 { const int* src; const int* dst; uint* ebuf; int* cnt; int E; int cap; int bbeg; int bend; };

__global__ __launch_bounds__(256) void partition_all_k(P4 g0, P4 g1, P4 g2, P4 g3,
    int* __restrict__ bcur, int range){
  P4 G; int gi;
  int b = blockIdx.x;
  if(b < g0.bend){ G = g0; gi = 0; }
  else if(b < g1.bend){ G = g1; gi = 1; }
  else if(b < g2.bend){ G = g2; gi = 2; }
  else { G = g3; gi = 3; }
  const int lb = b - G.bbeg, nb = G.bend - G.bbeg;
  __shared__ int hist[8], base[8];
  const int tid = threadIdx.x;
  int* bc = bcur + gi*8;
  for(int c0 = lb*256; c0 < G.E; c0 += nb*256){
    int i = c0 + tid;
    int d = 0, s = 0, bk = -1;
    if(i < G.E){ d = G.dst[i]; s = G.src[i]; bk = d / range; }
    if(tid < 8) hist[tid] = 0;
    __syncthreads();
    int rank = 0;
    if(bk >= 0){
      rank = atomicAdd(&hist[bk], 1);
      atomicAdd(&G.cnt[d], 1);
    }
    __syncthreads();
    if(tid < 8) base[tid] = hist[tid] ? atomicAdd(&bc[tid], hist[tid]) : 0;
    __syncthreads();
    if(bk >= 0){
      int pos = base[bk] + rank;
      if(pos < G.cap) G.ebuf[(size_t)bk*G.cap + pos] = ((uint)s << 13) | (uint)(d - bk*range);
    }
    __syncthreads();
  }
}

struct SB4 { const uint* ebuf; int cap; int* cursor; int* colv; int bbeg; int bend; };
__global__ __launch_bounds__(256) void scatter_all_k(SB4 g0, SB4 g1, SB4 g2, SB4 g3,
    const int* __restrict__ bcur, int range){
  SB4 G; int gi;
  int b = blockIdx.x;
  if(b < g0.bend){ G = g0; gi = 0; }
  else if(b < g1.bend){ G = g1; gi = 1; }
  else if(b < g2.bend){ G = g2; gi = 2; }
  else { G = g3; gi = 3; }
  const int local = b - G.bbeg, J = (G.bend - G.bbeg) >> 3;
  const int bk = local & 7, j = local >> 3;
  int nb = bcur[gi*8 + bk]; if(nb > G.cap) nb = G.cap;
  const uint* eb = G.ebuf + (size_t)bk*G.cap;
  int* ub = G.cursor + bk*range;
  int per = (nb + J - 1)/J;
  int beg = j*per, end = beg + per; if(end > nb) end = nb;
  for(int i = beg + threadIdx.x; i < end; i += 256){
    uint e = eb[i];
    int p = atomicAdd(&ub[e & 8191u], 1);
    G.colv[p] = (int)(e >> 13);
  }
}

__global__ __launch_bounds__(1024) void scan4_k(
    const int* c0, const int* c1, const int* c2, const int* c3,
    int* o0, int* o1, int* o2, int* o3,
    int* u0, int* u1, int* u2, int* u3, int n){
  const int* cnt = blockIdx.x==0?c0:(blockIdx.x==1?c1:(blockIdx.x==2?c2:c3));
  int* ofs    = blockIdx.x==0?o0:(blockIdx.x==1?o1:(blockIdx.x==2?o2:o3));
  int* cursor = blockIdx.x==0?u0:(blockIdx.x==1?u1:(blockIdx.x==2?u2:u3));
  __shared__ int wsum[16];
  __shared__ int carry_s;
  int tid = threadIdx.x, wid = tid >> 6, lane = tid & 63;
  if(tid == 0) carry_s = 0;
  __syncthreads();
  for(int base = 0; base < n; base += 4096){
    int i0 = base + tid*4;
    int4 v = make_int4(0,0,0,0);
    if(i0 + 3 < n) v = *(const int4*)(cnt + i0);
    else if(i0 < n){
      v.x = cnt[i0];
      if(i0+1 < n) v.y = cnt[i0+1];
      if(i0+2 < n) v.z = cnt[i0+2];
    }
    int s1 = v.x + v.y, s2 = s1 + v.z, tot = s2 + v.w;
    int x = tot;
    #pragma unroll
    for(int off = 1; off < 64; off <<= 1){
      int t = __shfl_up(x, off);
      if(lane >= off) x += t;
    }
    if(lane == 63) wsum[wid] = x;
    __syncthreads();
    if(tid < 16){
      int y = wsum[tid];
      #pragma unroll
      for(int off = 1; off < 16; off <<= 1){
        int t = __shfl_up(y, off);
        if(tid >= off) y += t;
      }
      wsum[tid] = y;
    }
    __syncthreads();
    int pre = (wid ? wsum[wid-1] : 0) + carry_s + (x - tot);
    if(i0 + 3 < n){
      int4 o = make_int4(pre, pre+v.x, pre+s1, pre+s2);
      *(int4*)(ofs + i0) = o;
      *(int4*)(cursor + i0) = o;
    } else if(i0 < n){
      ofs[i0] = pre; cursor[i0] = pre;
      if(i0+1 < n){ ofs[i0+1] = pre+v.x; cursor[i0+1] = pre+v.x; }
      if(i0+2 < n){ ofs[i0+2] = pre+s1; cursor[i0+2] = pre+s1; }
    }
    __syncthreads();
    if(tid == 0) carry_s += wsum[15];
    __syncthreads();
  }
  if(tid == 0) ofs[n] = carry_s;
}

// ================= preprocessing (fused) =================
__global__ void cvt_all_k(const float* i0, const float* i1, const float* i2, const float* i3,
    ushort* o0, ushort* o1, ushort* o2, ushort* o3, int4 cum){
  int i = blockIdx.x*blockDim.x + threadIdx.x;
  const float* in; ushort* out; int base;
  if(i < cum.x){ in=i0; out=o0; base=0; }
  else if(i < cum.y){ in=i1; out=o1; base=cum.x; }
  else if(i < cum.z){ in=i2; out=o2; base=cum.y; }
  else if(i < cum.w){ in=i3; out=o3; base=cum.z; }
  else return;
  int l = i - base;
  float4 v = ((const float4*)in)[l];
  ushort4 o; o.x=f2b(v.x); o.y=f2b(v.y); o.z=f2b(v.z); o.w=f2b(v.w);
  ((ushort4*)out)[l] = o;
}

struct WTD { const float* W; ushort* WT; int K; int N; };
struct WTAll { WTD d[7]; int cum[8]; };
__global__ void wT_all_k(WTAll a){
  int idx = blockIdx.x*blockDim.x + threadIdx.x;
  if(idx >= a.cum[7]) return;
  int j = 0;
  #pragma unroll
  for(int t = 1; t < 7; t++) if(idx >= a.cum[t]) j = t;
  int l = idx - a.cum[j];
  WTD d = a.d[j];
  int n = l / d.K, k = l - n*d.K;
  d.WT[l] = (n < d.N) ? f2b(d.W[(size_t)k*d.N + n]) : (ushort)0;
}

__global__ void wTg3_k(const float* W0, const float* W1, const float* W2, ushort* WT){
  int idx = blockIdx.x*blockDim.x + threadIdx.x;
  if(idx >= 3*32768) return;
  int g = idx >> 15, rem = idx & 32767;
  const float* W = g==0 ? W0 : (g==1 ? W1 : W2);
  int h = rem >> 13, r2 = rem & 8191;
  int n = r2 >> 6, k = r2 & 63;
  WT[idx] = f2b(W[(size_t)k*512 + h*128 + n]);
}

struct FD { const float* W; const float* a; float* out; int K; int D; };
struct FAll { FD d[10]; };
__global__ void fold_all_k(FAll f){
  FD d = f.d[blockIdx.x];
  for(int i = threadIdx.x; i < d.K*4; i += 256){
    int k = i >> 2, h = i & 3;
    const float* wr = d.W + (size_t)k*4*d.D + (size_t)h*d.D;
    const float* ar = d.a + (size_t)h*d.D;
    float s = 0.f;
    for(int dd = 0; dd < d.D; dd++) s += wr[dd]*ar[dd];
    d.out[i] = s;
  }
}

// ================= gemv =================
__device__ inline void ld4v(const float* p, float* v){
  float4 t = *(const float4*)p; v[0]=t.x; v[1]=t.y; v[2]=t.z; v[3]=t.w;
}
__device__ inline void ld4v(const ushort* p, float* v){
  ushort4 t = *(const ushort4*)p; v[0]=b2f(t.x); v[1]=b2f(t.y); v[2]=b2f(t.z); v[3]=b2f(t.w);
}

__global__ __launch_bounds__(256) void gemv4v_seg3(const ushort* __restrict__ A,
    const float* __restrict__ W0, const float* __restrict__ W1, const float* __restrict__ W2,
    float* __restrict__ outv, int M, int b1, int b2){
  const int w = (blockIdx.x*blockDim.x + threadIdx.x) >> 6;
  const int lane = threadIdx.x & 63;
  const int r = lane >> 4, q = lane & 15;
  int row = w*4 + r;
  bool valid = row < M;
  int rowc = valid ? row : (M-1);
  const float* Wf = rowc < b1 ? W0 : (rowc < b2 ? W1 : W2);
  float av[4];
  ld4v(A + (size_t)rowc*64 + q*4, av);
  float a[4] = {0.f,0.f,0.f,0.f};
  #pragma unroll
  for(int kk = 0; kk < 4; kk++){
    float4 wv = *(const float4*)(Wf + (q*4+kk)*4);
    a[0] += av[kk]*wv.x; a[1] += av[kk]*wv.y; a[2] += av[kk]*wv.z; a[3] += av[kk]*wv.w;
  }
  #pragma unroll
  for(int off = 1; off < 16; off <<= 1){
    a[0] += __shfl_xor(a[0], off); a[1] += __shfl_xor(a[1], off);
    a[2] += __shfl_xor(a[2], off); a[3] += __shfl_xor(a[3], off);
  }
  if(valid && q == 0){
    float4 o; o.x=a[0]; o.y=a[1]; o.z=a[2]; o.w=a[3];
    *(float4*)(outv + (size_t)row*4) = o;
  }
}

__global__ __launch_bounds__(256) void gemv4v_er3(const ushort* __restrict__ A,
    const float* __restrict__ W0, const float* __restrict__ W1, const float* __restrict__ W2,
    float* __restrict__ o0, float* __restrict__ o1, float* __restrict__ o2, int M){
  const int w = (blockIdx.x*blockDim.x + threadIdx.x) >> 6;
  const int lane = threadIdx.x & 63;
  const int r = lane >> 4, q = lane & 15;
  int row = w*4 + r;
  bool valid = row < M;
  int rowc = valid ? row : (M-1);
  float av[4];
  ld4v(A + (size_t)rowc*64 + q*4, av);
  float a[12];
  #pragma unroll
  for(int t = 0; t < 12; t++) a[t] = 0.f;
  #pragma unroll
  for(int kk = 0; kk < 4; kk++){
    float4 w0 = *(const float4*)(W0 + (q*4+kk)*4);
    float4 w1 = *(const float4*)(W1 + (q*4+kk)*4);
    float4 w2 = *(const float4*)(W2 + (q*4+kk)*4);
    a[0] += av[kk]*w0.x; a[1] += av[kk]*w0.y; a[2] += av[kk]*w0.z; a[3] += av[kk]*w0.w;
    a[4] += av[kk]*w1.x; a[5] += av[kk]*w1.y; a[6] += av[kk]*w1.z; a[7] += av[kk]*w1.w;
    a[8] += av[kk]*w2.x; a[9] += av[kk]*w2.y; a[10]+= av[kk]*w2.z; a[11]+= av[kk]*w2.w;
  }
  #pragma unroll
  for(int off = 1; off < 16; off <<= 1)
    #pragma unroll
    for(int t = 0; t < 12; t++) a[t] += __shfl_xor(a[t], off);
  if(valid && q == 0){
    float4 x; x.x=a[0]; x.y=a[1]; x.z=a[2]; x.w=a[3];
    *(float4*)(o0 + (size_t)row*4) = x;
    float4 y; y.x=a[4]; y.y=a[5]; y.z=a[6]; y.w=a[7];
    *(float4*)(o1 + (size_t)row*4) = y;
    float4 z; z.x=a[8]; z.y=a[9]; z.z=a[10]; z.w=a[11];
    *(float4*)(o2 + (size_t)row*4) = z;
  }
}

template<typename T>
__global__ __launch_bounds__(256) void gemv8v(const T* __restrict__ A,
    const float* __restrict__ Wfa, const float* __restrict__ Wfb,
    float* __restrict__ oa, float* __restrict__ ob, int M, int lda){
  const int w = (blockIdx.x*blockDim.x + threadIdx.x) >> 6;
  const int lane = threadIdx.x & 63;
  const int r = lane >> 5, q = lane & 31;
  int row = w*2 + r;
  bool valid = row < M;
  int rowc = valid ? row : (M-1);
  float av[4];
  ld4v(A + (size_t)rowc*lda + q*4, av);
  float a[4] = {0.f,0.f,0.f,0.f}, b[4] = {0.f,0.f,0.f,0.f};
  #pragma unroll
  for(int kk = 0; kk < 4; kk++){
    float4 wa = *(const float4*)(Wfa + (q*4+kk)*4);
    float4 wb = *(const float4*)(Wfb + (q*4+kk)*4);
    a[0] += av[kk]*wa.x; a[1] += av[kk]*wa.y; a[2] += av[kk]*wa.z; a[3] += av[kk]*wa.w;
    b[0] += av[kk]*wb.x; b[1] += av[kk]*wb.y; b[2] += av[kk]*wb.z; b[3] += av[kk]*wb.w;
  }
  #pragma unroll
  for(int off = 1; off < 32; off <<= 1){
    a[0] += __shfl_xor(a[0], off); a[1] += __shfl_xor(a[1], off);
    a[2] += __shfl_xor(a[2], off); a[3] += __shfl_xor(a[3], off);
    b[0] += __shfl_xor(b[0], off); b[1] += __shfl_xor(b[1], off);
    b[2] += __shfl_xor(b[2], off); b[3] += __shfl_xor(b[3], off);
  }
  if(valid && q == 0){
    float4 o; o.x=a[0]; o.y=a[1]; o.z=a[2]; o.w=a[3];
    *(float4*)(oa + (size_t)row*4) = o;
    float4 p; p.x=b[0]; p.y=b[1]; p.z=b[2]; p.w=b[3];
    *(float4*)(ob + (size_t)row*4) = p;
  }
}

// ================= batched bf16 MFMA GEMM (blockIdx.z = segment) =================
struct GSeg { const ushort* A; const ushort* BT; const float* bias; void* C; int ldc; };

template<int BN, typename OutT, bool BIAS>
__global__ __launch_bounds__(256) void gemm_mfma_b(GSeg s0, GSeg s1, GSeg s2,
    int M, int N, int K, int lda){
  constexpr int BM = 128, BK = 64;
  constexpr int NI = BN/32;
  constexpr int AIT = BM*BK/(256*8);
  constexpr int BIT = BN*BK/(256*8);
  __shared__ ushort lds[BM*BK + BN*BK];
  ushort* ldsA = lds;
  ushort* ldsB = lds + BM*BK;
  GSeg S = blockIdx.z == 0 ? s0 : (blockIdx.z == 1 ? s1 : s2);
  const int tid = threadIdx.x, wid = tid >> 6, lane = tid & 63;
  const int wr = wid >> 1, wc = wid & 1;
  const int rowbase = blockIdx.x*BM;
  const int colbase = blockIdx.y*BN;

  f32x4 acc[4][NI];
  #pragma unroll
  for(int mi = 0; mi < 4; mi++)
    #pragma unroll
    for(int ni = 0; ni < NI; ni++) acc[mi][ni] = (f32x4)0.f;

  for(int k0 = 0; k0 < K; k0 += BK){
    #pragma unroll
    for(int it = 0; it < AIT; it++){
      int idx = it*256 + wid*64 + lane;
      int r = idx >> 3, sl = idx & 7;
      int kb = sl ^ (r & 7);
      int grow = rowbase + r; if(grow >= M) grow = M-1;
      const ushort* src = S.A + (size_t)grow*lda + k0 + kb*8;
      __builtin_amdgcn_global_load_lds(AS1(src), AS3(ldsA + (size_t)(it*256 + wid*64)*8), 16, 0, 0);
    }
    #pragma unroll
    for(int it = 0; it < BIT; it++){
      int idx = it*256 + wid*64 + lane;
      int r = idx >> 3, sl = idx & 7;
      int kb = sl ^ (r & 7);
      const ushort* src = S.BT + (size_t)(colbase + r)*K + k0 + kb*8;
      __builtin_amdgcn_global_load_lds(AS1(src), AS3(ldsB + (size_t)(it*256 + wid*64)*8), 16, 0, 0);
    }
    __syncthreads();
    #pragma unroll
    for(int kk = 0; kk < 2; kk++){
      bh8 af[4], bf[NI];
      #pragma unroll
      for(int mi = 0; mi < 4; mi++){
        int arow = wr*64 + mi*16 + (lane & 15);
        int kb = kk*4 + (lane >> 4);
        af[mi] = *(const bh8*)(ldsA + arow*BK + ((kb ^ (arow & 7)) << 3));
      }
      #pragma unroll
      for(int ni = 0; ni < NI; ni++){
        int brow = wc*(BN/2) + ni*16 + (lane & 15);
        int kb = kk*4 + (lane >> 4);
        bf[ni] = *(const bh8*)(ldsB + brow*BK + ((kb ^ (brow & 7)) << 3));
      }
      #pragma unroll
      for(int mi = 0; mi < 4; mi++)
        #pragma unroll
        for(int ni = 0; ni < NI; ni++)
          acc[mi][ni] = __builtin_amdgcn_mfma_f32_16x16x32_bf16(af[mi], bf[ni], acc[mi][ni], 0, 0, 0);
    }
    __syncthreads();
  }
  OutT* C = (OutT*)S.C;
  #pragma unroll
  for(int mi = 0; mi < 4; mi++){
    #pragma unroll
    for(int ni = 0; ni < NI; ni++){
      int col = colbase + wc*(BN/2) + ni*16 + (lane & 15);
      if(col >= N) continue;
      float bv = BIAS ? S.bias[col] : 0.f;
      #pragma unroll
      for(int j = 0; j < 4; j++){
        int row = rowbase + wr*64 + mi*16 + (lane >> 4)*4 + j;
        if(row >= M) continue;
        float v = acc[mi][ni][j] + bv;
        if constexpr (sizeof(OutT) == 4) C[(size_t)row*S.ldc + col] = v;
        else                             C[(size_t)row*S.ldc + col] = (OutT)f2b(v);
      }
    }
  }
}

// ================= fused bipartite tail: hcat_slice = elu(agg@Wg^T+b) @ Wpn =================
__global__ __launch_bounds__(256) void bip_tail_k(
    const ushort* __restrict__ agg,     // [3][M][256]
    const ushort* __restrict__ WTg3,    // [3][4][128][64] k-contiguous
    const ushort* __restrict__ WpnT,    // [64][512] = Wpn^T
    const float* bias0, const float* bias1, const float* bias2,
    ushort* __restrict__ hcat,          // [M][256]; cols 64+seg*64..
    int M){
  __shared__ ushort ldsA[128*64];
  __shared__ ushort ldsB[128*64];
  __shared__ ushort ldsP[128*128];
  __shared__ ushort ldsW[64*128];
  const int seg = blockIdx.z;
  const ushort* A  = agg + (size_t)seg*M*256;
  const ushort* Wg = WTg3 + (size_t)seg*32768;
  const float* bias = seg==0 ? bias0 : (seg==1 ? bias1 : bias2);
  ushort* outp = hcat + 64 + seg*64;
  const int tid = threadIdx.x, lane = tid & 63, wid = tid >> 6;
  const int wr = wid >> 1, wc = wid & 1;
  const int rowbase = blockIdx.x*128;

  f32x4 acc_out[4][2];
  #pragma unroll
  for(int mi = 0; mi < 4; mi++){ acc_out[mi][0] = (f32x4)0.f; acc_out[mi][1] = (f32x4)0.f; }

  for(int hh = 0; hh < 4; hh++){
    #pragma unroll
    for(int it = 0; it < 4; it++){
      int idx = it*256 + tid;
      int r = idx >> 3, sl = idx & 7;
      int kb = sl ^ (r & 7);
      int grow = rowbase + r; if(grow >= M) grow = M-1;
      __builtin_amdgcn_global_load_lds(AS1(A + (size_t)grow*256 + hh*64 + kb*8),
                                       AS3(ldsA + (size_t)idx*8), 16, 0, 0);
    }
    #pragma unroll
    for(int it = 0; it < 4; it++){
      int idx = it*256 + tid;
      int r = idx >> 3, sl = idx & 7;
      int kb = sl ^ (r & 7);
      __builtin_amdgcn_global_load_lds(AS1(Wg + hh*8192 + r*64 + kb*8),
                                       AS3(ldsB + (size_t)idx*8), 16, 0, 0);
    }
    #pragma unroll
    for(int it = 0; it < 4; it++){
      int idx = it*256 + tid;
      int r = idx >> 4, sl = idx & 15;
      int kb = sl ^ (r & 7);
      __builtin_amdgcn_global_load_lds(AS1(WpnT + (size_t)r*512 + hh*128 + kb*8),
                                       AS3(ldsW + (size_t)idx*8), 16, 0, 0);
    }
    __syncthreads();
    f32x4 accp[4][4];
    #pragma unroll
    for(int mi = 0; mi < 4; mi++)
      #pragma unroll
      for(int ni = 0; ni < 4; ni++) accp[mi][ni] = (f32x4)0.f;
    #pragma unroll
    for(int kk = 0; kk < 2; kk++){
      bh8 af[4], bf[4];
      int kb = kk*4 + (lane >> 4);
      #pragma unroll
      for(int mi = 0; mi < 4; mi++){
        int arow = wr*64 + mi*16 + (lane & 15);
        af[mi] = *(const bh8*)(ldsA + arow*64 + ((kb ^ (arow & 7)) << 3));
      }
      #pragma unroll
      for(int ni = 0; ni < 4; ni++){
        int brow = wc*64 + ni*16 + (lane & 15);
        bf[ni] = *(const bh8*)(ldsB + brow*64 + ((kb ^ (brow & 7)) << 3));
      }
      #pragma unroll
      for(int mi = 0; mi < 4; mi++)
        #pragma unroll
        for(int ni = 0; ni < 4; ni++)
          accp[mi][ni] = __builtin_amdgcn_mfma_f32_16x16x32_bf16(af[mi], bf[ni], accp[mi][ni], 0, 0, 0);
    }
    #pragma unroll
    for(int mi = 0; mi < 4; mi++)
      #pragma unroll
      for(int ni = 0; ni < 4; ni++){
        int col = wc*64 + ni*16 + (lane & 15);
        float bv = bias[hh*128 + col];
        int rbase = wr*64 + mi*16 + (lane >> 4)*4;
        #pragma unroll
        for(int j = 0; j < 4; j++){
          float v = accp[mi][ni][j] + bv;
          v = v > 0.f ? v : (__expf(v) - 1.f);
          int row = rbase + j;
          ldsP[row*128 + ((((col >> 3) ^ (row & 7))) << 3) + (col & 7)] = f2b(v);
        }
      }
    __syncthreads();
    #pragma unroll
    for(int kk = 0; kk < 4; kk++){
      bh8 af[4], bf[2];
      int kb = kk*4 + (lane >> 4);
      #pragma unroll
      for(int mi = 0; mi < 4; mi++){
        int arow = wr*64 + mi*16 + (lane & 15);
        af[mi] = *(const bh8*)(ldsP + arow*128 + ((kb ^ (arow & 7)) << 3));
      }
      #pragma unroll
      for(int ni = 0; ni < 2; ni++){
        int brow = wc*32 + ni*16 + (lane & 15);
        bf[ni] = *(const bh8*)(ldsW + brow*128 + ((kb ^ (brow & 7)) << 3));
      }
      #pragma unroll
      for(int mi = 0; mi < 4; mi++)
        #pragma unroll
        for(int ni = 0; ni < 2; ni++)
          acc_out[mi][ni] = __builtin_amdgcn_mfma_f32_16x16x32_bf16(af[mi], bf[ni], acc_out[mi][ni], 0, 0, 0);
    }
    __syncthreads();
  }
  #pragma unroll
  for(int mi = 0; mi < 4; mi++)
    #pragma unroll
    for(int ni = 0; ni < 2; ni++){
      int col = wc*32 + ni*16 + (lane & 15);
      #pragma unroll
      for(int j = 0; j < 4; j++){
        int row = rowbase + wr*64 + mi*16 + (lane >> 4)*4 + j;
        if(row >= M) continue;
        outp[(size_t)row*256 + col] = f2b(acc_out[mi][ni][j]);
      }
    }
}

// ================= metapath GAT aggregate (D=32, 128 feat) =================
// Deepened load pipeline: 16 edges/iter, 4 independent row loads per lane.
__global__ __launch_bounds__(256) void gat_agg_meta(
    const ushort* __restrict__ hs, const float* __restrict__ el,
    const float* __restrict__ er, const int* __restrict__ ofs,
    const int* __restrict__ colv, const float* __restrict__ bias,
    ushort* __restrict__ outv, int Nd){
  const int wslot = threadIdx.x >> 6;
  const int node = blockIdx.x*4 + wslot;
  const int lane = threadIdx.x & 63;
  __shared__ int   lds_s[4][64];
  __shared__ float lds_w[4][256];
  if(node >= Nd) return;
  const int e0 = ofs[node], e1 = ofs[node+1];
  const int g = lane >> 4, q = lane & 15;
  const int hh = q >> 2;
  const float4 erv = *(const float4*)(er + (size_t)node*4);
  float m0=-INFINITY, m1=-INFINITY, m2=-INFINITY, m3=-INFINITY;
  float sw0=0.f, sw1=0.f, sw2=0.f, sw3=0.f;
  float acc[8];
  #pragma unroll
  for(int r = 0; r < 8; r++) acc[r] = 0.f;

  for(int base = e0; base < e1; base += 64){
    int nch = e1 - base; if(nch > 64) nch = 64;
    int s_l = colv[base + (lane < nch ? lane : nch-1)];
    float4 ev = *(const float4*)(el + (size_t)s_l*4);
    float x0 = ev.x + erv.x; x0 = x0 > 0.f ? x0 : 0.2f*x0;
    float x1 = ev.y + erv.y; x1 = x1 > 0.f ? x1 : 0.2f*x1;
    float x2 = ev.z + erv.z; x2 = x2 > 0.f ? x2 : 0.2f*x2;
    float x3 = ev.w + erv.w; x3 = x3 > 0.f ? x3 : 0.2f*x3;
    if(lane >= nch){ x0 = x1 = x2 = x3 = -INFINITY; }
    float c0=x0, c1=x1, c2=x2, c3=x3;
    #pragma unroll
    for(int off = 32; off; off >>= 1){
      c0 = fmaxf(c0, __shfl_xor(c0, off));
      c1 = fmaxf(c1, __shfl_xor(c1, off));
      c2 = fmaxf(c2, __shfl_xor(c2, off));
      c3 = fmaxf(c3, __shfl_xor(c3, off));
    }
    float n0 = fmaxf(m0,c0), n1 = fmaxf(m1,c1), n2 = fmaxf(m2,c2), n3 = fmaxf(m3,c3);
    float r0 = __expf(m0-n0), r1 = __expf(m1-n1), r2 = __expf(m2-n2), r3 = __expf(m3-n3);
    float w0 = __expf(x0-n0), w1 = __expf(x1-n1), w2 = __expf(x2-n2), w3 = __expf(x3-n3);
    sw0 = sw0*r0 + w0; sw1 = sw1*r1 + w1; sw2 = sw2*r2 + w2; sw3 = sw3*r3 + w3;
    float rh = hh==0 ? r0 : (hh==1 ? r1 : (hh==2 ? r2 : r3));
    #pragma unroll
    for(int r = 0; r < 8; r++) acc[r] *= rh;
    m0=n0; m1=n1; m2=n2; m3=n3;
    lds_s[wslot][lane] = s_l;
    lds_w[wslot][lane*4+0] = w0; lds_w[wslot][lane*4+1] = w1;
    lds_w[wslot][lane*4+2] = w2; lds_w[wslot][lane*4+3] = w3;
    // padded entries (>=nch) have w==0 and clamped s (duplicate row -> cache hit)
    int npad = (nch + 15) & ~15;
    for(int j = 0; j < npad; j += 16){
      int sv[4]; float wv[4];
      #pragma unroll
      for(int u = 0; u < 4; u++){
        sv[u] = lds_s[wslot][j + u*4 + g];
        wv[u] = lds_w[wslot][(j + u*4 + g)*4 + hh];
      }
      bh8 vv[4];
      #pragma unroll
      for(int u = 0; u < 4; u++)
        vv[u] = *(const bh8*)(hs + (size_t)sv[u]*128 + q*8);
      #pragma unroll
      for(int u = 0; u < 4; u++)
        #pragma unroll
        for(int r = 0; r < 8; r++) acc[r] += wv[u] * b2f((ushort)vv[u][r]);
    }
  }
  #pragma unroll
  for(int off = 32; off; off >>= 1){
    sw0 += __shfl_xor(sw0, off); sw1 += __shfl_xor(sw1, off);
    sw2 += __shfl_xor(sw2, off); sw3 += __shfl_xor(sw3, off);
  }
  #pragma unroll
  for(int r = 0; r < 8; r++){
    acc[r] += __shfl_xor(acc[r], 16);
    acc[r] += __shfl_xor(acc[r], 32);
  }
  float swh = hh==0 ? sw0 : (hh==1 ? sw1 : (hh==2 ? sw2 : sw3));
  float den = (swh == 0.f) ? 1.f : swh;
  if(g == 0){
    bh8 ov;
    #pragma unroll
    for(int r = 0; r < 8; r++){
      float v = acc[r]/den + bias[q*8 + r];
      v = v > 0.f ? v : (__expf(v) - 1.f);
      ov[r] = (short)f2b(v);
    }
    *(bh8*)(outv + (size_t)node*128 + q*8) = ov;
  }
}

// ================= bipartite GAT aggregate, low-degree version =================
// deg<=8 fast path: colv/el cached in registers (single el gather), 8 proj loads batched.
struct ASeg { const int* ofs; const int* colv; const float* el; const float* er; ushort* agg; };
__global__ __launch_bounds__(256) void gat_agg_proj3(ASeg s0, ASeg s1, ASeg s2,
    const ushort* __restrict__ proj, int2 pbase, int Nd, int nb){
  const int seg = blockIdx.x / nb;
  const ASeg S = seg == 0 ? s0 : (seg == 1 ? s1 : s2);
  const ushort* pj = proj + (size_t)(seg == 0 ? 0 : (seg == 1 ? pbase.x : pbase.y))*64;
  const int node = (blockIdx.x - seg*nb)*16 + (threadIdx.x >> 4);
  const int q = threadIdx.x & 15;
  if(node >= Nd) return;
  const int e0 = S.ofs[node], e1 = S.ofs[node+1];
  const int deg = e1 - e0;
  const float4 erv = *(const float4*)(S.er + (size_t)node*4);
  float sw0=0.f, sw1=0.f, sw2=0.f, sw3=0.f;
  float acc[4][4];
  #pragma unroll
  for(int d = 0; d < 4; d++)
    #pragma unroll
    for(int h = 0; h < 4; h++) acc[d][h] = 0.f;

  if(deg <= 8){
    const int ebase = (deg > 0) ? e0 : 0;
    int sv[8];
    #pragma unroll
    for(int u = 0; u < 8; u++) sv[u] = S.colv[ebase + (u < deg ? u : 0)];
    float xa[8], xb[8], xc[8], xd[8];
    #pragma unroll
    for(int u = 0; u < 8; u++){
      float4 ev = *(const float4*)(S.el + (size_t)sv[u]*4);
      float t0 = ev.x + erv.x; xa[u] = t0 > 0.f ? t0 : 0.2f*t0;
      float t1 = ev.y + erv.y; xb[u] = t1 > 0.f ? t1 : 0.2f*t1;
      float t2 = ev.z + erv.z; xc[u] = t2 > 0.f ? t2 : 0.2f*t2;
      float t3 = ev.w + erv.w; xd[u] = t3 > 0.f ? t3 : 0.2f*t3;
    }
    float m0=-INFINITY, m1=-INFINITY, m2=-INFINITY, m3=-INFINITY;
    #pragma unroll
    for(int u = 0; u < 8; u++) if(u < deg){
      m0 = fmaxf(m0, xa[u]); m1 = fmaxf(m1, xb[u]);
      m2 = fmaxf(m2, xc[u]); m3 = fmaxf(m3, xd[u]);
    }
    ushort4 pv[8];
    #pragma unroll
    for(int u = 0; u < 8; u++) pv[u] = *(const ushort4*)(pj + (size_t)sv[u]*64 + q*4);
    #pragma unroll
    for(int u = 0; u < 8; u++) if(u < deg){
      float w0 = __expf(xa[u]-m0), w1 = __expf(xb[u]-m1);
      float w2 = __expf(xc[u]-m2), w3 = __expf(xd[u]-m3);
      sw0 += w0; sw1 += w1; sw2 += w2; sw3 += w3;
      float f0 = b2f(pv[u].x), f1 = b2f(pv[u].y), f2 = b2f(pv[u].z), f3 = b2f(pv[u].w);
      acc[0][0] += w0*f0; acc[0][1] += w1*f0; acc[0][2] += w2*f0; acc[0][3] += w3*f0;
      acc[1][0] += w0*f1; acc[1][1] += w1*f1; acc[1][2] += w2*f1; acc[1][3] += w3*f1;
      acc[2][0] += w0*f2; acc[2][1] += w1*f2; acc[2][2] += w2*f2; acc[2][3] += w3*f2;
      acc[3][0] += w0*f3; acc[3][1] += w1*f3; acc[3][2] += w2*f3; acc[3][3] += w3*f3;
    }
  } else {
    // two-pass fallback for high degree
    float m0=-INFINITY, m1=-INFINITY, m2=-INFINITY, m3=-INFINITY;
    for(int e = e0; e < e1; e++){
      int s = S.colv[e];
      float4 ev = *(const float4*)(S.el + (size_t)s*4);
      float x0 = ev.x + erv.x; x0 = x0 > 0.f ? x0 : 0.2f*x0;
      float x1 = ev.y + erv.y; x1 = x1 > 0.f ? x1 : 0.2f*x1;
      float x2 = ev.z + erv.z; x2 = x2 > 0.f ? x2 : 0.2f*x2;
      float x3 = ev.w + erv.w; x3 = x3 > 0.f ? x3 : 0.2f*x3;
      m0 = fmaxf(m0,x0); m1 = fmaxf(m1,x1); m2 = fmaxf(m2,x2); m3 = fmaxf(m3,x3);
    }
    for(int e = e0; e < e1; e++){
      int s = S.colv[e];
      float4 ev = *(const float4*)(S.el + (size_t)s*4);
      float x0 = ev.x + erv.x; x0 = x0 > 0.f ? x0 : 0.2f*x0;
      float x1 = ev.y + erv.y; x1 = x1 > 0.f ? x1 : 0.2f*x1;
      float x2 = ev.z + erv.z; x2 = x2 > 0.f ? x2 : 0.2f*x2;
      float x3 = ev.w + erv.w; x3 = x3 > 0.f ? x3 : 0.2f*x3;
      float w0 = __expf(x0-m0), w1 = __expf(x1-m1);
      float w2 = __expf(x2-m2), w3 = __expf(x3-m3);
      sw0 += w0; sw1 += w1; sw2 += w2; sw3 += w3;
      ushort4 p = *(const ushort4*)(pj + (size_t)s*64 + q*4);
      float f0 = b2f(p.x), f1 = b2f(p.y), f2 = b2f(p.z), f3 = b2f(p.w);
      acc[0][0] += w0*f0; acc[0][1] += w1*f0; acc[0][2] += w2*f0; acc[0][3] += w3*f0;
      acc[1][0] += w0*f1; acc[1][1] += w1*f1; acc[1][2] += w2*f1; acc[1][3] += w3*f1;
      acc[2][0] += w0*f2; acc[2][1] += w1*f2; acc[2][2] += w2*f2; acc[2][3] += w3*f2;
      acc[3][0] += w0*f3; acc[3][1] += w1*f3; acc[3][2] += w2*f3; acc[3][3] += w3*f3;
    }
  }
  float dn[4];
  dn[0] = (sw0 == 0.f) ? 1.f : sw0;
  dn[1] = (sw1 == 0.f) ? 1.f : sw1;
  dn[2] = (sw2 == 0.f) ? 1.f : sw2;
  dn[3] = (sw3 == 0.f) ? 1.f : sw3;
  ushort* orow = S.agg + (size_t)node*256;
  #pragma unroll
  for(int h = 0; h < 4; h++){
    ushort4 o;
    o.x = f2b(acc[0][h]/dn[h]); o.y = f2b(acc[1][h]/dn[h]);
    o.z = f2b(acc[2][h]/dn[h]); o.w = f2b(acc[3][h]/dn[h]);
    *(ushort4*)(orow + h*64 + q*4) = o;
  }
}

// ================= host orchestration =================
extern "C" void kernel_launch(void* const* d_in, const int* in_sizes, int n_in,
                              void* d_out, int out_size, void* d_ws, size_t ws_size,
                              hipStream_t stream){
  const float* hp   = (const float*)d_in[0];
  const float* hq   = (const float*)d_in[1];
  const float* hk   = (const float*)d_in[2];
  const float* ha   = (const float*)d_in[3];
  const int* meta_src = (const int*)d_in[4];
  const int* meta_dst = (const int*)d_in[5];
  const int* q_src = (const int*)d_in[6];
  const int* q_dst = (const int*)d_in[7];
  const int* k_src = (const int*)d_in[8];
  const int* k_dst = (const int*)d_in[9];
  const int* a_src = (const int*)d_in[10];
  const int* a_dst = (const int*)d_in[11];
  const float* W0  = (const float*)d_in[12]; const float* al0 = (const float*)d_in[13];
  const float* ar0 = (const float*)d_in[14]; const float* b0  = (const float*)d_in[15];
  const float* W1  = (const float*)d_in[16]; const float* al1 = (const float*)d_in[17];
  const float* ar1 = (const float*)d_in[18]; const float* b1  = (const float*)d_in[19];
  const float* Wq  = (const float*)d_in[20]; const float* alq = (const float*)d_in[21];
  const float* arq = (const float*)d_in[22]; const float* bq  = (const float*)d_in[23];
  const float* Wkw = (const float*)d_in[24]; const float* alkw= (const float*)d_in[25];
  const float* arkw= (const float*)d_in[26]; const float* bkw = (const float*)d_in[27];
  const float* Watt= (const float*)d_in[28]; const float* alatt=(const float*)d_in[29];
  const float* aratt=(const float*)d_in[30]; const float* batt= (const float*)d_in[31];
  const float* Wpnn_a = (const float*)d_in[32];
  const float* Wpn_a  = (const float*)d_in[33];
  const float* Wpnn   = (const float*)d_in[34];
  const float* Wpn    = (const float*)d_in[35];
  const float* Wpred  = (const float*)d_in[36];
  const float* bpred  = (const float*)d_in[37];
  (void)n_in; (void)out_size; (void)ws_size;

  const int IN = 128, ATT = 64;
  const int NP = in_sizes[0]/IN, NQ = in_sizes[1]/ATT, NK = in_sizes[2]/ATT, NA = in_sizes[3]/ATT;
  const int EM = in_sizes[4], EQ = in_sizes[6], EK = in_sizes[8], EA = in_sizes[10];
  const int range = (NP + 7)/8;
  const int NS = NQ + NK + NA;

  // ----- workspace layout -----
  uint8_t* wp = (uint8_t*)d_ws;
  auto alloc = [&](size_t bytes)->uint8_t*{
    uint8_t* p = wp; wp += (bytes + 255) & ~(size_t)255; return p;
  };
  ushort* hcat_b = (ushort*)alloc((size_t)NP*256*2);
  ushort* hbuf_b = (ushort*)alloc((size_t)NP*128*2);
  ushort* hp_b   = (ushort*)alloc((size_t)NP*128*2);
  ushort* hpd_b  = (ushort*)alloc((size_t)NP*64*2);
  ushort* hs_b   = (ushort*)alloc((size_t)NP*128*2);
  ushort* feat_all = (ushort*)alloc((size_t)NS*64*2);
  ushort* proj_all = (ushort*)alloc((size_t)NS*64*2);
  ushort* agg_all  = (ushort*)alloc((size_t)3*NP*256*2);
  float* el    = (float*)alloc((size_t)NP*4*4);
  float* er    = (float*)alloc((size_t)NP*4*4);
  float* el_all= (float*)alloc((size_t)NS*4*4);
  float* er_all= (float*)alloc((size_t)3*NP*4*4);
  float* wf    = (float*)alloc((size_t)10*512*4);
  int* cnt4    = (int*)alloc((size_t)(4*NP+32)*4);
  int* bcur    = cnt4 + 4*NP;
  int* cur4    = (int*)alloc((size_t)4*NP*4);
  int* ofsm    = (int*)alloc((size_t)(NP+4)*4);
  int* ofsq    = (int*)alloc((size_t)(NP+4)*4);
  int* ofsk    = (int*)alloc((size_t)(NP+4)*4);
  int* ofsa    = (int*)alloc((size_t)(NP+4)*4);
  int* colm    = (int*)alloc((size_t)EM*4);
  int* colq    = (int*)alloc((size_t)EQ*4);
  int* colk    = (int*)alloc((size_t)EK*4);
  int* cola    = (int*)alloc((size_t)EA*4);
  const int capM = EM/4+1024, capQ = EQ/4+1024, capK = EK/4+1024, capA = EA/4+1024;
  uint* ebm = (uint*)alloc((size_t)8*capM*4);
  uint* ebq = (uint*)alloc((size_t)8*capQ*4);
  uint* ebk = (uint*)alloc((size_t)8*capK*4);
  uint* eba = (uint*)alloc((size_t)8*capA*4);
  ushort* W0T    = (ushort*)alloc(128*128*2);
  ushort* W1T    = (ushort*)alloc(128*128*2);
  ushort* WTg3   = (ushort*)alloc((size_t)3*4*128*64*2);
  ushort* WpnT   = (ushort*)alloc((size_t)64*512*2);
  ushort* WpnnT  = (ushort*)alloc(64*128*2);
  ushort* Wpnn_aT= (ushort*)alloc(64*128*2);
  ushort* Wpn_aT = (ushort*)alloc(64*64*2);
  ushort* WpredT = (ushort*)alloc((size_t)1024*256*2);

  // ----- CSR build (4 dispatches: fill, partition+count, scan4, scatter) -----
  fill_zero_i32<<<(4*NP+32+255)/256, 256, 0, stream>>>(cnt4, 4*NP+32);
  {
    int bm = EM/1024 + 1, bq2 = EQ/1024 + 1, bk2 = EK/1024 + 1, ba2 = EA/1024 + 1;
    P4 g0{meta_src, meta_dst, ebm, cnt4 + 0*NP, EM, capM, 0, bm};
    P4 g1{q_src, q_dst, ebq, cnt4 + 1*NP, EQ, capQ, bm, bm+bq2};
    P4 g2{k_src, k_dst, ebk, cnt4 + 2*NP, EK, capK, bm+bq2, bm+bq2+bk2};
    P4 g3{a_src, a_dst, eba, cnt4 + 3*NP, EA, capA, bm+bq2+bk2, bm+bq2+bk2+ba2};
    partition_all_k<<<g3.bend, 256, 0, stream>>>(g0, g1, g2, g3, bcur, range);
  }
  auto Jof = [&](int E){ int J = E/65536 + 8; if(J > 48) J = 48; return J; };
  {
    scan4_k<<<4, 1024, 0, stream>>>(cnt4, cnt4+NP, cnt4+2*NP, cnt4+3*NP,
                                    ofsm, ofsq, ofsk, ofsa,
                                    cur4, cur4+NP, cur4+2*NP, cur4+3*NP, NP);
    int jm = 8*Jof(EM), jq = 8*Jof(EQ), jk = 8*Jof(EK), ja = 8*Jof(EA);
    SB4 s0{ebm, capM, cur4 + 0*NP, colm, 0, jm};
    SB4 s1{ebq, capQ, cur4 + 1*NP, colq, jm, jm+jq};
    SB4 s2{ebk, capK, cur4 + 2*NP, colk, jm+jq, jm+jq+jk};
    SB4 s3{eba, capA, cur4 + 3*NP, cola, jm+jq+jk, jm+jq+jk+ja};
    scatter_all_k<<<s3.bend, 256, 0, stream>>>(s0, s1, s2, s3, bcur, range);
  }

  // ----- conversions + weight prep (4 dispatches) -----
  {
    int c0 = NP*128/4, c1 = c0 + NQ*64/4, c2 = c1 + NK*64/4, c3 = c2 + NA*64/4;
    cvt_all_k<<<(c3+255)/256, 256, 0, stream>>>(hp, hq, hk, ha,
        hp_b, feat_all, feat_all + (size_t)NQ*64, feat_all + (size_t)(NQ+NK)*64,
        make_int4(c0, c1, c2, c3));
  }
  {
    WTAll a;
    a.d[0] = {W0, W0T, 128, 128};      a.d[1] = {W1, W1T, 128, 128};
    a.d[2] = {Wpn, WpnT, 512, 64};     a.d[3] = {Wpnn, WpnnT, 128, 64};
    a.d[4] = {Wpnn_a, Wpnn_aT, 128, 64}; a.d[5] = {Wpn_a, Wpn_aT, 64, 64};
    a.d[6] = {Wpred, WpredT, 256, 1000};
    int items[7] = {128*128, 128*128, 64*512, 64*128, 64*128, 64*64, 1024*256};
    a.cum[0] = 0;
    for(int t = 0; t < 7; t++) a.cum[t+1] = a.cum[t] + items[t];
    wT_all_k<<<(a.cum[7]+255)/256, 256, 0, stream>>>(a);
  }
  wTg3_k<<<(3*32768+255)/256, 256, 0, stream>>>(Wq, Wkw, Watt, WTg3);
  {
    FAll f;
    f.d[0] = {W0, al0, wf+0*512, 128, 32};  f.d[1] = {W0, ar0, wf+1*512, 128, 32};
    f.d[2] = {W1, al1, wf+2*512, 128, 32};  f.d[3] = {W1, ar1, wf+3*512, 128, 32};
    f.d[4] = {Wq, alq, wf+4*512, 64, 128};  f.d[5] = {Wq, arq, wf+5*512, 64, 128};
    f.d[6] = {Wkw, alkw, wf+6*512, 64, 128};f.d[7] = {Wkw, arkw, wf+7*512, 64, 128};
    f.d[8] = {Watt, alatt, wf+8*512, 64, 128};f.d[9] = {Watt, aratt, wf+9*512, 64, 128};
    fold_all_k<<<10, 256, 0, stream>>>(f);
  }

  auto launch_gemm = [&]<int BN, typename OutT, bool BIAS>(
      GSeg a, GSeg b, GSeg c, int nseg, int M, int N, int K, int lda){
    int Npad = (N + BN - 1)/BN*BN;
    dim3 g((M + 127)/128, Npad/BN, nseg);
    gemm_mfma_b<BN, OutT, BIAS><<<g, 256, 0, stream>>>(a, b, c, M, N, K, lda);
  };
  GSeg z{};

  // ----- metapath GAT layer 0 -----
  launch_gemm.template operator()<128, ushort, false>(
      GSeg{hp_b, W0T, nullptr, hs_b, 128}, z, z, 1, NP, 128, 128, 128);
  gemv8v<ushort><<<(NP/2+3)/4, 256, 0, stream>>>(hp_b, wf+0*512, wf+1*512, el, er, NP, 128);
  gat_agg_meta<<<(NP+3)/4, 256, 0, stream>>>(hs_b, el, er, ofsm, colm, b0, hbuf_b, NP);

  // ----- metapath GAT layer 1 -----
  launch_gemm.template operator()<128, ushort, false>(
      GSeg{hbuf_b, W1T, nullptr, hs_b, 128}, z, z, 1, NP, 128, 128, 128);
  gemv8v<ushort><<<(NP/2+3)/4, 256, 0, stream>>>(hbuf_b, wf+2*512, wf+3*512, el, er, NP, 128);
  gat_agg_meta<<<(NP+3)/4, 256, 0, stream>>>(hs_b, el, er, ofsm, colm, b1, hbuf_b, NP);

  // ----- batched: hcat[:,0:64] = h @ Wpnn ; hpd = hp @ Wpnn_a -----
  launch_gemm.template operator()<64, ushort, false>(
      GSeg{hbuf_b, WpnnT, nullptr, hcat_b, 256},
      GSeg{hp_b, Wpnn_aT, nullptr, hpd_b, 64}, z, 2, NP, 64, 128, 128);

  // ----- bipartite GATs (batched) -----
  launch_gemm.template operator()<64, ushort, false>(
      GSeg{feat_all, Wpn_aT, nullptr, proj_all, 64}, z, z, 1, NS, 64, 64, 64);
  gemv4v_seg3<<<(NS/4+3)/4, 256, 0, stream>>>(proj_all, wf+4*512, wf+6*512, wf+8*512,
      el_all, NS, NQ, NQ+NK);
  gemv4v_er3<<<(NP/4+3)/4, 256, 0, stream>>>(hpd_b, wf+5*512, wf+7*512, wf+9*512,
      er_all, er_all + (size_t)NP*4, er_all + (size_t)2*NP*4, NP);
  {
    int nb = (NP+15)/16;
    ASeg a0{ofsq, colq, el_all,                    er_all,                    agg_all};
    ASeg a1{ofsk, colk, el_all + (size_t)NQ*4,     er_all + (size_t)NP*4,     agg_all + (size_t)NP*256};
    ASeg a2{ofsa, cola, el_all + (size_t)(NQ+NK)*4,er_all + (size_t)2*NP*4,   agg_all + (size_t)2*NP*256};
    gat_agg_proj3<<<3*nb, 256, 0, stream>>>(a0, a1, a2, proj_all, make_int2(NQ, NQ+NK), NP, nb);
  }
  // fused tail: hcat[:,64+seg*64 ..] = elu(agg@Wg^T+b) @ Wpn
  {
    dim3 g((NP+127)/128, 1, 3);
    bip_tail_k<<<g, 256, 0, stream>>>(agg_all, WTg3, WpnT, bq, bkw, batt, hcat_b, NP);
  }

  // ----- final: out = hcat @ Wpred + bpred -----
  launch_gemm.template operator()<128, float, true>(
      GSeg{hcat_b, WpredT, bpred, d_out, 1000}, z, z, 1, NP, 1000, 256, 256);
}

// Round 13
// 715.464 us; speedup vs baseline: 1.9073x; 1.0597x over previous
//
#include <hip/hip_runtime.h>
#include <hip/hip_bf16.h>
#include <math.h>
#include <stdint.h>

typedef __attribute__((ext_vector_type(8))) short bh8;
typedef __attribute__((ext_vector_type(4))) float f32x4;

#define AS1(p) ((const __attribute__((address_space(1))) void*)(p))
#define AS3(p) ((__attribute__((address_space(3))) void*)(p))
#define PSL 2048

__device__ inline ushort f2b(float f){
  uint u = __builtin_bit_cast(uint, f);
  u += 0x7fff + ((u >> 16) & 1);
  return (ushort)(u >> 16);
}
__device__ inline float b2f(ushort b){ return __builtin_bit_cast(float, (uint)b << 16); }

// ================= CSR build =================
__global__ void fill_zero_i32(int* __restrict__ p, int n){
  int i = blockIdx.x*blockDim.x + threadIdx.x;
  if(i < n) p[i] = 0;
}

// Partition v2: 2048 edges/block held in registers; per-wave LDS histogram;
// ONE padded-line reservation per bucket per block; per-wave LDS cursors.
// No per-edge global atomics.
struct P4 { const int* src; const int* dst; uint* ebuf; int E; int cap; int bbeg; int bend; };

__global__ __launch_bounds__(256) void partition_all_k(P4 g0, P4 g1, P4 g2, P4 g3,
    int* __restrict__ bcur, int range){
  P4 G; int gi;
  int b = blockIdx.x;
  if(b < g0.bend){ G = g0; gi = 0; }
  else if(b < g1.bend){ G = g1; gi = 1; }
  else if(b < g2.bend){ G = g2; gi = 2; }
  else { G = g3; gi = 3; }
  const int beg = (b - G.bbeg)*PSL;
  const int tid = threadIdx.x, w = tid >> 6;
  __shared__ int hist4[4][8];
  __shared__ int cur4[4][8];
  if(tid < 32) (&hist4[0][0])[tid] = 0;
  __syncthreads();
  int dv[8], sv[8], bv[8];
  const int bi = beg + tid*8;
  if(beg + PSL <= G.E){
    int4 d0 = *(const int4*)(G.dst + bi);
    int4 d1 = *(const int4*)(G.dst + bi + 4);
    int4 s0 = *(const int4*)(G.src + bi);
    int4 s1 = *(const int4*)(G.src + bi + 4);
    dv[0]=d0.x; dv[1]=d0.y; dv[2]=d0.z; dv[3]=d0.w;
    dv[4]=d1.x; dv[5]=d1.y; dv[6]=d1.z; dv[7]=d1.w;
    sv[0]=s0.x; sv[1]=s0.y; sv[2]=s0.z; sv[3]=s0.w;
    sv[4]=s1.x; sv[5]=s1.y; sv[6]=s1.z; sv[7]=s1.w;
    #pragma unroll
    for(int u = 0; u < 8; u++) bv[u] = dv[u]/range;
  } else {
    #pragma unroll
    for(int u = 0; u < 8; u++){
      int i = bi + u;
      bool ok = i < G.E;
      dv[u] = ok ? G.dst[i] : 0;
      sv[u] = ok ? G.src[i] : 0;
      bv[u] = ok ? dv[u]/range : -1;
    }
  }
  #pragma unroll
  for(int u = 0; u < 8; u++) if(bv[u] >= 0) atomicAdd(&hist4[w][bv[u]], 1);
  __syncthreads();
  if(tid < 8){
    int h0 = hist4[0][tid], h1 = hist4[1][tid], h2 = hist4[2][tid], h3 = hist4[3][tid];
    int tot = h0 + h1 + h2 + h3;
    int bs = tot ? atomicAdd(&bcur[(gi*8 + tid)*16], tot) : 0;
    cur4[0][tid] = bs;
    cur4[1][tid] = bs + h0;
    cur4[2][tid] = bs + h0 + h1;
    cur4[3][tid] = bs + h0 + h1 + h2;
  }
  __syncthreads();
  #pragma unroll
  for(int u = 0; u < 8; u++) if(bv[u] >= 0){
    int pos = atomicAdd(&cur4[w][bv[u]], 1);
    if(pos < G.cap) G.ebuf[(size_t)bv[u]*G.cap + pos] = ((uint)sv[u] << 13) | (uint)(dv[u] - bv[u]*range);
  }
}

// Atomic-free counting: per (graph,bucket,j) block builds an LDS histogram of its
// ebuf slice and writes it as partial j. scan4 sums the J partials.
struct H4 { const uint* ebuf; int cap; };
__global__ __launch_bounds__(256) void hist_all_k(H4 h0, H4 h1, H4 h2, H4 h3,
    const int* __restrict__ bcur, int* __restrict__ part,
    int range, int NPL, int J, int NP){
  __shared__ int h[8192];
  const int x = blockIdx.x;
  const int g = x/(8*J);
  const int rem = x - g*8*J;
  const int bk = rem/J, j = rem - bk*J;
  H4 H = g==0 ? h0 : (g==1 ? h1 : (g==2 ? h2 : h3));
  for(int i = threadIdx.x; i < range; i += 256) h[i] = 0;
  __syncthreads();
  int nb = bcur[(g*8 + bk)*16]; if(nb > H.cap) nb = H.cap;
  const uint* eb = H.ebuf + (size_t)bk*H.cap;
  int per = (nb + J - 1)/J;
  int lo = j*per, hi = lo + per; if(hi > nb) hi = nb;
  for(int i = lo + threadIdx.x; i < hi; i += 256)
    atomicAdd(&h[eb[i] & 8191u], 1);
  __syncthreads();
  int lim = NP - bk*range; if(lim > range) lim = range;
  int* dst = part + ((size_t)g*J + j)*NPL + bk*range;
  for(int i = threadIdx.x; i < lim; i += 256) dst[i] = h[i];
}

struct SB4 { const uint* ebuf; int cap; int* cursor; int* colv; int bbeg; int bend; };
__global__ __launch_bounds__(256) void scatter_all_k(SB4 g0, SB4 g1, SB4 g2, SB4 g3,
    const int* __restrict__ bcur, int range){
  SB4 G; int gi;
  int b = blockIdx.x;
  if(b < g0.bend){ G = g0; gi = 0; }
  else if(b < g1.bend){ G = g1; gi = 1; }
  else if(b < g2.bend){ G = g2; gi = 2; }
  else { G = g3; gi = 3; }
  const int local = b - G.bbeg, J = (G.bend - G.bbeg) >> 3;
  const int bk = local & 7, j = local >> 3;
  int nb = bcur[(gi*8 + bk)*16]; if(nb > G.cap) nb = G.cap;
  const uint* eb = G.ebuf + (size_t)bk*G.cap;
  int* ub = G.cursor + bk*range;
  int per = (nb + J - 1)/J;
  int beg = j*per, end = beg + per; if(end > nb) end = nb;
  for(int i = beg + threadIdx.x; i < end; i += 256){
    uint e = eb[i];
    int p = atomicAdd(&ub[e & 8191u], 1);
    G.colv[p] = (int)(e >> 13);
  }
}

// 4 independent exclusive scans over summed J-partials, one block each
__global__ __launch_bounds__(1024) void scan4_k(
    const int* __restrict__ part, int J, int NPL,
    int* o0, int* o1, int* o2, int* o3,
    int* u0, int* u1, int* u2, int* u3, int n){
  const int* pg = part + (size_t)blockIdx.x*J*NPL;
  int* ofs    = blockIdx.x==0?o0:(blockIdx.x==1?o1:(blockIdx.x==2?o2:o3));
  int* cursor = blockIdx.x==0?u0:(blockIdx.x==1?u1:(blockIdx.x==2?u2:u3));
  __shared__ int wsum[16];
  __shared__ int carry_s;
  int tid = threadIdx.x, wid = tid >> 6, lane = tid & 63;
  if(tid == 0) carry_s = 0;
  __syncthreads();
  for(int base = 0; base < n; base += 4096){
    int i0 = base + tid*4;
    int4 v = make_int4(0,0,0,0);
    if(i0 + 3 < n){
      for(int j = 0; j < J; j++){
        int4 t = *(const int4*)(pg + (size_t)j*NPL + i0);
        v.x += t.x; v.y += t.y; v.z += t.z; v.w += t.w;
      }
    } else if(i0 < n){
      for(int j = 0; j < J; j++){
        v.x += pg[(size_t)j*NPL + i0];
        if(i0+1 < n) v.y += pg[(size_t)j*NPL + i0+1];
        if(i0+2 < n) v.z += pg[(size_t)j*NPL + i0+2];
      }
    }
    int s1 = v.x + v.y, s2 = s1 + v.z, tot = s2 + v.w;
    int x = tot;
    #pragma unroll
    for(int off = 1; off < 64; off <<= 1){
      int t = __shfl_up(x, off);
      if(lane >= off) x += t;
    }
    if(lane == 63) wsum[wid] = x;
    __syncthreads();
    if(tid < 16){
      int y = wsum[tid];
      #pragma unroll
      for(int off = 1; off < 16; off <<= 1){
        int t = __shfl_up(y, off);
        if(tid >= off) y += t;
      }
      wsum[tid] = y;
    }
    __syncthreads();
    int pre = (wid ? wsum[wid-1] : 0) + carry_s + (x - tot);
    if(i0 + 3 < n){
      int4 o = make_int4(pre, pre+v.x, pre+s1, pre+s2);
      *(int4*)(ofs + i0) = o;
      *(int4*)(cursor + i0) = o;
    } else if(i0 < n){
      ofs[i0] = pre; cursor[i0] = pre;
      if(i0+1 < n){ ofs[i0+1] = pre+v.x; cursor[i0+1] = pre+v.x; }
      if(i0+2 < n){ ofs[i0+2] = pre+s1; cursor[i0+2] = pre+s1; }
    }
    __syncthreads();
    if(tid == 0) carry_s += wsum[15];
    __syncthreads();
  }
  if(tid == 0) ofs[n] = carry_s;
}

// ================= preprocessing (fused) =================
__global__ void cvt_all_k(const float* i0, const float* i1, const float* i2, const float* i3,
    ushort* o0, ushort* o1, ushort* o2, ushort* o3, int4 cum){
  int i = blockIdx.x*blockDim.x + threadIdx.x;
  const float* in; ushort* out; int base;
  if(i < cum.x){ in=i0; out=o0; base=0; }
  else if(i < cum.y){ in=i1; out=o1; base=cum.x; }
  else if(i < cum.z){ in=i2; out=o2; base=cum.y; }
  else if(i < cum.w){ in=i3; out=o3; base=cum.z; }
  else return;
  int l = i - base;
  float4 v = ((const float4*)in)[l];
  ushort4 o; o.x=f2b(v.x); o.y=f2b(v.y); o.z=f2b(v.z); o.w=f2b(v.w);
  ((ushort4*)out)[l] = o;
}

struct WTD { const float* W; ushort* WT; int K; int N; };
struct WTAll { WTD d[7]; int cum[8]; };
__global__ void wT_all_k(WTAll a){
  int idx = blockIdx.x*blockDim.x + threadIdx.x;
  if(idx >= a.cum[7]) return;
  int j = 0;
  #pragma unroll
  for(int t = 1; t < 7; t++) if(idx >= a.cum[t]) j = t;
  int l = idx - a.cum[j];
  WTD d = a.d[j];
  int n = l / d.K, k = l - n*d.K;
  d.WT[l] = (n < d.N) ? f2b(d.W[(size_t)k*d.N + n]) : (ushort)0;
}

__global__ void wTg3_k(const float* W0, const float* W1, const float* W2, ushort* WT){
  int idx = blockIdx.x*blockDim.x + threadIdx.x;
  if(idx >= 3*32768) return;
  int g = idx >> 15, rem = idx & 32767;
  const float* W = g==0 ? W0 : (g==1 ? W1 : W2);
  int h = rem >> 13, r2 = rem & 8191;
  int n = r2 >> 6, k = r2 & 63;
  WT[idx] = f2b(W[(size_t)k*512 + h*128 + n]);
}

struct FD { const float* W; const float* a; float* out; int K; int D; };
struct FAll { FD d[10]; };
__global__ void fold_all_k(FAll f){
  FD d = f.d[blockIdx.x];
  for(int i = threadIdx.x; i < d.K*4; i += 256){
    int k = i >> 2, h = i & 3;
    const float* wr = d.W + (size_t)k*4*d.D + (size_t)h*d.D;
    const float* ar = d.a + (size_t)h*d.D;
    float s = 0.f;
    for(int dd = 0; dd < d.D; dd++) s += wr[dd]*ar[dd];
    d.out[i] = s;
  }
}

// ================= gemv =================
__device__ inline void ld4v(const float* p, float* v){
  float4 t = *(const float4*)p; v[0]=t.x; v[1]=t.y; v[2]=t.z; v[3]=t.w;
}
__device__ inline void ld4v(const ushort* p, float* v){
  ushort4 t = *(const ushort4*)p; v[0]=b2f(t.x); v[1]=b2f(t.y); v[2]=b2f(t.z); v[3]=b2f(t.w);
}

__global__ __launch_bounds__(256) void gemv4v_seg3(const ushort* __restrict__ A,
    const float* __restrict__ W0, const float* __restrict__ W1, const float* __restrict__ W2,
    float* __restrict__ outv, int M, int b1, int b2){
  const int w = (blockIdx.x*blockDim.x + threadIdx.x) >> 6;
  const int lane = threadIdx.x & 63;
  const int r = lane >> 4, q = lane & 15;
  int row = w*4 + r;
  bool valid = row < M;
  int rowc = valid ? row : (M-1);
  const float* Wf = rowc < b1 ? W0 : (rowc < b2 ? W1 : W2);
  float av[4];
  ld4v(A + (size_t)rowc*64 + q*4, av);
  float a[4] = {0.f,0.f,0.f,0.f};
  #pragma unroll
  for(int kk = 0; kk < 4; kk++){
    float4 wv = *(const float4*)(Wf + (q*4+kk)*4);
    a[0] += av[kk]*wv.x; a[1] += av[kk]*wv.y; a[2] += av[kk]*wv.z; a[3] += av[kk]*wv.w;
  }
  #pragma unroll
  for(int off = 1; off < 16; off <<= 1){
    a[0] += __shfl_xor(a[0], off); a[1] += __shfl_xor(a[1], off);
    a[2] += __shfl_xor(a[2], off); a[3] += __shfl_xor(a[3], off);
  }
  if(valid && q == 0){
    float4 o; o.x=a[0]; o.y=a[1]; o.z=a[2]; o.w=a[3];
    *(float4*)(outv + (size_t)row*4) = o;
  }
}

__global__ __launch_bounds__(256) void gemv4v_er3(const ushort* __restrict__ A,
    const float* __restrict__ W0, const float* __restrict__ W1, const float* __restrict__ W2,
    float* __restrict__ o0, float* __restrict__ o1, float* __restrict__ o2, int M){
  const int w = (blockIdx.x*blockDim.x + threadIdx.x) >> 6;
  const int lane = threadIdx.x & 63;
  const int r = lane >> 4, q = lane & 15;
  int row = w*4 + r;
  bool valid = row < M;
  int rowc = valid ? row : (M-1);
  float av[4];
  ld4v(A + (size_t)rowc*64 + q*4, av);
  float a[12];
  #pragma unroll
  for(int t = 0; t < 12; t++) a[t] = 0.f;
  #pragma unroll
  for(int kk = 0; kk < 4; kk++){
    float4 w0 = *(const float4*)(W0 + (q*4+kk)*4);
    float4 w1 = *(const float4*)(W1 + (q*4+kk)*4);
    float4 w2 = *(const float4*)(W2 + (q*4+kk)*4);
    a[0] += av[kk]*w0.x; a[1] += av[kk]*w0.y; a[2] += av[kk]*w0.z; a[3] += av[kk]*w0.w;
    a[4] += av[kk]*w1.x; a[5] += av[kk]*w1.y; a[6] += av[kk]*w1.z; a[7] += av[kk]*w1.w;
    a[8] += av[kk]*w2.x; a[9] += av[kk]*w2.y; a[10]+= av[kk]*w2.z; a[11]+= av[kk]*w2.w;
  }
  #pragma unroll
  for(int off = 1; off < 16; off <<= 1)
    #pragma unroll
    for(int t = 0; t < 12; t++) a[t] += __shfl_xor(a[t], off);
  if(valid && q == 0){
    float4 x; x.x=a[0]; x.y=a[1]; x.z=a[2]; x.w=a[3];
    *(float4*)(o0 + (size_t)row*4) = x;
    float4 y; y.x=a[4]; y.y=a[5]; y.z=a[6]; y.w=a[7];
    *(float4*)(o1 + (size_t)row*4) = y;
    float4 z; z.x=a[8]; z.y=a[9]; z.z=a[10]; z.w=a[11];
    *(float4*)(o2 + (size_t)row*4) = z;
  }
}

template<typename T>
__global__ __launch_bounds__(256) void gemv8v(const T* __restrict__ A,
    const float* __restrict__ Wfa, const float* __restrict__ Wfb,
    float* __restrict__ oa, float* __restrict__ ob, int M, int lda){
  const int w = (blockIdx.x*blockDim.x + threadIdx.x) >> 6;
  const int lane = threadIdx.x & 63;
  const int r = lane >> 5, q = lane & 31;
  int row = w*2 + r;
  bool valid = row < M;
  int rowc = valid ? row : (M-1);
  float av[4];
  ld4v(A + (size_t)rowc*lda + q*4, av);
  float a[4] = {0.f,0.f,0.f,0.f}, b[4] = {0.f,0.f,0.f,0.f};
  #pragma unroll
  for(int kk = 0; kk < 4; kk++){
    float4 wa = *(const float4*)(Wfa + (q*4+kk)*4);
    float4 wb = *(const float4*)(Wfb + (q*4+kk)*4);
    a[0] += av[kk]*wa.x; a[1] += av[kk]*wa.y; a[2] += av[kk]*wa.z; a[3] += av[kk]*wa.w;
    b[0] += av[kk]*wb.x; b[1] += av[kk]*wb.y; b[2] += av[kk]*wb.z; b[3] += av[kk]*wb.w;
  }
  #pragma unroll
  for(int off = 1; off < 32; off <<= 1){
    a[0] += __shfl_xor(a[0], off); a[1] += __shfl_xor(a[1], off);
    a[2] += __shfl_xor(a[2], off); a[3] += __shfl_xor(a[3], off);
    b[0] += __shfl_xor(b[0], off); b[1] += __shfl_xor(b[1], off);
    b[2] += __shfl_xor(b[2], off); b[3] += __shfl_xor(b[3], off);
  }
  if(valid && q == 0){
    float4 o; o.x=a[0]; o.y=a[1]; o.z=a[2]; o.w=a[3];
    *(float4*)(oa + (size_t)row*4) = o;
    float4 p; p.x=b[0]; p.y=b[1]; p.z=b[2]; p.w=b[3];
    *(float4*)(ob + (size_t)row*4) = p;
  }
}

// ================= batched bf16 MFMA GEMM (blockIdx.z = segment) =================
struct GSeg { const ushort* A; const ushort* BT; const float* bias; void* C; int ldc; };

template<int BN, typename OutT, bool BIAS>
__global__ __launch_bounds__(256) void gemm_mfma_b(GSeg s0, GSeg s1, GSeg s2,
    int M, int N, int K, int lda){
  constexpr int BM = 128, BK = 64;
  constexpr int NI = BN/32;
  constexpr int AIT = BM*BK/(256*8);
  constexpr int BIT = BN*BK/(256*8);
  __shared__ ushort lds[BM*BK + BN*BK];
  ushort* ldsA = lds;
  ushort* ldsB = lds + BM*BK;
  GSeg S = blockIdx.z == 0 ? s0 : (blockIdx.z == 1 ? s1 : s2);
  const int tid = threadIdx.x, wid = tid >> 6, lane = tid & 63;
  const int wr = wid >> 1, wc = wid & 1;
  const int rowbase = blockIdx.x*BM;
  const int colbase = blockIdx.y*BN;

  f32x4 acc[4][NI];
  #pragma unroll
  for(int mi = 0; mi < 4; mi++)
    #pragma unroll
    for(int ni = 0; ni < NI; ni++) acc[mi][ni] = (f32x4)0.f;

  for(int k0 = 0; k0 < K; k0 += BK){
    #pragma unroll
    for(int it = 0; it < AIT; it++){
      int idx = it*256 + wid*64 + lane;
      int r = idx >> 3, sl = idx & 7;
      int kb = sl ^ (r & 7);
      int grow = rowbase + r; if(grow >= M) grow = M-1;
      const ushort* src = S.A + (size_t)grow*lda + k0 + kb*8;
      __builtin_amdgcn_global_load_lds(AS1(src), AS3(ldsA + (size_t)(it*256 + wid*64)*8), 16, 0, 0);
    }
    #pragma unroll
    for(int it = 0; it < BIT; it++){
      int idx = it*256 + wid*64 + lane;
      int r = idx >> 3, sl = idx & 7;
      int kb = sl ^ (r & 7);
      const ushort* src = S.BT + (size_t)(colbase + r)*K + k0 + kb*8;
      __builtin_amdgcn_global_load_lds(AS1(src), AS3(ldsB + (size_t)(it*256 + wid*64)*8), 16, 0, 0);
    }
    __syncthreads();
    #pragma unroll
    for(int kk = 0; kk < 2; kk++){
      bh8 af[4], bf[NI];
      #pragma unroll
      for(int mi = 0; mi < 4; mi++){
        int arow = wr*64 + mi*16 + (lane & 15);
        int kb = kk*4 + (lane >> 4);
        af[mi] = *(const bh8*)(ldsA + arow*BK + ((kb ^ (arow & 7)) << 3));
      }
      #pragma unroll
      for(int ni = 0; ni < NI; ni++){
        int brow = wc*(BN/2) + ni*16 + (lane & 15);
        int kb = kk*4 + (lane >> 4);
        bf[ni] = *(const bh8*)(ldsB + brow*BK + ((kb ^ (brow & 7)) << 3));
      }
      #pragma unroll
      for(int mi = 0; mi < 4; mi++)
        #pragma unroll
        for(int ni = 0; ni < NI; ni++)
          acc[mi][ni] = __builtin_amdgcn_mfma_f32_16x16x32_bf16(af[mi], bf[ni], acc[mi][ni], 0, 0, 0);
    }
    __syncthreads();
  }
  OutT* C = (OutT*)S.C;
  #pragma unroll
  for(int mi = 0; mi < 4; mi++){
    #pragma unroll
    for(int ni = 0; ni < NI; ni++){
      int col = colbase + wc*(BN/2) + ni*16 + (lane & 15);
      if(col >= N) continue;
      float bv = BIAS ? S.bias[col] : 0.f;
      #pragma unroll
      for(int j = 0; j < 4; j++){
        int row = rowbase + wr*64 + mi*16 + (lane >> 4)*4 + j;
        if(row >= M) continue;
        float v = acc[mi][ni][j] + bv;
        if constexpr (sizeof(OutT) == 4) C[(size_t)row*S.ldc + col] = v;
        else                             C[(size_t)row*S.ldc + col] = (OutT)f2b(v);
      }
    }
  }
}

// ================= fused bipartite tail =================
__global__ __launch_bounds__(256) void bip_tail_k(
    const ushort* __restrict__ agg, const ushort* __restrict__ WTg3,
    const ushort* __restrict__ WpnT,
    const float* bias0, const float* bias1, const float* bias2,
    ushort* __restrict__ hcat, int M){
  __shared__ ushort ldsA[128*64];
  __shared__ ushort ldsB[128*64];
  __shared__ ushort ldsP[128*128];
  __shared__ ushort ldsW[64*128];
  const int seg = blockIdx.z;
  const ushort* A  = agg + (size_t)seg*M*256;
  const ushort* Wg = WTg3 + (size_t)seg*32768;
  const float* bias = seg==0 ? bias0 : (seg==1 ? bias1 : bias2);
  ushort* outp = hcat + 64 + seg*64;
  const int tid = threadIdx.x, lane = tid & 63, wid = tid >> 6;
  const int wr = wid >> 1, wc = wid & 1;
  const int rowbase = blockIdx.x*128;

  f32x4 acc_out[4][2];
  #pragma unroll
  for(int mi = 0; mi < 4; mi++){ acc_out[mi][0] = (f32x4)0.f; acc_out[mi][1] = (f32x4)0.f; }

  for(int hh = 0; hh < 4; hh++){
    #pragma unroll
    for(int it = 0; it < 4; it++){
      int idx = it*256 + tid;
      int r = idx >> 3, sl = idx & 7;
      int kb = sl ^ (r & 7);
      int grow = rowbase + r; if(grow >= M) grow = M-1;
      __builtin_amdgcn_global_load_lds(AS1(A + (size_t)grow*256 + hh*64 + kb*8),
                                       AS3(ldsA + (size_t)idx*8), 16, 0, 0);
    }
    #pragma unroll
    for(int it = 0; it < 4; it++){
      int idx = it*256 + tid;
      int r = idx >> 3, sl = idx & 7;
      int kb = sl ^ (r & 7);
      __builtin_amdgcn_global_load_lds(AS1(Wg + hh*8192 + r*64 + kb*8),
                                       AS3(ldsB + (size_t)idx*8), 16, 0, 0);
    }
    #pragma unroll
    for(int it = 0; it < 4; it++){
      int idx = it*256 + tid;
      int r = idx >> 4, sl = idx & 15;
      int kb = sl ^ (r & 7);
      __builtin_amdgcn_global_load_lds(AS1(WpnT + (size_t)r*512 + hh*128 + kb*8),
                                       AS3(ldsW + (size_t)idx*8), 16, 0, 0);
    }
    __syncthreads();
    f32x4 accp[4][4];
    #pragma unroll
    for(int mi = 0; mi < 4; mi++)
      #pragma unroll
      for(int ni = 0; ni < 4; ni++) accp[mi][ni] = (f32x4)0.f;
    #pragma unroll
    for(int kk = 0; kk < 2; kk++){
      bh8 af[4], bf[4];
      int kb = kk*4 + (lane >> 4);
      #pragma unroll
      for(int mi = 0; mi < 4; mi++){
        int arow = wr*64 + mi*16 + (lane & 15);
        af[mi] = *(const bh8*)(ldsA + arow*64 + ((kb ^ (arow & 7)) << 3));
      }
      #pragma unroll
      for(int ni = 0; ni < 4; ni++){
        int brow = wc*64 + ni*16 + (lane & 15);
        bf[ni] = *(const bh8*)(ldsB + brow*64 + ((kb ^ (brow & 7)) << 3));
      }
      #pragma unroll
      for(int mi = 0; mi < 4; mi++)
        #pragma unroll
        for(int ni = 0; ni < 4; ni++)
          accp[mi][ni] = __builtin_amdgcn_mfma_f32_16x16x32_bf16(af[mi], bf[ni], accp[mi][ni], 0, 0, 0);
    }
    #pragma unroll
    for(int mi = 0; mi < 4; mi++)
      #pragma unroll
      for(int ni = 0; ni < 4; ni++){
        int col = wc*64 + ni*16 + (lane & 15);
        float bv = bias[hh*128 + col];
        int rbase = wr*64 + mi*16 + (lane >> 4)*4;
        #pragma unroll
        for(int j = 0; j < 4; j++){
          float v = accp[mi][ni][j] + bv;
          v = v > 0.f ? v : (__expf(v) - 1.f);
          int row = rbase + j;
          ldsP[row*128 + ((((col >> 3) ^ (row & 7))) << 3) + (col & 7)] = f2b(v);
        }
      }
    __syncthreads();
    #pragma unroll
    for(int kk = 0; kk < 4; kk++){
      bh8 af[4], bf[2];
      int kb = kk*4 + (lane >> 4);
      #pragma unroll
      for(int mi = 0; mi < 4; mi++){
        int arow = wr*64 + mi*16 + (lane & 15);
        af[mi] = *(const bh8*)(ldsP + arow*128 + ((kb ^ (arow & 7)) << 3));
      }
      #pragma unroll
      for(int ni = 0; ni < 2; ni++){
        int brow = wc*32 + ni*16 + (lane & 15);
        bf[ni] = *(const bh8*)(ldsW + brow*128 + ((kb ^ (brow & 7)) << 3));
      }
      #pragma unroll
      for(int mi = 0; mi < 4; mi++)
        #pragma unroll
        for(int ni = 0; ni < 2; ni++)
          acc_out[mi][ni] = __builtin_amdgcn_mfma_f32_16x16x32_bf16(af[mi], bf[ni], acc_out[mi][ni], 0, 0, 0);
    }
    __syncthreads();
  }
  #pragma unroll
  for(int mi = 0; mi < 4; mi++)
    #pragma unroll
    for(int ni = 0; ni < 2; ni++){
      int col = wc*32 + ni*16 + (lane & 15);
      #pragma unroll
      for(int j = 0; j < 4; j++){
        int row = rowbase + wr*64 + mi*16 + (lane >> 4)*4 + j;
        if(row >= M) continue;
        outp[(size_t)row*256 + col] = f2b(acc_out[mi][ni][j]);
      }
    }
}

// ================= metapath GAT aggregate (D=32, 128 feat) =================
__global__ __launch_bounds__(256) void gat_agg_meta(
    const ushort* __restrict__ hs, const float* __restrict__ el,
    const float* __restrict__ er, const int* __restrict__ ofs,
    const int* __restrict__ colv, const float* __restrict__ bias,
    ushort* __restrict__ outv, int Nd){
  const int wslot = threadIdx.x >> 6;
  const int node = blockIdx.x*4 + wslot;
  const int lane = threadIdx.x & 63;
  __shared__ int   lds_s[4][64];
  __shared__ float lds_w[4][256];
  if(node >= Nd) return;
  const int e0 = ofs[node], e1 = ofs[node+1];
  const int g = lane >> 4, q = lane & 15;
  const int hh = q >> 2;
  const float4 erv = *(const float4*)(er + (size_t)node*4);
  float m0=-INFINITY, m1=-INFINITY, m2=-INFINITY, m3=-INFINITY;
  float sw0=0.f, sw1=0.f, sw2=0.f, sw3=0.f;
  float acc[8];
  #pragma unroll
  for(int r = 0; r < 8; r++) acc[r] = 0.f;

  for(int base = e0; base < e1; base += 64){
    int nch = e1 - base; if(nch > 64) nch = 64;
    int s_l = colv[base + (lane < nch ? lane : nch-1)];
    float4 ev = *(const float4*)(el + (size_t)s_l*4);
    float x0 = ev.x + erv.x; x0 = x0 > 0.f ? x0 : 0.2f*x0;
    float x1 = ev.y + erv.y; x1 = x1 > 0.f ? x1 : 0.2f*x1;
    float x2 = ev.z + erv.z; x2 = x2 > 0.f ? x2 : 0.2f*x2;
    float x3 = ev.w + erv.w; x3 = x3 > 0.f ? x3 : 0.2f*x3;
    if(lane >= nch){ x0 = x1 = x2 = x3 = -INFINITY; }
    float c0=x0, c1=x1, c2=x2, c3=x3;
    #pragma unroll
    for(int off = 32; off; off >>= 1){
      c0 = fmaxf(c0, __shfl_xor(c0, off));
      c1 = fmaxf(c1, __shfl_xor(c1, off));
      c2 = fmaxf(c2, __shfl_xor(c2, off));
      c3 = fmaxf(c3, __shfl_xor(c3, off));
    }
    float n0 = fmaxf(m0,c0), n1 = fmaxf(m1,c1), n2 = fmaxf(m2,c2), n3 = fmaxf(m3,c3);
    float r0 = __expf(m0-n0), r1 = __expf(m1-n1), r2 = __expf(m2-n2), r3 = __expf(m3-n3);
    float w0 = __expf(x0-n0), w1 = __expf(x1-n1), w2 = __expf(x2-n2), w3 = __expf(x3-n3);
    sw0 = sw0*r0 + w0; sw1 = sw1*r1 + w1; sw2 = sw2*r2 + w2; sw3 = sw3*r3 + w3;
    float rh = hh==0 ? r0 : (hh==1 ? r1 : (hh==2 ? r2 : r3));
    #pragma unroll
    for(int r = 0; r < 8; r++) acc[r] *= rh;
    m0=n0; m1=n1; m2=n2; m3=n3;
    lds_s[wslot][lane] = s_l;
    lds_w[wslot][lane*4+0] = w0; lds_w[wslot][lane*4+1] = w1;
    lds_w[wslot][lane*4+2] = w2; lds_w[wslot][lane*4+3] = w3;
    int npad = (nch + 15) & ~15;
    for(int j = 0; j < npad; j += 16){
      int sv[4]; float wv[4];
      #pragma unroll
      for(int u = 0; u < 4; u++){
        sv[u] = lds_s[wslot][j + u*4 + g];
        wv[u] = lds_w[wslot][(j + u*4 + g)*4 + hh];
      }
      bh8 vv[4];
      #pragma unroll
      for(int u = 0; u < 4; u++)
        vv[u] = *(const bh8*)(hs + (size_t)sv[u]*128 + q*8);
      #pragma unroll
      for(int u = 0; u < 4; u++)
        #pragma unroll
        for(int r = 0; r < 8; r++) acc[r] += wv[u] * b2f((ushort)vv[u][r]);
    }
  }
  #pragma unroll
  for(int off = 32; off; off >>= 1){
    sw0 += __shfl_xor(sw0, off); sw1 += __shfl_xor(sw1, off);
    sw2 += __shfl_xor(sw2, off); sw3 += __shfl_xor(sw3, off);
  }
  #pragma unroll
  for(int r = 0; r < 8; r++){
    acc[r] += __shfl_xor(acc[r], 16);
    acc[r] += __shfl_xor(acc[r], 32);
  }
  float swh = hh==0 ? sw0 : (hh==1 ? sw1 : (hh==2 ? sw2 : sw3));
  float den = (swh == 0.f) ? 1.f : swh;
  if(g == 0){
    bh8 ov;
    #pragma unroll
    for(int r = 0; r < 8; r++){
      float v = acc[r]/den + bias[q*8 + r];
      v = v > 0.f ? v : (__expf(v) - 1.f);
      ov[r] = (short)f2b(v);
    }
    *(bh8*)(outv + (size_t)node*128 + q*8) = ov;
  }
}

// ================= bipartite GAT aggregate, low-degree version =================
struct ASeg { const int* ofs; const int* colv; const float* el; const float* er; ushort* agg; };
__global__ __launch_bounds__(256) void gat_agg_proj3(ASeg s0, ASeg s1, ASeg s2,
    const ushort* __restrict__ proj, int2 pbase, int Nd, int nb){
  const int seg = blockIdx.x / nb;
  const ASeg S = seg == 0 ? s0 : (seg == 1 ? s1 : s2);
  const ushort* pj = proj + (size_t)(seg == 0 ? 0 : (seg == 1 ? pbase.x : pbase.y))*64;
  const int node = (blockIdx.x - seg*nb)*16 + (threadIdx.x >> 4);
  const int q = threadIdx.x & 15;
  if(node >= Nd) return;
  const int e0 = S.ofs[node], e1 = S.ofs[node+1];
  const int deg = e1 - e0;
  const float4 erv = *(const float4*)(S.er + (size_t)node*4);
  float sw0=0.f, sw1=0.f, sw2=0.f, sw3=0.f;
  float acc[4][4];
  #pragma unroll
  for(int d = 0; d < 4; d++)
    #pragma unroll
    for(int h = 0; h < 4; h++) acc[d][h] = 0.f;

  if(deg <= 8){
    const int ebase = (deg > 0) ? e0 : 0;
    int sv[8];
    #pragma unroll
    for(int u = 0; u < 8; u++) sv[u] = S.colv[ebase + (u < deg ? u : 0)];
    float xa[8], xb[8], xc[8], xd[8];
    #pragma unroll
    for(int u = 0; u < 8; u++){
      float4 ev = *(const float4*)(S.el + (size_t)sv[u]*4);
      float t0 = ev.x + erv.x; xa[u] = t0 > 0.f ? t0 : 0.2f*t0;
      float t1 = ev.y + erv.y; xb[u] = t1 > 0.f ? t1 : 0.2f*t1;
      float t2 = ev.z + erv.z; xc[u] = t2 > 0.f ? t2 : 0.2f*t2;
      float t3 = ev.w + erv.w; xd[u] = t3 > 0.f ? t3 : 0.2f*t3;
    }
    float m0=-INFINITY, m1=-INFINITY, m2=-INFINITY, m3=-INFINITY;
    #pragma unroll
    for(int u = 0; u < 8; u++) if(u < deg){
      m0 = fmaxf(m0, xa[u]); m1 = fmaxf(m1, xb[u]);
      m2 = fmaxf(m2, xc[u]); m3 = fmaxf(m3, xd[u]);
    }
    ushort4 pv[8];
    #pragma unroll
    for(int u = 0; u < 8; u++) pv[u] = *(const ushort4*)(pj + (size_t)sv[u]*64 + q*4);
    #pragma unroll
    for(int u = 0; u < 8; u++) if(u < deg){
      float w0 = __expf(xa[u]-m0), w1 = __expf(xb[u]-m1);
      float w2 = __expf(xc[u]-m2), w3 = __expf(xd[u]-m3);
      sw0 += w0; sw1 += w1; sw2 += w2; sw3 += w3;
      float f0 = b2f(pv[u].x), f1 = b2f(pv[u].y), f2 = b2f(pv[u].z), f3 = b2f(pv[u].w);
      acc[0][0] += w0*f0; acc[0][1] += w1*f0; acc[0][2] += w2*f0; acc[0][3] += w3*f0;
      acc[1][0] += w0*f1; acc[1][1] += w1*f1; acc[1][2] += w2*f1; acc[1][3] += w3*f1;
      acc[2][0] += w0*f2; acc[2][1] += w1*f2; acc[2][2] += w2*f2; acc[2][3] += w3*f2;
      acc[3][0] += w0*f3; acc[3][1] += w1*f3; acc[3][2] += w2*f3; acc[3][3] += w3*f3;
    }
  } else {
    float m0=-INFINITY, m1=-INFINITY, m2=-INFINITY, m3=-INFINITY;
    for(int e = e0; e < e1; e++){
      int s = S.colv[e];
      float4 ev = *(const float4*)(S.el + (size_t)s*4);
      float x0 = ev.x + erv.x; x0 = x0 > 0.f ? x0 : 0.2f*x0;
      float x1 = ev.y + erv.y; x1 = x1 > 0.f ? x1 : 0.2f*x1;
      float x2 = ev.z + erv.z; x2 = x2 > 0.f ? x2 : 0.2f*x2;
      float x3 = ev.w + erv.w; x3 = x3 > 0.f ? x3 : 0.2f*x3;
      m0 = fmaxf(m0,x0); m1 = fmaxf(m1,x1); m2 = fmaxf(m2,x2); m3 = fmaxf(m3,x3);
    }
    for(int e = e0; e < e1; e++){
      int s = S.colv[e];
      float4 ev = *(const float4*)(S.el + (size_t)s*4);
      float x0 = ev.x + erv.x; x0 = x0 > 0.f ? x0 : 0.2f*x0;
      float x1 = ev.y + erv.y; x1 = x1 > 0.f ? x1 : 0.2f*x1;
      float x2 = ev.z + erv.z; x2 = x2 > 0.f ? x2 : 0.2f*x2;
      float x3 = ev.w + erv.w; x3 = x3 > 0.f ? x3 : 0.2f*x3;
      float w0 = __expf(x0-m0), w1 = __expf(x1-m1);
      float w2 = __expf(x2-m2), w3 = __expf(x3-m3);
      sw0 += w0; sw1 += w1; sw2 += w2; sw3 += w3;
      ushort4 p = *(const ushort4*)(pj + (size_t)s*64 + q*4);
      float f0 = b2f(p.x), f1 = b2f(p.y), f2 = b2f(p.z), f3 = b2f(p.w);
      acc[0][0] += w0*f0; acc[0][1] += w1*f0; acc[0][2] += w2*f0; acc[0][3] += w3*f0;
      acc[1][0] += w0*f1; acc[1][1] += w1*f1; acc[1][2] += w2*f1; acc[1][3] += w3*f1;
      acc[2][0] += w0*f2; acc[2][1] += w1*f2; acc[2][2] += w2*f2; acc[2][3] += w3*f2;
      acc[3][0] += w0*f3; acc[3][1] += w1*f3; acc[3][2] += w2*f3; acc[3][3] += w3*f3;
    }
  }
  float dn[4];
  dn[0] = (sw0 == 0.f) ? 1.f : sw0;
  dn[1] = (sw1 == 0.f) ? 1.f : sw1;
  dn[2] = (sw2 == 0.f) ? 1.f : sw2;
  dn[3] = (sw3 == 0.f) ? 1.f : sw3;
  ushort* orow = S.agg + (size_t)node*256;
  #pragma unroll
  for(int h = 0; h < 4; h++){
    ushort4 o;
    o.x = f2b(acc[0][h]/dn[h]); o.y = f2b(acc[1][h]/dn[h]);
    o.z = f2b(acc[2][h]/dn[h]); o.w = f2b(acc[3][h]/dn[h]);
    *(ushort4*)(orow + h*64 + q*4) = o;
  }
}

// ================= host orchestration =================
extern "C" void kernel_launch(void* const* d_in, const int* in_sizes, int n_in,
                              void* d_out, int out_size, void* d_ws, size_t ws_size,
                              hipStream_t stream){
  const float* hp   = (const float*)d_in[0];
  const float* hq   = (const float*)d_in[1];
  const float* hk   = (const float*)d_in[2];
  const float* ha   = (const float*)d_in[3];
  const int* meta_src = (const int*)d_in[4];
  const int* meta_dst = (const int*)d_in[5];
  const int* q_src = (const int*)d_in[6];
  const int* q_dst = (const int*)d_in[7];
  const int* k_src = (const int*)d_in[8];
  const int* k_dst = (const int*)d_in[9];
  const int* a_src = (const int*)d_in[10];
  const int* a_dst = (const int*)d_in[11];
  const float* W0  = (const float*)d_in[12]; const float* al0 = (const float*)d_in[13];
  const float* ar0 = (const float*)d_in[14]; const float* b0  = (const float*)d_in[15];
  const float* W1  = (const float*)d_in[16]; const float* al1 = (const float*)d_in[17];
  const float* ar1 = (const float*)d_in[18]; const float* b1  = (const float*)d_in[19];
  const float* Wq  = (const float*)d_in[20]; const float* alq = (const float*)d_in[21];
  const float* arq = (const float*)d_in[22]; const float* bq  = (const float*)d_in[23];
  const float* Wkw = (const float*)d_in[24]; const float* alkw= (const float*)d_in[25];
  const float* arkw= (const float*)d_in[26]; const float* bkw = (const float*)d_in[27];
  const float* Watt= (const float*)d_in[28]; const float* alatt=(const float*)d_in[29];
  const float* aratt=(const float*)d_in[30]; const float* batt= (const float*)d_in[31];
  const float* Wpnn_a = (const float*)d_in[32];
  const float* Wpn_a  = (const float*)d_in[33];
  const float* Wpnn   = (const float*)d_in[34];
  const float* Wpn    = (const float*)d_in[35];
  const float* Wpred  = (const float*)d_in[36];
  const float* bpred  = (const float*)d_in[37];
  (void)n_in; (void)out_size; (void)ws_size;

  const int IN = 128, ATT = 64;
  const int NP = in_sizes[0]/IN, NQ = in_sizes[1]/ATT, NK = in_sizes[2]/ATT, NA = in_sizes[3]/ATT;
  const int EM = in_sizes[4], EQ = in_sizes[6], EK = in_sizes[8], EA = in_sizes[10];
  const int range = (NP + 7)/8;
  const int NS = NQ + NK + NA;
  const int JH = 8;                       // histogram partials per bucket
  const int NPL = (NP + 3) & ~3;          // partial array stride (int4-aligned)

  // ----- workspace layout -----
  uint8_t* wp = (uint8_t*)d_ws;
  auto alloc = [&](size_t bytes)->uint8_t*{
    uint8_t* p = wp; wp += (bytes + 255) & ~(size_t)255; return p;
  };
  ushort* hcat_b = (ushort*)alloc((size_t)NP*256*2);
  ushort* hbuf_b = (ushort*)alloc((size_t)NP*128*2);
  ushort* hp_b   = (ushort*)alloc((size_t)NP*128*2);
  ushort* hpd_b  = (ushort*)alloc((size_t)NP*64*2);
  ushort* hs_b   = (ushort*)alloc((size_t)NP*128*2);
  ushort* feat_all = (ushort*)alloc((size_t)NS*64*2);
  ushort* proj_all = (ushort*)alloc((size_t)NS*64*2);
  ushort* agg_all  = (ushort*)alloc((size_t)3*NP*256*2);
  float* el    = (float*)alloc((size_t)NP*4*4);
  float* er    = (float*)alloc((size_t)NP*4*4);
  float* el_all= (float*)alloc((size_t)NS*4*4);
  float* er_all= (float*)alloc((size_t)3*NP*4*4);
  float* wf    = (float*)alloc((size_t)10*512*4);
  int* bcur    = (int*)alloc((size_t)512*4);          // 32 counters, 64B padded
  int* part    = (int*)alloc((size_t)4*JH*NPL*4);     // count partials
  int* cur4    = (int*)alloc((size_t)4*NP*4);
  int* ofsm    = (int*)alloc((size_t)(NP+4)*4);
  int* ofsq    = (int*)alloc((size_t)(NP+4)*4);
  int* ofsk    = (int*)alloc((size_t)(NP+4)*4);
  int* ofsa    = (int*)alloc((size_t)(NP+4)*4);
  int* colm    = (int*)alloc((size_t)EM*4);
  int* colq    = (int*)alloc((size_t)EQ*4);
  int* colk    = (int*)alloc((size_t)EK*4);
  int* cola    = (int*)alloc((size_t)EA*4);
  const int capM = EM/4+1024, capQ = EQ/4+1024, capK = EK/4+1024, capA = EA/4+1024;
  uint* ebm = (uint*)alloc((size_t)8*capM*4);
  uint* ebq = (uint*)alloc((size_t)8*capQ*4);
  uint* ebk = (uint*)alloc((size_t)8*capK*4);
  uint* eba = (uint*)alloc((size_t)8*capA*4);
  ushort* W0T    = (ushort*)alloc(128*128*2);
  ushort* W1T    = (ushort*)alloc(128*128*2);
  ushort* WTg3   = (ushort*)alloc((size_t)3*4*128*64*2);
  ushort* WpnT   = (ushort*)alloc((size_t)64*512*2);
  ushort* WpnnT  = (ushort*)alloc(64*128*2);
  ushort* Wpnn_aT= (ushort*)alloc(64*128*2);
  ushort* Wpn_aT = (ushort*)alloc(64*64*2);
  ushort* WpredT = (ushort*)alloc((size_t)1024*256*2);

  // ----- CSR build (5 dispatches: fill, partition, hist, scan4, scatter) -----
  fill_zero_i32<<<2, 256, 0, stream>>>(bcur, 512);
  {
    int bm = (EM+PSL-1)/PSL, bq2 = (EQ+PSL-1)/PSL, bk2 = (EK+PSL-1)/PSL, ba2 = (EA+PSL-1)/PSL;
    P4 g0{meta_src, meta_dst, ebm, EM, capM, 0, bm};
    P4 g1{q_src, q_dst, ebq, EQ, capQ, bm, bm+bq2};
    P4 g2{k_src, k_dst, ebk, EK, capK, bm+bq2, bm+bq2+bk2};
    P4 g3{a_src, a_dst, eba, EA, capA, bm+bq2+bk2, bm+bq2+bk2+ba2};
    partition_all_k<<<g3.bend, 256, 0, stream>>>(g0, g1, g2, g3, bcur, range);
  }
  {
    H4 h0{ebm, capM}, h1{ebq, capQ}, h2{ebk, capK}, h3{eba, capA};
    hist_all_k<<<4*8*JH, 256, 0, stream>>>(h0, h1, h2, h3, bcur, part, range, NPL, JH, NP);
    scan4_k<<<4, 1024, 0, stream>>>(part, JH, NPL,
                                    ofsm, ofsq, ofsk, ofsa,
                                    cur4, cur4+NP, cur4+2*NP, cur4+3*NP, NP);
    auto Jof = [&](int E){ int J = E/65536 + 8; if(J > 48) J = 48; return J; };
    int jm = 8*Jof(EM), jq = 8*Jof(EQ), jk = 8*Jof(EK), ja = 8*Jof(EA);
    SB4 s0{ebm, capM, cur4 + 0*NP, colm, 0, jm};
    SB4 s1{ebq, capQ, cur4 + 1*NP, colq, jm, jm+jq};
    SB4 s2{ebk, capK, cur4 + 2*NP, colk, jm+jq, jm+jq+jk};
    SB4 s3{eba, capA, cur4 + 3*NP, cola, jm+jq+jk, jm+jq+jk+ja};
    scatter_all_k<<<s3.bend, 256, 0, stream>>>(s0, s1, s2, s3, bcur, range);
  }

  // ----- conversions + weight prep (4 dispatches) -----
  {
    int c0 = NP*128/4, c1 = c0 + NQ*64/4, c2 = c1 + NK*64/4, c3 = c2 + NA*64/4;
    cvt_all_k<<<(c3+255)/256, 256, 0, stream>>>(hp, hq, hk, ha,
        hp_b, feat_all, feat_all + (size_t)NQ*64, feat_all + (size_t)(NQ+NK)*64,
        make_int4(c0, c1, c2, c3));
  }
  {
    WTAll a;
    a.d[0] = {W0, W0T, 128, 128};      a.d[1] = {W1, W1T, 128, 128};
    a.d[2] = {Wpn, WpnT, 512, 64};     a.d[3] = {Wpnn, WpnnT, 128, 64};
    a.d[4] = {Wpnn_a, Wpnn_aT, 128, 64}; a.d[5] = {Wpn_a, Wpn_aT, 64, 64};
    a.d[6] = {Wpred, WpredT, 256, 1000};
    int items[7] = {128*128, 128*128, 64*512, 64*128, 64*128, 64*64, 1024*256};
    a.cum[0] = 0;
    for(int t = 0; t < 7; t++) a.cum[t+1] = a.cum[t] + items[t];
    wT_all_k<<<(a.cum[7]+255)/256, 256, 0, stream>>>(a);
  }
  wTg3_k<<<(3*32768+255)/256, 256, 0, stream>>>(Wq, Wkw, Watt, WTg3);
  {
    FAll f;
    f.d[0] = {W0, al0, wf+0*512, 128, 32};  f.d[1] = {W0, ar0, wf+1*512, 128, 32};
    f.d[2] = {W1, al1, wf+2*512, 128, 32};  f.d[3] = {W1, ar1, wf+3*512, 128, 32};
    f.d[4] = {Wq, alq, wf+4*512, 64, 128};  f.d[5] = {Wq, arq, wf+5*512, 64, 128};
    f.d[6] = {Wkw, alkw, wf+6*512, 64, 128};f.d[7] = {Wkw, arkw, wf+7*512, 64, 128};
    f.d[8] = {Watt, alatt, wf+8*512, 64, 128};f.d[9] = {Watt, aratt, wf+9*512, 64, 128};
    fold_all_k<<<10, 256, 0, stream>>>(f);
  }

  auto launch_gemm = [&]<int BN, typename OutT, bool BIAS>(
      GSeg a, GSeg b, GSeg c, int nseg, int M, int N, int K, int lda){
    int Npad = (N + BN - 1)/BN*BN;
    dim3 g((M + 127)/128, Npad/BN, nseg);
    gemm_mfma_b<BN, OutT, BIAS><<<g, 256, 0, stream>>>(a, b, c, M, N, K, lda);
  };
  GSeg z{};

  // ----- metapath GAT layer 0 -----
  launch_gemm.template operator()<128, ushort, false>(
      GSeg{hp_b, W0T, nullptr, hs_b, 128}, z, z, 1, NP, 128, 128, 128);
  gemv8v<ushort><<<(NP/2+3)/4, 256, 0, stream>>>(hp_b, wf+0*512, wf+1*512, el, er, NP, 128);
  gat_agg_meta<<<(NP+3)/4, 256, 0, stream>>>(hs_b, el, er, ofsm, colm, b0, hbuf_b, NP);

  // ----- metapath GAT layer 1 -----
  launch_gemm.template operator()<128, ushort, false>(
      GSeg{hbuf_b, W1T, nullptr, hs_b, 128}, z, z, 1, NP, 128, 128, 128);
  gemv8v<ushort><<<(NP/2+3)/4, 256, 0, stream>>>(hbuf_b, wf+2*512, wf+3*512, el, er, NP, 128);
  gat_agg_meta<<<(NP+3)/4, 256, 0, stream>>>(hs_b, el, er, ofsm, colm, b1, hbuf_b, NP);

  // ----- batched: hcat[:,0:64] = h @ Wpnn ; hpd = hp @ Wpnn_a -----
  launch_gemm.template operator()<64, ushort, false>(
      GSeg{hbuf_b, WpnnT, nullptr, hcat_b, 256},
      GSeg{hp_b, Wpnn_aT, nullptr, hpd_b, 64}, z, 2, NP, 64, 128, 128);

  // ----- bipartite GATs (batched) -----
  launch_gemm.template operator()<64, ushort, false>(
      GSeg{feat_all, Wpn_aT, nullptr, proj_all, 64}, z, z, 1, NS, 64, 64, 64);
  gemv4v_seg3<<<(NS/4+3)/4, 256, 0, stream>>>(proj_all, wf+4*512, wf+6*512, wf+8*512,
      el_all, NS, NQ, NQ+NK);
  gemv4v_er3<<<(NP/4+3)/4, 256, 0, stream>>>(hpd_b, wf+5*512, wf+7*512, wf+9*512,
      er_all, er_all + (size_t)NP*4, er_all + (size_t)2*NP*4, NP);
  {
    int nb = (NP+15)/16;
    ASeg a0{ofsq, colq, el_all,                    er_all,                    agg_all};
    ASeg a1{ofsk, colk, el_all + (size_t)NQ*4,     er_all + (size_t)NP*4,     agg_all + (size_t)NP*256};
    ASeg a2{ofsa, cola, el_all + (size_t)(NQ+NK)*4,er_all + (size_t)2*NP*4,   agg_all + (size_t)2*NP*256};
    gat_agg_proj3<<<3*nb, 256, 0, stream>>>(a0, a1, a2, proj_all, make_int2(NQ, NQ+NK), NP, nb);
  }
  {
    dim3 g((NP+127)/128, 1, 3);
    bip_tail_k<<<g, 256, 0, stream>>>(agg_all, WTg3, WpnT, bq, bkw, batt, hcat_b, NP);
  }

  // ----- final: out = hcat @ Wpred + bpred -----
  launch_gemm.template operator()<128, float, true>(
      GSeg{hcat_b, WpredT, bpred, d_out, 1000}, z, z, 1, NP, 1000, 256, 256);
}

// Round 14
// 713.588 us; speedup vs baseline: 1.9123x; 1.0026x over previous
//
#include <hip/hip_runtime.h>
#include <hip/hip_bf16.h>
#include <math.h>
#include <stdint.h>

typedef __attribute__((ext_vector_type(8))) short bh8;
typedef __attribute__((ext_vector_type(4))) float f32x4;

#define AS1(p) ((const __attribute__((address_space(1))) void*)(p))
#define AS3(p) ((__attribute__((address_space(3))) void*)(p))
#define PSL 2048

__device__ inline ushort f2b(float f){
  uint u = __builtin_bit_cast(uint, f);
  u += 0x7fff + ((u >> 16) & 1);
  return (ushort)(u >> 16);
}
__device__ inline float b2f(ushort b){ return __builtin_bit_cast(float, (uint)b << 16); }

// ================= CSR build =================
__global__ void fill_zero_i32(int* __restrict__ p, int n){
  int i = blockIdx.x*blockDim.x + threadIdx.x;
  if(i < n) p[i] = 0;
}

// Partition: 2048 edges/block in registers; per-wave LDS histogram; one padded
// reservation per bucket per block; per-wave LDS cursors. No per-edge global atomics.
struct P4 { const int* src; const int* dst; uint* ebuf; int E; int cap; int bbeg; int bend; };

__global__ __launch_bounds__(256) void partition_all_k(P4 g0, P4 g1, P4 g2, P4 g3,
    int* __restrict__ bcur, int range){
  P4 G; int gi;
  int b = blockIdx.x;
  if(b < g0.bend){ G = g0; gi = 0; }
  else if(b < g1.bend){ G = g1; gi = 1; }
  else if(b < g2.bend){ G = g2; gi = 2; }
  else { G = g3; gi = 3; }
  const int beg = (b - G.bbeg)*PSL;
  const int tid = threadIdx.x, w = tid >> 6;
  __shared__ int hist4[4][8];
  __shared__ int cur4[4][8];
  if(tid < 32) (&hist4[0][0])[tid] = 0;
  __syncthreads();
  int dv[8], sv[8], bv[8];
  const int bi = beg + tid*8;
  if(beg + PSL <= G.E){
    int4 d0 = *(const int4*)(G.dst + bi);
    int4 d1 = *(const int4*)(G.dst + bi + 4);
    int4 s0 = *(const int4*)(G.src + bi);
    int4 s1 = *(const int4*)(G.src + bi + 4);
    dv[0]=d0.x; dv[1]=d0.y; dv[2]=d0.z; dv[3]=d0.w;
    dv[4]=d1.x; dv[5]=d1.y; dv[6]=d1.z; dv[7]=d1.w;
    sv[0]=s0.x; sv[1]=s0.y; sv[2]=s0.z; sv[3]=s0.w;
    sv[4]=s1.x; sv[5]=s1.y; sv[6]=s1.z; sv[7]=s1.w;
    #pragma unroll
    for(int u = 0; u < 8; u++) bv[u] = dv[u]/range;
  } else {
    #pragma unroll
    for(int u = 0; u < 8; u++){
      int i = bi + u;
      bool ok = i < G.E;
      dv[u] = ok ? G.dst[i] : 0;
      sv[u] = ok ? G.src[i] : 0;
      bv[u] = ok ? dv[u]/range : -1;
    }
  }
  #pragma unroll
  for(int u = 0; u < 8; u++) if(bv[u] >= 0) atomicAdd(&hist4[w][bv[u]], 1);
  __syncthreads();
  if(tid < 8){
    int h0 = hist4[0][tid], h1 = hist4[1][tid], h2 = hist4[2][tid], h3 = hist4[3][tid];
    int tot = h0 + h1 + h2 + h3;
    int bs = tot ? atomicAdd(&bcur[(gi*8 + tid)*16], tot) : 0;
    cur4[0][tid] = bs;
    cur4[1][tid] = bs + h0;
    cur4[2][tid] = bs + h0 + h1;
    cur4[3][tid] = bs + h0 + h1 + h2;
  }
  __syncthreads();
  #pragma unroll
  for(int u = 0; u < 8; u++) if(bv[u] >= 0){
    int pos = atomicAdd(&cur4[w][bv[u]], 1);
    if(pos < G.cap) G.ebuf[(size_t)bv[u]*G.cap + pos] = ((uint)sv[u] << 13) | (uint)(dv[u] - bv[u]*range);
  }
}

// Atomic-free counting: per (graph,bucket,j) LDS histogram -> partial j.
struct H4 { const uint* ebuf; int cap; };
__global__ __launch_bounds__(256) void hist_all_k(H4 h0, H4 h1, H4 h2, H4 h3,
    const int* __restrict__ bcur, int* __restrict__ part,
    int range, int NPL, int J, int NP){
  __shared__ int h[8192];
  const int x = blockIdx.x;
  const int g = x/(8*J);
  const int rem = x - g*8*J;
  const int bk = rem/J, j = rem - bk*J;
  H4 H = g==0 ? h0 : (g==1 ? h1 : (g==2 ? h2 : h3));
  for(int i = threadIdx.x; i < range; i += 256) h[i] = 0;
  __syncthreads();
  int nb = bcur[(g*8 + bk)*16]; if(nb > H.cap) nb = H.cap;
  const uint* eb = H.ebuf + (size_t)bk*H.cap;
  int per = (nb + J - 1)/J;
  int lo = j*per, hi = lo + per; if(hi > nb) hi = nb;
  for(int i = lo + threadIdx.x; i < hi; i += 256)
    atomicAdd(&h[eb[i] & 8191u], 1);
  __syncthreads();
  int lim = NP - bk*range; if(lim > range) lim = range;
  int* dst = part + ((size_t)g*J + j)*NPL + bk*range;
  for(int i = threadIdx.x; i < lim; i += 256) dst[i] = h[i];
}

// Scatter v2: LDS cursors seeded from ofs + prefix of j-partials. No global atomics.
struct SC4 { const uint* ebuf; int cap; const int* ofs; int* colv; };
__global__ __launch_bounds__(256) void scatter_lds_k(SC4 g0, SC4 g1, SC4 g2, SC4 g3,
    const int* __restrict__ bcur, const int* __restrict__ part,
    int range, int NPL, int J, int NP){
  __shared__ int cur[8192];
  const int x = blockIdx.x;
  const int g = x/(8*J);
  const int rem = x - g*8*J;
  const int bk = rem/J, j = rem - bk*J;
  SC4 G = g==0 ? g0 : (g==1 ? g1 : (g==2 ? g2 : g3));
  int lim = NP - bk*range; if(lim > range) lim = range;
  const int* pp = part + (size_t)g*J*NPL + bk*range;
  for(int i = threadIdx.x; i < lim; i += 256){
    int c = G.ofs[bk*range + i];
    for(int jj = 0; jj < j; jj++) c += pp[(size_t)jj*NPL + i];
    cur[i] = c;
  }
  __syncthreads();
  int nb = bcur[(g*8 + bk)*16]; if(nb > G.cap) nb = G.cap;
  const uint* eb = G.ebuf + (size_t)bk*G.cap;
  int per = (nb + J - 1)/J;
  int lo = j*per, hi = lo + per; if(hi > nb) hi = nb;
  for(int i = lo + threadIdx.x; i < hi; i += 256){
    uint e = eb[i];
    int p = atomicAdd(&cur[e & 8191u], 1);
    G.colv[p] = (int)(e >> 13);
  }
}

// 4 independent exclusive scans over summed J-partials
__global__ __launch_bounds__(1024) void scan4_k(
    const int* __restrict__ part, int J, int NPL,
    int* o0, int* o1, int* o2, int* o3, int n){
  const int* pg = part + (size_t)blockIdx.x*J*NPL;
  int* ofs = blockIdx.x==0?o0:(blockIdx.x==1?o1:(blockIdx.x==2?o2:o3));
  __shared__ int wsum[16];
  __shared__ int carry_s;
  int tid = threadIdx.x, wid = tid >> 6, lane = tid & 63;
  if(tid == 0) carry_s = 0;
  __syncthreads();
  for(int base = 0; base < n; base += 4096){
    int i0 = base + tid*4;
    int4 v = make_int4(0,0,0,0);
    if(i0 + 3 < n){
      for(int j = 0; j < J; j++){
        int4 t = *(const int4*)(pg + (size_t)j*NPL + i0);
        v.x += t.x; v.y += t.y; v.z += t.z; v.w += t.w;
      }
    } else if(i0 < n){
      for(int j = 0; j < J; j++){
        v.x += pg[(size_t)j*NPL + i0];
        if(i0+1 < n) v.y += pg[(size_t)j*NPL + i0+1];
        if(i0+2 < n) v.z += pg[(size_t)j*NPL + i0+2];
      }
    }
    int s1 = v.x + v.y, s2 = s1 + v.z, tot = s2 + v.w;
    int x = tot;
    #pragma unroll
    for(int off = 1; off < 64; off <<= 1){
      int t = __shfl_up(x, off);
      if(lane >= off) x += t;
    }
    if(lane == 63) wsum[wid] = x;
    __syncthreads();
    if(tid < 16){
      int y = wsum[tid];
      #pragma unroll
      for(int off = 1; off < 16; off <<= 1){
        int t = __shfl_up(y, off);
        if(tid >= off) y += t;
      }
      wsum[tid] = y;
    }
    __syncthreads();
    int pre = (wid ? wsum[wid-1] : 0) + carry_s + (x - tot);
    if(i0 + 3 < n){
      *(int4*)(ofs + i0) = make_int4(pre, pre+v.x, pre+s1, pre+s2);
    } else if(i0 < n){
      ofs[i0] = pre;
      if(i0+1 < n) ofs[i0+1] = pre+v.x;
      if(i0+2 < n) ofs[i0+2] = pre+s1;
    }
    __syncthreads();
    if(tid == 0) carry_s += wsum[15];
    __syncthreads();
  }
  if(tid == 0) ofs[n] = carry_s;
}

// ================= preprocessing (fused) =================
__global__ void cvt_all_k(const float* i0, const float* i1, const float* i2, const float* i3,
    ushort* o0, ushort* o1, ushort* o2, ushort* o3, int4 cum){
  int i = blockIdx.x*blockDim.x + threadIdx.x;
  const float* in; ushort* out; int base;
  if(i < cum.x){ in=i0; out=o0; base=0; }
  else if(i < cum.y){ in=i1; out=o1; base=cum.x; }
  else if(i < cum.z){ in=i2; out=o2; base=cum.y; }
  else if(i < cum.w){ in=i3; out=o3; base=cum.z; }
  else return;
  int l = i - base;
  float4 v = ((const float4*)in)[l];
  ushort4 o; o.x=f2b(v.x); o.y=f2b(v.y); o.z=f2b(v.z); o.w=f2b(v.w);
  ((ushort4*)out)[l] = o;
}

struct WTD { const float* W; ushort* WT; int K; int N; };
struct WTAll { WTD d[7]; int cum[8]; };
__global__ void wT_all_k(WTAll a){
  int idx = blockIdx.x*blockDim.x + threadIdx.x;
  if(idx >= a.cum[7]) return;
  int j = 0;
  #pragma unroll
  for(int t = 1; t < 7; t++) if(idx >= a.cum[t]) j = t;
  int l = idx - a.cum[j];
  WTD d = a.d[j];
  int n = l / d.K, k = l - n*d.K;
  d.WT[l] = (n < d.N) ? f2b(d.W[(size_t)k*d.N + n]) : (ushort)0;
}

__global__ void wTg3_k(const float* W0, const float* W1, const float* W2, ushort* WT){
  int idx = blockIdx.x*blockDim.x + threadIdx.x;
  if(idx >= 3*32768) return;
  int g = idx >> 15, rem = idx & 32767;
  const float* W = g==0 ? W0 : (g==1 ? W1 : W2);
  int h = rem >> 13, r2 = rem & 8191;
  int n = r2 >> 6, k = r2 & 63;
  WT[idx] = f2b(W[(size_t)k*512 + h*128 + n]);
}

struct FD { const float* W; const float* a; float* out; int K; int D; };
struct FAll { FD d[10]; };
__global__ void fold_all_k(FAll f){
  FD d = f.d[blockIdx.x];
  for(int i = threadIdx.x; i < d.K*4; i += 256){
    int k = i >> 2, h = i & 3;
    const float* wr = d.W + (size_t)k*4*d.D + (size_t)h*d.D;
    const float* ar = d.a + (size_t)h*d.D;
    float s = 0.f;
    for(int dd = 0; dd < d.D; dd++) s += wr[dd]*ar[dd];
    d.out[i] = s;
  }
}

// ================= gemv =================
__device__ inline void ld4v(const float* p, float* v){
  float4 t = *(const float4*)p; v[0]=t.x; v[1]=t.y; v[2]=t.z; v[3]=t.w;
}
__device__ inline void ld4v(const ushort* p, float* v){
  ushort4 t = *(const ushort4*)p; v[0]=b2f(t.x); v[1]=b2f(t.y); v[2]=b2f(t.z); v[3]=b2f(t.w);
}

__global__ __launch_bounds__(256) void gemv4v_seg3(const ushort* __restrict__ A,
    const float* __restrict__ W0, const float* __restrict__ W1, const float* __restrict__ W2,
    float* __restrict__ outv, int M, int b1, int b2){
  const int w = (blockIdx.x*blockDim.x + threadIdx.x) >> 6;
  const int lane = threadIdx.x & 63;
  const int r = lane >> 4, q = lane & 15;
  int row = w*4 + r;
  bool valid = row < M;
  int rowc = valid ? row : (M-1);
  const float* Wf = rowc < b1 ? W0 : (rowc < b2 ? W1 : W2);
  float av[4];
  ld4v(A + (size_t)rowc*64 + q*4, av);
  float a[4] = {0.f,0.f,0.f,0.f};
  #pragma unroll
  for(int kk = 0; kk < 4; kk++){
    float4 wv = *(const float4*)(Wf + (q*4+kk)*4);
    a[0] += av[kk]*wv.x; a[1] += av[kk]*wv.y; a[2] += av[kk]*wv.z; a[3] += av[kk]*wv.w;
  }
  #pragma unroll
  for(int off = 1; off < 16; off <<= 1){
    a[0] += __shfl_xor(a[0], off); a[1] += __shfl_xor(a[1], off);
    a[2] += __shfl_xor(a[2], off); a[3] += __shfl_xor(a[3], off);
  }
  if(valid && q == 0){
    float4 o; o.x=a[0]; o.y=a[1]; o.z=a[2]; o.w=a[3];
    *(float4*)(outv + (size_t)row*4) = o;
  }
}

__global__ __launch_bounds__(256) void gemv4v_er3(const ushort* __restrict__ A,
    const float* __restrict__ W0, const float* __restrict__ W1, const float* __restrict__ W2,
    float* __restrict__ o0, float* __restrict__ o1, float* __restrict__ o2, int M){
  const int w = (blockIdx.x*blockDim.x + threadIdx.x) >> 6;
  const int lane = threadIdx.x & 63;
  const int r = lane >> 4, q = lane & 15;
  int row = w*4 + r;
  bool valid = row < M;
  int rowc = valid ? row : (M-1);
  float av[4];
  ld4v(A + (size_t)rowc*64 + q*4, av);
  float a[12];
  #pragma unroll
  for(int t = 0; t < 12; t++) a[t] = 0.f;
  #pragma unroll
  for(int kk = 0; kk < 4; kk++){
    float4 w0 = *(const float4*)(W0 + (q*4+kk)*4);
    float4 w1 = *(const float4*)(W1 + (q*4+kk)*4);
    float4 w2 = *(const float4*)(W2 + (q*4+kk)*4);
    a[0] += av[kk]*w0.x; a[1] += av[kk]*w0.y; a[2] += av[kk]*w0.z; a[3] += av[kk]*w0.w;
    a[4] += av[kk]*w1.x; a[5] += av[kk]*w1.y; a[6] += av[kk]*w1.z; a[7] += av[kk]*w1.w;
    a[8] += av[kk]*w2.x; a[9] += av[kk]*w2.y; a[10]+= av[kk]*w2.z; a[11]+= av[kk]*w2.w;
  }
  #pragma unroll
  for(int off = 1; off < 16; off <<= 1)
    #pragma unroll
    for(int t = 0; t < 12; t++) a[t] += __shfl_xor(a[t], off);
  if(valid && q == 0){
    float4 x; x.x=a[0]; x.y=a[1]; x.z=a[2]; x.w=a[3];
    *(float4*)(o0 + (size_t)row*4) = x;
    float4 y; y.x=a[4]; y.y=a[5]; y.z=a[6]; y.w=a[7];
    *(float4*)(o1 + (size_t)row*4) = y;
    float4 z; z.x=a[8]; z.y=a[9]; z.z=a[10]; z.w=a[11];
    *(float4*)(o2 + (size_t)row*4) = z;
  }
}

template<typename T>
__global__ __launch_bounds__(256) void gemv8v(const T* __restrict__ A,
    const float* __restrict__ Wfa, const float* __restrict__ Wfb,
    float* __restrict__ oa, float* __restrict__ ob, int M, int lda){
  const int w = (blockIdx.x*blockDim.x + threadIdx.x) >> 6;
  const int lane = threadIdx.x & 63;
  const int r = lane >> 5, q = lane & 31;
  int row = w*2 + r;
  bool valid = row < M;
  int rowc = valid ? row : (M-1);
  float av[4];
  ld4v(A + (size_t)rowc*lda + q*4, av);
  float a[4] = {0.f,0.f,0.f,0.f}, b[4] = {0.f,0.f,0.f,0.f};
  #pragma unroll
  for(int kk = 0; kk < 4; kk++){
    float4 wa = *(const float4*)(Wfa + (q*4+kk)*4);
    float4 wb = *(const float4*)(Wfb + (q*4+kk)*4);
    a[0] += av[kk]*wa.x; a[1] += av[kk]*wa.y; a[2] += av[kk]*wa.z; a[3] += av[kk]*wa.w;
    b[0] += av[kk]*wb.x; b[1] += av[kk]*wb.y; b[2] += av[kk]*wb.z; b[3] += av[kk]*wb.w;
  }
  #pragma unroll
  for(int off = 1; off < 32; off <<= 1){
    a[0] += __shfl_xor(a[0], off); a[1] += __shfl_xor(a[1], off);
    a[2] += __shfl_xor(a[2], off); a[3] += __shfl_xor(a[3], off);
    b[0] += __shfl_xor(b[0], off); b[1] += __shfl_xor(b[1], off);
    b[2] += __shfl_xor(b[2], off); b[3] += __shfl_xor(b[3], off);
  }
  if(valid && q == 0){
    float4 o; o.x=a[0]; o.y=a[1]; o.z=a[2]; o.w=a[3];
    *(float4*)(oa + (size_t)row*4) = o;
    float4 p; p.x=b[0]; p.y=b[1]; p.z=b[2]; p.w=b[3];
    *(float4*)(ob + (size_t)row*4) = p;
  }
}

// ================= batched bf16 MFMA GEMM (per-segment M/K/lda) =================
struct GSeg { const ushort* A; const ushort* BT; const float* bias; void* C; int ldc; int M; int K; int lda; };

template<int BN, typename OutT, bool BIAS>
__global__ __launch_bounds__(256) void gemm_mfma_b(GSeg s0, GSeg s1, GSeg s2, int N){
  constexpr int BM = 128, BK = 64;
  constexpr int NI = BN/32;
  constexpr int AIT = BM*BK/(256*8);
  constexpr int BIT = BN*BK/(256*8);
  __shared__ ushort lds[BM*BK + BN*BK];
  ushort* ldsA = lds;
  ushort* ldsB = lds + BM*BK;
  GSeg S = blockIdx.z == 0 ? s0 : (blockIdx.z == 1 ? s1 : s2);
  const int rowbase = blockIdx.x*BM;
  if(rowbase >= S.M) return;
  const int tid = threadIdx.x, wid = tid >> 6, lane = tid & 63;
  const int wr = wid >> 1, wc = wid & 1;
  const int colbase = blockIdx.y*BN;

  f32x4 acc[4][NI];
  #pragma unroll
  for(int mi = 0; mi < 4; mi++)
    #pragma unroll
    for(int ni = 0; ni < NI; ni++) acc[mi][ni] = (f32x4)0.f;

  for(int k0 = 0; k0 < S.K; k0 += BK){
    #pragma unroll
    for(int it = 0; it < AIT; it++){
      int idx = it*256 + wid*64 + lane;
      int r = idx >> 3, sl = idx & 7;
      int kb = sl ^ (r & 7);
      int grow = rowbase + r; if(grow >= S.M) grow = S.M-1;
      const ushort* src = S.A + (size_t)grow*S.lda + k0 + kb*8;
      __builtin_amdgcn_global_load_lds(AS1(src), AS3(ldsA + (size_t)(it*256 + wid*64)*8), 16, 0, 0);
    }
    #pragma unroll
    for(int it = 0; it < BIT; it++){
      int idx = it*256 + wid*64 + lane;
      int r = idx >> 3, sl = idx & 7;
      int kb = sl ^ (r & 7);
      const ushort* src = S.BT + (size_t)(colbase + r)*S.K + k0 + kb*8;
      __builtin_amdgcn_global_load_lds(AS1(src), AS3(ldsB + (size_t)(it*256 + wid*64)*8), 16, 0, 0);
    }
    __syncthreads();
    #pragma unroll
    for(int kk = 0; kk < 2; kk++){
      bh8 af[4], bf[NI];
      #pragma unroll
      for(int mi = 0; mi < 4; mi++){
        int arow = wr*64 + mi*16 + (lane & 15);
        int kb = kk*4 + (lane >> 4);
        af[mi] = *(const bh8*)(ldsA + arow*BK + ((kb ^ (arow & 7)) << 3));
      }
      #pragma unroll
      for(int ni = 0; ni < NI; ni++){
        int brow = wc*(BN/2) + ni*16 + (lane & 15);
        int kb = kk*4 + (lane >> 4);
        bf[ni] = *(const bh8*)(ldsB + brow*BK + ((kb ^ (brow & 7)) << 3));
      }
      #pragma unroll
      for(int mi = 0; mi < 4; mi++)
        #pragma unroll
        for(int ni = 0; ni < NI; ni++)
          acc[mi][ni] = __builtin_amdgcn_mfma_f32_16x16x32_bf16(af[mi], bf[ni], acc[mi][ni], 0, 0, 0);
    }
    __syncthreads();
  }
  OutT* C = (OutT*)S.C;
  #pragma unroll
  for(int mi = 0; mi < 4; mi++){
    #pragma unroll
    for(int ni = 0; ni < NI; ni++){
      int col = colbase + wc*(BN/2) + ni*16 + (lane & 15);
      if(col >= N) continue;
      float bv = BIAS ? S.bias[col] : 0.f;
      #pragma unroll
      for(int j = 0; j < 4; j++){
        int row = rowbase + wr*64 + mi*16 + (lane >> 4)*4 + j;
        if(row >= S.M) continue;
        float v = acc[mi][ni][j] + bv;
        if constexpr (sizeof(OutT) == 4) C[(size_t)row*S.ldc + col] = v;
        else                             C[(size_t)row*S.ldc + col] = (OutT)f2b(v);
      }
    }
  }
}

// ================= fused bipartite tail =================
__global__ __launch_bounds__(256) void bip_tail_k(
    const ushort* __restrict__ agg, const ushort* __restrict__ WTg3,
    const ushort* __restrict__ WpnT,
    const float* bias0, const float* bias1, const float* bias2,
    ushort* __restrict__ hcat, int M){
  __shared__ ushort ldsA[128*64];
  __shared__ ushort ldsB[128*64];
  __shared__ ushort ldsP[128*128];
  __shared__ ushort ldsW[64*128];
  const int seg = blockIdx.z;
  const ushort* A  = agg + (size_t)seg*M*256;
  const ushort* Wg = WTg3 + (size_t)seg*32768;
  const float* bias = seg==0 ? bias0 : (seg==1 ? bias1 : bias2);
  ushort* outp = hcat + 64 + seg*64;
  const int tid = threadIdx.x, lane = tid & 63, wid = tid >> 6;
  const int wr = wid >> 1, wc = wid & 1;
  const int rowbase = blockIdx.x*128;

  f32x4 acc_out[4][2];
  #pragma unroll
  for(int mi = 0; mi < 4; mi++){ acc_out[mi][0] = (f32x4)0.f; acc_out[mi][1] = (f32x4)0.f; }

  for(int hh = 0; hh < 4; hh++){
    #pragma unroll
    for(int it = 0; it < 4; it++){
      int idx = it*256 + tid;
      int r = idx >> 3, sl = idx & 7;
      int kb = sl ^ (r & 7);
      int grow = rowbase + r; if(grow >= M) grow = M-1;
      __builtin_amdgcn_global_load_lds(AS1(A + (size_t)grow*256 + hh*64 + kb*8),
                                       AS3(ldsA + (size_t)idx*8), 16, 0, 0);
    }
    #pragma unroll
    for(int it = 0; it < 4; it++){
      int idx = it*256 + tid;
      int r = idx >> 3, sl = idx & 7;
      int kb = sl ^ (r & 7);
      __builtin_amdgcn_global_load_lds(AS1(Wg + hh*8192 + r*64 + kb*8),
                                       AS3(ldsB + (size_t)idx*8), 16, 0, 0);
    }
    #pragma unroll
    for(int it = 0; it < 4; it++){
      int idx = it*256 + tid;
      int r = idx >> 4, sl = idx & 15;
      int kb = sl ^ (r & 7);
      __builtin_amdgcn_global_load_lds(AS1(WpnT + (size_t)r*512 + hh*128 + kb*8),
                                       AS3(ldsW + (size_t)idx*8), 16, 0, 0);
    }
    __syncthreads();
    f32x4 accp[4][4];
    #pragma unroll
    for(int mi = 0; mi < 4; mi++)
      #pragma unroll
      for(int ni = 0; ni < 4; ni++) accp[mi][ni] = (f32x4)0.f;
    #pragma unroll
    for(int kk = 0; kk < 2; kk++){
      bh8 af[4], bf[4];
      int kb = kk*4 + (lane >> 4);
      #pragma unroll
      for(int mi = 0; mi < 4; mi++){
        int arow = wr*64 + mi*16 + (lane & 15);
        af[mi] = *(const bh8*)(ldsA + arow*64 + ((kb ^ (arow & 7)) << 3));
      }
      #pragma unroll
      for(int ni = 0; ni < 4; ni++){
        int brow = wc*64 + ni*16 + (lane & 15);
        bf[ni] = *(const bh8*)(ldsB + brow*64 + ((kb ^ (brow & 7)) << 3));
      }
      #pragma unroll
      for(int mi = 0; mi < 4; mi++)
        #pragma unroll
        for(int ni = 0; ni < 4; ni++)
          accp[mi][ni] = __builtin_amdgcn_mfma_f32_16x16x32_bf16(af[mi], bf[ni], accp[mi][ni], 0, 0, 0);
    }
    #pragma unroll
    for(int mi = 0; mi < 4; mi++)
      #pragma unroll
      for(int ni = 0; ni < 4; ni++){
        int col = wc*64 + ni*16 + (lane & 15);
        float bv = bias[hh*128 + col];
        int rbase = wr*64 + mi*16 + (lane >> 4)*4;
        #pragma unroll
        for(int j = 0; j < 4; j++){
          float v = accp[mi][ni][j] + bv;
          v = v > 0.f ? v : (__expf(v) - 1.f);
          int row = rbase + j;
          ldsP[row*128 + ((((col >> 3) ^ (row & 7))) << 3) + (col & 7)] = f2b(v);
        }
      }
    __syncthreads();
    #pragma unroll
    for(int kk = 0; kk < 4; kk++){
      bh8 af[4], bf[2];
      int kb = kk*4 + (lane >> 4);
      #pragma unroll
      for(int mi = 0; mi < 4; mi++){
        int arow = wr*64 + mi*16 + (lane & 15);
        af[mi] = *(const bh8*)(ldsP + arow*128 + ((kb ^ (arow & 7)) << 3));
      }
      #pragma unroll
      for(int ni = 0; ni < 2; ni++){
        int brow = wc*32 + ni*16 + (lane & 15);
        bf[ni] = *(const bh8*)(ldsW + brow*128 + ((kb ^ (brow & 7)) << 3));
      }
      #pragma unroll
      for(int mi = 0; mi < 4; mi++)
        #pragma unroll
        for(int ni = 0; ni < 2; ni++)
          acc_out[mi][ni] = __builtin_amdgcn_mfma_f32_16x16x32_bf16(af[mi], bf[ni], acc_out[mi][ni], 0, 0, 0);
    }
    __syncthreads();
  }
  #pragma unroll
  for(int mi = 0; mi < 4; mi++)
    #pragma unroll
    for(int ni = 0; ni < 2; ni++){
      int col = wc*32 + ni*16 + (lane & 15);
      #pragma unroll
      for(int j = 0; j < 4; j++){
        int row = rowbase + wr*64 + mi*16 + (lane >> 4)*4 + j;
        if(row >= M) continue;
        outp[(size_t)row*256 + col] = f2b(acc_out[mi][ni][j]);
      }
    }
}

// ================= metapath GAT aggregate (8 loads in flight/lane) =================
__global__ __launch_bounds__(256) void gat_agg_meta(
    const ushort* __restrict__ hs, const float* __restrict__ el,
    const float* __restrict__ er, const int* __restrict__ ofs,
    const int* __restrict__ colv, const float* __restrict__ bias,
    ushort* __restrict__ outv, int Nd){
  const int wslot = threadIdx.x >> 6;
  const int node = blockIdx.x*4 + wslot;
  const int lane = threadIdx.x & 63;
  __shared__ int   lds_s[4][64];
  __shared__ float lds_w[4][256];
  if(node >= Nd) return;
  const int e0 = ofs[node], e1 = ofs[node+1];
  const int g = lane >> 4, q = lane & 15;
  const int hh = q >> 2;
  const float4 erv = *(const float4*)(er + (size_t)node*4);
  float m0=-INFINITY, m1=-INFINITY, m2=-INFINITY, m3=-INFINITY;
  float sw0=0.f, sw1=0.f, sw2=0.f, sw3=0.f;
  float acc[8];
  #pragma unroll
  for(int r = 0; r < 8; r++) acc[r] = 0.f;

  for(int base = e0; base < e1; base += 64){
    int nch = e1 - base; if(nch > 64) nch = 64;
    int s_l = colv[base + (lane < nch ? lane : nch-1)];
    float4 ev = *(const float4*)(el + (size_t)s_l*4);
    float x0 = ev.x + erv.x; x0 = x0 > 0.f ? x0 : 0.2f*x0;
    float x1 = ev.y + erv.y; x1 = x1 > 0.f ? x1 : 0.2f*x1;
    float x2 = ev.z + erv.z; x2 = x2 > 0.f ? x2 : 0.2f*x2;
    float x3 = ev.w + erv.w; x3 = x3 > 0.f ? x3 : 0.2f*x3;
    if(lane >= nch){ x0 = x1 = x2 = x3 = -INFINITY; }
    float c0=x0, c1=x1, c2=x2, c3=x3;
    #pragma unroll
    for(int off = 32; off; off >>= 1){
      c0 = fmaxf(c0, __shfl_xor(c0, off));
      c1 = fmaxf(c1, __shfl_xor(c1, off));
      c2 = fmaxf(c2, __shfl_xor(c2, off));
      c3 = fmaxf(c3, __shfl_xor(c3, off));
    }
    float n0 = fmaxf(m0,c0), n1 = fmaxf(m1,c1), n2 = fmaxf(m2,c2), n3 = fmaxf(m3,c3);
    float r0 = __expf(m0-n0), r1 = __expf(m1-n1), r2 = __expf(m2-n2), r3 = __expf(m3-n3);
    float w0 = __expf(x0-n0), w1 = __expf(x1-n1), w2 = __expf(x2-n2), w3 = __expf(x3-n3);
    sw0 = sw0*r0 + w0; sw1 = sw1*r1 + w1; sw2 = sw2*r2 + w2; sw3 = sw3*r3 + w3;
    float rh = hh==0 ? r0 : (hh==1 ? r1 : (hh==2 ? r2 : r3));
    #pragma unroll
    for(int r = 0; r < 8; r++) acc[r] *= rh;
    m0=n0; m1=n1; m2=n2; m3=n3;
    lds_s[wslot][lane] = s_l;
    lds_w[wslot][lane*4+0] = w0; lds_w[wslot][lane*4+1] = w1;
    lds_w[wslot][lane*4+2] = w2; lds_w[wslot][lane*4+3] = w3;
    int npad = (nch + 31) & ~31;
    for(int j = 0; j < npad; j += 32){
      int sv[8]; float wv[8];
      #pragma unroll
      for(int u = 0; u < 8; u++){
        sv[u] = lds_s[wslot][j + u*4 + g];
        wv[u] = lds_w[wslot][(j + u*4 + g)*4 + hh];
      }
      bh8 vv[8];
      #pragma unroll
      for(int u = 0; u < 8; u++)
        vv[u] = *(const bh8*)(hs + (size_t)sv[u]*128 + q*8);
      #pragma unroll
      for(int u = 0; u < 8; u++)
        #pragma unroll
        for(int r = 0; r < 8; r++) acc[r] += wv[u] * b2f((ushort)vv[u][r]);
    }
  }
  #pragma unroll
  for(int off = 32; off; off >>= 1){
    sw0 += __shfl_xor(sw0, off); sw1 += __shfl_xor(sw1, off);
    sw2 += __shfl_xor(sw2, off); sw3 += __shfl_xor(sw3, off);
  }
  #pragma unroll
  for(int r = 0; r < 8; r++){
    acc[r] += __shfl_xor(acc[r], 16);
    acc[r] += __shfl_xor(acc[r], 32);
  }
  float swh = hh==0 ? sw0 : (hh==1 ? sw1 : (hh==2 ? sw2 : sw3));
  float den = (swh == 0.f) ? 1.f : swh;
  if(g == 0){
    bh8 ov;
    #pragma unroll
    for(int r = 0; r < 8; r++){
      float v = acc[r]/den + bias[q*8 + r];
      v = v > 0.f ? v : (__expf(v) - 1.f);
      ov[r] = (short)f2b(v);
    }
    *(bh8*)(outv + (size_t)node*128 + q*8) = ov;
  }
}

// ================= bipartite GAT aggregate, low-degree version =================
struct ASeg { const int* ofs; const int* colv; const float* el; const float* er; ushort* agg; };
__global__ __launch_bounds__(256) void gat_agg_proj3(ASeg s0, ASeg s1, ASeg s2,
    const ushort* __restrict__ proj, int2 pbase, int Nd, int nb){
  const int seg = blockIdx.x / nb;
  const ASeg S = seg == 0 ? s0 : (seg == 1 ? s1 : s2);
  const ushort* pj = proj + (size_t)(seg == 0 ? 0 : (seg == 1 ? pbase.x : pbase.y))*64;
  const int node = (blockIdx.x - seg*nb)*16 + (threadIdx.x >> 4);
  const int q = threadIdx.x & 15;
  if(node >= Nd) return;
  const int e0 = S.ofs[node], e1 = S.ofs[node+1];
  const int deg = e1 - e0;
  const float4 erv = *(const float4*)(S.er + (size_t)node*4);
  float sw0=0.f, sw1=0.f, sw2=0.f, sw3=0.f;
  float acc[4][4];
  #pragma unroll
  for(int d = 0; d < 4; d++)
    #pragma unroll
    for(int h = 0; h < 4; h++) acc[d][h] = 0.f;

  if(deg <= 8){
    const int ebase = (deg > 0) ? e0 : 0;
    int sv[8];
    #pragma unroll
    for(int u = 0; u < 8; u++) sv[u] = S.colv[ebase + (u < deg ? u : 0)];
    float xa[8], xb[8], xc[8], xd[8];
    #pragma unroll
    for(int u = 0; u < 8; u++){
      float4 ev = *(const float4*)(S.el + (size_t)sv[u]*4);
      float t0 = ev.x + erv.x; xa[u] = t0 > 0.f ? t0 : 0.2f*t0;
      float t1 = ev.y + erv.y; xb[u] = t1 > 0.f ? t1 : 0.2f*t1;
      float t2 = ev.z + erv.z; xc[u] = t2 > 0.f ? t2 : 0.2f*t2;
      float t3 = ev.w + erv.w; xd[u] = t3 > 0.f ? t3 : 0.2f*t3;
    }
    float m0=-INFINITY, m1=-INFINITY, m2=-INFINITY, m3=-INFINITY;
    #pragma unroll
    for(int u = 0; u < 8; u++) if(u < deg){
      m0 = fmaxf(m0, xa[u]); m1 = fmaxf(m1, xb[u]);
      m2 = fmaxf(m2, xc[u]); m3 = fmaxf(m3, xd[u]);
    }
    ushort4 pv[8];
    #pragma unroll
    for(int u = 0; u < 8; u++) pv[u] = *(const ushort4*)(pj + (size_t)sv[u]*64 + q*4);
    #pragma unroll
    for(int u = 0; u < 8; u++) if(u < deg){
      float w0 = __expf(xa[u]-m0), w1 = __expf(xb[u]-m1);
      float w2 = __expf(xc[u]-m2), w3 = __expf(xd[u]-m3);
      sw0 += w0; sw1 += w1; sw2 += w2; sw3 += w3;
      float f0 = b2f(pv[u].x), f1 = b2f(pv[u].y), f2 = b2f(pv[u].z), f3 = b2f(pv[u].w);
      acc[0][0] += w0*f0; acc[0][1] += w1*f0; acc[0][2] += w2*f0; acc[0][3] += w3*f0;
      acc[1][0] += w0*f1; acc[1][1] += w1*f1; acc[1][2] += w2*f1; acc[1][3] += w3*f1;
      acc[2][0] += w0*f2; acc[2][1] += w1*f2; acc[2][2] += w2*f2; acc[2][3] += w3*f2;
      acc[3][0] += w0*f3; acc[3][1] += w1*f3; acc[3][2] += w2*f3; acc[3][3] += w3*f3;
    }
  } else {
    float m0=-INFINITY, m1=-INFINITY, m2=-INFINITY, m3=-INFINITY;
    for(int e = e0; e < e1; e++){
      int s = S.colv[e];
      float4 ev = *(const float4*)(S.el + (size_t)s*4);
      float x0 = ev.x + erv.x; x0 = x0 > 0.f ? x0 : 0.2f*x0;
      float x1 = ev.y + erv.y; x1 = x1 > 0.f ? x1 : 0.2f*x1;
      float x2 = ev.z + erv.z; x2 = x2 > 0.f ? x2 : 0.2f*x2;
      float x3 = ev.w + erv.w; x3 = x3 > 0.f ? x3 : 0.2f*x3;
      m0 = fmaxf(m0,x0); m1 = fmaxf(m1,x1); m2 = fmaxf(m2,x2); m3 = fmaxf(m3,x3);
    }
    for(int e = e0; e < e1; e++){
      int s = S.colv[e];
      float4 ev = *(const float4*)(S.el + (size_t)s*4);
      float x0 = ev.x + erv.x; x0 = x0 > 0.f ? x0 : 0.2f*x0;
      float x1 = ev.y + erv.y; x1 = x1 > 0.f ? x1 : 0.2f*x1;
      float x2 = ev.z + erv.z; x2 = x2 > 0.f ? x2 : 0.2f*x2;
      float x3 = ev.w + erv.w; x3 = x3 > 0.f ? x3 : 0.2f*x3;
      float w0 = __expf(x0-m0), w1 = __expf(x1-m1);
      float w2 = __expf(x2-m2), w3 = __expf(x3-m3);
      sw0 += w0; sw1 += w1; sw2 += w2; sw3 += w3;
      ushort4 p = *(const ushort4*)(pj + (size_t)s*64 + q*4);
      float f0 = b2f(p.x), f1 = b2f(p.y), f2 = b2f(p.z), f3 = b2f(p.w);
      acc[0][0] += w0*f0; acc[0][1] += w1*f0; acc[0][2] += w2*f0; acc[0][3] += w3*f0;
      acc[1][0] += w0*f1; acc[1][1] += w1*f1; acc[1][2] += w2*f1; acc[1][3] += w3*f1;
      acc[2][0] += w0*f2; acc[2][1] += w1*f2; acc[2][2] += w2*f2; acc[2][3] += w3*f2;
      acc[3][0] += w0*f3; acc[3][1] += w1*f3; acc[3][2] += w2*f3; acc[3][3] += w3*f3;
    }
  }
  float dn[4];
  dn[0] = (sw0 == 0.f) ? 1.f : sw0;
  dn[1] = (sw1 == 0.f) ? 1.f : sw1;
  dn[2] = (sw2 == 0.f) ? 1.f : sw2;
  dn[3] = (sw3 == 0.f) ? 1.f : sw3;
  ushort* orow = S.agg + (size_t)node*256;
  #pragma unroll
  for(int h = 0; h < 4; h++){
    ushort4 o;
    o.x = f2b(acc[0][h]/dn[h]); o.y = f2b(acc[1][h]/dn[h]);
    o.z = f2b(acc[2][h]/dn[h]); o.w = f2b(acc[3][h]/dn[h]);
    *(ushort4*)(orow + h*64 + q*4) = o;
  }
}

// ================= host orchestration =================
extern "C" void kernel_launch(void* const* d_in, const int* in_sizes, int n_in,
                              void* d_out, int out_size, void* d_ws, size_t ws_size,
                              hipStream_t stream){
  const float* hp   = (const float*)d_in[0];
  const float* hq   = (const float*)d_in[1];
  const float* hk   = (const float*)d_in[2];
  const float* ha   = (const float*)d_in[3];
  const int* meta_src = (const int*)d_in[4];
  const int* meta_dst = (const int*)d_in[5];
  const int* q_src = (const int*)d_in[6];
  const int* q_dst = (const int*)d_in[7];
  const int* k_src = (const int*)d_in[8];
  const int* k_dst = (const int*)d_in[9];
  const int* a_src = (const int*)d_in[10];
  const int* a_dst = (const int*)d_in[11];
  const float* W0  = (const float*)d_in[12]; const float* al0 = (const float*)d_in[13];
  const float* ar0 = (const float*)d_in[14]; const float* b0  = (const float*)d_in[15];
  const float* W1  = (const float*)d_in[16]; const float* al1 = (const float*)d_in[17];
  const float* ar1 = (const float*)d_in[18]; const float* b1  = (const float*)d_in[19];
  const float* Wq  = (const float*)d_in[20]; const float* alq = (const float*)d_in[21];
  const float* arq = (const float*)d_in[22]; const float* bq  = (const float*)d_in[23];
  const float* Wkw = (const float*)d_in[24]; const float* alkw= (const float*)d_in[25];
  const float* arkw= (const float*)d_in[26]; const float* bkw = (const float*)d_in[27];
  const float* Watt= (const float*)d_in[28]; const float* alatt=(const float*)d_in[29];
  const float* aratt=(const float*)d_in[30]; const float* batt= (const float*)d_in[31];
  const float* Wpnn_a = (const float*)d_in[32];
  const float* Wpn_a  = (const float*)d_in[33];
  const float* Wpnn   = (const float*)d_in[34];
  const float* Wpn    = (const float*)d_in[35];
  const float* Wpred  = (const float*)d_in[36];
  const float* bpred  = (const float*)d_in[37];
  (void)n_in; (void)out_size; (void)ws_size;

  const int IN = 128, ATT = 64;
  const int NP = in_sizes[0]/IN, NQ = in_sizes[1]/ATT, NK = in_sizes[2]/ATT, NA = in_sizes[3]/ATT;
  const int EM = in_sizes[4], EQ = in_sizes[6], EK = in_sizes[8], EA = in_sizes[10];
  const int range = (NP + 7)/8;
  const int NS = NQ + NK + NA;
  const int JH = 8;
  const int NPL = (NP + 3) & ~3;

  // ----- workspace layout -----
  uint8_t* wp = (uint8_t*)d_ws;
  auto alloc = [&](size_t bytes)->uint8_t*{
    uint8_t* p = wp; wp += (bytes + 255) & ~(size_t)255; return p;
  };
  ushort* hcat_b = (ushort*)alloc((size_t)NP*256*2);
  ushort* hbuf_b = (ushort*)alloc((size_t)NP*128*2);
  ushort* hp_b   = (ushort*)alloc((size_t)NP*128*2);
  ushort* hpd_b  = (ushort*)alloc((size_t)NP*64*2);
  ushort* hs_b   = (ushort*)alloc((size_t)NP*128*2);
  ushort* feat_all = (ushort*)alloc((size_t)NS*64*2);
  ushort* proj_all = (ushort*)alloc((size_t)NS*64*2);
  ushort* agg_all  = (ushort*)alloc((size_t)3*NP*256*2);
  float* el    = (float*)alloc((size_t)NP*4*4);
  float* er    = (float*)alloc((size_t)NP*4*4);
  float* el_all= (float*)alloc((size_t)NS*4*4);
  float* er_all= (float*)alloc((size_t)3*NP*4*4);
  float* wf    = (float*)alloc((size_t)10*512*4);
  int* bcur    = (int*)alloc((size_t)512*4);
  int* part    = (int*)alloc((size_t)4*JH*NPL*4);
  int* ofsm    = (int*)alloc((size_t)(NP+4)*4);
  int* ofsq    = (int*)alloc((size_t)(NP+4)*4);
  int* ofsk    = (int*)alloc((size_t)(NP+4)*4);
  int* ofsa    = (int*)alloc((size_t)(NP+4)*4);
  int* colm    = (int*)alloc((size_t)EM*4);
  int* colq    = (int*)alloc((size_t)EQ*4);
  int* colk    = (int*)alloc((size_t)EK*4);
  int* cola    = (int*)alloc((size_t)EA*4);
  const int capM = EM/4+1024, capQ = EQ/4+1024, capK = EK/4+1024, capA = EA/4+1024;
  uint* ebm = (uint*)alloc((size_t)8*capM*4);
  uint* ebq = (uint*)alloc((size_t)8*capQ*4);
  uint* ebk = (uint*)alloc((size_t)8*capK*4);
  uint* eba = (uint*)alloc((size_t)8*capA*4);
  ushort* W0T    = (ushort*)alloc(128*128*2);
  ushort* W1T    = (ushort*)alloc(128*128*2);
  ushort* WTg3   = (ushort*)alloc((size_t)3*4*128*64*2);
  ushort* WpnT   = (ushort*)alloc((size_t)64*512*2);
  ushort* WpnnT  = (ushort*)alloc(64*128*2);
  ushort* Wpnn_aT= (ushort*)alloc(64*128*2);
  ushort* Wpn_aT = (ushort*)alloc(64*64*2);
  ushort* WpredT = (ushort*)alloc((size_t)1024*256*2);

  // ----- CSR build (5 dispatches, zero global atomics after partition) -----
  fill_zero_i32<<<2, 256, 0, stream>>>(bcur, 512);
  {
    int bm = (EM+PSL-1)/PSL, bq2 = (EQ+PSL-1)/PSL, bk2 = (EK+PSL-1)/PSL, ba2 = (EA+PSL-1)/PSL;
    P4 g0{meta_src, meta_dst, ebm, EM, capM, 0, bm};
    P4 g1{q_src, q_dst, ebq, EQ, capQ, bm, bm+bq2};
    P4 g2{k_src, k_dst, ebk, EK, capK, bm+bq2, bm+bq2+bk2};
    P4 g3{a_src, a_dst, eba, EA, capA, bm+bq2+bk2, bm+bq2+bk2+ba2};
    partition_all_k<<<g3.bend, 256, 0, stream>>>(g0, g1, g2, g3, bcur, range);
  }
  {
    H4 h0{ebm, capM}, h1{ebq, capQ}, h2{ebk, capK}, h3{eba, capA};
    hist_all_k<<<4*8*JH, 256, 0, stream>>>(h0, h1, h2, h3, bcur, part, range, NPL, JH, NP);
    scan4_k<<<4, 1024, 0, stream>>>(part, JH, NPL, ofsm, ofsq, ofsk, ofsa, NP);
    SC4 s0{ebm, capM, ofsm, colm};
    SC4 s1{ebq, capQ, ofsq, colq};
    SC4 s2{ebk, capK, ofsk, colk};
    SC4 s3{eba, capA, ofsa, cola};
    scatter_lds_k<<<4*8*JH, 256, 0, stream>>>(s0, s1, s2, s3, bcur, part, range, NPL, JH, NP);
  }

  // ----- conversions + weight prep (4 dispatches) -----
  {
    int c0 = NP*128/4, c1 = c0 + NQ*64/4, c2 = c1 + NK*64/4, c3 = c2 + NA*64/4;
    cvt_all_k<<<(c3+255)/256, 256, 0, stream>>>(hp, hq, hk, ha,
        hp_b, feat_all, feat_all + (size_t)NQ*64, feat_all + (size_t)(NQ+NK)*64,
        make_int4(c0, c1, c2, c3));
  }
  {
    WTAll a;
    a.d[0] = {W0, W0T, 128, 128};      a.d[1] = {W1, W1T, 128, 128};
    a.d[2] = {Wpn, WpnT, 512, 64};     a.d[3] = {Wpnn, WpnnT, 128, 64};
    a.d[4] = {Wpnn_a, Wpnn_aT, 128, 64}; a.d[5] = {Wpn_a, Wpn_aT, 64, 64};
    a.d[6] = {Wpred, WpredT, 256, 1000};
    int items[7] = {128*128, 128*128, 64*512, 64*128, 64*128, 64*64, 1024*256};
    a.cum[0] = 0;
    for(int t = 0; t < 7; t++) a.cum[t+1] = a.cum[t] + items[t];
    wT_all_k<<<(a.cum[7]+255)/256, 256, 0, stream>>>(a);
  }
  wTg3_k<<<(3*32768+255)/256, 256, 0, stream>>>(Wq, Wkw, Watt, WTg3);
  {
    FAll f;
    f.d[0] = {W0, al0, wf+0*512, 128, 32};  f.d[1] = {W0, ar0, wf+1*512, 128, 32};
    f.d[2] = {W1, al1, wf+2*512, 128, 32};  f.d[3] = {W1, ar1, wf+3*512, 128, 32};
    f.d[4] = {Wq, alq, wf+4*512, 64, 128};  f.d[5] = {Wq, arq, wf+5*512, 64, 128};
    f.d[6] = {Wkw, alkw, wf+6*512, 64, 128};f.d[7] = {Wkw, arkw, wf+7*512, 64, 128};
    f.d[8] = {Watt, alatt, wf+8*512, 64, 128};f.d[9] = {Watt, aratt, wf+9*512, 64, 128};
    fold_all_k<<<10, 256, 0, stream>>>(f);
  }

  auto launch_gemm = [&]<int BN, typename OutT, bool BIAS>(
      GSeg a, GSeg b, GSeg c, int nseg, int maxM, int N){
    int Npad = (N + BN - 1)/BN*BN;
    dim3 g((maxM + 127)/128, Npad/BN, nseg);
    gemm_mfma_b<BN, OutT, BIAS><<<g, 256, 0, stream>>>(a, b, c, N);
  };
  GSeg z{};

  // ----- metapath GAT layer 0 -----
  launch_gemm.template operator()<128, ushort, false>(
      GSeg{hp_b, W0T, nullptr, hs_b, 128, NP, 128, 128}, z, z, 1, NP, 128);
  gemv8v<ushort><<<(NP/2+3)/4, 256, 0, stream>>>(hp_b, wf+0*512, wf+1*512, el, er, NP, 128);
  gat_agg_meta<<<(NP+3)/4, 256, 0, stream>>>(hs_b, el, er, ofsm, colm, b0, hbuf_b, NP);

  // ----- metapath GAT layer 1 -----
  launch_gemm.template operator()<128, ushort, false>(
      GSeg{hbuf_b, W1T, nullptr, hs_b, 128, NP, 128, 128}, z, z, 1, NP, 128);
  gemv8v<ushort><<<(NP/2+3)/4, 256, 0, stream>>>(hbuf_b, wf+2*512, wf+3*512, el, er, NP, 128);
  gat_agg_meta<<<(NP+3)/4, 256, 0, stream>>>(hs_b, el, er, ofsm, colm, b1, hbuf_b, NP);

  // ----- batched small GEMMs: proj (NS,K=64) + hcat0 + hpd (NP,K=128) -----
  launch_gemm.template operator()<64, ushort, false>(
      GSeg{feat_all, Wpn_aT, nullptr, proj_all, 64, NS, 64, 64},
      GSeg{hbuf_b, WpnnT, nullptr, hcat_b, 256, NP, 128, 128},
      GSeg{hp_b, Wpnn_aT, nullptr, hpd_b, 64, NP, 128, 128}, 3, NS > NP ? NS : NP, 64);

  // ----- bipartite GATs -----
  gemv4v_seg3<<<(NS/4+3)/4, 256, 0, stream>>>(proj_all, wf+4*512, wf+6*512, wf+8*512,
      el_all, NS, NQ, NQ+NK);
  gemv4v_er3<<<(NP/4+3)/4, 256, 0, stream>>>(hpd_b, wf+5*512, wf+7*512, wf+9*512,
      er_all, er_all + (size_t)NP*4, er_all + (size_t)2*NP*4, NP);
  {
    int nb = (NP+15)/16;
    ASeg a0{ofsq, colq, el_all,                    er_all,                    agg_all};
    ASeg a1{ofsk, colk, el_all + (size_t)NQ*4,     er_all + (size_t)NP*4,     agg_all + (size_t)NP*256};
    ASeg a2{ofsa, cola, el_all + (size_t)(NQ+NK)*4,er_all + (size_t)2*NP*4,   agg_all + (size_t)2*NP*256};
    gat_agg_proj3<<<3*nb, 256, 0, stream>>>(a0, a1, a2, proj_all, make_int2(NQ, NQ+NK), NP, nb);
  }
  {
    dim3 g((NP+127)/128, 1, 3);
    bip_tail_k<<<g, 256, 0, stream>>>(agg_all, WTg3, WpnT, bq, bkw, batt, hcat_b, NP);
  }

  // ----- final: out = hcat @ Wpred + bpred -----
  launch_gemm.template operator()<128, float, true>(
      GSeg{hcat_b, WpredT, bpred, d_out, 1000, NP, 256, 256}, z, z, 1, NP, 1000);
}